// Round 11
// baseline (1747.387 us; speedup 1.0000x reference)
//
#include <hip/hip_runtime.h>
#include <math.h>

#define T_LEN 4096
#define DMODEL 2048
#define NH 16
#define CQKV 6144
#define CQKVZ 8192
#define SCALE 0.08838834764831845f   // 128^-0.5

using bf16x8 = __attribute__((ext_vector_type(8))) short;
using f32x4  = __attribute__((ext_vector_type(4))) float;

__device__ __forceinline__ float siluf(float x) { return x / (1.0f + __expf(-x)); }

__device__ __forceinline__ unsigned short f2bf(float f) {  // RNE
  unsigned int u = __float_as_uint(f);
  u = (u + 0x7FFFu + ((u >> 16) & 1u)) >> 16;
  return (unsigned short)u;
}
__device__ __forceinline__ float bf2f(unsigned short u) {
  return __uint_as_float(((unsigned int)u) << 16);
}
__device__ __forceinline__ ushort4 pack4(float a, float b, float c, float d) {
  ushort4 r; r.x = f2bf(a); r.y = f2bf(b); r.z = f2bf(c); r.w = f2bf(d); return r;
}

// async global->LDS, 16 bytes per lane; LDS dest is wave-uniform base (+ lane*16 implicit)
__device__ __forceinline__ void gl_lds16(const unsigned short* g, unsigned short* l) {
  __builtin_amdgcn_global_load_lds(
      (const __attribute__((address_space(1))) void*)g,
      (__attribute__((address_space(3))) void*)l, 16, 0, 0);
}

// ---------------- RMSNorm over D=2048; MODE: 1 = f32+bf16, 2 = bf16 only ----------------
template<int MODE>
__global__ __launch_bounds__(256) void rmsnorm_kernel(const float* __restrict__ x,
                                                      const float* __restrict__ w,
                                                      float* __restrict__ outf,
                                                      unsigned short* __restrict__ outb) {
  const int t = blockIdx.x;
  const int tid = threadIdx.x;
  const float4* xr = (const float4*)(x + (size_t)t * DMODEL);
  float4 v0 = xr[tid];
  float4 v1 = xr[tid + 256];
  float s = v0.x*v0.x + v0.y*v0.y + v0.z*v0.z + v0.w*v0.w
          + v1.x*v1.x + v1.y*v1.y + v1.z*v1.z + v1.w*v1.w;
#pragma unroll
  for (int off = 32; off > 0; off >>= 1) s += __shfl_down(s, off);
  __shared__ float red[4];
  if ((tid & 63) == 0) red[tid >> 6] = s;
  __syncthreads();
  const float tot = red[0] + red[1] + red[2] + red[3];
  const float r = rsqrtf(tot * (1.0f / DMODEL) + 1e-5f);
  const float4* wr = (const float4*)w;
  const float4 w0 = wr[tid], w1 = wr[tid + 256];
  float4 o0, o1;
  o0.x = v0.x*r*w0.x; o0.y = v0.y*r*w0.y; o0.z = v0.z*r*w0.z; o0.w = v0.w*r*w0.w;
  o1.x = v1.x*r*w1.x; o1.y = v1.y*r*w1.y; o1.z = v1.z*r*w1.z; o1.w = v1.w*r*w1.w;
  if (MODE == 1) {
    float4* orow = (float4*)(outf + (size_t)t * DMODEL);
    orow[tid] = o0;
    orow[tid + 256] = o1;
  }
  ushort4* brow = (ushort4*)(outb + (size_t)t * DMODEL);
  brow[tid] = pack4(o0.x, o0.y, o0.z, o0.w);
  brow[tid + 256] = pack4(o1.x, o1.y, o1.z, o1.w);
}

// ---------------- fp32 -> bf16 bulk convert ----------------
__global__ __launch_bounds__(256) void f2b_kernel(const float* __restrict__ in,
                                                  unsigned short* __restrict__ out) {
  const size_t i = (size_t)blockIdx.x * 256 + threadIdx.x;
  const float4 a = ((const float4*)in)[2 * i];
  const float4 b = ((const float4*)in)[2 * i + 1];
  ((ushort4*)out)[2 * i] = pack4(a.x, a.y, a.z, a.w);
  ((ushort4*)out)[2 * i + 1] = pack4(b.x, b.y, b.z, b.w);
}

// ---------------- pipelined bf16 MFMA GEMM: C[M][N] = A[M][K] * B[N][K]^T -------------------
// BM x BN block (8 waves, 2M x 4N, 64x64 per-wave tile), BK=32, 2 LDS buffers, 2 blocks/CU.
// EPI: 0 = bf16 store, 1 = fp32 accumulate, 2 = silu(gate)*acc -> bf16 in place
template<int EPI, int BM, int BN>
__global__ __launch_bounds__(512, 4) void gemm256_kernel(const unsigned short* __restrict__ A,
                                                         const unsigned short* __restrict__ B,
                                                         float* __restrict__ Cf,
                                                         unsigned short* __restrict__ Cb,
                                                         int M, int N, int K) {
  constexpr int MI = 4;            // wave rows = 64
  constexpr int NI = BN / 64;      // wave cols = BN/4
  constexpr int AW = BM / 128;
  constexpr int BW = BN / 128;
  __shared__ __align__(16) unsigned short lds[2][(BM + BN) * 32];
  const int nbm = M / BM, nbn = N / BN, nwg = nbm * nbn;
  const int nt = K >> 5;
  int bmi, bni;
  {
    const int bid = blockIdx.x;
    const int cpx = nwg >> 3;
    int sc = 1;
    while (sc * sc < cpx) sc <<= 1;
    if (sc * sc > cpx) sc >>= 1;
    const int scn = (sc > 0) ? (cpx / sc) : 0;
    if ((nwg & 7) == 0 && sc > 0 && sc * scn == cpx && (nbm % sc) == 0 && (nbn % scn) == 0) {
      const int chunk = bid & 7, widx = bid >> 3;
      const int regc = nbn / scn;
      bmi = (chunk / regc) * sc + widx / scn;
      bni = (chunk % regc) * scn + widx % scn;
    } else {
      bmi = bid / nbn; bni = bid % nbn;
    }
  }
  const int bm = bmi * BM, bn = bni * BN;
  const int tid = threadIdx.x;
  const int wv = tid >> 6, ln = tid & 63;
  const int fr = ln & 15, qq = ln >> 4;
  const int wm = wv >> 2, wn = wv & 3;
  const int ra0 = wm * 64, rb0 = wn * (BN / 4);
  const int lrow = ln >> 2;
  const int lslot = ln & 3;

  f32x4 acc[MI][NI];
  const f32x4 zero = {0.f, 0.f, 0.f, 0.f};
#pragma unroll
  for (int mi = 0; mi < MI; mi++)
#pragma unroll
    for (int ni = 0; ni < NI; ni++) acc[mi][ni] = zero;

  auto stage = [&](int buf, int t) {
    const int k0 = t << 5;
#pragma unroll
    for (int q = 0; q < AW; q++) {
      const int lr = q * 128 + wv * 16 + lrow;
      const int sl = lslot ^ ((lr >> 1) & 3);
      gl_lds16(A + (size_t)(bm + lr) * K + k0 + sl * 8,
               &lds[buf][(q * 128 + wv * 16) * 32]);
    }
#pragma unroll
    for (int q = 0; q < BW; q++) {
      const int lr = q * 128 + wv * 16 + lrow;
      const int sl = lslot ^ ((lr >> 1) & 3);
      gl_lds16(B + (size_t)(bn + lr) * K + k0 + sl * 8,
               &lds[buf][BM * 32 + (q * 128 + wv * 16) * 32]);
    }
  };

  stage(0, 0);
  asm volatile("s_waitcnt vmcnt(0)" ::: "memory");
  __builtin_amdgcn_s_barrier();
  asm volatile("" ::: "memory");

  for (int t = 0; t < nt; t++) {
    if (t + 1 < nt) stage((t + 1) & 1, t + 1);
    const unsigned short* lA = &lds[t & 1][0];
    const unsigned short* lB = &lds[t & 1][BM * 32];
    bf16x8 bfr[NI];
#pragma unroll
    for (int ni = 0; ni < NI; ni++) {
      const int r = rb0 + ni * 16 + fr;
      bfr[ni] = *(const bf16x8*)&lB[r * 32 + ((qq ^ ((r >> 1) & 3)) << 3)];
    }
    bf16x8 afr[MI];
#pragma unroll
    for (int mi = 0; mi < MI; mi++) {
      const int r = ra0 + mi * 16 + fr;
      afr[mi] = *(const bf16x8*)&lA[r * 32 + ((qq ^ ((r >> 1) & 3)) << 3)];
    }
    __builtin_amdgcn_s_setprio(1);
#pragma unroll
    for (int mi = 0; mi < MI; mi++)
#pragma unroll
      for (int ni = 0; ni < NI; ni++)
        acc[mi][ni] = __builtin_amdgcn_mfma_f32_16x16x32_bf16(afr[mi], bfr[ni], acc[mi][ni], 0, 0, 0);
    __builtin_amdgcn_s_setprio(0);
    if (t + 1 < nt) {
      asm volatile("s_waitcnt lgkmcnt(0)" ::: "memory");
      asm volatile("s_waitcnt vmcnt(0)" ::: "memory");
      __builtin_amdgcn_s_barrier();
      asm volatile("" ::: "memory");
    }
  }

  const int cm4 = qq * 4;
#pragma unroll
  for (int mi = 0; mi < MI; mi++) {
#pragma unroll
    for (int ni = 0; ni < NI; ni++) {
#pragma unroll
      for (int r = 0; r < 4; r++) {
        const int grow = bm + ra0 + mi * 16 + cm4 + r;
        const int gcol = bn + rb0 + ni * 16 + fr;
        const size_t off = (size_t)grow * N + gcol;
        const float v = acc[mi][ni][r];
        if (EPI == 0) {
          Cb[off] = f2bf(v);
        } else if (EPI == 1) {
          Cf[off] += v;
        } else {
          Cb[off] = f2bf(siluf(bf2f(Cb[off])) * v);
        }
      }
    }
  }
}

// ---------------- ba = h @ ba_w^T ----------------
__global__ __launch_bounds__(256) void ba_gemm_kernel(const float* __restrict__ h_in,
                                                      const float* __restrict__ ba_w,
                                                      float* __restrict__ ba_out) {
  __shared__ __align__(16) float hl[2048];
  __shared__ float red[32][9];
  const int t = blockIdx.x;
  const int tid = threadIdx.x;
  const float4* hr = (const float4*)(h_in + (size_t)t * DMODEL);
  ((float4*)hl)[tid] = hr[tid];
  ((float4*)hl)[tid + 256] = hr[tid + 256];
  __syncthreads();
  const int c = tid & 31;
  const int p = tid >> 5;
  const float* wrow = ba_w + (size_t)c * DMODEL + p * 256;
  const float* hrow = hl + p * 256;
  float s = 0.f;
#pragma unroll 8
  for (int k = 0; k < 256; k++) s += hrow[k] * wrow[k];
  red[c][p] = s;
  __syncthreads();
  if (tid < 32) {
    float tot = 0.f;
#pragma unroll
    for (int q = 0; q < 8; q++) tot += red[tid][q];
    ba_out[(size_t)t * 32 + tid] = tot;
  }
}

// ---------------- extract z columns from bf16 qkvz ----------------
__global__ __launch_bounds__(256) void zcopy_kernel(const unsigned short* __restrict__ qkvz,
                                                    unsigned short* __restrict__ z) {
  const int idx = blockIdx.x * 256 + threadIdx.x;
  const int t = idx >> 8;
  const int c8 = (idx & 255) * 8;
  *(uint4*)(z + (size_t)t * 2048 + c8) =
      *(const uint4*)(qkvz + (size_t)t * CQKVZ + CQKV + c8);
}

// ---------------- causal depthwise conv (K=4) + SiLU; bf16 in, fp32 out ----------------
__global__ __launch_bounds__(256) void conv_silu_kernel(const unsigned short* __restrict__ qkvz,
                                                        const float* __restrict__ conv_w,
                                                        const float* __restrict__ mask,
                                                        float* __restrict__ mixed) {
  const int idx = blockIdx.x * 256 + threadIdx.x;
  const int c4 = (idx % 1536) * 4;
  const int t = idx / 1536;
  const float4 w0 = *(const float4*)(conv_w + (size_t)c4 * 4);
  const float4 w1 = *(const float4*)(conv_w + (size_t)c4 * 4 + 4);
  const float4 w2 = *(const float4*)(conv_w + (size_t)c4 * 4 + 8);
  const float4 w3 = *(const float4*)(conv_w + (size_t)c4 * 4 + 12);
  const float wj0[4] = {w0.x, w0.y, w0.z, w0.w};
  const float wj1[4] = {w1.x, w1.y, w1.z, w1.w};
  const float wj2[4] = {w2.x, w2.y, w2.z, w2.w};
  const float wj3[4] = {w3.x, w3.y, w3.z, w3.w};
  float4 acc = make_float4(0.f, 0.f, 0.f, 0.f);
#pragma unroll
  for (int j = 0; j < 4; j++) {
    const int tt = t - 3 + j;
    if (tt < 0) continue;
    const float m = mask[tt];
    const ushort4 xb = *(const ushort4*)(qkvz + (size_t)tt * CQKVZ + c4);
    acc.x += bf2f(xb.x) * m * wj0[j];
    acc.y += bf2f(xb.y) * m * wj1[j];
    acc.z += bf2f(xb.z) * m * wj2[j];
    acc.w += bf2f(xb.w) * m * wj3[j];
  }
  acc.x = siluf(acc.x); acc.y = siluf(acc.y); acc.z = siluf(acc.z); acc.w = siluf(acc.w);
  *(float4*)(mixed + (size_t)t * CQKV + c4) = acc;
}

// ---------------- l2norm over Dk=128 for q,k heads (in place, fp32) ----------------
__global__ __launch_bounds__(256) void l2norm_kernel(float* __restrict__ mixed) {
  const int r = blockIdx.x * 4 + (threadIdx.x >> 6);
  const int lane = threadIdx.x & 63;
  const int t = r >> 5;
  const int hh = r & 31;
  float* p = mixed + (size_t)t * CQKV + hh * 128 + lane * 2;
  float2 v = *(float2*)p;
  float s = v.x * v.x + v.y * v.y;
#pragma unroll
  for (int off = 32; off > 0; off >>= 1) s += __shfl_down(s, off);
  s = __shfl(s, 0);
  const float rn = rsqrtf(s + 1e-6f);
  v.x *= rn; v.y *= rn;
  *(float2*)p = v;
}

// ---------------- beta, g ----------------
__global__ __launch_bounds__(256) void beta_g_kernel(const float* __restrict__ ba,
                                                     const float* __restrict__ A_log,
                                                     const float* __restrict__ dt_bias,
                                                     const float* __restrict__ mask,
                                                     float* __restrict__ beta,
                                                     float* __restrict__ g) {
  const int idx = blockIdx.x * 256 + threadIdx.x;
  const int t = idx >> 4;
  const int h = idx & 15;
  const float b = ba[(size_t)t * 32 + h];
  const float a = ba[(size_t)t * 32 + 16 + h];
  const float m = mask[t];
  beta[idx] = m / (1.0f + expf(-b));
  const float xx = a + dt_bias[h];
  const float sp = (xx > 20.0f) ? xx : log1pf(expf(xx));
  g[idx] = -expf(A_log[h]) * sp * m;
}

// ---------------- per-chunk cumsum of g + decay factors ----------------
__global__ __launch_bounds__(256) void gcs_kernel(const float* __restrict__ g,
                                                  float* __restrict__ gcsbuf,
                                                  float* __restrict__ edkbuf,
                                                  float* __restrict__ egqbuf,
                                                  float* __restrict__ adecbuf) {
  const int idx = blockIdx.x * 256 + threadIdx.x;  // chunk id = h*64 + n
  if (idx >= 1024) return;
  const int h = idx >> 6;
  const int n = idx & 63;
  const int t0 = n * 64;
  float s = 0.f;
  for (int i = 0; i < 64; i++) {
    s += g[(size_t)(t0 + i) * NH + h];
    gcsbuf[(size_t)idx * 64 + i] = s;
  }
  const float glast = s;
  adecbuf[idx] = __expf(glast);
  for (int i = 0; i < 64; i++) {
    const float gi = gcsbuf[(size_t)idx * 64 + i];
    edkbuf[(size_t)idx * 64 + i] = __expf(glast - gi);
    egqbuf[(size_t)idx * 64 + i] = __expf(gi) * SCALE;
  }
}

// ---------------- per-chunk: A=(k_beta k^T)*decay (strict lower), attn=(q k^T)*decay*scale ----------------
__global__ __launch_bounds__(256) void pre_attn_kernel(const float* __restrict__ mixed,
                                                       const float* __restrict__ gcsbuf,
                                                       const float* __restrict__ betabuf,
                                                       float* __restrict__ abuf,
                                                       float* __restrict__ attnbuf) {
  __shared__ __align__(16) float kl[64][132];
  __shared__ float gcs_s[64];
  __shared__ float betal[64];
  const int blk = blockIdx.x;
  const int h = blk >> 6;
  const int n = blk & 63;
  const int t0 = n * 64;
  const int tid = threadIdx.x;
  if (tid < 64) {
    gcs_s[tid] = gcsbuf[(size_t)blk * 64 + tid];
    betal[tid] = betabuf[(size_t)(t0 + tid) * NH + h];
  }
#pragma unroll
  for (int rep = 0; rep < 8; rep++) {
    const int lin = rep * 256 + tid;
    const int i = lin >> 5;
    const int d = (lin & 31) * 4;
    const float4 kv = *(const float4*)(mixed + (size_t)(t0 + i) * CQKV + 2048 + h * 128 + d);
    *(float4*)&kl[i][d] = kv;
  }
  __syncthreads();
  const int cj = tid & 15;
  const int ri = tid >> 4;
  const int i0 = ri * 4, j0 = cj * 4;
  float accA[4][4], accQ[4][4];
#pragma unroll
  for (int a = 0; a < 4; a++)
#pragma unroll
    for (int b = 0; b < 4; b++) { accA[a][b] = 0.f; accQ[a][b] = 0.f; }
  const float* qbase = mixed + (size_t)t0 * CQKV + h * 128;
#pragma unroll 4
  for (int d = 0; d < 128; d++) {
    const float kj0 = kl[j0][d], kj1 = kl[j0 + 1][d], kj2 = kl[j0 + 2][d], kj3 = kl[j0 + 3][d];
#pragma unroll
    for (int a = 0; a < 4; a++) {
      const float ka = kl[i0 + a][d];
      const float qa = qbase[(size_t)(i0 + a) * CQKV + d];
      accA[a][0] += ka * kj0; accA[a][1] += ka * kj1; accA[a][2] += ka * kj2; accA[a][3] += ka * kj3;
      accQ[a][0] += qa * kj0; accQ[a][1] += qa * kj1; accQ[a][2] += qa * kj2; accQ[a][3] += qa * kj3;
    }
  }
#pragma unroll
  for (int a = 0; a < 4; a++) {
    const int i = i0 + a;
    const float gi = gcs_s[i];
    const float bi = betal[i];
    float4 Av, Qv;
    float dec;
    dec = __expf(fminf(gi - gcs_s[j0 + 0], 0.f));
    Av.x = (i > j0 + 0) ? accA[a][0] * bi * dec : 0.f;
    Qv.x = (i >= j0 + 0) ? accQ[a][0] * dec * SCALE : 0.f;
    dec = __expf(fminf(gi - gcs_s[j0 + 1], 0.f));
    Av.y = (i > j0 + 1) ? accA[a][1] * bi * dec : 0.f;
    Qv.y = (i >= j0 + 1) ? accQ[a][1] * dec * SCALE : 0.f;
    dec = __expf(fminf(gi - gcs_s[j0 + 2], 0.f));
    Av.z = (i > j0 + 2) ? accA[a][2] * bi * dec : 0.f;
    Qv.z = (i >= j0 + 2) ? accQ[a][2] * dec * SCALE : 0.f;
    dec = __expf(fminf(gi - gcs_s[j0 + 3], 0.f));
    Av.w = (i > j0 + 3) ? accA[a][3] * bi * dec : 0.f;
    Qv.w = (i >= j0 + 3) ? accQ[a][3] * dec * SCALE : 0.f;
    *(float4*)(abuf + (size_t)blk * 4096 + i * 64 + j0) = Av;
    *(float4*)(attnbuf + (size_t)blk * 4096 + i * 64 + j0) = Qv;
  }
}

// ---------------- per-chunk: T = (I+A)^-1, then T *= beta[col] ----------------
__global__ __launch_bounds__(256) void pre_solve_kernel(const float* __restrict__ abuf,
                                                        const float* __restrict__ betabuf,
                                                        float* __restrict__ tbuf) {
  __shared__ float Al[64][65];
  __shared__ float Tl[64][65];
  const int blk = blockIdx.x;
  const int h = blk >> 6;
  const int n = blk & 63;
  const int t0 = n * 64;
  const int tid = threadIdx.x;
#pragma unroll
  for (int rep = 0; rep < 4; rep++) {
    const int lin = rep * 256 + tid;
    const int i = lin >> 4;
    const int j = (lin & 15) * 4;
    const float4 av = *(const float4*)(abuf + (size_t)blk * 4096 + i * 64 + j);
    Al[i][j] = av.x; Al[i][j + 1] = av.y; Al[i][j + 2] = av.z; Al[i][j + 3] = av.w;
  }
  __syncthreads();
  if (tid < 64) {
    const int j = tid;
    const float bj = betabuf[(size_t)(t0 + j) * NH + h];
    for (int i = 0; i < 64; i++) {
      float s = (i == j) ? 1.0f : 0.0f;
      for (int l = j; l < i; l++) s -= Al[i][l] * Tl[l][j];
      Tl[i][j] = s;
    }
    for (int i = j; i < 64; i++) Tl[i][j] *= bj;
  }
  __syncthreads();
#pragma unroll
  for (int rep = 0; rep < 4; rep++) {
    const int lin = rep * 256 + tid;
    const int i = lin >> 4;
    const int j = (lin & 15) * 4;
    float4 tv;
    tv.x = Tl[i][j]; tv.y = Tl[i][j + 1]; tv.z = Tl[i][j + 2]; tv.w = Tl[i][j + 3];
    *(float4*)(tbuf + (size_t)blk * 4096 + i * 64 + j) = tv;
  }
}

// ---------------- per-chunk: u = Tb @ v (f32, l4-packed [blk][l>>2][c][l&3]) ;
//                  w = Tb @ (k * e^gcs), stored NEGATED, plain layout ----
__global__ __launch_bounds__(256) void pre_uw_kernel(const float* __restrict__ mixed,
                                                     const float* __restrict__ tbuf,
                                                     const float* __restrict__ gcsbuf,
                                                     float* __restrict__ ubuf,
                                                     unsigned short* __restrict__ wbf) {
  __shared__ __align__(16) float Tl[64][68];
  __shared__ __align__(16) float xl[64][132];
  __shared__ float egcs[64];
  const int blk = blockIdx.x;
  const int h = blk >> 6;
  const int n = blk & 63;
  const int t0 = n * 64;
  const int tid = threadIdx.x;
  if (tid < 64) egcs[tid] = __expf(gcsbuf[(size_t)blk * 64 + tid]);
#pragma unroll
  for (int rep = 0; rep < 4; rep++) {
    const int lin = rep * 256 + tid;
    const int i = lin >> 4;
    const int j = (lin & 15) * 4;
    const float4 tv = *(const float4*)(tbuf + (size_t)blk * 4096 + i * 64 + j);
    *(float4*)&Tl[i][j] = tv;
  }
#pragma unroll
  for (int rep = 0; rep < 8; rep++) {
    const int lin = rep * 256 + tid;
    const int i = lin >> 5;
    const int d = (lin & 31) * 4;
    const float4 vv = *(const float4*)(mixed + (size_t)(t0 + i) * CQKV + 4096 + h * 128 + d);
    *(float4*)&xl[i][d] = vv;
  }
  __syncthreads();
  const int cgu = tid & 15;
  const int riu = tid >> 4;
  const int i0 = riu * 4;
  const int d0 = cgu * 8;
  float acc[4][8];
#pragma unroll
  for (int a = 0; a < 4; a++)
#pragma unroll
    for (int b = 0; b < 8; b++) acc[a][b] = 0.f;
#pragma unroll 2
  for (int j = 0; j < 64; j++) {
    const float tv[4] = {Tl[i0][j], Tl[i0 + 1][j], Tl[i0 + 2][j], Tl[i0 + 3][j]};
    const float4 x0 = *(const float4*)&xl[j][d0];
    const float4 x1 = *(const float4*)&xl[j][d0 + 4];
    const float xv[8] = {x0.x, x0.y, x0.z, x0.w, x1.x, x1.y, x1.z, x1.w};
#pragma unroll
    for (int a = 0; a < 4; a++)
#pragma unroll
      for (int b = 0; b < 8; b++) acc[a][b] += tv[a] * xv[b];
  }
  // u store: l4-packed layout addr = blk*8192 + (l>>2)*512 + c*4 + (l&3); here l>>2 = riu.
#pragma unroll
  for (int b = 0; b < 8; b++) {
    *(float4*)(ubuf + (size_t)blk * 8192 + riu * 512 + (size_t)(d0 + b) * 4) =
        make_float4(acc[0][b], acc[1][b], acc[2][b], acc[3][b]);
  }
  __syncthreads();
#pragma unroll
  for (int rep = 0; rep < 8; rep++) {
    const int lin = rep * 256 + tid;
    const int i = lin >> 5;
    const int d = (lin & 31) * 4;
    float4 kv = *(const float4*)(mixed + (size_t)(t0 + i) * CQKV + 2048 + h * 128 + d);
    const float e = egcs[i];
    kv.x *= e; kv.y *= e; kv.z *= e; kv.w *= e;
    *(float4*)&xl[i][d] = kv;
  }
  __syncthreads();
#pragma unroll
  for (int a = 0; a < 4; a++)
#pragma unroll
    for (int b = 0; b < 8; b++) acc[a][b] = 0.f;
#pragma unroll 2
  for (int j = 0; j < 64; j++) {
    const float tv[4] = {Tl[i0][j], Tl[i0 + 1][j], Tl[i0 + 2][j], Tl[i0 + 3][j]};
    const float4 x0 = *(const float4*)&xl[j][d0];
    const float4 x1 = *(const float4*)&xl[j][d0 + 4];
    const float xv[8] = {x0.x, x0.y, x0.z, x0.w, x1.x, x1.y, x1.z, x1.w};
#pragma unroll
    for (int a = 0; a < 4; a++)
#pragma unroll
      for (int b = 0; b < 8; b++) acc[a][b] += tv[a] * xv[b];
  }
  // store -w, plain layout (scan reads to registers; no bank swizzle needed)
#pragma unroll
  for (int a = 0; a < 4; a++) {
    const int l = i0 + a;
    unsigned short* wp = wbf + (size_t)(t0 + l) * 2048 + h * 128 + cgu * 8;
    *(ushort4*)wp = pack4(-acc[a][0], -acc[a][1], -acc[a][2], -acc[a][3]);
    *(ushort4*)(wp + 4) = pack4(-acc[a][4], -acc[a][5], -acc[a][6], -acc[a][7]);
  }
}

// ---------------- per-chunk: kdT[blk][d][l] = bf16(k*edk) plain; qe = bf16(q*egq) ----------------
__global__ __launch_bounds__(256) void ktrans_kernel(const float* __restrict__ mixed,
                                                     const float* __restrict__ edkbuf,
                                                     const float* __restrict__ egqbuf,
                                                     unsigned short* __restrict__ kdT,
                                                     unsigned short* __restrict__ qe) {
  __shared__ __align__(16) float kl[64][132];
  __shared__ float edk_s[64];
  __shared__ float egq_s[64];
  const int blk = blockIdx.x;
  const int h = blk >> 6;
  const int n = blk & 63;
  const int t0 = n * 64;
  const int tid = threadIdx.x;
  if (tid < 64) {
    edk_s[tid] = edkbuf[(size_t)blk * 64 + tid];
    egq_s[tid] = egqbuf[(size_t)blk * 64 + tid];
  }
#pragma unroll
  for (int q = 0; q < 8; q++) {
    const int idx = tid + q * 256;
    const int l = idx >> 5, c4 = (idx & 31) * 4;
    *(float4*)&kl[l][c4] = *(const float4*)(mixed + (size_t)(t0 + l) * CQKV + 2048 + h * 128 + c4);
  }
  __syncthreads();
#pragma unroll
  for (int q = 0; q < 4; q++) {
    const int idx = tid + q * 256;
    const int d = idx >> 3, lsl = idx & 7;
    const int l8 = lsl * 8;
    float v[8];
#pragma unroll
    for (int j = 0; j < 8; j++) v[j] = kl[l8 + j][d] * edk_s[l8 + j];
    unsigned short* p = kdT + (size_t)blk * 8192 + d * 64 + l8;
    *(ushort4*)p = pack4(v[0], v[1], v[2], v[3]);
    *(ushort4*)(p + 4) = pack4(v[4], v[5], v[6], v[7]);
  }
#pragma unroll
  for (int q = 0; q < 8; q++) {
    const int idx = tid + q * 256;
    const int i = idx >> 5, c4 = (idx & 31) * 4;
    const float4 v = *(const float4*)(mixed + (size_t)(t0 + i) * CQKV + h * 128 + c4);
    const float e = egq_s[i];
    *(ushort4*)(qe + (size_t)(t0 + i) * 2048 + h * 128 + c4) =
        pack4(v.x * e, v.y * e, v.z * e, v.w * e);
  }
}

// ---------------- MFMA scan, register-resident operands: 8 waves x 16 c-columns, NO barriers -
// w/kT fragments live in VGPRs (global->reg, L2-resident; identical across waves so LDS
// replication is pointless). Only LDS use: wave-private privA/privB accumulator transposes
// (compiler-ordered via lgkmcnt). Single-buffered frag prefetch: reload chunk n+1's frags
// immediately after their last use in chunk n. Exports d4/l4-packed (coalesced).
// blocks >=16: weight f2b + residual copy (512 threads).
__global__ __launch_bounds__(512, 2) void scan_kernel(const unsigned short* __restrict__ wbf,
                                                      const unsigned short* __restrict__ kdT,
                                                      const float* __restrict__ ubuf,
                                                      const float* __restrict__ adecbuf,
                                                      unsigned short* __restrict__ STb,
                                                      unsigned short* __restrict__ vtb,
                                                      const float* __restrict__ gw,
                                                      const float* __restrict__ uw,
                                                      const float* __restrict__ dw,
                                                      const float* __restrict__ ow,
                                                      const float* __restrict__ xin,
                                                      unsigned short* __restrict__ Wg,
                                                      unsigned short* __restrict__ Wu,
                                                      unsigned short* __restrict__ Wd,
                                                      unsigned short* __restrict__ Wo,
                                                      float* __restrict__ outc) {
  __shared__ __align__(16) unsigned short privAll[8][3072]; // per wave: A 16x128 | B 16x64
  if (blockIdx.x >= 16) {
    // side work (512 thr): Wg 4096 + Wu 4096 + Wd 4096 + Wo 1024 + copy 2048 = 15360 blocks
    const int xb = blockIdx.x - 16;
    const int tid = threadIdx.x;
    if (xb < 13312) {
      const float* src; unsigned short* dst; size_t u;
      if (xb < 4096)       { src = gw; dst = Wg; u = (size_t)xb * 512 + tid; }
      else if (xb < 8192)  { src = uw; dst = Wu; u = (size_t)(xb - 4096) * 512 + tid; }
      else if (xb < 12288) { src = dw; dst = Wd; u = (size_t)(xb - 8192) * 512 + tid; }
      else                 { src = ow; dst = Wo; u = (size_t)(xb - 12288) * 512 + tid; }
      const float4 a = ((const float4*)src)[2 * u];
      const float4 b = ((const float4*)src)[2 * u + 1];
      ((ushort4*)dst)[2 * u] = pack4(a.x, a.y, a.z, a.w);
      ((ushort4*)dst)[2 * u + 1] = pack4(b.x, b.y, b.z, b.w);
    } else {
      const size_t i = (size_t)(xb - 13312) * 512 + tid;
      ((float4*)outc)[2 * i] = ((const float4*)xin)[2 * i];
      ((float4*)outc)[2 * i + 1] = ((const float4*)xin)[2 * i + 1];
    }
    return;
  }
  const int h = blockIdx.x;
  const int tid = threadIdx.x;
  const int ln = tid & 63;
  const int wv = tid >> 6;        // 0..7
  const int fr = ln & 15;
  const int g  = ln >> 4;         // 0..3
  const int c0 = wv * 16;
  const int fsw = fr & 7;
  unsigned short* privA = &privAll[wv][0];     // [16 c][128 d], slot-swizzled
  unsigned short* privB = &privAll[wv][2048];  // [16 c][64 l], slot-swizzled
  const f32x4 zero = {0.f, 0.f, 0.f, 0.f};

  f32x4 acc2[8];                  // S^T state for this wave's 16 columns, d-tile dt
#pragma unroll
  for (int dt = 0; dt < 8; dt++) acc2[dt] = zero;

  // register-resident operand fragments (identical across waves; L2-served)
  bf16x8 wf[4][4];                // [ks][lt]: w row lt*16+fr, d = ks*32 + g*8
  bf16x8 kf[2][8];                // [ks][dt]: kT row dt*16+fr, l = ks*32 + g*8
  float4 ur4[4];
  float ad;
  // prologue: chunk 0 operands
#pragma unroll
  for (int ks = 0; ks < 4; ks++)
#pragma unroll
    for (int lt = 0; lt < 4; lt++)
      wf[ks][lt] = *(const bf16x8*)(wbf + (size_t)(lt * 16 + fr) * 2048 + h * 128 + ks * 32 + g * 8);
#pragma unroll
  for (int ks = 0; ks < 2; ks++)
#pragma unroll
    for (int dt = 0; dt < 8; dt++)
      kf[ks][dt] = *(const bf16x8*)(kdT + (size_t)(h * 64) * 8192 + (dt * 16 + fr) * 64 + ks * 32 + g * 8);
#pragma unroll
  for (int lt = 0; lt < 4; lt++)
    ur4[lt] = *(const float4*)(ubuf + (size_t)(h * 64) * 8192 + (lt * 4 + g) * 512 + (c0 + fr) * 4);
  ad = adecbuf[h * 64];

  for (int n = 0; n < 64; n++) {
    const int blk = h * 64 + n;
    // (1) dump S_n^T -> privA (wave-private) ; export S_n coalesced (d4-packed)
#pragma unroll
    for (int dt = 0; dt < 8; dt++) {
      const int slot = dt * 2 + (g >> 1);
      const ushort4 pv = pack4(acc2[dt][0], acc2[dt][1], acc2[dt][2], acc2[dt][3]);
      *(ushort4*)&privA[fr * 128 + ((slot ^ fsw) << 3) + (g & 1) * 4] = pv;
      *(ushort4*)(STb + (size_t)blk * 16384 + (dt * 4 + g) * 512 + (c0 + fr) * 4) = pv;
    }
    // (2) MFMA1: v_new = u + (-w) @ S  (A = wf regs, B = privA LDS)
    f32x4 acc1[4];
#pragma unroll
    for (int lt = 0; lt < 4; lt++) {
      f32x4 t;
      t[0] = ur4[lt].x; t[1] = ur4[lt].y; t[2] = ur4[lt].z; t[3] = ur4[lt].w;
      acc1[lt] = t;
    }
#pragma unroll
    for (int ks = 0; ks < 4; ks++) {
      const int kb = ks * 4 + g;
      const bf16x8 b = *(const bf16x8*)&privA[fr * 128 + ((kb ^ fsw) << 3)];
#pragma unroll
      for (int lt = 0; lt < 4; lt++)
        acc1[lt] = __builtin_amdgcn_mfma_f32_16x16x32_bf16(wf[ks][lt], b, acc1[lt], 0, 0, 0);
    }
    // (3) wf/ur4 dead: reload for chunk n+1 (latency hidden under rest of this chunk)
    if (n + 1 < 64) {
      const int t1 = (n + 1) * 64;
#pragma unroll
      for (int ks = 0; ks < 4; ks++)
#pragma unroll
        for (int lt = 0; lt < 4; lt++)
          wf[ks][lt] = *(const bf16x8*)(wbf + (size_t)(t1 + lt * 16 + fr) * 2048 + h * 128 + ks * 32 + g * 8);
#pragma unroll
      for (int lt = 0; lt < 4; lt++)
        ur4[lt] = *(const float4*)(ubuf + (size_t)(blk + 1) * 8192 + (lt * 4 + g) * 512 + (c0 + fr) * 4);
    }
    // (4) v_new^T -> privB ; export v_new^T coalesced (l4-packed)
#pragma unroll
    for (int lt = 0; lt < 4; lt++) {
      const int slot = lt * 2 + (g >> 1);
      const ushort4 pv = pack4(acc1[lt][0], acc1[lt][1], acc1[lt][2], acc1[lt][3]);
      *(ushort4*)&privB[fr * 64 + ((slot ^ fsw) << 3) + (g & 1) * 4] = pv;
      *(ushort4*)(vtb + (size_t)blk * 8192 + (lt * 4 + g) * 512 + (c0 + fr) * 4) = pv;
    }
    // (5) MFMA2: S = adec*S + kdec^T @ v_new  (A = kf regs, B = privB LDS)
#pragma unroll
    for (int dt = 0; dt < 8; dt++) {
      acc2[dt][0] *= ad; acc2[dt][1] *= ad; acc2[dt][2] *= ad; acc2[dt][3] *= ad;
    }
#pragma unroll
    for (int ks = 0; ks < 2; ks++) {
      const int kb = ks * 4 + g;
      const bf16x8 b = *(const bf16x8*)&privB[fr * 64 + ((kb ^ fsw) << 3)];
#pragma unroll
      for (int dt = 0; dt < 8; dt++)
        acc2[dt] = __builtin_amdgcn_mfma_f32_16x16x32_bf16(kf[ks][dt], b, acc2[dt], 0, 0, 0);
    }
    // (6) kf/ad dead: reload for chunk n+1
    if (n + 1 < 64) {
      const size_t kb_ = (size_t)(blk + 1) * 8192;
#pragma unroll
      for (int ks = 0; ks < 2; ks++)
#pragma unroll
        for (int dt = 0; dt < 8; dt++)
          kf[ks][dt] = *(const bf16x8*)(kdT + kb_ + (dt * 16 + fr) * 64 + ks * 32 + g * 8);
      ad = adecbuf[blk + 1];
    }
  }
}

// ---------------- MFMA o-compute + fused gated RMSNorm (reads d4/l4-packed ST/vt) ----------------
__global__ __launch_bounds__(256) void ocomp_kernel(const unsigned short* __restrict__ qe,
                                                    const unsigned short* __restrict__ STbuf,
                                                    const unsigned short* __restrict__ vtbuf,
                                                    const float* __restrict__ attnbuf,
                                                    const unsigned short* __restrict__ zb,
                                                    const float* __restrict__ onw,
                                                    unsigned short* __restrict__ ob) {
  __shared__ __align__(16) unsigned short STl[128 * 128];  // [c][d]
  __shared__ __align__(16) unsigned short vtl[128 * 64];   // [c][l]
  __shared__ __align__(16) unsigned short ql[64 * 128];    // [i][d]
  __shared__ __align__(16) unsigned short al[64 * 64];     // [i][l]
  const int blk = blockIdx.x;
  const int h = blk >> 6;
  const int n = blk & 63;
  const int t0 = n * 64;
  const int tid = threadIdx.x;
  // ST: d4-packed -> [c][d] swizzled LDS. uint4 o covers (dq = o>>6, cols 2w,2w+1, w = o&63)
#pragma unroll
  for (int q = 0; q < 8; q++) {
    const int o = tid + q * 256;
    const int dq = o >> 6, w = o & 63;
    const uint4 v = *(const uint4*)(STbuf + (size_t)blk * 16384 + (size_t)o * 8);
    const int cA = 2 * w, cB = 2 * w + 1;
    uint2 h0; h0.x = v.x; h0.y = v.y;
    uint2 h1; h1.x = v.z; h1.y = v.w;
    *(uint2*)&STl[cA * 128 + (((dq >> 1) ^ (cA & 7)) << 3) + (dq & 1) * 4] = h0;
    *(uint2*)&STl[cB * 128 + (((dq >> 1) ^ (cB & 7)) << 3) + (dq & 1) * 4] = h1;
  }
  // vt: l4-packed -> [c][l] swizzled LDS
#pragma unroll
  for (int q = 0; q < 4; q++) {
    const int o = tid + q * 256;
    const int lq = o >> 6, w = o & 63;
    const uint4 v = *(const uint4*)(vtbuf + (size_t)blk * 8192 + (size_t)o * 8);
    const int cA = 2 * w, cB = 2 * w + 1;
    uint2 h0; h0.x = v.x; h0.y = v.y;
    uint2 h1; h1.x = v.z; h1.y = v.w;
    *(uint2*)&vtl[cA * 64 + (((lq >> 1) ^ (cA & 7)) << 3) + (lq & 1) * 4] = h0;
    *(uint2*)&vtl[cB * 64 + (((lq >> 1) ^ (cB & 7)) << 3) + (lq & 1) * 4] = h1;
  }
#pragma unroll
  for (int q = 0; q < 4; q++) {
    const int idx = tid + q * 256;
    const int i = idx >> 4, dg = idx & 15;
    *(uint4*)&ql[i * 128 + ((dg ^ (i & 7)) << 3)] =
        *(const uint4*)(qe + (size_t)(t0 + i) * 2048 + h * 128 + dg * 8);
  }
#pragma unroll
  for (int q = 0; q < 4; q++) {
    const int idx = tid + q * 256;
    const int i = idx >> 4, l4 = (idx & 15) * 4;
    const float4 v = *(const float4*)(attnbuf + (size_t)blk * 4096 + i * 64 + l4);
    *(ushort4*)&al[i * 64 + (((l4 >> 3) ^ (i & 7)) << 3) + (l4 & 7)] =
        pack4(v.x, v.y, v.z, v.w);
  }
  __syncthreads();
  const int ln = tid & 63;
  const int wv = tid >> 6;
  const int fr = ln & 15;
  const int g = ln >> 4;
  const int i0 = wv * 16;
  f32x4 acc[8];
  const f32x4 zero = {0.f, 0.f, 0.f, 0.f};
#pragma unroll
  for (int nt = 0; nt < 8; nt++) acc[nt] = zero;
#pragma unroll
  for (int ks = 0; ks < 4; ks++) {
    const int kb = ks * 4 + g;
    const int ar = i0 + fr;
    const bf16x8 a = *(const bf16x8*)&ql[ar * 128 + ((kb ^ (ar & 7)) << 3)];
#pragma unroll
    for (int nt = 0; nt < 8; nt++) {
      const int c = nt * 16 + fr;
      const bf16x8 b = *(const bf16x8*)&STl[c * 128 + ((kb ^ (c & 7)) << 3)];
      acc[nt] = __builtin_amdgcn_mfma_f32_16x16x32_bf16(a, b, acc[nt], 0, 0, 0);
    }
  }
#pragma unroll
  for (int ks = 0; ks < 2; ks++) {
    const int kb = ks * 4 + g;
    const int ar = i0 + fr;
    const bf16x8 a = *(const bf16x8*)&al[ar * 64 + ((kb ^ (ar & 7)) << 3)];
#pragma unroll
    for (int nt = 0; nt < 8; nt++) {
      const int c = nt * 16 + fr;
      const bf16x8 b = *(const bf16x8*)&vtl[c * 64 + ((kb ^ (c & 7)) << 3)];
      acc[nt] = __builtin_amdgcn_mfma_f32_16x16x32_bf16(a, b, acc[nt], 0, 0, 0);
    }
  }
  float s0 = 0.f, s1 = 0.f, s2 = 0.f, s3 = 0.f;
#pragma unroll
  for (int nt = 0; nt < 8; nt++) {
    s0 += acc[nt][0] * acc[nt][0];
    s1 += acc[nt][1] * acc[nt][1];
    s2 += acc[nt][2] * acc[nt][2];
    s3 += acc[nt][3] * acc[nt][3];
  }
#pragma unroll
  for (int m = 1; m < 16; m <<= 1) {
    s0 += __shfl_xor(s0, m);
    s1 += __shfl_xor(s1, m);
    s2 += __shfl_xor(s2, m);
    s3 += __shfl_xor(s3, m);
  }
  float rn[4];
  rn[0] = rsqrtf(s0 * (1.0f / 128.0f) + 1e-5f);
  rn[1] = rsqrtf(s1 * (1.0f / 128.0f) + 1e-5f);
  rn[2] = rsqrtf(s2 * (1.0f / 128.0f) + 1e-5f);
  rn[3] = rsqrtf(s3 * (1.0f / 128.0f) + 1e-5f);
#pragma unroll
  for (int nt = 0; nt < 8; nt++) {
    const int c = nt * 16 + fr;
    const float wn = onw[c];
#pragma unroll
    for (int r = 0; r < 4; r++) {
      const size_t off = (size_t)(t0 + i0 + g * 4 + r) * 2048 + h * 128 + c;
      const float zz = siluf(bf2f(zb[off]));
      ob[off] = f2bf(acc[nt][r] * rn[r] * wn * zz);
    }
  }
}

extern "C" void kernel_launch(void* const* d_in, const int* in_sizes, int n_in,
                              void* d_out, int out_size, void* d_ws, size_t ws_size,
                              hipStream_t stream) {
  (void)in_sizes; (void)n_in; (void)out_size;
  const float* x        = (const float*)d_in[0];
  const float* mask     = (const float*)d_in[1];
  const float* ln1_w    = (const float*)d_in[2];
  const float* qkvz_w   = (const float*)d_in[3];
  const float* ba_w     = (const float*)d_in[4];
  const float* conv_w   = (const float*)d_in[5];
  const float* A_log    = (const float*)d_in[6];
  const float* dt_bias  = (const float*)d_in[7];
  const float* o_norm_w = (const float*)d_in[8];
  const float* out_w    = (const float*)d_in[9];
  const float* ln2_w    = (const float*)d_in[10];
  const float* gate_w   = (const float*)d_in[11];
  const float* up_w     = (const float*)d_in[12];
  const float* down_w   = (const float*)d_in[13];
  float* out = (float*)d_out;

  const size_t NEED_BYTES = (size_t)75825152 * 4;
  if (ws_size < NEED_BYTES) return;

  float* ws = (float*)d_ws;
  float* mixed_buf = ws;
  unsigned short* Wg = (unsigned short*)ws;
  unsigned short* Wu = (unsigned short*)(ws + 8388608);
  unsigned short* Wd = (unsigned short*)(ws + 16777216);
  unsigned short* qkvz_bf = (unsigned short*)(ws + 25165824);
  float* u_buf = ws + 25165824;
  unsigned short* wbf = (unsigned short*)(ws + 33554432);
  unsigned short* kdT = (unsigned short*)(ws + 37748736);
  unsigned short* gate_bf = (unsigned short*)(ws + 25165824);
  unsigned short* z_bf = (unsigned short*)(ws + 41943040);
  float* h_buf = ws + 46137344;
  float* a_buf = ws + 46137344;
  unsigned short* vt_buf = (unsigned short*)(ws + 46137344);
  float* t_buf = ws + 50331648;
  unsigned short* qe_bf = (unsigned short*)(ws + 50331648);  // after pre_uw, t_buf is dead
  unsigned short* h_bf  = (unsigned short*)(ws + 54525952);
  unsigned short* ob    = (unsigned short*)(ws + 54525952);
  unsigned short* h2_bf = (unsigned short*)(ws + 54525952);
  float* attn_buf = ws + 58720256;
  unsigned short* Wq = (unsigned short*)(ws + 62914560);
  unsigned short* ST_buf = (unsigned short*)(ws + 62914560);
  unsigned short* Wo = (unsigned short*)(ws + 71303168);
  float* ba_buf   = ws + 73400320;
  float* beta_buf = ws + 73531392;
  float* g_buf    = ws + 73596928;
  float* gcs_buf  = ws + 73662464;
  float* edk_buf  = ws + 73728000;
  float* egq_buf  = ws + 73793536;
  float* adec_buf = ws + 73859072;

  rmsnorm_kernel<1><<<4096, 256, 0, stream>>>(x, ln1_w, h_buf, h_bf);
  f2b_kernel<<<8192, 256, 0, stream>>>(qkvz_w, Wq);
  gemm256_kernel<0, 128, 256><<<1024, 512, 0, stream>>>(h_bf, Wq, nullptr, qkvz_bf, 4096, 8192, 2048);
  ba_gemm_kernel<<<4096, 256, 0, stream>>>(h_buf, ba_w, ba_buf);
  zcopy_kernel<<<4096, 256, 0, stream>>>(qkvz_bf, z_bf);
  conv_silu_kernel<<<24576, 256, 0, stream>>>(qkvz_bf, conv_w, mask, mixed_buf);
  l2norm_kernel<<<32768, 256, 0, stream>>>(mixed_buf);
  beta_g_kernel<<<256, 256, 0, stream>>>(ba_buf, A_log, dt_bias, mask, beta_buf, g_buf);
  gcs_kernel<<<4, 256, 0, stream>>>(g_buf, gcs_buf, edk_buf, egq_buf, adec_buf);
  pre_attn_kernel<<<1024, 256, 0, stream>>>(mixed_buf, gcs_buf, beta_buf, a_buf, attn_buf);
  pre_solve_kernel<<<1024, 256, 0, stream>>>(a_buf, beta_buf, t_buf);
  pre_uw_kernel<<<1024, 256, 0, stream>>>(mixed_buf, t_buf, gcs_buf, u_buf, wbf);
  ktrans_kernel<<<1024, 256, 0, stream>>>(mixed_buf, edk_buf, egq_buf, kdT, qe_bf);
  // register-resident MFMA scan (16 blocks, 8 waves, no barriers) + fused f2b/copy (15360 blocks)
  scan_kernel<<<15376, 512, 0, stream>>>(wbf, kdT, u_buf, adec_buf, ST_buf, vt_buf,
                                         gate_w, up_w, down_w, out_w, x,
                                         Wg, Wu, Wd, Wo, out);
  ocomp_kernel<<<1024, 256, 0, stream>>>(qe_bf, ST_buf, vt_buf, attn_buf,
                                         z_bf, o_norm_w, ob);
  gemm256_kernel<1, 128, 128><<<512, 512, 0, stream>>>(ob, Wo, out, nullptr, 4096, 2048, 2048);
  rmsnorm_kernel<2><<<4096, 256, 0, stream>>>(out, ln2_w, nullptr, h2_bf);
  gemm256_kernel<0, 128, 256><<<1024, 512, 0, stream>>>(h2_bf, Wg, nullptr, gate_bf, 4096, 8192, 2048);
  gemm256_kernel<2, 128, 256><<<1024, 512, 0, stream>>>(h2_bf, Wu, nullptr, gate_bf, 4096, 8192, 2048);
  gemm256_kernel<1, 128, 128><<<512, 512, 0, stream>>>(gate_bf, Wd, out, nullptr, 4096, 2048, 8192);
}

// Round 12
// 1398.026 us; speedup vs baseline: 1.2499x; 1.2499x over previous
//
#include <hip/hip_runtime.h>
#include <math.h>

#define T_LEN 4096
#define DMODEL 2048
#define NH 16
#define CQKV 6144
#define CQKVZ 8192
#define SCALE 0.08838834764831845f   // 128^-0.5

using bf16x8 = __attribute__((ext_vector_type(8))) short;
using f32x4  = __attribute__((ext_vector_type(4))) float;

__device__ __forceinline__ float siluf(float x) { return x / (1.0f + __expf(-x)); }

__device__ __forceinline__ unsigned short f2bf(float f) {  // RNE
  unsigned int u = __float_as_uint(f);
  u = (u + 0x7FFFu + ((u >> 16) & 1u)) >> 16;
  return (unsigned short)u;
}
__device__ __forceinline__ float bf2f(unsigned short u) {
  return __uint_as_float(((unsigned int)u) << 16);
}
__device__ __forceinline__ ushort4 pack4(float a, float b, float c, float d) {
  ushort4 r; r.x = f2bf(a); r.y = f2bf(b); r.z = f2bf(c); r.w = f2bf(d); return r;
}

// async global->LDS, 16 bytes per lane; LDS dest is wave-uniform base (+ lane*16 implicit)
__device__ __forceinline__ void gl_lds16(const unsigned short* g, unsigned short* l) {
  __builtin_amdgcn_global_load_lds(
      (const __attribute__((address_space(1))) void*)g,
      (__attribute__((address_space(3))) void*)l, 16, 0, 0);
}

// ---------------- RMSNorm over D=2048; MODE: 1 = f32+bf16, 2 = bf16 only ----------------
template<int MODE>
__global__ __launch_bounds__(256) void rmsnorm_kernel(const float* __restrict__ x,
                                                      const float* __restrict__ w,
                                                      float* __restrict__ outf,
                                                      unsigned short* __restrict__ outb) {
  const int t = blockIdx.x;
  const int tid = threadIdx.x;
  const float4* xr = (const float4*)(x + (size_t)t * DMODEL);
  float4 v0 = xr[tid];
  float4 v1 = xr[tid + 256];
  float s = v0.x*v0.x + v0.y*v0.y + v0.z*v0.z + v0.w*v0.w
          + v1.x*v1.x + v1.y*v1.y + v1.z*v1.z + v1.w*v1.w;
#pragma unroll
  for (int off = 32; off > 0; off >>= 1) s += __shfl_down(s, off);
  __shared__ float red[4];
  if ((tid & 63) == 0) red[tid >> 6] = s;
  __syncthreads();
  const float tot = red[0] + red[1] + red[2] + red[3];
  const float r = rsqrtf(tot * (1.0f / DMODEL) + 1e-5f);
  const float4* wr = (const float4*)w;
  const float4 w0 = wr[tid], w1 = wr[tid + 256];
  float4 o0, o1;
  o0.x = v0.x*r*w0.x; o0.y = v0.y*r*w0.y; o0.z = v0.z*r*w0.z; o0.w = v0.w*r*w0.w;
  o1.x = v1.x*r*w1.x; o1.y = v1.y*r*w1.y; o1.z = v1.z*r*w1.z; o1.w = v1.w*r*w1.w;
  if (MODE == 1) {
    float4* orow = (float4*)(outf + (size_t)t * DMODEL);
    orow[tid] = o0;
    orow[tid + 256] = o1;
  }
  ushort4* brow = (ushort4*)(outb + (size_t)t * DMODEL);
  brow[tid] = pack4(o0.x, o0.y, o0.z, o0.w);
  brow[tid + 256] = pack4(o1.x, o1.y, o1.z, o1.w);
}

// ---------------- fp32 -> bf16 bulk convert ----------------
__global__ __launch_bounds__(256) void f2b_kernel(const float* __restrict__ in,
                                                  unsigned short* __restrict__ out) {
  const size_t i = (size_t)blockIdx.x * 256 + threadIdx.x;
  const float4 a = ((const float4*)in)[2 * i];
  const float4 b = ((const float4*)in)[2 * i + 1];
  ((ushort4*)out)[2 * i] = pack4(a.x, a.y, a.z, a.w);
  ((ushort4*)out)[2 * i + 1] = pack4(b.x, b.y, b.z, b.w);
}

// ---------------- pipelined bf16 MFMA GEMM: C[M][N] = A[M][K] * B[N][K]^T -------------------
// BM x BN block (8 waves, 2M x 4N, 64x64 per-wave tile), BK=32, 3 LDS buffers, 2 blocks/CU:
// stage tile t+2 during tile t, counted vmcnt (never drains in steady state), ONE barrier/tile.
// EPI: 0 = bf16 store, 1 = fp32 accumulate, 2 = silu(gate)*acc -> bf16 in place
template<int EPI, int BM, int BN>
__global__ __launch_bounds__(512, 4) void gemm256_kernel(const unsigned short* __restrict__ A,
                                                         const unsigned short* __restrict__ B,
                                                         float* __restrict__ Cf,
                                                         unsigned short* __restrict__ Cb,
                                                         int M, int N, int K) {
  constexpr int MI = 4;            // wave rows = 64
  constexpr int NI = BN / 64;      // wave cols = BN/4
  constexpr int AW = BM / 128;
  constexpr int BW = BN / 128;
  __shared__ __align__(16) unsigned short lds[3][(BM + BN) * 32];
  const int nbm = M / BM, nbn = N / BN, nwg = nbm * nbn;
  const int nt = K >> 5;
  int bmi, bni;
  {
    const int bid = blockIdx.x;
    const int cpx = nwg >> 3;
    int sc = 1;
    while (sc * sc < cpx) sc <<= 1;
    if (sc * sc > cpx) sc >>= 1;
    const int scn = (sc > 0) ? (cpx / sc) : 0;
    if ((nwg & 7) == 0 && sc > 0 && sc * scn == cpx && (nbm % sc) == 0 && (nbn % scn) == 0) {
      const int chunk = bid & 7, widx = bid >> 3;
      const int regc = nbn / scn;
      bmi = (chunk / regc) * sc + widx / scn;
      bni = (chunk % regc) * scn + widx % scn;
    } else {
      bmi = bid / nbn; bni = bid % nbn;
    }
  }
  const int bm = bmi * BM, bn = bni * BN;
  const int tid = threadIdx.x;
  const int wv = tid >> 6, ln = tid & 63;
  const int fr = ln & 15, qq = ln >> 4;
  const int wm = wv >> 2, wn = wv & 3;
  const int ra0 = wm * 64, rb0 = wn * (BN / 4);
  const int lrow = ln >> 2;
  const int lslot = ln & 3;

  f32x4 acc[MI][NI];
  const f32x4 zero = {0.f, 0.f, 0.f, 0.f};
#pragma unroll
  for (int mi = 0; mi < MI; mi++)
#pragma unroll
    for (int ni = 0; ni < NI; ni++) acc[mi][ni] = zero;

  auto stage = [&](int buf, int t) {
    const int k0 = t << 5;
#pragma unroll
    for (int q = 0; q < AW; q++) {
      const int lr = q * 128 + wv * 16 + lrow;
      const int sl = lslot ^ ((lr >> 1) & 3);
      gl_lds16(A + (size_t)(bm + lr) * K + k0 + sl * 8,
               &lds[buf][(q * 128 + wv * 16) * 32]);
    }
#pragma unroll
    for (int q = 0; q < BW; q++) {
      const int lr = q * 128 + wv * 16 + lrow;
      const int sl = lslot ^ ((lr >> 1) & 3);
      gl_lds16(B + (size_t)(bn + lr) * K + k0 + sl * 8,
               &lds[buf][BM * 32 + (q * 128 + wv * 16) * 32]);
    }
  };

  // prologue: tiles 0,1 staged; wait tile0 only (tile1's loads stay outstanding)
  stage(0, 0);
  stage(1, 1);
  asm volatile("s_waitcnt vmcnt(%0)" :: "i"(AW + BW) : "memory");
  __builtin_amdgcn_s_barrier();
  asm volatile("" ::: "memory");

  for (int t = 0; t < nt; t++) {
    const int cb = t % 3;
    const int b2 = (t + 2) % 3;
    const unsigned short* lA = &lds[cb][0];
    const unsigned short* lB = &lds[cb][BM * 32];
    bf16x8 bfr[NI];
#pragma unroll
    for (int ni = 0; ni < NI; ni++) {
      const int r = rb0 + ni * 16 + fr;
      bfr[ni] = *(const bf16x8*)&lB[r * 32 + ((qq ^ ((r >> 1) & 3)) << 3)];
    }
    bf16x8 afr[MI];
#pragma unroll
    for (int mi = 0; mi < MI; mi++) {
      const int r = ra0 + mi * 16 + fr;
      afr[mi] = *(const bf16x8*)&lA[r * 32 + ((qq ^ ((r >> 1) & 3)) << 3)];
    }
    if (t + 2 < nt) stage(b2, t + 2);
    __builtin_amdgcn_s_setprio(1);
#pragma unroll
    for (int mi = 0; mi < MI; mi++)
#pragma unroll
      for (int ni = 0; ni < NI; ni++)
        acc[mi][ni] = __builtin_amdgcn_mfma_f32_16x16x32_bf16(afr[mi], bfr[ni], acc[mi][ni], 0, 0, 0);
    __builtin_amdgcn_s_setprio(0);
    if (t + 1 < nt) {
      // my ds_reads of buf[cb] retired before anyone overwrites it (t+3 stage is post-barrier)
      asm volatile("s_waitcnt lgkmcnt(0)" ::: "memory");
      if (t + 2 < nt) {
        asm volatile("s_waitcnt vmcnt(%0)" :: "i"(AW + BW) : "memory");  // t+1 landed
      } else {
        asm volatile("s_waitcnt vmcnt(0)" ::: "memory");                 // tail drain
      }
      __builtin_amdgcn_s_barrier();
      asm volatile("" ::: "memory");
    }
  }

  const int cm4 = qq * 4;
#pragma unroll
  for (int mi = 0; mi < MI; mi++) {
#pragma unroll
    for (int ni = 0; ni < NI; ni++) {
#pragma unroll
      for (int r = 0; r < 4; r++) {
        const int grow = bm + ra0 + mi * 16 + cm4 + r;
        const int gcol = bn + rb0 + ni * 16 + fr;
        const size_t off = (size_t)grow * N + gcol;
        const float v = acc[mi][ni][r];
        if (EPI == 0) {
          Cb[off] = f2bf(v);
        } else if (EPI == 1) {
          Cf[off] += v;
        } else {
          Cb[off] = f2bf(siluf(bf2f(Cb[off])) * v);
        }
      }
    }
  }
}

// ---------------- ba = h @ ba_w^T ----------------
__global__ __launch_bounds__(256) void ba_gemm_kernel(const float* __restrict__ h_in,
                                                      const float* __restrict__ ba_w,
                                                      float* __restrict__ ba_out) {
  __shared__ __align__(16) float hl[2048];
  __shared__ float red[32][9];
  const int t = blockIdx.x;
  const int tid = threadIdx.x;
  const float4* hr = (const float4*)(h_in + (size_t)t * DMODEL);
  ((float4*)hl)[tid] = hr[tid];
  ((float4*)hl)[tid + 256] = hr[tid + 256];
  __syncthreads();
  const int c = tid & 31;
  const int p = tid >> 5;
  const float* wrow = ba_w + (size_t)c * DMODEL + p * 256;
  const float* hrow = hl + p * 256;
  float s = 0.f;
#pragma unroll 8
  for (int k = 0; k < 256; k++) s += hrow[k] * wrow[k];
  red[c][p] = s;
  __syncthreads();
  if (tid < 32) {
    float tot = 0.f;
#pragma unroll
    for (int q = 0; q < 8; q++) tot += red[tid][q];
    ba_out[(size_t)t * 32 + tid] = tot;
  }
}

// ---------------- extract z columns from bf16 qkvz ----------------
__global__ __launch_bounds__(256) void zcopy_kernel(const unsigned short* __restrict__ qkvz,
                                                    unsigned short* __restrict__ z) {
  const int idx = blockIdx.x * 256 + threadIdx.x;
  const int t = idx >> 8;
  const int c8 = (idx & 255) * 8;
  *(uint4*)(z + (size_t)t * 2048 + c8) =
      *(const uint4*)(qkvz + (size_t)t * CQKVZ + CQKV + c8);
}

// ---------------- causal depthwise conv (K=4) + SiLU; bf16 in, fp32 out ----------------
__global__ __launch_bounds__(256) void conv_silu_kernel(const unsigned short* __restrict__ qkvz,
                                                        const float* __restrict__ conv_w,
                                                        const float* __restrict__ mask,
                                                        float* __restrict__ mixed) {
  const int idx = blockIdx.x * 256 + threadIdx.x;
  const int c4 = (idx % 1536) * 4;
  const int t = idx / 1536;
  const float4 w0 = *(const float4*)(conv_w + (size_t)c4 * 4);
  const float4 w1 = *(const float4*)(conv_w + (size_t)c4 * 4 + 4);
  const float4 w2 = *(const float4*)(conv_w + (size_t)c4 * 4 + 8);
  const float4 w3 = *(const float4*)(conv_w + (size_t)c4 * 4 + 12);
  const float wj0[4] = {w0.x, w0.y, w0.z, w0.w};
  const float wj1[4] = {w1.x, w1.y, w1.z, w1.w};
  const float wj2[4] = {w2.x, w2.y, w2.z, w2.w};
  const float wj3[4] = {w3.x, w3.y, w3.z, w3.w};
  float4 acc = make_float4(0.f, 0.f, 0.f, 0.f);
#pragma unroll
  for (int j = 0; j < 4; j++) {
    const int tt = t - 3 + j;
    if (tt < 0) continue;
    const float m = mask[tt];
    const ushort4 xb = *(const ushort4*)(qkvz + (size_t)tt * CQKVZ + c4);
    acc.x += bf2f(xb.x) * m * wj0[j];
    acc.y += bf2f(xb.y) * m * wj1[j];
    acc.z += bf2f(xb.z) * m * wj2[j];
    acc.w += bf2f(xb.w) * m * wj3[j];
  }
  acc.x = siluf(acc.x); acc.y = siluf(acc.y); acc.z = siluf(acc.z); acc.w = siluf(acc.w);
  *(float4*)(mixed + (size_t)t * CQKV + c4) = acc;
}

// ---------------- l2norm over Dk=128 for q,k heads (in place, fp32) ----------------
__global__ __launch_bounds__(256) void l2norm_kernel(float* __restrict__ mixed) {
  const int r = blockIdx.x * 4 + (threadIdx.x >> 6);
  const int lane = threadIdx.x & 63;
  const int t = r >> 5;
  const int hh = r & 31;
  float* p = mixed + (size_t)t * CQKV + hh * 128 + lane * 2;
  float2 v = *(float2*)p;
  float s = v.x * v.x + v.y * v.y;
#pragma unroll
  for (int off = 32; off > 0; off >>= 1) s += __shfl_down(s, off);
  s = __shfl(s, 0);
  const float rn = rsqrtf(s + 1e-6f);
  v.x *= rn; v.y *= rn;
  *(float2*)p = v;
}

// ---------------- beta, g ----------------
__global__ __launch_bounds__(256) void beta_g_kernel(const float* __restrict__ ba,
                                                     const float* __restrict__ A_log,
                                                     const float* __restrict__ dt_bias,
                                                     const float* __restrict__ mask,
                                                     float* __restrict__ beta,
                                                     float* __restrict__ g) {
  const int idx = blockIdx.x * 256 + threadIdx.x;
  const int t = idx >> 4;
  const int h = idx & 15;
  const float b = ba[(size_t)t * 32 + h];
  const float a = ba[(size_t)t * 32 + 16 + h];
  const float m = mask[t];
  beta[idx] = m / (1.0f + expf(-b));
  const float xx = a + dt_bias[h];
  const float sp = (xx > 20.0f) ? xx : log1pf(expf(xx));
  g[idx] = -expf(A_log[h]) * sp * m;
}

// ---------------- per-chunk cumsum of g + decay factors ----------------
__global__ __launch_bounds__(256) void gcs_kernel(const float* __restrict__ g,
                                                  float* __restrict__ gcsbuf,
                                                  float* __restrict__ edkbuf,
                                                  float* __restrict__ egqbuf,
                                                  float* __restrict__ adecbuf) {
  const int idx = blockIdx.x * 256 + threadIdx.x;  // chunk id = h*64 + n
  if (idx >= 1024) return;
  const int h = idx >> 6;
  const int n = idx & 63;
  const int t0 = n * 64;
  float s = 0.f;
  for (int i = 0; i < 64; i++) {
    s += g[(size_t)(t0 + i) * NH + h];
    gcsbuf[(size_t)idx * 64 + i] = s;
  }
  const float glast = s;
  adecbuf[idx] = __expf(glast);
  for (int i = 0; i < 64; i++) {
    const float gi = gcsbuf[(size_t)idx * 64 + i];
    edkbuf[(size_t)idx * 64 + i] = __expf(glast - gi);
    egqbuf[(size_t)idx * 64 + i] = __expf(gi) * SCALE;
  }
}

// ---------------- per-chunk: A=(k_beta k^T)*decay (strict lower), attn=(q k^T)*decay*scale ----------------
__global__ __launch_bounds__(256) void pre_attn_kernel(const float* __restrict__ mixed,
                                                       const float* __restrict__ gcsbuf,
                                                       const float* __restrict__ betabuf,
                                                       float* __restrict__ abuf,
                                                       float* __restrict__ attnbuf) {
  __shared__ __align__(16) float kl[64][132];
  __shared__ float gcs_s[64];
  __shared__ float betal[64];
  const int blk = blockIdx.x;
  const int h = blk >> 6;
  const int n = blk & 63;
  const int t0 = n * 64;
  const int tid = threadIdx.x;
  if (tid < 64) {
    gcs_s[tid] = gcsbuf[(size_t)blk * 64 + tid];
    betal[tid] = betabuf[(size_t)(t0 + tid) * NH + h];
  }
#pragma unroll
  for (int rep = 0; rep < 8; rep++) {
    const int lin = rep * 256 + tid;
    const int i = lin >> 5;
    const int d = (lin & 31) * 4;
    const float4 kv = *(const float4*)(mixed + (size_t)(t0 + i) * CQKV + 2048 + h * 128 + d);
    *(float4*)&kl[i][d] = kv;
  }
  __syncthreads();
  const int cj = tid & 15;
  const int ri = tid >> 4;
  const int i0 = ri * 4, j0 = cj * 4;
  float accA[4][4], accQ[4][4];
#pragma unroll
  for (int a = 0; a < 4; a++)
#pragma unroll
    for (int b = 0; b < 4; b++) { accA[a][b] = 0.f; accQ[a][b] = 0.f; }
  const float* qbase = mixed + (size_t)t0 * CQKV + h * 128;
#pragma unroll 4
  for (int d = 0; d < 128; d++) {
    const float kj0 = kl[j0][d], kj1 = kl[j0 + 1][d], kj2 = kl[j0 + 2][d], kj3 = kl[j0 + 3][d];
#pragma unroll
    for (int a = 0; a < 4; a++) {
      const float ka = kl[i0 + a][d];
      const float qa = qbase[(size_t)(i0 + a) * CQKV + d];
      accA[a][0] += ka * kj0; accA[a][1] += ka * kj1; accA[a][2] += ka * kj2; accA[a][3] += ka * kj3;
      accQ[a][0] += qa * kj0; accQ[a][1] += qa * kj1; accQ[a][2] += qa * kj2; accQ[a][3] += qa * kj3;
    }
  }
#pragma unroll
  for (int a = 0; a < 4; a++) {
    const int i = i0 + a;
    const float gi = gcs_s[i];
    const float bi = betal[i];
    float4 Av, Qv;
    float dec;
    dec = __expf(fminf(gi - gcs_s[j0 + 0], 0.f));
    Av.x = (i > j0 + 0) ? accA[a][0] * bi * dec : 0.f;
    Qv.x = (i >= j0 + 0) ? accQ[a][0] * dec * SCALE : 0.f;
    dec = __expf(fminf(gi - gcs_s[j0 + 1], 0.f));
    Av.y = (i > j0 + 1) ? accA[a][1] * bi * dec : 0.f;
    Qv.y = (i >= j0 + 1) ? accQ[a][1] * dec * SCALE : 0.f;
    dec = __expf(fminf(gi - gcs_s[j0 + 2], 0.f));
    Av.z = (i > j0 + 2) ? accA[a][2] * bi * dec : 0.f;
    Qv.z = (i >= j0 + 2) ? accQ[a][2] * dec * SCALE : 0.f;
    dec = __expf(fminf(gi - gcs_s[j0 + 3], 0.f));
    Av.w = (i > j0 + 3) ? accA[a][3] * bi * dec : 0.f;
    Qv.w = (i >= j0 + 3) ? accQ[a][3] * dec * SCALE : 0.f;
    *(float4*)(abuf + (size_t)blk * 4096 + i * 64 + j0) = Av;
    *(float4*)(attnbuf + (size_t)blk * 4096 + i * 64 + j0) = Qv;
  }
}

// ---------------- per-chunk: T = (I+A)^-1, then T *= beta[col] ----------------
__global__ __launch_bounds__(256) void pre_solve_kernel(const float* __restrict__ abuf,
                                                        const float* __restrict__ betabuf,
                                                        float* __restrict__ tbuf) {
  __shared__ float Al[64][65];
  __shared__ float Tl[64][65];
  const int blk = blockIdx.x;
  const int h = blk >> 6;
  const int n = blk & 63;
  const int t0 = n * 64;
  const int tid = threadIdx.x;
#pragma unroll
  for (int rep = 0; rep < 4; rep++) {
    const int lin = rep * 256 + tid;
    const int i = lin >> 4;
    const int j = (lin & 15) * 4;
    const float4 av = *(const float4*)(abuf + (size_t)blk * 4096 + i * 64 + j);
    Al[i][j] = av.x; Al[i][j + 1] = av.y; Al[i][j + 2] = av.z; Al[i][j + 3] = av.w;
  }
  __syncthreads();
  if (tid < 64) {
    const int j = tid;
    const float bj = betabuf[(size_t)(t0 + j) * NH + h];
    for (int i = 0; i < 64; i++) {
      float s = (i == j) ? 1.0f : 0.0f;
      for (int l = j; l < i; l++) s -= Al[i][l] * Tl[l][j];
      Tl[i][j] = s;
    }
    for (int i = j; i < 64; i++) Tl[i][j] *= bj;
  }
  __syncthreads();
#pragma unroll
  for (int rep = 0; rep < 4; rep++) {
    const int lin = rep * 256 + tid;
    const int i = lin >> 4;
    const int j = (lin & 15) * 4;
    float4 tv;
    tv.x = Tl[i][j]; tv.y = Tl[i][j + 1]; tv.z = Tl[i][j + 2]; tv.w = Tl[i][j + 3];
    *(float4*)(tbuf + (size_t)blk * 4096 + i * 64 + j) = tv;
  }
}

// ---------------- per-chunk: u = Tb @ v (f32, l4-packed [blk][l>>2][c][l&3]) ;
//                  w = Tb @ (k * e^gcs), stored NEGATED + slot-swizzled ----
__global__ __launch_bounds__(256) void pre_uw_kernel(const float* __restrict__ mixed,
                                                     const float* __restrict__ tbuf,
                                                     const float* __restrict__ gcsbuf,
                                                     float* __restrict__ ubuf,
                                                     unsigned short* __restrict__ wbf) {
  __shared__ __align__(16) float Tl[64][68];
  __shared__ __align__(16) float xl[64][132];
  __shared__ float egcs[64];
  const int blk = blockIdx.x;
  const int h = blk >> 6;
  const int n = blk & 63;
  const int t0 = n * 64;
  const int tid = threadIdx.x;
  if (tid < 64) egcs[tid] = __expf(gcsbuf[(size_t)blk * 64 + tid]);
#pragma unroll
  for (int rep = 0; rep < 4; rep++) {
    const int lin = rep * 256 + tid;
    const int i = lin >> 4;
    const int j = (lin & 15) * 4;
    const float4 tv = *(const float4*)(tbuf + (size_t)blk * 4096 + i * 64 + j);
    *(float4*)&Tl[i][j] = tv;
  }
#pragma unroll
  for (int rep = 0; rep < 8; rep++) {
    const int lin = rep * 256 + tid;
    const int i = lin >> 5;
    const int d = (lin & 31) * 4;
    const float4 vv = *(const float4*)(mixed + (size_t)(t0 + i) * CQKV + 4096 + h * 128 + d);
    *(float4*)&xl[i][d] = vv;
  }
  __syncthreads();
  const int cgu = tid & 15;
  const int riu = tid >> 4;
  const int i0 = riu * 4;
  const int d0 = cgu * 8;
  float acc[4][8];
#pragma unroll
  for (int a = 0; a < 4; a++)
#pragma unroll
    for (int b = 0; b < 8; b++) acc[a][b] = 0.f;
#pragma unroll 2
  for (int j = 0; j < 64; j++) {
    const float tv[4] = {Tl[i0][j], Tl[i0 + 1][j], Tl[i0 + 2][j], Tl[i0 + 3][j]};
    const float4 x0 = *(const float4*)&xl[j][d0];
    const float4 x1 = *(const float4*)&xl[j][d0 + 4];
    const float xv[8] = {x0.x, x0.y, x0.z, x0.w, x1.x, x1.y, x1.z, x1.w};
#pragma unroll
    for (int a = 0; a < 4; a++)
#pragma unroll
      for (int b = 0; b < 8; b++) acc[a][b] += tv[a] * xv[b];
  }
  // u store: l4-packed layout addr = blk*8192 + (l>>2)*512 + c*4 + (l&3); here l>>2 = riu.
#pragma unroll
  for (int b = 0; b < 8; b++) {
    *(float4*)(ubuf + (size_t)blk * 8192 + riu * 512 + (size_t)(d0 + b) * 4) =
        make_float4(acc[0][b], acc[1][b], acc[2][b], acc[3][b]);
  }
  __syncthreads();
#pragma unroll
  for (int rep = 0; rep < 8; rep++) {
    const int lin = rep * 256 + tid;
    const int i = lin >> 5;
    const int d = (lin & 31) * 4;
    float4 kv = *(const float4*)(mixed + (size_t)(t0 + i) * CQKV + 2048 + h * 128 + d);
    const float e = egcs[i];
    kv.x *= e; kv.y *= e; kv.z *= e; kv.w *= e;
    *(float4*)&xl[i][d] = kv;
  }
  __syncthreads();
#pragma unroll
  for (int a = 0; a < 4; a++)
#pragma unroll
    for (int b = 0; b < 8; b++) acc[a][b] = 0.f;
#pragma unroll 2
  for (int j = 0; j < 64; j++) {
    const float tv[4] = {Tl[i0][j], Tl[i0 + 1][j], Tl[i0 + 2][j], Tl[i0 + 3][j]};
    const float4 x0 = *(const float4*)&xl[j][d0];
    const float4 x1 = *(const float4*)&xl[j][d0 + 4];
    const float xv[8] = {x0.x, x0.y, x0.z, x0.w, x1.x, x1.y, x1.z, x1.w};
#pragma unroll
    for (int a = 0; a < 4; a++)
#pragma unroll
      for (int b = 0; b < 8; b++) acc[a][b] += tv[a] * xv[b];
  }
  // store -w, column-slot swizzled by (row&7) so scan can global_load_lds linearly
#pragma unroll
  for (int a = 0; a < 4; a++) {
    const int l = i0 + a;
    unsigned short* wp = wbf + (size_t)(t0 + l) * 2048 + h * 128 + ((cgu ^ (l & 7)) << 3);
    *(ushort4*)wp = pack4(-acc[a][0], -acc[a][1], -acc[a][2], -acc[a][3]);
    *(ushort4*)(wp + 4) = pack4(-acc[a][4], -acc[a][5], -acc[a][6], -acc[a][7]);
  }
}

// ---------------- per-chunk: kdT[blk][d][l] = bf16(k*edk) slot-swizzled; qe = bf16(q*egq) ----------------
__global__ __launch_bounds__(256) void ktrans_kernel(const float* __restrict__ mixed,
                                                     const float* __restrict__ edkbuf,
                                                     const float* __restrict__ egqbuf,
                                                     unsigned short* __restrict__ kdT,
                                                     unsigned short* __restrict__ qe) {
  __shared__ __align__(16) float kl[64][132];
  __shared__ float edk_s[64];
  __shared__ float egq_s[64];
  const int blk = blockIdx.x;
  const int h = blk >> 6;
  const int n = blk & 63;
  const int t0 = n * 64;
  const int tid = threadIdx.x;
  if (tid < 64) {
    edk_s[tid] = edkbuf[(size_t)blk * 64 + tid];
    egq_s[tid] = egqbuf[(size_t)blk * 64 + tid];
  }
#pragma unroll
  for (int q = 0; q < 8; q++) {
    const int idx = tid + q * 256;
    const int l = idx >> 5, c4 = (idx & 31) * 4;
    *(float4*)&kl[l][c4] = *(const float4*)(mixed + (size_t)(t0 + l) * CQKV + 2048 + h * 128 + c4);
  }
  __syncthreads();
#pragma unroll
  for (int q = 0; q < 4; q++) {
    const int idx = tid + q * 256;
    const int d = idx >> 3, lsl = idx & 7;
    const int l8 = lsl * 8;
    float v[8];
#pragma unroll
    for (int j = 0; j < 8; j++) v[j] = kl[l8 + j][d] * edk_s[l8 + j];
    unsigned short* p = kdT + (size_t)blk * 8192 + d * 64 + ((lsl ^ (d & 7)) << 3);
    *(ushort4*)p = pack4(v[0], v[1], v[2], v[3]);
    *(ushort4*)(p + 4) = pack4(v[4], v[5], v[6], v[7]);
  }
#pragma unroll
  for (int q = 0; q < 8; q++) {
    const int idx = tid + q * 256;
    const int i = idx >> 5, c4 = (idx & 31) * 4;
    const float4 v = *(const float4*)(mixed + (size_t)(t0 + i) * CQKV + h * 128 + c4);
    const float e = egq_s[i];
    *(ushort4*)(qe + (size_t)(t0 + i) * 2048 + h * 128 + c4) =
        pack4(v.x * e, v.y * e, v.z * e, v.w * e);
  }
}

// ---------------- MFMA scan, column-decomposed: 8 waves x 16 c-columns, NO cross-wave data ---
// Exports in d4-packed layouts (coalesced): STb[blk][(d>>2)*512 + c*4 + (d&3)],
// vtb[blk][(l>>2)*512 + c*4 + (l&3)]. u read from l4-packed ubuf (4x float4 per chunk).
// blocks 0..15: per-head scan; ONE barrier/chunk (counted vmcnt(17)).
// blocks >=16: weight f2b + residual copy (512 threads).
__global__ __launch_bounds__(512, 1) void scan_kernel(const unsigned short* __restrict__ wbf,
                                                      const unsigned short* __restrict__ kdT,
                                                      const float* __restrict__ ubuf,
                                                      const float* __restrict__ adecbuf,
                                                      unsigned short* __restrict__ STb,
                                                      unsigned short* __restrict__ vtb,
                                                      const float* __restrict__ gw,
                                                      const float* __restrict__ uw,
                                                      const float* __restrict__ dw,
                                                      const float* __restrict__ ow,
                                                      const float* __restrict__ xin,
                                                      unsigned short* __restrict__ Wg,
                                                      unsigned short* __restrict__ Wu,
                                                      unsigned short* __restrict__ Wd,
                                                      unsigned short* __restrict__ Wo,
                                                      float* __restrict__ outc) {
  __shared__ __align__(16) unsigned short stage[2][16384];  // [w 8192 | kT 8192] shorts each
  __shared__ __align__(16) unsigned short privAll[8][3072]; // per wave: A 16x128 | B 16x64
  if (blockIdx.x >= 16) {
    // side work (512 thr): Wg 4096 + Wu 4096 + Wd 4096 + Wo 1024 + copy 2048 = 15360 blocks
    const int xb = blockIdx.x - 16;
    const int tid = threadIdx.x;
    if (xb < 13312) {
      const float* src; unsigned short* dst; size_t u;
      if (xb < 4096)       { src = gw; dst = Wg; u = (size_t)xb * 512 + tid; }
      else if (xb < 8192)  { src = uw; dst = Wu; u = (size_t)(xb - 4096) * 512 + tid; }
      else if (xb < 12288) { src = dw; dst = Wd; u = (size_t)(xb - 8192) * 512 + tid; }
      else                 { src = ow; dst = Wo; u = (size_t)(xb - 12288) * 512 + tid; }
      const float4 a = ((const float4*)src)[2 * u];
      const float4 b = ((const float4*)src)[2 * u + 1];
      ((ushort4*)dst)[2 * u] = pack4(a.x, a.y, a.z, a.w);
      ((ushort4*)dst)[2 * u + 1] = pack4(b.x, b.y, b.z, b.w);
    } else {
      const size_t i = (size_t)(xb - 13312) * 512 + tid;
      ((float4*)outc)[2 * i] = ((const float4*)xin)[2 * i];
      ((float4*)outc)[2 * i + 1] = ((const float4*)xin)[2 * i + 1];
    }
    return;
  }
  const int h = blockIdx.x;
  const int tid = threadIdx.x;
  const int ln = tid & 63;
  const int wv = tid >> 6;        // 0..7
  const int fr = ln & 15;
  const int g  = ln >> 4;         // 0..3
  const int c0 = wv * 16;
  const int fsw = fr & 7;
  unsigned short* privA = &privAll[wv][0];     // [16 c][128 d], slot-swizzled
  unsigned short* privB = &privAll[wv][2048];  // [16 c][64 l], slot-swizzled
  const f32x4 zero = {0.f, 0.f, 0.f, 0.f};

  f32x4 acc2[8];                  // S^T state for this wave's 16 columns, d-tile dt
#pragma unroll
  for (int dt = 0; dt < 8; dt++) acc2[dt] = zero;

  auto stage_wk = [&](int buf, int n1) {
    const int t0n = n1 * 64;
    const size_t kbase = (size_t)(h * 64 + n1) * 8192;
#pragma unroll
    for (int q = 0; q < 2; q++) {
      const int m = wv * 2 + q;   // 0..15
      gl_lds16(wbf + (size_t)(t0n + m * 4 + (ln >> 4)) * 2048 + h * 128 + (ln & 15) * 8,
               &stage[buf][m * 512]);
      gl_lds16(kdT + kbase + (m * 8 + (ln >> 3)) * 64 + (ln & 7) * 8,
               &stage[buf][8192 + m * 512]);
    }
  };

  // prologue: u/adec for chunk 0 + stage chunk 0
  float4 ur4[4];
#pragma unroll
  for (int lt = 0; lt < 4; lt++)
    ur4[lt] = *(const float4*)(ubuf + (size_t)(h * 64) * 8192 + (lt * 4 + g) * 512 + (c0 + fr) * 4);
  float ad = adecbuf[h * 64];
  stage_wk(0, 0);
  asm volatile("s_waitcnt vmcnt(0)" ::: "memory");
  __builtin_amdgcn_s_barrier();
  asm volatile("" ::: "memory");

  for (int n = 0; n < 64; n++) {
    const int blk = h * 64 + n;
    const unsigned short* wl = &stage[n & 1][0];
    const unsigned short* kl = &stage[n & 1][8192];
    // (1) issue staging for n+1 first (oldest VMEM ops of this chunk)
    if (n + 1 < 64) stage_wk((n + 1) & 1, n + 1);
    __builtin_amdgcn_sched_barrier(0);
    // (2) prefetch u/adec for n+1 (4 coalesced float4 + 1 scalar; younger than staging)
    float4 ur4n[4];
    float adn = 0.f;
    if (n + 1 < 64) {
      const size_t ub = (size_t)(blk + 1) * 8192;
#pragma unroll
      for (int lt = 0; lt < 4; lt++)
        ur4n[lt] = *(const float4*)(ubuf + ub + (lt * 4 + g) * 512 + (c0 + fr) * 4);
      adn = adecbuf[blk + 1];
    } else {
      const float4 z4 = make_float4(0.f, 0.f, 0.f, 0.f);
#pragma unroll
      for (int lt = 0; lt < 4; lt++) ur4n[lt] = z4;
    }
    __builtin_amdgcn_sched_barrier(0);
    // (3) dump S_n^T -> privA (wave-private) ; export S_n coalesced (d4-packed)
#pragma unroll
    for (int dt = 0; dt < 8; dt++) {
      const int slot = dt * 2 + (g >> 1);
      const ushort4 pv = pack4(acc2[dt][0], acc2[dt][1], acc2[dt][2], acc2[dt][3]);
      *(ushort4*)&privA[fr * 128 + ((slot ^ fsw) << 3) + (g & 1) * 4] = pv;
      *(ushort4*)(STb + (size_t)blk * 16384 + (dt * 4 + g) * 512 + (c0 + fr) * 4) = pv;
    }
    // (4) MFMA1: v_new = u + (-w) @ S  (A from shared staged w, B from privA)
    f32x4 acc1[4];
#pragma unroll
    for (int lt = 0; lt < 4; lt++) {
      f32x4 t;
      t[0] = ur4[lt].x; t[1] = ur4[lt].y; t[2] = ur4[lt].z; t[3] = ur4[lt].w;
      acc1[lt] = t;
    }
#pragma unroll
    for (int ks = 0; ks < 4; ks++) {
      const int kb = ks * 4 + g;
      const bf16x8 b = *(const bf16x8*)&privA[fr * 128 + ((kb ^ fsw) << 3)];
#pragma unroll
      for (int lt = 0; lt < 4; lt++) {
        const bf16x8 a = *(const bf16x8*)&wl[(lt * 16 + fr) * 128 + ((kb ^ fsw) << 3)];
        acc1[lt] = __builtin_amdgcn_mfma_f32_16x16x32_bf16(a, b, acc1[lt], 0, 0, 0);
      }
    }
    // (5) v_new^T -> privB ; export v_new^T coalesced (l4-packed)
#pragma unroll
    for (int lt = 0; lt < 4; lt++) {
      const int slot = lt * 2 + (g >> 1);
      const ushort4 pv = pack4(acc1[lt][0], acc1[lt][1], acc1[lt][2], acc1[lt][3]);
      *(ushort4*)&privB[fr * 64 + ((slot ^ fsw) << 3) + (g & 1) * 4] = pv;
      *(ushort4*)(vtb + (size_t)blk * 8192 + (lt * 4 + g) * 512 + (c0 + fr) * 4) = pv;
    }
    // (6) MFMA2: S = adec*S + kdec^T @ v_new
#pragma unroll
    for (int dt = 0; dt < 8; dt++) {
      acc2[dt][0] *= ad; acc2[dt][1] *= ad; acc2[dt][2] *= ad; acc2[dt][3] *= ad;
    }
#pragma unroll
    for (int ks = 0; ks < 2; ks++) {
      const int kb = ks * 4 + g;
      const bf16x8 b = *(const bf16x8*)&privB[fr * 64 + ((kb ^ fsw) << 3)];
#pragma unroll
      for (int dt = 0; dt < 8; dt++) {
        const bf16x8 a = *(const bf16x8*)&kl[(dt * 16 + fr) * 64 + ((kb ^ fsw) << 3)];
        acc2[dt] = __builtin_amdgcn_mfma_f32_16x16x32_bf16(a, b, acc2[dt], 0, 0, 0);
      }
    }
    // (7) roll prefetched operands
#pragma unroll
    for (int lt = 0; lt < 4; lt++) ur4[lt] = ur4n[lt];
    ad = adn;
    // (8) publish staging: counted vmcnt (youngest 17 = 4 u + 1 adec + 12 export stores)
    if (n + 1 < 64) {
      asm volatile("s_waitcnt lgkmcnt(0)" ::: "memory");
      __builtin_amdgcn_sched_barrier(0);
      asm volatile("s_waitcnt vmcnt(17)" ::: "memory");
      __builtin_amdgcn_sched_barrier(0);
      __builtin_amdgcn_s_barrier();
      __builtin_amdgcn_sched_barrier(0);
    }
  }
}

// ---------------- MFMA o-compute + fused gated RMSNorm (reads d4/l4-packed ST/vt) ----------------
__global__ __launch_bounds__(256) void ocomp_kernel(const unsigned short* __restrict__ qe,
                                                    const unsigned short* __restrict__ STbuf,
                                                    const unsigned short* __restrict__ vtbuf,
                                                    const float* __restrict__ attnbuf,
                                                    const unsigned short* __restrict__ zb,
                                                    const float* __restrict__ onw,
                                                    unsigned short* __restrict__ ob) {
  __shared__ __align__(16) unsigned short STl[128 * 128];  // [c][d]
  __shared__ __align__(16) unsigned short vtl[128 * 64];   // [c][l]
  __shared__ __align__(16) unsigned short ql[64 * 128];    // [i][d]
  __shared__ __align__(16) unsigned short al[64 * 64];     // [i][l]
  const int blk = blockIdx.x;
  const int h = blk >> 6;
  const int n = blk & 63;
  const int t0 = n * 64;
  const int tid = threadIdx.x;
  // ST: d4-packed -> [c][d] swizzled LDS. uint4 o covers (dq = o>>6, cols 2w,2w+1, w = o&63)
#pragma unroll
  for (int q = 0; q < 8; q++) {
    const int o = tid + q * 256;
    const int dq = o >> 6, w = o & 63;
    const uint4 v = *(const uint4*)(STbuf + (size_t)blk * 16384 + (size_t)o * 8);
    const int cA = 2 * w, cB = 2 * w + 1;
    uint2 h0; h0.x = v.x; h0.y = v.y;
    uint2 h1; h1.x = v.z; h1.y = v.w;
    *(uint2*)&STl[cA * 128 + (((dq >> 1) ^ (cA & 7)) << 3) + (dq & 1) * 4] = h0;
    *(uint2*)&STl[cB * 128 + (((dq >> 1) ^ (cB & 7)) << 3) + (dq & 1) * 4] = h1;
  }
  // vt: l4-packed -> [c][l] swizzled LDS
#pragma unroll
  for (int q = 0; q < 4; q++) {
    const int o = tid + q * 256;
    const int lq = o >> 6, w = o & 63;
    const uint4 v = *(const uint4*)(vtbuf + (size_t)blk * 8192 + (size_t)o * 8);
    const int cA = 2 * w, cB = 2 * w + 1;
    uint2 h0; h0.x = v.x; h0.y = v.y;
    uint2 h1; h1.x = v.z; h1.y = v.w;
    *(uint2*)&vtl[cA * 64 + (((lq >> 1) ^ (cA & 7)) << 3) + (lq & 1) * 4] = h0;
    *(uint2*)&vtl[cB * 64 + (((lq >> 1) ^ (cB & 7)) << 3) + (lq & 1) * 4] = h1;
  }
#pragma unroll
  for (int q = 0; q < 4; q++) {
    const int idx = tid + q * 256;
    const int i = idx >> 4, dg = idx & 15;
    *(uint4*)&ql[i * 128 + ((dg ^ (i & 7)) << 3)] =
        *(const uint4*)(qe + (size_t)(t0 + i) * 2048 + h * 128 + dg * 8);
  }
#pragma unroll
  for (int q = 0; q < 4; q++) {
    const int idx = tid + q * 256;
    const int i = idx >> 4, l4 = (idx & 15) * 4;
    const float4 v = *(const float4*)(attnbuf + (size_t)blk * 4096 + i * 64 + l4);
    *(ushort4*)&al[i * 64 + (((l4 >> 3) ^ (i & 7)) << 3) + (l4 & 7)] =
        pack4(v.x, v.y, v.z, v.w);
  }
  __syncthreads();
  const int ln = tid & 63;
  const int wv = tid >> 6;
  const int fr = ln & 15;
  const int g = ln >> 4;
  const int i0 = wv * 16;
  f32x4 acc[8];
  const f32x4 zero = {0.f, 0.f, 0.f, 0.f};
#pragma unroll
  for (int nt = 0; nt < 8; nt++) acc[nt] = zero;
#pragma unroll
  for (int ks = 0; ks < 4; ks++) {
    const int kb = ks * 4 + g;
    const int ar = i0 + fr;
    const bf16x8 a = *(const bf16x8*)&ql[ar * 128 + ((kb ^ (ar & 7)) << 3)];
#pragma unroll
    for (int nt = 0; nt < 8; nt++) {
      const int c = nt * 16 + fr;
      const bf16x8 b = *(const bf16x8*)&STl[c * 128 + ((kb ^ (c & 7)) << 3)];
      acc[nt] = __builtin_amdgcn_mfma_f32_16x16x32_bf16(a, b, acc[nt], 0, 0, 0);
    }
  }
#pragma unroll
  for (int ks = 0; ks < 2; ks++) {
    const int kb = ks * 4 + g;
    const int ar = i0 + fr;
    const bf16x8 a = *(const bf16x8*)&al[ar * 64 + ((kb ^ (ar & 7)) << 3)];
#pragma unroll
    for (int nt = 0; nt < 8; nt++) {
      const int c = nt * 16 + fr;
      const bf16x8 b = *(const bf16x8*)&vtl[c * 64 + ((kb ^ (c & 7)) << 3)];
      acc[nt] = __builtin_amdgcn_mfma_f32_16x16x32_bf16(a, b, acc[nt], 0, 0, 0);
    }
  }
  float s0 = 0.f, s1 = 0.f, s2 = 0.f, s3 = 0.f;
#pragma unroll
  for (int nt = 0; nt < 8; nt++) {
    s0 += acc[nt][0] * acc[nt][0];
    s1 += acc[nt][1] * acc[nt][1];
    s2 += acc[nt][2] * acc[nt][2];
    s3 += acc[nt][3] * acc[nt][3];
  }
#pragma unroll
  for (int m = 1; m < 16; m <<= 1) {
    s0 += __shfl_xor(s0, m);
    s1 += __shfl_xor(s1, m);
    s2 += __shfl_xor(s2, m);
    s3 += __shfl_xor(s3, m);
  }
  float rn[4];
  rn[0] = rsqrtf(s0 * (1.0f / 128.0f) + 1e-5f);
  rn[1] = rsqrtf(s1 * (1.0f / 128.0f) + 1e-5f);
  rn[2] = rsqrtf(s2 * (1.0f / 128.0f) + 1e-5f);
  rn[3] = rsqrtf(s3 * (1.0f / 128.0f) + 1e-5f);
#pragma unroll
  for (int nt = 0; nt < 8; nt++) {
    const int c = nt * 16 + fr;
    const float wn = onw[c];
#pragma unroll
    for (int r = 0; r < 4; r++) {
      const size_t off = (size_t)(t0 + i0 + g * 4 + r) * 2048 + h * 128 + c;
      const float zz = siluf(bf2f(zb[off]));
      ob[off] = f2bf(acc[nt][r] * rn[r] * wn * zz);
    }
  }
}

extern "C" void kernel_launch(void* const* d_in, const int* in_sizes, int n_in,
                              void* d_out, int out_size, void* d_ws, size_t ws_size,
                              hipStream_t stream) {
  (void)in_sizes; (void)n_in; (void)out_size;
  const float* x        = (const float*)d_in[0];
  const float* mask     = (const float*)d_in[1];
  const float* ln1_w    = (const float*)d_in[2];
  const float* qkvz_w   = (const float*)d_in[3];
  const float* ba_w     = (const float*)d_in[4];
  const float* conv_w   = (const float*)d_in[5];
  const float* A_log    = (const float*)d_in[6];
  const float* dt_bias  = (const float*)d_in[7];
  const float* o_norm_w = (const float*)d_in[8];
  const float* out_w    = (const float*)d_in[9];
  const float* ln2_w    = (const float*)d_in[10];
  const float* gate_w   = (const float*)d_in[11];
  const float* up_w     = (const float*)d_in[12];
  const float* down_w   = (const float*)d_in[13];
  float* out = (float*)d_out;

  const size_t NEED_BYTES = (size_t)75825152 * 4;
  if (ws_size < NEED_BYTES) return;

  float* ws = (float*)d_ws;
  float* mixed_buf = ws;
  unsigned short* Wg = (unsigned short*)ws;
  unsigned short* Wu = (unsigned short*)(ws + 8388608);
  unsigned short* Wd = (unsigned short*)(ws + 16777216);
  unsigned short* qkvz_bf = (unsigned short*)(ws + 25165824);
  float* u_buf = ws + 25165824;
  unsigned short* wbf = (unsigned short*)(ws + 33554432);
  unsigned short* kdT = (unsigned short*)(ws + 37748736);
  unsigned short* gate_bf = (unsigned short*)(ws + 25165824);
  unsigned short* z_bf = (unsigned short*)(ws + 41943040);
  float* h_buf = ws + 46137344;
  float* a_buf = ws + 46137344;
  unsigned short* vt_buf = (unsigned short*)(ws + 46137344);
  float* t_buf = ws + 50331648;
  unsigned short* qe_bf = (unsigned short*)(ws + 50331648);  // after pre_uw, t_buf is dead
  unsigned short* h_bf  = (unsigned short*)(ws + 54525952);
  unsigned short* ob    = (unsigned short*)(ws + 54525952);
  unsigned short* h2_bf = (unsigned short*)(ws + 54525952);
  float* attn_buf = ws + 58720256;
  unsigned short* Wq = (unsigned short*)(ws + 62914560);
  unsigned short* ST_buf = (unsigned short*)(ws + 62914560);
  unsigned short* Wo = (unsigned short*)(ws + 71303168);
  float* ba_buf   = ws + 73400320;
  float* beta_buf = ws + 73531392;
  float* g_buf    = ws + 73596928;
  float* gcs_buf  = ws + 73662464;
  float* edk_buf  = ws + 73728000;
  float* egq_buf  = ws + 73793536;
  float* adec_buf = ws + 73859072;

  rmsnorm_kernel<1><<<4096, 256, 0, stream>>>(x, ln1_w, h_buf, h_bf);
  f2b_kernel<<<8192, 256, 0, stream>>>(qkvz_w, Wq);
  gemm256_kernel<0, 128, 256><<<1024, 512, 0, stream>>>(h_bf, Wq, nullptr, qkvz_bf, 4096, 8192, 2048);
  ba_gemm_kernel<<<4096, 256, 0, stream>>>(h_buf, ba_w, ba_buf);
  zcopy_kernel<<<4096, 256, 0, stream>>>(qkvz_bf, z_bf);
  conv_silu_kernel<<<24576, 256, 0, stream>>>(qkvz_bf, conv_w, mask, mixed_buf);
  l2norm_kernel<<<32768, 256, 0, stream>>>(mixed_buf);
  beta_g_kernel<<<256, 256, 0, stream>>>(ba_buf, A_log, dt_bias, mask, beta_buf, g_buf);
  gcs_kernel<<<4, 256, 0, stream>>>(g_buf, gcs_buf, edk_buf, egq_buf, adec_buf);
  pre_attn_kernel<<<1024, 256, 0, stream>>>(mixed_buf, gcs_buf, beta_buf, a_buf, attn_buf);
  pre_solve_kernel<<<1024, 256, 0, stream>>>(a_buf, beta_buf, t_buf);
  pre_uw_kernel<<<1024, 256, 0, stream>>>(mixed_buf, t_buf, gcs_buf, u_buf, wbf);
  ktrans_kernel<<<1024, 256, 0, stream>>>(mixed_buf, edk_buf, egq_buf, kdT, qe_bf);
  // column-decomposed MFMA scan (16 blocks, 8 waves) + fused f2b/copy (15360 blocks)
  scan_kernel<<<15376, 512, 0, stream>>>(wbf, kdT, u_buf, adec_buf, ST_buf, vt_buf,
                                         gate_w, up_w, down_w, out_w, x,
                                         Wg, Wu, Wd, Wo, out);
  ocomp_kernel<<<1024, 256, 0, stream>>>(qe_bf, ST_buf, vt_buf, attn_buf,
                                         z_bf, o_norm_w, ob);
  gemm256_kernel<1, 128, 128><<<512, 512, 0, stream>>>(ob, Wo, out, nullptr, 4096, 2048, 2048);
  rmsnorm_kernel<2><<<4096, 256, 0, stream>>>(out, ln2_w, nullptr, h2_bf);
  gemm256_kernel<0, 128, 256><<<1024, 512, 0, stream>>>(h2_bf, Wg, nullptr, gate_bf, 4096, 8192, 2048);
  gemm256_kernel<2, 128, 256><<<1024, 512, 0, stream>>>(h2_bf, Wu, nullptr, gate_bf, 4096, 8192, 2048);
  gemm256_kernel<1, 128, 128><<<512, 512, 0, stream>>>(gate_bf, Wd, out, nullptr, 4096, 2048, 8192);
}

// Round 14
// 1374.836 us; speedup vs baseline: 1.2710x; 1.0169x over previous
//
#include <hip/hip_runtime.h>
#include <math.h>

#define T_LEN 4096
#define DMODEL 2048
#define NH 16
#define CQKV 6144
#define CQKVZ 8192
#define SCALE 0.08838834764831845f   // 128^-0.5

using bf16x8 = __attribute__((ext_vector_type(8))) short;
using f32x4  = __attribute__((ext_vector_type(4))) float;

__device__ __forceinline__ float siluf(float x) { return x / (1.0f + __expf(-x)); }

__device__ __forceinline__ unsigned short f2bf(float f) {  // RNE
  unsigned int u = __float_as_uint(f);
  u = (u + 0x7FFFu + ((u >> 16) & 1u)) >> 16;
  return (unsigned short)u;
}
__device__ __forceinline__ float bf2f(unsigned short u) {
  return __uint_as_float(((unsigned int)u) << 16);
}
__device__ __forceinline__ ushort4 pack4(float a, float b, float c, float d) {
  ushort4 r; r.x = f2bf(a); r.y = f2bf(b); r.z = f2bf(c); r.w = f2bf(d); return r;
}

// async global->LDS, 16 bytes per lane; LDS dest is wave-uniform base (+ lane*16 implicit)
__device__ __forceinline__ void gl_lds16(const unsigned short* g, unsigned short* l) {
  __builtin_amdgcn_global_load_lds(
      (const __attribute__((address_space(1))) void*)g,
      (__attribute__((address_space(3))) void*)l, 16, 0, 0);
}

// ---------------- RMSNorm over D=2048; MODE: 1 = f32+bf16, 2 = bf16 only ----------------
template<int MODE>
__global__ __launch_bounds__(256) void rmsnorm_kernel(const float* __restrict__ x,
                                                      const float* __restrict__ w,
                                                      float* __restrict__ outf,
                                                      unsigned short* __restrict__ outb) {
  const int t = blockIdx.x;
  const int tid = threadIdx.x;
  const float4* xr = (const float4*)(x + (size_t)t * DMODEL);
  float4 v0 = xr[tid];
  float4 v1 = xr[tid + 256];
  float s = v0.x*v0.x + v0.y*v0.y + v0.z*v0.z + v0.w*v0.w
          + v1.x*v1.x + v1.y*v1.y + v1.z*v1.z + v1.w*v1.w;
#pragma unroll
  for (int off = 32; off > 0; off >>= 1) s += __shfl_down(s, off);
  __shared__ float red[4];
  if ((tid & 63) == 0) red[tid >> 6] = s;
  __syncthreads();
  const float tot = red[0] + red[1] + red[2] + red[3];
  const float r = rsqrtf(tot * (1.0f / DMODEL) + 1e-5f);
  const float4* wr = (const float4*)w;
  const float4 w0 = wr[tid], w1 = wr[tid + 256];
  float4 o0, o1;
  o0.x = v0.x*r*w0.x; o0.y = v0.y*r*w0.y; o0.z = v0.z*r*w0.z; o0.w = v0.w*r*w0.w;
  o1.x = v1.x*r*w1.x; o1.y = v1.y*r*w1.y; o1.z = v1.z*r*w1.z; o1.w = v1.w*r*w1.w;
  if (MODE == 1) {
    float4* orow = (float4*)(outf + (size_t)t * DMODEL);
    orow[tid] = o0;
    orow[tid + 256] = o1;
  }
  ushort4* brow = (ushort4*)(outb + (size_t)t * DMODEL);
  brow[tid] = pack4(o0.x, o0.y, o0.z, o0.w);
  brow[tid + 256] = pack4(o1.x, o1.y, o1.z, o1.w);
}

// ---------------- fp32 -> bf16 bulk convert ----------------
__global__ __launch_bounds__(256) void f2b_kernel(const float* __restrict__ in,
                                                  unsigned short* __restrict__ out) {
  const size_t i = (size_t)blockIdx.x * 256 + threadIdx.x;
  const float4 a = ((const float4*)in)[2 * i];
  const float4 b = ((const float4*)in)[2 * i + 1];
  ((ushort4*)out)[2 * i] = pack4(a.x, a.y, a.z, a.w);
  ((ushort4*)out)[2 * i + 1] = pack4(b.x, b.y, b.z, b.w);
}

// ---------------- 8-phase-style 256x256 bf16 MFMA GEMM (fat shapes): C = A @ B^T ------------
// BK=64 as 2 k-halves; 8 LDS slots of 16KB (2 tiles x {Ak0,Ak1,Bk0,Bk1}); 4 phases/tile,
// each phase: {frag ds_reads, stage ONE half (2 gl_lds/wave), barrier, setprio, 16 MFMA,
// setprio, barrier}; boundary counted vmcnt(4) (vmcnt(0) only at tail). Swizzle:
// phys_slot = slot ^ ((row>>1)&3), conflict-free ds_read_b128; source pre-inverse-swizzled.
template<int EPI>
__global__ __launch_bounds__(512, 2) void gemm8p_kernel(const unsigned short* __restrict__ A,
                                                        const unsigned short* __restrict__ B,
                                                        float* __restrict__ Cf,
                                                        unsigned short* __restrict__ Cb,
                                                        int M, int N, int K) {
  __shared__ __align__(16) unsigned short lds[8][8192];   // 8 slots x 16 KB
  const int nbm = M >> 8, nbn = N >> 8, nwg = nbm * nbn;
  const int nt = K >> 6;   // K-tiles of 64
  int bmi, bni;
  {
    const int bid = blockIdx.x;
    const int cpx = nwg >> 3;
    int sc = 1;
    while (sc * sc < cpx) sc <<= 1;
    if (sc * sc > cpx) sc >>= 1;
    const int scn = (sc > 0) ? (cpx / sc) : 0;
    if ((nwg & 7) == 0 && sc > 0 && sc * scn == cpx && (nbm % sc) == 0 && (nbn % scn) == 0) {
      const int chunk = bid & 7, widx = bid >> 3;
      const int regc = nbn / scn;
      bmi = (chunk / regc) * sc + widx / scn;
      bni = (chunk % regc) * scn + widx % scn;
    } else {
      bmi = bid / nbn; bni = bid % nbn;
    }
  }
  const int bm = bmi << 8, bn = bni << 8;
  const int tid = threadIdx.x;
  const int wv = tid >> 6, ln = tid & 63;
  const int fr = ln & 15, qq = ln >> 4;
  const int wm = wv >> 2, wn = wv & 3;           // wave tile: rows wm*128, cols wn*64
  const int rsw = (fr >> 1) & 3;                 // read swizzle term
  const int s_sl = (ln & 3) ^ ((ln >> 3) & 3);   // staging source slot (inverse swizzle)

  f32x4 acc[8][4];
  const f32x4 zero = {0.f, 0.f, 0.f, 0.f};
#pragma unroll
  for (int mf = 0; mf < 8; mf++)
#pragma unroll
    for (int nf = 0; nf < 4; nf++) acc[mf][nf] = zero;

  bf16x8 afr[8], bfr[2];

  // stage one half: part 0=Ak0, 1=Ak1, 2=Bk0, 3=Bk1 of tile t2 -> slot ((t2&1)<<2)|part
  auto stage_half = [&](int t2, int part) {
    if (t2 >= nt) return;
    const unsigned short* Mat = (part >= 2) ? B : A;
    const int gb = (part >= 2) ? bn : bm;
    const int kk = part & 1;
    const int slot = ((t2 & 1) << 2) | part;
    const int k0 = t2 * 64 + kk * 32;
#pragma unroll
    for (int q = 0; q < 2; q++) {
      gl_lds16(Mat + (size_t)(gb + wv * 32 + q * 16 + (ln >> 2)) * K + k0 + s_sl * 8,
               &lds[slot][(wv * 32 + q * 16) * 32]);
    }
  };
  auto lda = [&](int tb, int kk) {
#pragma unroll
    for (int mf = 0; mf < 8; mf++) {
      const int ar = wm * 128 + mf * 16 + fr;
      afr[mf] = *(const bf16x8*)&lds[tb | kk][ar * 32 + ((qq ^ rsw) << 3)];
    }
  };
  auto ldb = [&](int tb, int kk, int nh) {
#pragma unroll
    for (int nj = 0; nj < 2; nj++) {
      const int br = wn * 64 + (nh * 2 + nj) * 16 + fr;
      bfr[nj] = *(const bf16x8*)&lds[tb | (2 + kk)][br * 32 + ((qq ^ rsw) << 3)];
    }
  };
  auto mm = [&](int nh) {
    __builtin_amdgcn_s_setprio(1);
#pragma unroll
    for (int mf = 0; mf < 8; mf++)
#pragma unroll
      for (int nj = 0; nj < 2; nj++)
        acc[mf][nh * 2 + nj] =
            __builtin_amdgcn_mfma_f32_16x16x32_bf16(afr[mf], bfr[nj], acc[mf][nh * 2 + nj], 0, 0, 0);
    __builtin_amdgcn_s_setprio(0);
  };

  // prologue: tile0 all 4 halves, tile1 k0 halves; wait tile0 (counted), publish
  stage_half(0, 0); stage_half(0, 2); stage_half(0, 1); stage_half(0, 3);
  stage_half(1, 0); stage_half(1, 2);
  asm volatile("s_waitcnt vmcnt(4)" ::: "memory");
  __builtin_amdgcn_s_barrier();
  asm volatile("" ::: "memory");

  for (int t = 0; t < nt; t++) {
    const int tb = (t & 1) << 2;
    // phase 0: (k0, N0); stage Ak1(t+1)
    lda(tb, 0); ldb(tb, 0, 0);
    stage_half(t + 1, 1);
    __builtin_amdgcn_s_barrier();
    mm(0);
    __builtin_amdgcn_s_barrier();
    // phase 1: (k0, N1); stage Bk1(t+1)
    ldb(tb, 0, 1);
    stage_half(t + 1, 3);
    __builtin_amdgcn_s_barrier();
    mm(1);
    __builtin_amdgcn_s_barrier();
    // phase 2: (k1, N1); stage Ak0(t+2)
    lda(tb, 1); ldb(tb, 1, 1);
    stage_half(t + 2, 0);
    __builtin_amdgcn_s_barrier();
    mm(1);
    __builtin_amdgcn_s_barrier();
    // phase 3: (k1, N0); stage Bk0(t+2)
    ldb(tb, 1, 0);
    stage_half(t + 2, 2);
    __builtin_amdgcn_s_barrier();
    mm(0);
    // tile boundary: counted vmcnt — next tile's 4 halves are older than newest in flight
    if (t + 1 < nt) {
      asm volatile("s_waitcnt lgkmcnt(0)" ::: "memory");
      __builtin_amdgcn_sched_barrier(0);
      if (t == nt - 2) {
        asm volatile("s_waitcnt vmcnt(0)" ::: "memory");
      } else {
        asm volatile("s_waitcnt vmcnt(4)" ::: "memory");
      }
      __builtin_amdgcn_sched_barrier(0);
      __builtin_amdgcn_s_barrier();
      __builtin_amdgcn_sched_barrier(0);
    }
  }

  const int cm4 = qq * 4;
#pragma unroll
  for (int mf = 0; mf < 8; mf++) {
#pragma unroll
    for (int nf = 0; nf < 4; nf++) {
#pragma unroll
      for (int r = 0; r < 4; r++) {
        const int grow = bm + wm * 128 + mf * 16 + cm4 + r;
        const int gcol = bn + wn * 64 + nf * 16 + fr;
        const size_t off = (size_t)grow * N + gcol;
        const float v = acc[mf][nf][r];
        if (EPI == 0) {
          Cb[off] = f2bf(v);
        } else if (EPI == 1) {
          Cf[off] += v;
        } else {
          Cb[off] = f2bf(siluf(bf2f(Cb[off])) * v);
        }
      }
    }
  }
}

// ---------------- pipelined bf16 MFMA GEMM (thin shapes): C[M][N] = A[M][K] * B[N][K]^T -----
// BM x BN block (8 waves, 64x64 per-wave tile), BK=32, 3 LDS buffers, counted vmcnt.
template<int EPI, int BM, int BN>
__global__ __launch_bounds__(512, 4) void gemm256_kernel(const unsigned short* __restrict__ A,
                                                         const unsigned short* __restrict__ B,
                                                         float* __restrict__ Cf,
                                                         unsigned short* __restrict__ Cb,
                                                         int M, int N, int K) {
  constexpr int MI = 4;
  constexpr int NI = BN / 64;
  constexpr int AW = BM / 128;
  constexpr int BW = BN / 128;
  __shared__ __align__(16) unsigned short lds[3][(BM + BN) * 32];
  const int nbm = M / BM, nbn = N / BN, nwg = nbm * nbn;
  const int nt = K >> 5;
  int bmi, bni;
  {
    const int bid = blockIdx.x;
    const int cpx = nwg >> 3;
    int sc = 1;
    while (sc * sc < cpx) sc <<= 1;
    if (sc * sc > cpx) sc >>= 1;
    const int scn = (sc > 0) ? (cpx / sc) : 0;
    if ((nwg & 7) == 0 && sc > 0 && sc * scn == cpx && (nbm % sc) == 0 && (nbn % scn) == 0) {
      const int chunk = bid & 7, widx = bid >> 3;
      const int regc = nbn / scn;
      bmi = (chunk / regc) * sc + widx / scn;
      bni = (chunk % regc) * scn + widx % scn;
    } else {
      bmi = bid / nbn; bni = bid % nbn;
    }
  }
  const int bm = bmi * BM, bn = bni * BN;
  const int tid = threadIdx.x;
  const int wv = tid >> 6, ln = tid & 63;
  const int fr = ln & 15, qq = ln >> 4;
  const int wm = wv >> 2, wn = wv & 3;
  const int ra0 = wm * 64, rb0 = wn * (BN / 4);
  const int lrow = ln >> 2;
  const int lslot = ln & 3;

  f32x4 acc[MI][NI];
  const f32x4 zero = {0.f, 0.f, 0.f, 0.f};
#pragma unroll
  for (int mi = 0; mi < MI; mi++)
#pragma unroll
    for (int ni = 0; ni < NI; ni++) acc[mi][ni] = zero;

  auto stage = [&](int buf, int t) {
    const int k0 = t << 5;
#pragma unroll
    for (int q = 0; q < AW; q++) {
      const int lr = q * 128 + wv * 16 + lrow;
      const int sl = lslot ^ ((lr >> 1) & 3);
      gl_lds16(A + (size_t)(bm + lr) * K + k0 + sl * 8,
               &lds[buf][(q * 128 + wv * 16) * 32]);
    }
#pragma unroll
    for (int q = 0; q < BW; q++) {
      const int lr = q * 128 + wv * 16 + lrow;
      const int sl = lslot ^ ((lr >> 1) & 3);
      gl_lds16(B + (size_t)(bn + lr) * K + k0 + sl * 8,
               &lds[buf][BM * 32 + (q * 128 + wv * 16) * 32]);
    }
  };

  stage(0, 0);
  stage(1, 1);
  asm volatile("s_waitcnt vmcnt(%0)" :: "i"(AW + BW) : "memory");
  __builtin_amdgcn_s_barrier();
  asm volatile("" ::: "memory");

  for (int t = 0; t < nt; t++) {
    const int cb = t % 3;
    const int b2 = (t + 2) % 3;
    const unsigned short* lA = &lds[cb][0];
    const unsigned short* lB = &lds[cb][BM * 32];
    bf16x8 bfr[NI];
#pragma unroll
    for (int ni = 0; ni < NI; ni++) {
      const int r = rb0 + ni * 16 + fr;
      bfr[ni] = *(const bf16x8*)&lB[r * 32 + ((qq ^ ((r >> 1) & 3)) << 3)];
    }
    bf16x8 afr[MI];
#pragma unroll
    for (int mi = 0; mi < MI; mi++) {
      const int r = ra0 + mi * 16 + fr;
      afr[mi] = *(const bf16x8*)&lA[r * 32 + ((qq ^ ((r >> 1) & 3)) << 3)];
    }
    if (t + 2 < nt) stage(b2, t + 2);
    __builtin_amdgcn_s_setprio(1);
#pragma unroll
    for (int mi = 0; mi < MI; mi++)
#pragma unroll
      for (int ni = 0; ni < NI; ni++)
        acc[mi][ni] = __builtin_amdgcn_mfma_f32_16x16x32_bf16(afr[mi], bfr[ni], acc[mi][ni], 0, 0, 0);
    __builtin_amdgcn_s_setprio(0);
    if (t + 1 < nt) {
      asm volatile("s_waitcnt lgkmcnt(0)" ::: "memory");
      if (t + 2 < nt) {
        asm volatile("s_waitcnt vmcnt(%0)" :: "i"(AW + BW) : "memory");
      } else {
        asm volatile("s_waitcnt vmcnt(0)" ::: "memory");
      }
      __builtin_amdgcn_s_barrier();
      asm volatile("" ::: "memory");
    }
  }

  const int cm4 = qq * 4;
#pragma unroll
  for (int mi = 0; mi < MI; mi++) {
#pragma unroll
    for (int ni = 0; ni < NI; ni++) {
#pragma unroll
      for (int r = 0; r < 4; r++) {
        const int grow = bm + ra0 + mi * 16 + cm4 + r;
        const int gcol = bn + rb0 + ni * 16 + fr;
        const size_t off = (size_t)grow * N + gcol;
        const float v = acc[mi][ni][r];
        if (EPI == 0) {
          Cb[off] = f2bf(v);
        } else if (EPI == 1) {
          Cf[off] += v;
        } else {
          Cb[off] = f2bf(siluf(bf2f(Cb[off])) * v);
        }
      }
    }
  }
}

// ---------------- ba = h @ ba_w^T ----------------
__global__ __launch_bounds__(256) void ba_gemm_kernel(const float* __restrict__ h_in,
                                                      const float* __restrict__ ba_w,
                                                      float* __restrict__ ba_out) {
  __shared__ __align__(16) float hl[2048];
  __shared__ float red[32][9];
  const int t = blockIdx.x;
  const int tid = threadIdx.x;
  const float4* hr = (const float4*)(h_in + (size_t)t * DMODEL);
  ((float4*)hl)[tid] = hr[tid];
  ((float4*)hl)[tid + 256] = hr[tid + 256];
  __syncthreads();
  const int c = tid & 31;
  const int p = tid >> 5;
  const float* wrow = ba_w + (size_t)c * DMODEL + p * 256;
  const float* hrow = hl + p * 256;
  float s = 0.f;
#pragma unroll 8
  for (int k = 0; k < 256; k++) s += hrow[k] * wrow[k];
  red[c][p] = s;
  __syncthreads();
  if (tid < 32) {
    float tot = 0.f;
#pragma unroll
    for (int q = 0; q < 8; q++) tot += red[tid][q];
    ba_out[(size_t)t * 32 + tid] = tot;
  }
}

// ---------------- extract z columns from bf16 qkvz ----------------
__global__ __launch_bounds__(256) void zcopy_kernel(const unsigned short* __restrict__ qkvz,
                                                    unsigned short* __restrict__ z) {
  const int idx = blockIdx.x * 256 + threadIdx.x;
  const int t = idx >> 8;
  const int c8 = (idx & 255) * 8;
  *(uint4*)(z + (size_t)t * 2048 + c8) =
      *(const uint4*)(qkvz + (size_t)t * CQKVZ + CQKV + c8);
}

// ---------------- causal depthwise conv (K=4) + SiLU; bf16 in, fp32 out ----------------
__global__ __launch_bounds__(256) void conv_silu_kernel(const unsigned short* __restrict__ qkvz,
                                                        const float* __restrict__ conv_w,
                                                        const float* __restrict__ mask,
                                                        float* __restrict__ mixed) {
  const int idx = blockIdx.x * 256 + threadIdx.x;
  const int c4 = (idx % 1536) * 4;
  const int t = idx / 1536;
  const float4 w0 = *(const float4*)(conv_w + (size_t)c4 * 4);
  const float4 w1 = *(const float4*)(conv_w + (size_t)c4 * 4 + 4);
  const float4 w2 = *(const float4*)(conv_w + (size_t)c4 * 4 + 8);
  const float4 w3 = *(const float4*)(conv_w + (size_t)c4 * 4 + 12);
  const float wj0[4] = {w0.x, w0.y, w0.z, w0.w};
  const float wj1[4] = {w1.x, w1.y, w1.z, w1.w};
  const float wj2[4] = {w2.x, w2.y, w2.z, w2.w};
  const float wj3[4] = {w3.x, w3.y, w3.z, w3.w};
  float4 acc = make_float4(0.f, 0.f, 0.f, 0.f);
#pragma unroll
  for (int j = 0; j < 4; j++) {
    const int tt = t - 3 + j;
    if (tt < 0) continue;
    const float m = mask[tt];
    const ushort4 xb = *(const ushort4*)(qkvz + (size_t)tt * CQKVZ + c4);
    acc.x += bf2f(xb.x) * m * wj0[j];
    acc.y += bf2f(xb.y) * m * wj1[j];
    acc.z += bf2f(xb.z) * m * wj2[j];
    acc.w += bf2f(xb.w) * m * wj3[j];
  }
  acc.x = siluf(acc.x); acc.y = siluf(acc.y); acc.z = siluf(acc.z); acc.w = siluf(acc.w);
  *(float4*)(mixed + (size_t)t * CQKV + c4) = acc;
}

// ---------------- l2norm over Dk=128 for q,k heads (in place, fp32) ----------------
__global__ __launch_bounds__(256) void l2norm_kernel(float* __restrict__ mixed) {
  const int r = blockIdx.x * 4 + (threadIdx.x >> 6);
  const int lane = threadIdx.x & 63;
  const int t = r >> 5;
  const int hh = r & 31;
  float* p = mixed + (size_t)t * CQKV + hh * 128 + lane * 2;
  float2 v = *(float2*)p;
  float s = v.x * v.x + v.y * v.y;
#pragma unroll
  for (int off = 32; off > 0; off >>= 1) s += __shfl_down(s, off);
  s = __shfl(s, 0);
  const float rn = rsqrtf(s + 1e-6f);
  v.x *= rn; v.y *= rn;
  *(float2*)p = v;
}

// ---------------- beta, g ----------------
__global__ __launch_bounds__(256) void beta_g_kernel(const float* __restrict__ ba,
                                                     const float* __restrict__ A_log,
                                                     const float* __restrict__ dt_bias,
                                                     const float* __restrict__ mask,
                                                     float* __restrict__ beta,
                                                     float* __restrict__ g) {
  const int idx = blockIdx.x * 256 + threadIdx.x;
  const int t = idx >> 4;
  const int h = idx & 15;
  const float b = ba[(size_t)t * 32 + h];
  const float a = ba[(size_t)t * 32 + 16 + h];
  const float m = mask[t];
  beta[idx] = m / (1.0f + expf(-b));
  const float xx = a + dt_bias[h];
  const float sp = (xx > 20.0f) ? xx : log1pf(expf(xx));
  g[idx] = -expf(A_log[h]) * sp * m;
}

// ---------------- per-chunk cumsum of g + decay factors ----------------
__global__ __launch_bounds__(256) void gcs_kernel(const float* __restrict__ g,
                                                  float* __restrict__ gcsbuf,
                                                  float* __restrict__ edkbuf,
                                                  float* __restrict__ egqbuf,
                                                  float* __restrict__ adecbuf) {
  const int idx = blockIdx.x * 256 + threadIdx.x;  // chunk id = h*64 + n
  if (idx >= 1024) return;
  const int h = idx >> 6;
  const int n = idx & 63;
  const int t0 = n * 64;
  float s = 0.f;
  for (int i = 0; i < 64; i++) {
    s += g[(size_t)(t0 + i) * NH + h];
    gcsbuf[(size_t)idx * 64 + i] = s;
  }
  const float glast = s;
  adecbuf[idx] = __expf(glast);
  for (int i = 0; i < 64; i++) {
    const float gi = gcsbuf[(size_t)idx * 64 + i];
    edkbuf[(size_t)idx * 64 + i] = __expf(glast - gi);
    egqbuf[(size_t)idx * 64 + i] = __expf(gi) * SCALE;
  }
}

// ---------------- per-chunk: A=(k_beta k^T)*decay (strict lower), attn=(q k^T)*decay*scale ----------------
__global__ __launch_bounds__(256) void pre_attn_kernel(const float* __restrict__ mixed,
                                                       const float* __restrict__ gcsbuf,
                                                       const float* __restrict__ betabuf,
                                                       float* __restrict__ abuf,
                                                       float* __restrict__ attnbuf) {
  __shared__ __align__(16) float kl[64][132];
  __shared__ float gcs_s[64];
  __shared__ float betal[64];
  const int blk = blockIdx.x;
  const int h = blk >> 6;
  const int n = blk & 63;
  const int t0 = n * 64;
  const int tid = threadIdx.x;
  if (tid < 64) {
    gcs_s[tid] = gcsbuf[(size_t)blk * 64 + tid];
    betal[tid] = betabuf[(size_t)(t0 + tid) * NH + h];
  }
#pragma unroll
  for (int rep = 0; rep < 8; rep++) {
    const int lin = rep * 256 + tid;
    const int i = lin >> 5;
    const int d = (lin & 31) * 4;
    const float4 kv = *(const float4*)(mixed + (size_t)(t0 + i) * CQKV + 2048 + h * 128 + d);
    *(float4*)&kl[i][d] = kv;
  }
  __syncthreads();
  const int cj = tid & 15;
  const int ri = tid >> 4;
  const int i0 = ri * 4, j0 = cj * 4;
  float accA[4][4], accQ[4][4];
#pragma unroll
  for (int a = 0; a < 4; a++)
#pragma unroll
    for (int b = 0; b < 4; b++) { accA[a][b] = 0.f; accQ[a][b] = 0.f; }
  const float* qbase = mixed + (size_t)t0 * CQKV + h * 128;
#pragma unroll 4
  for (int d = 0; d < 128; d++) {
    const float kj0 = kl[j0][d], kj1 = kl[j0 + 1][d], kj2 = kl[j0 + 2][d], kj3 = kl[j0 + 3][d];
#pragma unroll
    for (int a = 0; a < 4; a++) {
      const float ka = kl[i0 + a][d];
      const float qa = qbase[(size_t)(i0 + a) * CQKV + d];
      accA[a][0] += ka * kj0; accA[a][1] += ka * kj1; accA[a][2] += ka * kj2; accA[a][3] += ka * kj3;
      accQ[a][0] += qa * kj0; accQ[a][1] += qa * kj1; accQ[a][2] += qa * kj2; accQ[a][3] += qa * kj3;
    }
  }
#pragma unroll
  for (int a = 0; a < 4; a++) {
    const int i = i0 + a;
    const float gi = gcs_s[i];
    const float bi = betal[i];
    float4 Av, Qv;
    float dec;
    dec = __expf(fminf(gi - gcs_s[j0 + 0], 0.f));
    Av.x = (i > j0 + 0) ? accA[a][0] * bi * dec : 0.f;
    Qv.x = (i >= j0 + 0) ? accQ[a][0] * dec * SCALE : 0.f;
    dec = __expf(fminf(gi - gcs_s[j0 + 1], 0.f));
    Av.y = (i > j0 + 1) ? accA[a][1] * bi * dec : 0.f;
    Qv.y = (i >= j0 + 1) ? accQ[a][1] * dec * SCALE : 0.f;
    dec = __expf(fminf(gi - gcs_s[j0 + 2], 0.f));
    Av.z = (i > j0 + 2) ? accA[a][2] * bi * dec : 0.f;
    Qv.z = (i >= j0 + 2) ? accQ[a][2] * dec * SCALE : 0.f;
    dec = __expf(fminf(gi - gcs_s[j0 + 3], 0.f));
    Av.w = (i > j0 + 3) ? accA[a][3] * bi * dec : 0.f;
    Qv.w = (i >= j0 + 3) ? accQ[a][3] * dec * SCALE : 0.f;
    *(float4*)(abuf + (size_t)blk * 4096 + i * 64 + j0) = Av;
    *(float4*)(attnbuf + (size_t)blk * 4096 + i * 64 + j0) = Qv;
  }
}

// ---------------- per-chunk: T = (I+A)^-1, then T *= beta[col] ----------------
__global__ __launch_bounds__(256) void pre_solve_kernel(const float* __restrict__ abuf,
                                                        const float* __restrict__ betabuf,
                                                        float* __restrict__ tbuf) {
  __shared__ float Al[64][65];
  __shared__ float Tl[64][65];
  const int blk = blockIdx.x;
  const int h = blk >> 6;
  const int n = blk & 63;
  const int t0 = n * 64;
  const int tid = threadIdx.x;
#pragma unroll
  for (int rep = 0; rep < 4; rep++) {
    const int lin = rep * 256 + tid;
    const int i = lin >> 4;
    const int j = (lin & 15) * 4;
    const float4 av = *(const float4*)(abuf + (size_t)blk * 4096 + i * 64 + j);
    Al[i][j] = av.x; Al[i][j + 1] = av.y; Al[i][j + 2] = av.z; Al[i][j + 3] = av.w;
  }
  __syncthreads();
  if (tid < 64) {
    const int j = tid;
    const float bj = betabuf[(size_t)(t0 + j) * NH + h];
    for (int i = 0; i < 64; i++) {
      float s = (i == j) ? 1.0f : 0.0f;
      for (int l = j; l < i; l++) s -= Al[i][l] * Tl[l][j];
      Tl[i][j] = s;
    }
    for (int i = j; i < 64; i++) Tl[i][j] *= bj;
  }
  __syncthreads();
#pragma unroll
  for (int rep = 0; rep < 4; rep++) {
    const int lin = rep * 256 + tid;
    const int i = lin >> 4;
    const int j = (lin & 15) * 4;
    float4 tv;
    tv.x = Tl[i][j]; tv.y = Tl[i][j + 1]; tv.z = Tl[i][j + 2]; tv.w = Tl[i][j + 3];
    *(float4*)(tbuf + (size_t)blk * 4096 + i * 64 + j) = tv;
  }
}

// ---------------- per-chunk: u = Tb @ v (f32, l4-packed [blk][l>>2][c][l&3]) ;
//                  w = Tb @ (k * e^gcs), stored NEGATED + slot-swizzled ----
__global__ __launch_bounds__(256) void pre_uw_kernel(const float* __restrict__ mixed,
                                                     const float* __restrict__ tbuf,
                                                     const float* __restrict__ gcsbuf,
                                                     float* __restrict__ ubuf,
                                                     unsigned short* __restrict__ wbf) {
  __shared__ __align__(16) float Tl[64][68];
  __shared__ __align__(16) float xl[64][132];
  __shared__ float egcs[64];
  const int blk = blockIdx.x;
  const int h = blk >> 6;
  const int n = blk & 63;
  const int t0 = n * 64;
  const int tid = threadIdx.x;
  if (tid < 64) egcs[tid] = __expf(gcsbuf[(size_t)blk * 64 + tid]);
#pragma unroll
  for (int rep = 0; rep < 4; rep++) {
    const int lin = rep * 256 + tid;
    const int i = lin >> 4;
    const int j = (lin & 15) * 4;
    const float4 tv = *(const float4*)(tbuf + (size_t)blk * 4096 + i * 64 + j);
    *(float4*)&Tl[i][j] = tv;
  }
#pragma unroll
  for (int rep = 0; rep < 8; rep++) {
    const int lin = rep * 256 + tid;
    const int i = lin >> 5;
    const int d = (lin & 31) * 4;
    const float4 vv = *(const float4*)(mixed + (size_t)(t0 + i) * CQKV + 4096 + h * 128 + d);
    *(float4*)&xl[i][d] = vv;
  }
  __syncthreads();
  const int cgu = tid & 15;
  const int riu = tid >> 4;
  const int i0 = riu * 4;
  const int d0 = cgu * 8;
  float acc[4][8];
#pragma unroll
  for (int a = 0; a < 4; a++)
#pragma unroll
    for (int b = 0; b < 8; b++) acc[a][b] = 0.f;
#pragma unroll 2
  for (int j = 0; j < 64; j++) {
    const float tv[4] = {Tl[i0][j], Tl[i0 + 1][j], Tl[i0 + 2][j], Tl[i0 + 3][j]};
    const float4 x0 = *(const float4*)&xl[j][d0];
    const float4 x1 = *(const float4*)&xl[j][d0 + 4];
    const float xv[8] = {x0.x, x0.y, x0.z, x0.w, x1.x, x1.y, x1.z, x1.w};
#pragma unroll
    for (int a = 0; a < 4; a++)
#pragma unroll
      for (int b = 0; b < 8; b++) acc[a][b] += tv[a] * xv[b];
  }
  // u store: l4-packed layout addr = blk*8192 + (l>>2)*512 + c*4 + (l&3); here l>>2 = riu.
#pragma unroll
  for (int b = 0; b < 8; b++) {
    *(float4*)(ubuf + (size_t)blk * 8192 + riu * 512 + (size_t)(d0 + b) * 4) =
        make_float4(acc[0][b], acc[1][b], acc[2][b], acc[3][b]);
  }
  __syncthreads();
#pragma unroll
  for (int rep = 0; rep < 8; rep++) {
    const int lin = rep * 256 + tid;
    const int i = lin >> 5;
    const int d = (lin & 31) * 4;
    float4 kv = *(const float4*)(mixed + (size_t)(t0 + i) * CQKV + 2048 + h * 128 + d);
    const float e = egcs[i];
    kv.x *= e; kv.y *= e; kv.z *= e; kv.w *= e;
    *(float4*)&xl[i][d] = kv;
  }
  __syncthreads();
#pragma unroll
  for (int a = 0; a < 4; a++)
#pragma unroll
    for (int b = 0; b < 8; b++) acc[a][b] = 0.f;
#pragma unroll 2
  for (int j = 0; j < 64; j++) {
    const float tv[4] = {Tl[i0][j], Tl[i0 + 1][j], Tl[i0 + 2][j], Tl[i0 + 3][j]};
    const float4 x0 = *(const float4*)&xl[j][d0];
    const float4 x1 = *(const float4*)&xl[j][d0 + 4];
    const float xv[8] = {x0.x, x0.y, x0.z, x0.w, x1.x, x1.y, x1.z, x1.w};
#pragma unroll
    for (int a = 0; a < 4; a++)
#pragma unroll
      for (int b = 0; b < 8; b++) acc[a][b] += tv[a] * xv[b];
  }
  // store -w, column-slot swizzled by (row&7) so scan can global_load_lds linearly
#pragma unroll
  for (int a = 0; a < 4; a++) {
    const int l = i0 + a;
    unsigned short* wp = wbf + (size_t)(t0 + l) * 2048 + h * 128 + ((cgu ^ (l & 7)) << 3);
    *(ushort4*)wp = pack4(-acc[a][0], -acc[a][1], -acc[a][2], -acc[a][3]);
    *(ushort4*)(wp + 4) = pack4(-acc[a][4], -acc[a][5], -acc[a][6], -acc[a][7]);
  }
}

// ---------------- per-chunk: kdT[blk][d][l] = bf16(k*edk) slot-swizzled; qe = bf16(q*egq) ----------------
__global__ __launch_bounds__(256) void ktrans_kernel(const float* __restrict__ mixed,
                                                     const float* __restrict__ edkbuf,
                                                     const float* __restrict__ egqbuf,
                                                     unsigned short* __restrict__ kdT,
                                                     unsigned short* __restrict__ qe) {
  __shared__ __align__(16) float kl[64][132];
  __shared__ float edk_s[64];
  __shared__ float egq_s[64];
  const int blk = blockIdx.x;
  const int h = blk >> 6;
  const int n = blk & 63;
  const int t0 = n * 64;
  const int tid = threadIdx.x;
  if (tid < 64) {
    edk_s[tid] = edkbuf[(size_t)blk * 64 + tid];
    egq_s[tid] = egqbuf[(size_t)blk * 64 + tid];
  }
#pragma unroll
  for (int q = 0; q < 8; q++) {
    const int idx = tid + q * 256;
    const int l = idx >> 5, c4 = (idx & 31) * 4;
    *(float4*)&kl[l][c4] = *(const float4*)(mixed + (size_t)(t0 + l) * CQKV + 2048 + h * 128 + c4);
  }
  __syncthreads();
#pragma unroll
  for (int q = 0; q < 4; q++) {
    const int idx = tid + q * 256;
    const int d = idx >> 3, lsl = idx & 7;
    const int l8 = lsl * 8;
    float v[8];
#pragma unroll
    for (int j = 0; j < 8; j++) v[j] = kl[l8 + j][d] * edk_s[l8 + j];
    unsigned short* p = kdT + (size_t)blk * 8192 + d * 64 + ((lsl ^ (d & 7)) << 3);
    *(ushort4*)p = pack4(v[0], v[1], v[2], v[3]);
    *(ushort4*)(p + 4) = pack4(v[4], v[5], v[6], v[7]);
  }
#pragma unroll
  for (int q = 0; q < 8; q++) {
    const int idx = tid + q * 256;
    const int i = idx >> 5, c4 = (idx & 31) * 4;
    const float4 v = *(const float4*)(mixed + (size_t)(t0 + i) * CQKV + h * 128 + c4);
    const float e = egq_s[i];
    *(ushort4*)(qe + (size_t)(t0 + i) * 2048 + h * 128 + c4) =
        pack4(v.x * e, v.y * e, v.z * e, v.w * e);
  }
}

// ---------------- MFMA scan, column-decomposed: 8 waves x 16 c-columns, NO cross-wave data ---
// Exports in d4-packed layouts (coalesced): STb[blk][(d>>2)*512 + c*4 + (d&3)],
// vtb[blk][(l>>2)*512 + c*4 + (l&3)]. u read from l4-packed ubuf (4x float4 per chunk).
// blocks 0..15: per-head scan; ONE barrier/chunk (counted vmcnt(17)).
// blocks >=16: weight f2b + residual copy (512 threads).
__global__ __launch_bounds__(512, 1) void scan_kernel(const unsigned short* __restrict__ wbf,
                                                      const unsigned short* __restrict__ kdT,
                                                      const float* __restrict__ ubuf,
                                                      const float* __restrict__ adecbuf,
                                                      unsigned short* __restrict__ STb,
                                                      unsigned short* __restrict__ vtb,
                                                      const float* __restrict__ gw,
                                                      const float* __restrict__ uw,
                                                      const float* __restrict__ dw,
                                                      const float* __restrict__ ow,
                                                      const float* __restrict__ xin,
                                                      unsigned short* __restrict__ Wg,
                                                      unsigned short* __restrict__ Wu,
                                                      unsigned short* __restrict__ Wd,
                                                      unsigned short* __restrict__ Wo,
                                                      float* __restrict__ outc) {
  __shared__ __align__(16) unsigned short stage[2][16384];  // [w 8192 | kT 8192] shorts each
  __shared__ __align__(16) unsigned short privAll[8][3072]; // per wave: A 16x128 | B 16x64
  if (blockIdx.x >= 16) {
    // side work (512 thr): Wg 4096 + Wu 4096 + Wd 4096 + Wo 1024 + copy 2048 = 15360 blocks
    const int xb = blockIdx.x - 16;
    const int tid = threadIdx.x;
    if (xb < 13312) {
      const float* src; unsigned short* dst; size_t u;
      if (xb < 4096)       { src = gw; dst = Wg; u = (size_t)xb * 512 + tid; }
      else if (xb < 8192)  { src = uw; dst = Wu; u = (size_t)(xb - 4096) * 512 + tid; }
      else if (xb < 12288) { src = dw; dst = Wd; u = (size_t)(xb - 8192) * 512 + tid; }
      else                 { src = ow; dst = Wo; u = (size_t)(xb - 12288) * 512 + tid; }
      const float4 a = ((const float4*)src)[2 * u];
      const float4 b = ((const float4*)src)[2 * u + 1];
      ((ushort4*)dst)[2 * u] = pack4(a.x, a.y, a.z, a.w);
      ((ushort4*)dst)[2 * u + 1] = pack4(b.x, b.y, b.z, b.w);
    } else {
      const size_t i = (size_t)(xb - 13312) * 512 + tid;
      ((float4*)outc)[2 * i] = ((const float4*)xin)[2 * i];
      ((float4*)outc)[2 * i + 1] = ((const float4*)xin)[2 * i + 1];
    }
    return;
  }
  const int h = blockIdx.x;
  const int tid = threadIdx.x;
  const int ln = tid & 63;
  const int wv = tid >> 6;        // 0..7
  const int fr = ln & 15;
  const int g  = ln >> 4;         // 0..3
  const int c0 = wv * 16;
  const int fsw = fr & 7;
  unsigned short* privA = &privAll[wv][0];     // [16 c][128 d], slot-swizzled
  unsigned short* privB = &privAll[wv][2048];  // [16 c][64 l], slot-swizzled
  const f32x4 zero = {0.f, 0.f, 0.f, 0.f};

  f32x4 acc2[8];                  // S^T state for this wave's 16 columns, d-tile dt
#pragma unroll
  for (int dt = 0; dt < 8; dt++) acc2[dt] = zero;

  auto stage_wk = [&](int buf, int n1) {
    const int t0n = n1 * 64;
    const size_t kbase = (size_t)(h * 64 + n1) * 8192;
#pragma unroll
    for (int q = 0; q < 2; q++) {
      const int m = wv * 2 + q;   // 0..15
      gl_lds16(wbf + (size_t)(t0n + m * 4 + (ln >> 4)) * 2048 + h * 128 + (ln & 15) * 8,
               &stage[buf][m * 512]);
      gl_lds16(kdT + kbase + (m * 8 + (ln >> 3)) * 64 + (ln & 7) * 8,
               &stage[buf][8192 + m * 512]);
    }
  };

  // prologue: u/adec for chunk 0 + stage chunk 0
  float4 ur4[4];
#pragma unroll
  for (int lt = 0; lt < 4; lt++)
    ur4[lt] = *(const float4*)(ubuf + (size_t)(h * 64) * 8192 + (lt * 4 + g) * 512 + (c0 + fr) * 4);
  float ad = adecbuf[h * 64];
  stage_wk(0, 0);
  asm volatile("s_waitcnt vmcnt(0)" ::: "memory");
  __builtin_amdgcn_s_barrier();
  asm volatile("" ::: "memory");

  for (int n = 0; n < 64; n++) {
    const int blk = h * 64 + n;
    const unsigned short* wl = &stage[n & 1][0];
    const unsigned short* kl = &stage[n & 1][8192];
    // (1) issue staging for n+1 first (oldest VMEM ops of this chunk)
    if (n + 1 < 64) stage_wk((n + 1) & 1, n + 1);
    __builtin_amdgcn_sched_barrier(0);
    // (2) prefetch u/adec for n+1 (4 coalesced float4 + 1 scalar; younger than staging)
    float4 ur4n[4];
    float adn = 0.f;
    if (n + 1 < 64) {
      const size_t ub = (size_t)(blk + 1) * 8192;
#pragma unroll
      for (int lt = 0; lt < 4; lt++)
        ur4n[lt] = *(const float4*)(ubuf + ub + (lt * 4 + g) * 512 + (c0 + fr) * 4);
      adn = adecbuf[blk + 1];
    } else {
      const float4 z4 = make_float4(0.f, 0.f, 0.f, 0.f);
#pragma unroll
      for (int lt = 0; lt < 4; lt++) ur4n[lt] = z4;
    }
    __builtin_amdgcn_sched_barrier(0);
    // (3) dump S_n^T -> privA (wave-private) ; export S_n coalesced (d4-packed)
#pragma unroll
    for (int dt = 0; dt < 8; dt++) {
      const int slot = dt * 2 + (g >> 1);
      const ushort4 pv = pack4(acc2[dt][0], acc2[dt][1], acc2[dt][2], acc2[dt][3]);
      *(ushort4*)&privA[fr * 128 + ((slot ^ fsw) << 3) + (g & 1) * 4] = pv;
      *(ushort4*)(STb + (size_t)blk * 16384 + (dt * 4 + g) * 512 + (c0 + fr) * 4) = pv;
    }
    // (4) MFMA1: v_new = u + (-w) @ S  (A from shared staged w, B from privA)
    f32x4 acc1[4];
#pragma unroll
    for (int lt = 0; lt < 4; lt++) {
      f32x4 t;
      t[0] = ur4[lt].x; t[1] = ur4[lt].y; t[2] = ur4[lt].z; t[3] = ur4[lt].w;
      acc1[lt] = t;
    }
#pragma unroll
    for (int ks = 0; ks < 4; ks++) {
      const int kb = ks * 4 + g;
      const bf16x8 b = *(const bf16x8*)&privA[fr * 128 + ((kb ^ fsw) << 3)];
#pragma unroll
      for (int lt = 0; lt < 4; lt++) {
        const bf16x8 a = *(const bf16x8*)&wl[(lt * 16 + fr) * 128 + ((kb ^ fsw) << 3)];
        acc1[lt] = __builtin_amdgcn_mfma_f32_16x16x32_bf16(a, b, acc1[lt], 0, 0, 0);
      }
    }
    // (5) v_new^T -> privB ; export v_new^T coalesced (l4-packed)
#pragma unroll
    for (int lt = 0; lt < 4; lt++) {
      const int slot = lt * 2 + (g >> 1);
      const ushort4 pv = pack4(acc1[lt][0], acc1[lt][1], acc1[lt][2], acc1[lt][3]);
      *(ushort4*)&privB[fr * 64 + ((slot ^ fsw) << 3) + (g & 1) * 4] = pv;
      *(ushort4*)(vtb + (size_t)blk * 8192 + (lt * 4 + g) * 512 + (c0 + fr) * 4) = pv;
    }
    // (6) MFMA2: S = adec*S + kdec^T @ v_new
#pragma unroll
    for (int dt = 0; dt < 8; dt++) {
      acc2[dt][0] *= ad; acc2[dt][1] *= ad; acc2[dt][2] *= ad; acc2[dt][3] *= ad;
    }
#pragma unroll
    for (int ks = 0; ks < 2; ks++) {
      const int kb = ks * 4 + g;
      const bf16x8 b = *(const bf16x8*)&privB[fr * 64 + ((kb ^ fsw) << 3)];
#pragma unroll
      for (int dt = 0; dt < 8; dt++) {
        const bf16x8 a = *(const bf16x8*)&kl[(dt * 16 + fr) * 64 + ((kb ^ fsw) << 3)];
        acc2[dt] = __builtin_amdgcn_mfma_f32_16x16x32_bf16(a, b, acc2[dt], 0, 0, 0);
      }
    }
    // (7) roll prefetched operands
#pragma unroll
    for (int lt = 0; lt < 4; lt++) ur4[lt] = ur4n[lt];
    ad = adn;
    // (8) publish staging: counted vmcnt (youngest 17 = 4 u + 1 adec + 12 export stores)
    if (n + 1 < 64) {
      asm volatile("s_waitcnt lgkmcnt(0)" ::: "memory");
      __builtin_amdgcn_sched_barrier(0);
      asm volatile("s_waitcnt vmcnt(17)" ::: "memory");
      __builtin_amdgcn_sched_barrier(0);
      __builtin_amdgcn_s_barrier();
      __builtin_amdgcn_sched_barrier(0);
    }
  }
}

// ---------------- MFMA o-compute + fused gated RMSNorm (reads d4/l4-packed ST/vt) ----------------
__global__ __launch_bounds__(256) void ocomp_kernel(const unsigned short* __restrict__ qe,
                                                    const unsigned short* __restrict__ STbuf,
                                                    const unsigned short* __restrict__ vtbuf,
                                                    const float* __restrict__ attnbuf,
                                                    const unsigned short* __restrict__ zb,
                                                    const float* __restrict__ onw,
                                                    unsigned short* __restrict__ ob) {
  __shared__ __align__(16) unsigned short STl[128 * 128];  // [c][d]
  __shared__ __align__(16) unsigned short vtl[128 * 64];   // [c][l]
  __shared__ __align__(16) unsigned short ql[64 * 128];    // [i][d]
  __shared__ __align__(16) unsigned short al[64 * 64];     // [i][l]
  const int blk = blockIdx.x;
  const int h = blk >> 6;
  const int n = blk & 63;
  const int t0 = n * 64;
  const int tid = threadIdx.x;
  // ST: d4-packed -> [c][d] swizzled LDS. uint4 o covers (dq = o>>6, cols 2w,2w+1, w = o&63)
#pragma unroll
  for (int q = 0; q < 8; q++) {
    const int o = tid + q * 256;
    const int dq = o >> 6, w = o & 63;
    const uint4 v = *(const uint4*)(STbuf + (size_t)blk * 16384 + (size_t)o * 8);
    const int cA = 2 * w, cB = 2 * w + 1;
    uint2 h0; h0.x = v.x; h0.y = v.y;
    uint2 h1; h1.x = v.z; h1.y = v.w;
    *(uint2*)&STl[cA * 128 + (((dq >> 1) ^ (cA & 7)) << 3) + (dq & 1) * 4] = h0;
    *(uint2*)&STl[cB * 128 + (((dq >> 1) ^ (cB & 7)) << 3) + (dq & 1) * 4] = h1;
  }
  // vt: l4-packed -> [c][l] swizzled LDS
#pragma unroll
  for (int q = 0; q < 4; q++) {
    const int o = tid + q * 256;
    const int lq = o >> 6, w = o & 63;
    const uint4 v = *(const uint4*)(vtbuf + (size_t)blk * 8192 + (size_t)o * 8);
    const int cA = 2 * w, cB = 2 * w + 1;
    uint2 h0; h0.x = v.x; h0.y = v.y;
    uint2 h1; h1.x = v.z; h1.y = v.w;
    *(uint2*)&vtl[cA * 64 + (((lq >> 1) ^ (cA & 7)) << 3) + (lq & 1) * 4] = h0;
    *(uint2*)&vtl[cB * 64 + (((lq >> 1) ^ (cB & 7)) << 3) + (lq & 1) * 4] = h1;
  }
#pragma unroll
  for (int q = 0; q < 4; q++) {
    const int idx = tid + q * 256;
    const int i = idx >> 4, dg = idx & 15;
    *(uint4*)&ql[i * 128 + ((dg ^ (i & 7)) << 3)] =
        *(const uint4*)(qe + (size_t)(t0 + i) * 2048 + h * 128 + dg * 8);
  }
#pragma unroll
  for (int q = 0; q < 4; q++) {
    const int idx = tid + q * 256;
    const int i = idx >> 4, l4 = (idx & 15) * 4;
    const float4 v = *(const float4*)(attnbuf + (size_t)blk * 4096 + i * 64 + l4);
    *(ushort4*)&al[i * 64 + (((l4 >> 3) ^ (i & 7)) << 3) + (l4 & 7)] =
        pack4(v.x, v.y, v.z, v.w);
  }
  __syncthreads();
  const int ln = tid & 63;
  const int wv = tid >> 6;
  const int fr = ln & 15;
  const int g = ln >> 4;
  const int i0 = wv * 16;
  f32x4 acc[8];
  const f32x4 zero = {0.f, 0.f, 0.f, 0.f};
#pragma unroll
  for (int nt = 0; nt < 8; nt++) acc[nt] = zero;
#pragma unroll
  for (int ks = 0; ks < 4; ks++) {
    const int kb = ks * 4 + g;
    const int ar = i0 + fr;
    const bf16x8 a = *(const bf16x8*)&ql[ar * 128 + ((kb ^ (ar & 7)) << 3)];
#pragma unroll
    for (int nt = 0; nt < 8; nt++) {
      const int c = nt * 16 + fr;
      const bf16x8 b = *(const bf16x8*)&STl[c * 128 + ((kb ^ (c & 7)) << 3)];
      acc[nt] = __builtin_amdgcn_mfma_f32_16x16x32_bf16(a, b, acc[nt], 0, 0, 0);
    }
  }
#pragma unroll
  for (int ks = 0; ks < 2; ks++) {
    const int kb = ks * 4 + g;
    const int ar = i0 + fr;
    const bf16x8 a = *(const bf16x8*)&al[ar * 64 + ((kb ^ (ar & 7)) << 3)];
#pragma unroll
    for (int nt = 0; nt < 8; nt++) {
      const int c = nt * 16 + fr;
      const bf16x8 b = *(const bf16x8*)&vtl[c * 64 + ((kb ^ (c & 7)) << 3)];
      acc[nt] = __builtin_amdgcn_mfma_f32_16x16x32_bf16(a, b, acc[nt], 0, 0, 0);
    }
  }
  float s0 = 0.f, s1 = 0.f, s2 = 0.f, s3 = 0.f;
#pragma unroll
  for (int nt = 0; nt < 8; nt++) {
    s0 += acc[nt][0] * acc[nt][0];
    s1 += acc[nt][1] * acc[nt][1];
    s2 += acc[nt][2] * acc[nt][2];
    s3 += acc[nt][3] * acc[nt][3];
  }
#pragma unroll
  for (int m = 1; m < 16; m <<= 1) {
    s0 += __shfl_xor(s0, m);
    s1 += __shfl_xor(s1, m);
    s2 += __shfl_xor(s2, m);
    s3 += __shfl_xor(s3, m);
  }
  float rn[4];
  rn[0] = rsqrtf(s0 * (1.0f / 128.0f) + 1e-5f);
  rn[1] = rsqrtf(s1 * (1.0f / 128.0f) + 1e-5f);
  rn[2] = rsqrtf(s2 * (1.0f / 128.0f) + 1e-5f);
  rn[3] = rsqrtf(s3 * (1.0f / 128.0f) + 1e-5f);
#pragma unroll
  for (int nt = 0; nt < 8; nt++) {
    const int c = nt * 16 + fr;
    const float wn = onw[c];
#pragma unroll
    for (int r = 0; r < 4; r++) {
      const size_t off = (size_t)(t0 + i0 + g * 4 + r) * 2048 + h * 128 + c;
      const float zz = siluf(bf2f(zb[off]));
      ob[off] = f2bf(acc[nt][r] * rn[r] * wn * zz);
    }
  }
}

extern "C" void kernel_launch(void* const* d_in, const int* in_sizes, int n_in,
                              void* d_out, int out_size, void* d_ws, size_t ws_size,
                              hipStream_t stream) {
  (void)in_sizes; (void)n_in; (void)out_size;
  const float* x        = (const float*)d_in[0];
  const float* mask     = (const float*)d_in[1];
  const float* ln1_w    = (const float*)d_in[2];
  const float* qkvz_w   = (const float*)d_in[3];
  const float* ba_w     = (const float*)d_in[4];
  const float* conv_w   = (const float*)d_in[5];
  const float* A_log    = (const float*)d_in[6];
  const float* dt_bias  = (const float*)d_in[7];
  const float* o_norm_w = (const float*)d_in[8];
  const float* out_w    = (const float*)d_in[9];
  const float* ln2_w    = (const float*)d_in[10];
  const float* gate_w   = (const float*)d_in[11];
  const float* up_w     = (const float*)d_in[12];
  const float* down_w   = (const float*)d_in[13];
  float* out = (float*)d_out;

  const size_t NEED_BYTES = (size_t)75825152 * 4;
  if (ws_size < NEED_BYTES) return;

  float* ws = (float*)d_ws;
  float* mixed_buf = ws;
  unsigned short* Wg = (unsigned short*)ws;
  unsigned short* Wu = (unsigned short*)(ws + 8388608);
  unsigned short* Wd = (unsigned short*)(ws + 16777216);
  unsigned short* qkvz_bf = (unsigned short*)(ws + 25165824);
  float* u_buf = ws + 25165824;
  unsigned short* wbf = (unsigned short*)(ws + 33554432);
  unsigned short* kdT = (unsigned short*)(ws + 37748736);
  unsigned short* gate_bf = (unsigned short*)(ws + 25165824);
  unsigned short* z_bf = (unsigned short*)(ws + 41943040);
  float* h_buf = ws + 46137344;
  float* a_buf = ws + 46137344;
  unsigned short* vt_buf = (unsigned short*)(ws + 46137344);
  float* t_buf = ws + 50331648;
  unsigned short* qe_bf = (unsigned short*)(ws + 50331648);  // after pre_uw, t_buf is dead
  unsigned short* h_bf  = (unsigned short*)(ws + 54525952);
  unsigned short* ob    = (unsigned short*)(ws + 54525952);
  unsigned short* h2_bf = (unsigned short*)(ws + 54525952);
  float* attn_buf = ws + 58720256;
  unsigned short* Wq = (unsigned short*)(ws + 62914560);
  unsigned short* ST_buf = (unsigned short*)(ws + 62914560);
  unsigned short* Wo = (unsigned short*)(ws + 71303168);
  float* ba_buf   = ws + 73400320;
  float* beta_buf = ws + 73531392;
  float* g_buf    = ws + 73596928;
  float* gcs_buf  = ws + 73662464;
  float* edk_buf  = ws + 73728000;
  float* egq_buf  = ws + 73793536;
  float* adec_buf = ws + 73859072;

  rmsnorm_kernel<1><<<4096, 256, 0, stream>>>(x, ln1_w, h_buf, h_bf);
  f2b_kernel<<<8192, 256, 0, stream>>>(qkvz_w, Wq);
  gemm8p_kernel<0><<<512, 512, 0, stream>>>(h_bf, Wq, nullptr, qkvz_bf, 4096, 8192, 2048);
  ba_gemm_kernel<<<4096, 256, 0, stream>>>(h_buf, ba_w, ba_buf);
  zcopy_kernel<<<4096, 256, 0, stream>>>(qkvz_bf, z_bf);
  conv_silu_kernel<<<24576, 256, 0, stream>>>(qkvz_bf, conv_w, mask, mixed_buf);
  l2norm_kernel<<<32768, 256, 0, stream>>>(mixed_buf);
  beta_g_kernel<<<256, 256, 0, stream>>>(ba_buf, A_log, dt_bias, mask, beta_buf, g_buf);
  gcs_kernel<<<4, 256, 0, stream>>>(g_buf, gcs_buf, edk_buf, egq_buf, adec_buf);
  pre_attn_kernel<<<1024, 256, 0, stream>>>(mixed_buf, gcs_buf, beta_buf, a_buf, attn_buf);
  pre_solve_kernel<<<1024, 256, 0, stream>>>(a_buf, beta_buf, t_buf);
  pre_uw_kernel<<<1024, 256, 0, stream>>>(mixed_buf, t_buf, gcs_buf, u_buf, wbf);
  ktrans_kernel<<<1024, 256, 0, stream>>>(mixed_buf, edk_buf, egq_buf, kdT, qe_bf);
  // column-decomposed MFMA scan (16 blocks, 8 waves) + fused f2b/copy (15360 blocks)
  scan_kernel<<<15376, 512, 0, stream>>>(wbf, kdT, u_buf, adec_buf, ST_buf, vt_buf,
                                         gate_w, up_w, down_w, out_w, x,
                                         Wg, Wu, Wd, Wo, out);
  ocomp_kernel<<<1024, 256, 0, stream>>>(qe_bf, ST_buf, vt_buf, attn_buf,
                                         z_bf, o_norm_w, ob);
  gemm256_kernel<1, 128, 128><<<512, 512, 0, stream>>>(ob, Wo, out, nullptr, 4096, 2048, 2048);
  rmsnorm_kernel<2><<<4096, 256, 0, stream>>>(out, ln2_w, nullptr, h2_bf);
  gemm8p_kernel<0><<<512, 512, 0, stream>>>(h2_bf, Wg, nullptr, gate_bf, 4096, 8192, 2048);
  gemm8p_kernel<2><<<512, 512, 0, stream>>>(h2_bf, Wu, nullptr, gate_bf, 4096, 8192, 2048);
  gemm256_kernel<1, 128, 128><<<512, 512, 0, stream>>>(gate_bf, Wd, out, nullptr, 4096, 2048, 8192);
}

// Round 15
// 1296.834 us; speedup vs baseline: 1.3474x; 1.0601x over previous
//
#include <hip/hip_runtime.h>
#include <math.h>

#define T_LEN 4096
#define DMODEL 2048
#define NH 16
#define CQKV 6144
#define CQKVZ 8192
#define SCALE 0.08838834764831845f   // 128^-0.5

using bf16x8 = __attribute__((ext_vector_type(8))) short;
using f32x4  = __attribute__((ext_vector_type(4))) float;

__device__ __forceinline__ float siluf(float x) { return x / (1.0f + __expf(-x)); }

__device__ __forceinline__ unsigned short f2bf(float f) {  // RNE
  unsigned int u = __float_as_uint(f);
  u = (u + 0x7FFFu + ((u >> 16) & 1u)) >> 16;
  return (unsigned short)u;
}
__device__ __forceinline__ float bf2f(unsigned short u) {
  return __uint_as_float(((unsigned int)u) << 16);
}
__device__ __forceinline__ ushort4 pack4(float a, float b, float c, float d) {
  ushort4 r; r.x = f2bf(a); r.y = f2bf(b); r.z = f2bf(c); r.w = f2bf(d); return r;
}

// async global->LDS, 16 bytes per lane; LDS dest is wave-uniform base (+ lane*16 implicit)
__device__ __forceinline__ void gl_lds16(const unsigned short* g, unsigned short* l) {
  __builtin_amdgcn_global_load_lds(
      (const __attribute__((address_space(1))) void*)g,
      (__attribute__((address_space(3))) void*)l, 16, 0, 0);
}

// ---------------- RMSNorm over D=2048; MODE: 1 = f32+bf16, 2 = bf16 only ----------------
template<int MODE>
__global__ __launch_bounds__(256) void rmsnorm_kernel(const float* __restrict__ x,
                                                      const float* __restrict__ w,
                                                      float* __restrict__ outf,
                                                      unsigned short* __restrict__ outb) {
  const int t = blockIdx.x;
  const int tid = threadIdx.x;
  const float4* xr = (const float4*)(x + (size_t)t * DMODEL);
  float4 v0 = xr[tid];
  float4 v1 = xr[tid + 256];
  float s = v0.x*v0.x + v0.y*v0.y + v0.z*v0.z + v0.w*v0.w
          + v1.x*v1.x + v1.y*v1.y + v1.z*v1.z + v1.w*v1.w;
#pragma unroll
  for (int off = 32; off > 0; off >>= 1) s += __shfl_down(s, off);
  __shared__ float red[4];
  if ((tid & 63) == 0) red[tid >> 6] = s;
  __syncthreads();
  const float tot = red[0] + red[1] + red[2] + red[3];
  const float r = rsqrtf(tot * (1.0f / DMODEL) + 1e-5f);
  const float4* wr = (const float4*)w;
  const float4 w0 = wr[tid], w1 = wr[tid + 256];
  float4 o0, o1;
  o0.x = v0.x*r*w0.x; o0.y = v0.y*r*w0.y; o0.z = v0.z*r*w0.z; o0.w = v0.w*r*w0.w;
  o1.x = v1.x*r*w1.x; o1.y = v1.y*r*w1.y; o1.z = v1.z*r*w1.z; o1.w = v1.w*r*w1.w;
  if (MODE == 1) {
    float4* orow = (float4*)(outf + (size_t)t * DMODEL);
    orow[tid] = o0;
    orow[tid + 256] = o1;
  }
  ushort4* brow = (ushort4*)(outb + (size_t)t * DMODEL);
  brow[tid] = pack4(o0.x, o0.y, o0.z, o0.w);
  brow[tid + 256] = pack4(o1.x, o1.y, o1.z, o1.w);
}

// ---------------- fp32 -> bf16 bulk convert ----------------
__global__ __launch_bounds__(256) void f2b_kernel(const float* __restrict__ in,
                                                  unsigned short* __restrict__ out) {
  const size_t i = (size_t)blockIdx.x * 256 + threadIdx.x;
  const float4 a = ((const float4*)in)[2 * i];
  const float4 b = ((const float4*)in)[2 * i + 1];
  ((ushort4*)out)[2 * i] = pack4(a.x, a.y, a.z, a.w);
  ((ushort4*)out)[2 * i + 1] = pack4(b.x, b.y, b.z, b.w);
}

// ---------------- 4-phase slot-pipelined 256x256 bf16 MFMA GEMM (fat shapes): C = A @ B^T ---
// EPI: 0 = bf16 store; 3 = paired silu(gate)*up combine (B is 16-col-interleaved Wg/Wu,
// N=16384, output 4096x8192 bf16).
template<int EPI>
__global__ __launch_bounds__(512, 2) void gemm8p_kernel(const unsigned short* __restrict__ A,
                                                        const unsigned short* __restrict__ B,
                                                        float* __restrict__ Cf,
                                                        unsigned short* __restrict__ Cb,
                                                        int M, int N, int K) {
  __shared__ __align__(16) unsigned short lds[8][8192];   // 8 slots x 16 KB
  const int nbm = M >> 8, nbn = N >> 8, nwg = nbm * nbn;
  const int nt = K >> 6;   // K-tiles of 64
  int bmi, bni;
  {
    const int bid = blockIdx.x;
    const int cpx = nwg >> 3;
    int sc = 1;
    while (sc * sc < cpx) sc <<= 1;
    if (sc * sc > cpx) sc >>= 1;
    const int scn = (sc > 0) ? (cpx / sc) : 0;
    if ((nwg & 7) == 0 && sc > 0 && sc * scn == cpx && (nbm % sc) == 0 && (nbn % scn) == 0) {
      const int chunk = bid & 7, widx = bid >> 3;
      const int regc = nbn / scn;
      bmi = (chunk / regc) * sc + widx / scn;
      bni = (chunk % regc) * scn + widx % scn;
    } else {
      bmi = bid / nbn; bni = bid % nbn;
    }
  }
  const int bm = bmi << 8, bn = bni << 8;
  const int tid = threadIdx.x;
  const int wv = tid >> 6, ln = tid & 63;
  const int fr = ln & 15, qq = ln >> 4;
  const int wm = wv >> 2, wn = wv & 3;           // wave tile: rows wm*128, cols wn*64
  const int rsw = (fr >> 1) & 3;                 // read swizzle term
  const int s_sl = (ln & 3) ^ ((ln >> 3) & 3);   // staging source slot (inverse swizzle)

  f32x4 acc[8][4];
  const f32x4 zero = {0.f, 0.f, 0.f, 0.f};
#pragma unroll
  for (int mf = 0; mf < 8; mf++)
#pragma unroll
    for (int nf = 0; nf < 4; nf++) acc[mf][nf] = zero;

  bf16x8 afr[8], bfr[2];

  // stage one half: part 0=Ak0, 1=Ak1, 2=Bk0, 3=Bk1 of tile t2 -> slot ((t2&1)<<2)|part
  auto stage_half = [&](int t2, int part) {
    if (t2 >= nt) return;
    const unsigned short* Mat = (part >= 2) ? B : A;
    const int gb = (part >= 2) ? bn : bm;
    const int kk = part & 1;
    const int slot = ((t2 & 1) << 2) | part;
    const int k0 = t2 * 64 + kk * 32;
#pragma unroll
    for (int q = 0; q < 2; q++) {
      gl_lds16(Mat + (size_t)(gb + wv * 32 + q * 16 + (ln >> 2)) * K + k0 + s_sl * 8,
               &lds[slot][(wv * 32 + q * 16) * 32]);
    }
  };
  auto lda = [&](int tb, int kk) {
#pragma unroll
    for (int mf = 0; mf < 8; mf++) {
      const int ar = wm * 128 + mf * 16 + fr;
      afr[mf] = *(const bf16x8*)&lds[tb | kk][ar * 32 + ((qq ^ rsw) << 3)];
    }
  };
  auto ldb = [&](int tb, int kk, int nh) {
#pragma unroll
    for (int nj = 0; nj < 2; nj++) {
      const int br = wn * 64 + (nh * 2 + nj) * 16 + fr;
      bfr[nj] = *(const bf16x8*)&lds[tb | (2 + kk)][br * 32 + ((qq ^ rsw) << 3)];
    }
  };
  auto mm = [&](int nh) {
    __builtin_amdgcn_s_setprio(1);
#pragma unroll
    for (int mf = 0; mf < 8; mf++)
#pragma unroll
      for (int nj = 0; nj < 2; nj++)
        acc[mf][nh * 2 + nj] =
            __builtin_amdgcn_mfma_f32_16x16x32_bf16(afr[mf], bfr[nj], acc[mf][nh * 2 + nj], 0, 0, 0);
    __builtin_amdgcn_s_setprio(0);
  };

  // prologue: tile0 all 4 halves, tile1 k0 halves; wait tile0 (counted), publish
  stage_half(0, 0); stage_half(0, 2); stage_half(0, 1); stage_half(0, 3);
  stage_half(1, 0); stage_half(1, 2);
  asm volatile("s_waitcnt vmcnt(4)" ::: "memory");
  __builtin_amdgcn_s_barrier();
  asm volatile("" ::: "memory");

  for (int t = 0; t < nt; t++) {
    const int tb = (t & 1) << 2;
    // phase 0: (k0, N0); stage Ak1(t+1)
    lda(tb, 0); ldb(tb, 0, 0);
    stage_half(t + 1, 1);
    __builtin_amdgcn_s_barrier();
    mm(0);
    __builtin_amdgcn_s_barrier();
    // phase 1: (k0, N1); stage Bk1(t+1)
    ldb(tb, 0, 1);
    stage_half(t + 1, 3);
    __builtin_amdgcn_s_barrier();
    mm(1);
    __builtin_amdgcn_s_barrier();
    // phase 2: (k1, N1); stage Ak0(t+2)
    lda(tb, 1); ldb(tb, 1, 1);
    stage_half(t + 2, 0);
    __builtin_amdgcn_s_barrier();
    mm(1);
    __builtin_amdgcn_s_barrier();
    // phase 3: (k1, N0); stage Bk0(t+2)
    ldb(tb, 1, 0);
    stage_half(t + 2, 2);
    __builtin_amdgcn_s_barrier();
    mm(0);
    // tile boundary: counted vmcnt — next tile's 4 halves are older than newest in flight
    if (t + 1 < nt) {
      asm volatile("s_waitcnt lgkmcnt(0)" ::: "memory");
      __builtin_amdgcn_sched_barrier(0);
      if (t == nt - 2) {
        asm volatile("s_waitcnt vmcnt(0)" ::: "memory");
      } else {
        asm volatile("s_waitcnt vmcnt(4)" ::: "memory");
      }
      __builtin_amdgcn_sched_barrier(0);
      __builtin_amdgcn_s_barrier();
      __builtin_amdgcn_sched_barrier(0);
    }
  }

  const int cm4 = qq * 4;
  if (EPI == 3) {
    // paired combine: nf even = gate frag, nf odd = up frag at same output cols.
    // output col = bn/2 + wn*32 + (nf>>1)*16 + fr ; output row-stride 8192.
    const int bn2 = bn >> 1;
#pragma unroll
    for (int mf = 0; mf < 8; mf++) {
#pragma unroll
      for (int p = 0; p < 2; p++) {
#pragma unroll
        for (int r = 0; r < 4; r++) {
          const int grow = bm + wm * 128 + mf * 16 + cm4 + r;
          const int gcol = bn2 + wn * 32 + p * 16 + fr;
          Cb[(size_t)grow * 8192 + gcol] =
              f2bf(siluf(acc[mf][2 * p][r]) * acc[mf][2 * p + 1][r]);
        }
      }
    }
  } else {
#pragma unroll
    for (int mf = 0; mf < 8; mf++) {
#pragma unroll
      for (int nf = 0; nf < 4; nf++) {
#pragma unroll
        for (int r = 0; r < 4; r++) {
          const int grow = bm + wm * 128 + mf * 16 + cm4 + r;
          const int gcol = bn + wn * 64 + nf * 16 + fr;
          const size_t off = (size_t)grow * N + gcol;
          const float v = acc[mf][nf][r];
          if (EPI == 0) {
            Cb[off] = f2bf(v);
          } else {
            Cf[off] += v;
          }
        }
      }
    }
  }
}

// ---------------- pipelined bf16 MFMA GEMM (thin shapes): C[M][N] = A[M][K] * B[N][K]^T -----
// BM x BN block (8 waves, 64x64 per-wave tile), BK=32, 3 LDS buffers, counted vmcnt.
template<int EPI, int BM, int BN>
__global__ __launch_bounds__(512, 4) void gemm256_kernel(const unsigned short* __restrict__ A,
                                                         const unsigned short* __restrict__ B,
                                                         float* __restrict__ Cf,
                                                         unsigned short* __restrict__ Cb,
                                                         int M, int N, int K) {
  constexpr int MI = 4;
  constexpr int NI = BN / 64;
  constexpr int AW = BM / 128;
  constexpr int BW = BN / 128;
  __shared__ __align__(16) unsigned short lds[3][(BM + BN) * 32];
  const int nbm = M / BM, nbn = N / BN, nwg = nbm * nbn;
  const int nt = K >> 5;
  int bmi, bni;
  {
    const int bid = blockIdx.x;
    const int cpx = nwg >> 3;
    int sc = 1;
    while (sc * sc < cpx) sc <<= 1;
    if (sc * sc > cpx) sc >>= 1;
    const int scn = (sc > 0) ? (cpx / sc) : 0;
    if ((nwg & 7) == 0 && sc > 0 && sc * scn == cpx && (nbm % sc) == 0 && (nbn % scn) == 0) {
      const int chunk = bid & 7, widx = bid >> 3;
      const int regc = nbn / scn;
      bmi = (chunk / regc) * sc + widx / scn;
      bni = (chunk % regc) * scn + widx % scn;
    } else {
      bmi = bid / nbn; bni = bid % nbn;
    }
  }
  const int bm = bmi * BM, bn = bni * BN;
  const int tid = threadIdx.x;
  const int wv = tid >> 6, ln = tid & 63;
  const int fr = ln & 15, qq = ln >> 4;
  const int wm = wv >> 2, wn = wv & 3;
  const int ra0 = wm * 64, rb0 = wn * (BN / 4);
  const int lrow = ln >> 2;
  const int lslot = ln & 3;

  f32x4 acc[MI][NI];
  const f32x4 zero = {0.f, 0.f, 0.f, 0.f};
#pragma unroll
  for (int mi = 0; mi < MI; mi++)
#pragma unroll
    for (int ni = 0; ni < NI; ni++) acc[mi][ni] = zero;

  auto stage = [&](int buf, int t) {
    const int k0 = t << 5;
#pragma unroll
    for (int q = 0; q < AW; q++) {
      const int lr = q * 128 + wv * 16 + lrow;
      const int sl = lslot ^ ((lr >> 1) & 3);
      gl_lds16(A + (size_t)(bm + lr) * K + k0 + sl * 8,
               &lds[buf][(q * 128 + wv * 16) * 32]);
    }
#pragma unroll
    for (int q = 0; q < BW; q++) {
      const int lr = q * 128 + wv * 16 + lrow;
      const int sl = lslot ^ ((lr >> 1) & 3);
      gl_lds16(B + (size_t)(bn + lr) * K + k0 + sl * 8,
               &lds[buf][BM * 32 + (q * 128 + wv * 16) * 32]);
    }
  };

  stage(0, 0);
  stage(1, 1);
  asm volatile("s_waitcnt vmcnt(%0)" :: "i"(AW + BW) : "memory");
  __builtin_amdgcn_s_barrier();
  asm volatile("" ::: "memory");

  for (int t = 0; t < nt; t++) {
    const int cb = t % 3;
    const int b2 = (t + 2) % 3;
    const unsigned short* lA = &lds[cb][0];
    const unsigned short* lB = &lds[cb][BM * 32];
    bf16x8 bfr[NI];
#pragma unroll
    for (int ni = 0; ni < NI; ni++) {
      const int r = rb0 + ni * 16 + fr;
      bfr[ni] = *(const bf16x8*)&lB[r * 32 + ((qq ^ ((r >> 1) & 3)) << 3)];
    }
    bf16x8 afr[MI];
#pragma unroll
    for (int mi = 0; mi < MI; mi++) {
      const int r = ra0 + mi * 16 + fr;
      afr[mi] = *(const bf16x8*)&lA[r * 32 + ((qq ^ ((r >> 1) & 3)) << 3)];
    }
    if (t + 2 < nt) stage(b2, t + 2);
    __builtin_amdgcn_s_setprio(1);
#pragma unroll
    for (int mi = 0; mi < MI; mi++)
#pragma unroll
      for (int ni = 0; ni < NI; ni++)
        acc[mi][ni] = __builtin_amdgcn_mfma_f32_16x16x32_bf16(afr[mi], bfr[ni], acc[mi][ni], 0, 0, 0);
    __builtin_amdgcn_s_setprio(0);
    if (t + 1 < nt) {
      asm volatile("s_waitcnt lgkmcnt(0)" ::: "memory");
      if (t + 2 < nt) {
        asm volatile("s_waitcnt vmcnt(%0)" :: "i"(AW + BW) : "memory");
      } else {
        asm volatile("s_waitcnt vmcnt(0)" ::: "memory");
      }
      __builtin_amdgcn_s_barrier();
      asm volatile("" ::: "memory");
    }
  }

  const int cm4 = qq * 4;
#pragma unroll
  for (int mi = 0; mi < MI; mi++) {
#pragma unroll
    for (int ni = 0; ni < NI; ni++) {
#pragma unroll
      for (int r = 0; r < 4; r++) {
        const int grow = bm + ra0 + mi * 16 + cm4 + r;
        const int gcol = bn + rb0 + ni * 16 + fr;
        const size_t off = (size_t)grow * N + gcol;
        const float v = acc[mi][ni][r];
        if (EPI == 0) {
          Cb[off] = f2bf(v);
        } else if (EPI == 1) {
          Cf[off] += v;
        } else {
          Cb[off] = f2bf(siluf(bf2f(Cb[off])) * v);
        }
      }
    }
  }
}

// ---------------- ba = h @ ba_w^T ----------------
__global__ __launch_bounds__(256) void ba_gemm_kernel(const float* __restrict__ h_in,
                                                      const float* __restrict__ ba_w,
                                                      float* __restrict__ ba_out) {
  __shared__ __align__(16) float hl[2048];
  __shared__ float red[32][9];
  const int t = blockIdx.x;
  const int tid = threadIdx.x;
  const float4* hr = (const float4*)(h_in + (size_t)t * DMODEL);
  ((float4*)hl)[tid] = hr[tid];
  ((float4*)hl)[tid + 256] = hr[tid + 256];
  __syncthreads();
  const int c = tid & 31;
  const int p = tid >> 5;
  const float* wrow = ba_w + (size_t)c * DMODEL + p * 256;
  const float* hrow = hl + p * 256;
  float s = 0.f;
#pragma unroll 8
  for (int k = 0; k < 256; k++) s += hrow[k] * wrow[k];
  red[c][p] = s;
  __syncthreads();
  if (tid < 32) {
    float tot = 0.f;
#pragma unroll
    for (int q = 0; q < 8; q++) tot += red[tid][q];
    ba_out[(size_t)t * 32 + tid] = tot;
  }
}

// ---------------- extract z columns from bf16 qkvz ----------------
__global__ __launch_bounds__(256) void zcopy_kernel(const unsigned short* __restrict__ qkvz,
                                                    unsigned short* __restrict__ z) {
  const int idx = blockIdx.x * 256 + threadIdx.x;
  const int t = idx >> 8;
  const int c8 = (idx & 255) * 8;
  *(uint4*)(z + (size_t)t * 2048 + c8) =
      *(const uint4*)(qkvz + (size_t)t * CQKVZ + CQKV + c8);
}

// ---------------- causal depthwise conv (K=4) + SiLU; bf16 in, fp32 out ----------------
__global__ __launch_bounds__(256) void conv_silu_kernel(const unsigned short* __restrict__ qkvz,
                                                        const float* __restrict__ conv_w,
                                                        const float* __restrict__ mask,
                                                        float* __restrict__ mixed) {
  const int idx = blockIdx.x * 256 + threadIdx.x;
  const int c4 = (idx % 1536) * 4;
  const int t = idx / 1536;
  const float4 w0 = *(const float4*)(conv_w + (size_t)c4 * 4);
  const float4 w1 = *(const float4*)(conv_w + (size_t)c4 * 4 + 4);
  const float4 w2 = *(const float4*)(conv_w + (size_t)c4 * 4 + 8);
  const float4 w3 = *(const float4*)(conv_w + (size_t)c4 * 4 + 12);
  const float wj0[4] = {w0.x, w0.y, w0.z, w0.w};
  const float wj1[4] = {w1.x, w1.y, w1.z, w1.w};
  const float wj2[4] = {w2.x, w2.y, w2.z, w2.w};
  const float wj3[4] = {w3.x, w3.y, w3.z, w3.w};
  float4 acc = make_float4(0.f, 0.f, 0.f, 0.f);
#pragma unroll
  for (int j = 0; j < 4; j++) {
    const int tt = t - 3 + j;
    if (tt < 0) continue;
    const float m = mask[tt];
    const ushort4 xb = *(const ushort4*)(qkvz + (size_t)tt * CQKVZ + c4);
    acc.x += bf2f(xb.x) * m * wj0[j];
    acc.y += bf2f(xb.y) * m * wj1[j];
    acc.z += bf2f(xb.z) * m * wj2[j];
    acc.w += bf2f(xb.w) * m * wj3[j];
  }
  acc.x = siluf(acc.x); acc.y = siluf(acc.y); acc.z = siluf(acc.z); acc.w = siluf(acc.w);
  *(float4*)(mixed + (size_t)t * CQKV + c4) = acc;
}

// ---------------- l2norm over Dk=128 for q,k heads (in place, fp32) ----------------
__global__ __launch_bounds__(256) void l2norm_kernel(float* __restrict__ mixed) {
  const int r = blockIdx.x * 4 + (threadIdx.x >> 6);
  const int lane = threadIdx.x & 63;
  const int t = r >> 5;
  const int hh = r & 31;
  float* p = mixed + (size_t)t * CQKV + hh * 128 + lane * 2;
  float2 v = *(float2*)p;
  float s = v.x * v.x + v.y * v.y;
#pragma unroll
  for (int off = 32; off > 0; off >>= 1) s += __shfl_down(s, off);
  s = __shfl(s, 0);
  const float rn = rsqrtf(s + 1e-6f);
  v.x *= rn; v.y *= rn;
  *(float2*)p = v;
}

// ---------------- beta, g ----------------
__global__ __launch_bounds__(256) void beta_g_kernel(const float* __restrict__ ba,
                                                     const float* __restrict__ A_log,
                                                     const float* __restrict__ dt_bias,
                                                     const float* __restrict__ mask,
                                                     float* __restrict__ beta,
                                                     float* __restrict__ g) {
  const int idx = blockIdx.x * 256 + threadIdx.x;
  const int t = idx >> 4;
  const int h = idx & 15;
  const float b = ba[(size_t)t * 32 + h];
  const float a = ba[(size_t)t * 32 + 16 + h];
  const float m = mask[t];
  beta[idx] = m / (1.0f + expf(-b));
  const float xx = a + dt_bias[h];
  const float sp = (xx > 20.0f) ? xx : log1pf(expf(xx));
  g[idx] = -expf(A_log[h]) * sp * m;
}

// ---------------- per-chunk cumsum of g + decay factors ----------------
__global__ __launch_bounds__(256) void gcs_kernel(const float* __restrict__ g,
                                                  float* __restrict__ gcsbuf,
                                                  float* __restrict__ edkbuf,
                                                  float* __restrict__ egqbuf,
                                                  float* __restrict__ adecbuf) {
  const int idx = blockIdx.x * 256 + threadIdx.x;  // chunk id = h*64 + n
  if (idx >= 1024) return;
  const int h = idx >> 6;
  const int n = idx & 63;
  const int t0 = n * 64;
  float s = 0.f;
  for (int i = 0; i < 64; i++) {
    s += g[(size_t)(t0 + i) * NH + h];
    gcsbuf[(size_t)idx * 64 + i] = s;
  }
  const float glast = s;
  adecbuf[idx] = __expf(glast);
  for (int i = 0; i < 64; i++) {
    const float gi = gcsbuf[(size_t)idx * 64 + i];
    edkbuf[(size_t)idx * 64 + i] = __expf(glast - gi);
    egqbuf[(size_t)idx * 64 + i] = __expf(gi) * SCALE;
  }
}

// ---------------- per-chunk: A=(k_beta k^T)*decay (strict lower), attn=(q k^T)*decay*scale ----------------
__global__ __launch_bounds__(256) void pre_attn_kernel(const float* __restrict__ mixed,
                                                       const float* __restrict__ gcsbuf,
                                                       const float* __restrict__ betabuf,
                                                       float* __restrict__ abuf,
                                                       float* __restrict__ attnbuf) {
  __shared__ __align__(16) float kl[64][132];
  __shared__ float gcs_s[64];
  __shared__ float betal[64];
  const int blk = blockIdx.x;
  const int h = blk >> 6;
  const int n = blk & 63;
  const int t0 = n * 64;
  const int tid = threadIdx.x;
  if (tid < 64) {
    gcs_s[tid] = gcsbuf[(size_t)blk * 64 + tid];
    betal[tid] = betabuf[(size_t)(t0 + tid) * NH + h];
  }
#pragma unroll
  for (int rep = 0; rep < 8; rep++) {
    const int lin = rep * 256 + tid;
    const int i = lin >> 5;
    const int d = (lin & 31) * 4;
    const float4 kv = *(const float4*)(mixed + (size_t)(t0 + i) * CQKV + 2048 + h * 128 + d);
    *(float4*)&kl[i][d] = kv;
  }
  __syncthreads();
  const int cj = tid & 15;
  const int ri = tid >> 4;
  const int i0 = ri * 4, j0 = cj * 4;
  float accA[4][4], accQ[4][4];
#pragma unroll
  for (int a = 0; a < 4; a++)
#pragma unroll
    for (int b = 0; b < 4; b++) { accA[a][b] = 0.f; accQ[a][b] = 0.f; }
  const float* qbase = mixed + (size_t)t0 * CQKV + h * 128;
#pragma unroll 4
  for (int d = 0; d < 128; d++) {
    const float kj0 = kl[j0][d], kj1 = kl[j0 + 1][d], kj2 = kl[j0 + 2][d], kj3 = kl[j0 + 3][d];
#pragma unroll
    for (int a = 0; a < 4; a++) {
      const float ka = kl[i0 + a][d];
      const float qa = qbase[(size_t)(i0 + a) * CQKV + d];
      accA[a][0] += ka * kj0; accA[a][1] += ka * kj1; accA[a][2] += ka * kj2; accA[a][3] += ka * kj3;
      accQ[a][0] += qa * kj0; accQ[a][1] += qa * kj1; accQ[a][2] += qa * kj2; accQ[a][3] += qa * kj3;
    }
  }
#pragma unroll
  for (int a = 0; a < 4; a++) {
    const int i = i0 + a;
    const float gi = gcs_s[i];
    const float bi = betal[i];
    float4 Av, Qv;
    float dec;
    dec = __expf(fminf(gi - gcs_s[j0 + 0], 0.f));
    Av.x = (i > j0 + 0) ? accA[a][0] * bi * dec : 0.f;
    Qv.x = (i >= j0 + 0) ? accQ[a][0] * dec * SCALE : 0.f;
    dec = __expf(fminf(gi - gcs_s[j0 + 1], 0.f));
    Av.y = (i > j0 + 1) ? accA[a][1] * bi * dec : 0.f;
    Qv.y = (i >= j0 + 1) ? accQ[a][1] * dec * SCALE : 0.f;
    dec = __expf(fminf(gi - gcs_s[j0 + 2], 0.f));
    Av.z = (i > j0 + 2) ? accA[a][2] * bi * dec : 0.f;
    Qv.z = (i >= j0 + 2) ? accQ[a][2] * dec * SCALE : 0.f;
    dec = __expf(fminf(gi - gcs_s[j0 + 3], 0.f));
    Av.w = (i > j0 + 3) ? accA[a][3] * bi * dec : 0.f;
    Qv.w = (i >= j0 + 3) ? accQ[a][3] * dec * SCALE : 0.f;
    *(float4*)(abuf + (size_t)blk * 4096 + i * 64 + j0) = Av;
    *(float4*)(attnbuf + (size_t)blk * 4096 + i * 64 + j0) = Qv;
  }
}

// ---------------- per-chunk: T = (I+A)^-1, then T *= beta[col] ----------------
__global__ __launch_bounds__(256) void pre_solve_kernel(const float* __restrict__ abuf,
                                                        const float* __restrict__ betabuf,
                                                        float* __restrict__ tbuf) {
  __shared__ float Al[64][65];
  __shared__ float Tl[64][65];
  const int blk = blockIdx.x;
  const int h = blk >> 6;
  const int n = blk & 63;
  const int t0 = n * 64;
  const int tid = threadIdx.x;
#pragma unroll
  for (int rep = 0; rep < 4; rep++) {
    const int lin = rep * 256 + tid;
    const int i = lin >> 4;
    const int j = (lin & 15) * 4;
    const float4 av = *(const float4*)(abuf + (size_t)blk * 4096 + i * 64 + j);
    Al[i][j] = av.x; Al[i][j + 1] = av.y; Al[i][j + 2] = av.z; Al[i][j + 3] = av.w;
  }
  __syncthreads();
  if (tid < 64) {
    const int j = tid;
    const float bj = betabuf[(size_t)(t0 + j) * NH + h];
    for (int i = 0; i < 64; i++) {
      float s = (i == j) ? 1.0f : 0.0f;
      for (int l = j; l < i; l++) s -= Al[i][l] * Tl[l][j];
      Tl[i][j] = s;
    }
    for (int i = j; i < 64; i++) Tl[i][j] *= bj;
  }
  __syncthreads();
#pragma unroll
  for (int rep = 0; rep < 4; rep++) {
    const int lin = rep * 256 + tid;
    const int i = lin >> 4;
    const int j = (lin & 15) * 4;
    float4 tv;
    tv.x = Tl[i][j]; tv.y = Tl[i][j + 1]; tv.z = Tl[i][j + 2]; tv.w = Tl[i][j + 3];
    *(float4*)(tbuf + (size_t)blk * 4096 + i * 64 + j) = tv;
  }
}

// ---------------- per-chunk: u = Tb @ v (bf16, l4-packed [blk][l>>2][c][l&3]) ;
//                  w = Tb @ (k * e^gcs), stored NEGATED + slot-swizzled ----
__global__ __launch_bounds__(256) void pre_uw_kernel(const float* __restrict__ mixed,
                                                     const float* __restrict__ tbuf,
                                                     const float* __restrict__ gcsbuf,
                                                     unsigned short* __restrict__ ubf,
                                                     unsigned short* __restrict__ wbf) {
  __shared__ __align__(16) float Tl[64][68];
  __shared__ __align__(16) float xl[64][132];
  __shared__ float egcs[64];
  const int blk = blockIdx.x;
  const int h = blk >> 6;
  const int n = blk & 63;
  const int t0 = n * 64;
  const int tid = threadIdx.x;
  if (tid < 64) egcs[tid] = __expf(gcsbuf[(size_t)blk * 64 + tid]);
#pragma unroll
  for (int rep = 0; rep < 4; rep++) {
    const int lin = rep * 256 + tid;
    const int i = lin >> 4;
    const int j = (lin & 15) * 4;
    const float4 tv = *(const float4*)(tbuf + (size_t)blk * 4096 + i * 64 + j);
    *(float4*)&Tl[i][j] = tv;
  }
#pragma unroll
  for (int rep = 0; rep < 8; rep++) {
    const int lin = rep * 256 + tid;
    const int i = lin >> 5;
    const int d = (lin & 31) * 4;
    const float4 vv = *(const float4*)(mixed + (size_t)(t0 + i) * CQKV + 4096 + h * 128 + d);
    *(float4*)&xl[i][d] = vv;
  }
  __syncthreads();
  const int cgu = tid & 15;
  const int riu = tid >> 4;
  const int i0 = riu * 4;
  const int d0 = cgu * 8;
  float acc[4][8];
#pragma unroll
  for (int a = 0; a < 4; a++)
#pragma unroll
    for (int b = 0; b < 8; b++) acc[a][b] = 0.f;
#pragma unroll 2
  for (int j = 0; j < 64; j++) {
    const float tv[4] = {Tl[i0][j], Tl[i0 + 1][j], Tl[i0 + 2][j], Tl[i0 + 3][j]};
    const float4 x0 = *(const float4*)&xl[j][d0];
    const float4 x1 = *(const float4*)&xl[j][d0 + 4];
    const float xv[8] = {x0.x, x0.y, x0.z, x0.w, x1.x, x1.y, x1.z, x1.w};
#pragma unroll
    for (int a = 0; a < 4; a++)
#pragma unroll
      for (int b = 0; b < 8; b++) acc[a][b] += tv[a] * xv[b];
  }
  // u store: bf16 l4-packed layout elem = blk*8192 + riu*512 + (d0+b)*4 + (l&3)
#pragma unroll
  for (int b = 0; b < 8; b++) {
    *(ushort4*)(ubf + (size_t)blk * 8192 + riu * 512 + (size_t)(d0 + b) * 4) =
        pack4(acc[0][b], acc[1][b], acc[2][b], acc[3][b]);
  }
  __syncthreads();
#pragma unroll
  for (int rep = 0; rep < 8; rep++) {
    const int lin = rep * 256 + tid;
    const int i = lin >> 5;
    const int d = (lin & 31) * 4;
    float4 kv = *(const float4*)(mixed + (size_t)(t0 + i) * CQKV + 2048 + h * 128 + d);
    const float e = egcs[i];
    kv.x *= e; kv.y *= e; kv.z *= e; kv.w *= e;
    *(float4*)&xl[i][d] = kv;
  }
  __syncthreads();
#pragma unroll
  for (int a = 0; a < 4; a++)
#pragma unroll
    for (int b = 0; b < 8; b++) acc[a][b] = 0.f;
#pragma unroll 2
  for (int j = 0; j < 64; j++) {
    const float tv[4] = {Tl[i0][j], Tl[i0 + 1][j], Tl[i0 + 2][j], Tl[i0 + 3][j]};
    const float4 x0 = *(const float4*)&xl[j][d0];
    const float4 x1 = *(const float4*)&xl[j][d0 + 4];
    const float xv[8] = {x0.x, x0.y, x0.z, x0.w, x1.x, x1.y, x1.z, x1.w};
#pragma unroll
    for (int a = 0; a < 4; a++)
#pragma unroll
      for (int b = 0; b < 8; b++) acc[a][b] += tv[a] * xv[b];
  }
  // store -w, column-slot swizzled by (row&7) so scan can global_load_lds linearly
#pragma unroll
  for (int a = 0; a < 4; a++) {
    const int l = i0 + a;
    unsigned short* wp = wbf + (size_t)(t0 + l) * 2048 + h * 128 + ((cgu ^ (l & 7)) << 3);
    *(ushort4*)wp = pack4(-acc[a][0], -acc[a][1], -acc[a][2], -acc[a][3]);
    *(ushort4*)(wp + 4) = pack4(-acc[a][4], -acc[a][5], -acc[a][6], -acc[a][7]);
  }
}

// ---------------- per-chunk: kdT[blk][d][l] = bf16(k*edk) slot-swizzled; qe = bf16(q*egq) ----------------
__global__ __launch_bounds__(256) void ktrans_kernel(const float* __restrict__ mixed,
                                                     const float* __restrict__ edkbuf,
                                                     const float* __restrict__ egqbuf,
                                                     unsigned short* __restrict__ kdT,
                                                     unsigned short* __restrict__ qe) {
  __shared__ __align__(16) float kl[64][132];
  __shared__ float edk_s[64];
  __shared__ float egq_s[64];
  const int blk = blockIdx.x;
  const int h = blk >> 6;
  const int n = blk & 63;
  const int t0 = n * 64;
  const int tid = threadIdx.x;
  if (tid < 64) {
    edk_s[tid] = edkbuf[(size_t)blk * 64 + tid];
    egq_s[tid] = egqbuf[(size_t)blk * 64 + tid];
  }
#pragma unroll
  for (int q = 0; q < 8; q++) {
    const int idx = tid + q * 256;
    const int l = idx >> 5, c4 = (idx & 31) * 4;
    *(float4*)&kl[l][c4] = *(const float4*)(mixed + (size_t)(t0 + l) * CQKV + 2048 + h * 128 + c4);
  }
  __syncthreads();
#pragma unroll
  for (int q = 0; q < 4; q++) {
    const int idx = tid + q * 256;
    const int d = idx >> 3, lsl = idx & 7;
    const int l8 = lsl * 8;
    float v[8];
#pragma unroll
    for (int j = 0; j < 8; j++) v[j] = kl[l8 + j][d] * edk_s[l8 + j];
    unsigned short* p = kdT + (size_t)blk * 8192 + d * 64 + ((lsl ^ (d & 7)) << 3);
    *(ushort4*)p = pack4(v[0], v[1], v[2], v[3]);
    *(ushort4*)(p + 4) = pack4(v[4], v[5], v[6], v[7]);
  }
#pragma unroll
  for (int q = 0; q < 8; q++) {
    const int idx = tid + q * 256;
    const int i = idx >> 5, c4 = (idx & 31) * 4;
    const float4 v = *(const float4*)(mixed + (size_t)(t0 + i) * CQKV + h * 128 + c4);
    const float e = egq_s[i];
    *(ushort4*)(qe + (size_t)(t0 + i) * 2048 + h * 128 + c4) =
        pack4(v.x * e, v.y * e, v.z * e, v.w * e);
  }
}

// ---------------- MFMA scan, column-decomposed: 8 waves x 16 c-columns, NO cross-wave data ---
// u read bf16 l4-packed (4x ushort4 per chunk). Exports d4/l4-packed (coalesced).
// blocks 0..15: per-head scan; ONE barrier/chunk (counted vmcnt(17)).
// blocks >=16: weight f2b (Wgu interleaved / Wd / Wo) + residual copy (512 threads).
__global__ __launch_bounds__(512, 1) void scan_kernel(const unsigned short* __restrict__ wbf,
                                                      const unsigned short* __restrict__ kdT,
                                                      const unsigned short* __restrict__ ubf,
                                                      const float* __restrict__ adecbuf,
                                                      unsigned short* __restrict__ STb,
                                                      unsigned short* __restrict__ vtb,
                                                      const float* __restrict__ gw,
                                                      const float* __restrict__ uw,
                                                      const float* __restrict__ dw,
                                                      const float* __restrict__ ow,
                                                      const float* __restrict__ xin,
                                                      unsigned short* __restrict__ Wgu,
                                                      unsigned short* __restrict__ Wd,
                                                      unsigned short* __restrict__ Wo,
                                                      float* __restrict__ outc) {
  __shared__ __align__(16) unsigned short stage[2][16384];  // [w 8192 | kT 8192] shorts each
  __shared__ __align__(16) unsigned short privAll[8][3072]; // per wave: A 16x128 | B 16x64
  if (blockIdx.x >= 16) {
    // side work (512 thr): Wg 4096 + Wu 4096 + Wd 4096 + Wo 1024 + copy 2048 = 15360 blocks
    const int xb = blockIdx.x - 16;
    const int tid = threadIdx.x;
    if (xb < 8192) {
      // gate/up f2b with 16-row interleave into Wgu:
      // src row r -> dst row (r>>4)*32 + (r&15) (+16 for up)
      const bool isUp = (xb >= 4096);
      const float* src = isUp ? uw : gw;
      const size_t e = ((size_t)(isUp ? xb - 4096 : xb) * 512 + tid) * 8;
      const int r = (int)(e >> 11);
      const int col = (int)(e & 2047);
      const int drow = (r >> 4) * 32 + (r & 15) + (isUp ? 16 : 0);
      const float4 a = *(const float4*)(src + e);
      const float4 b = *(const float4*)(src + e + 4);
      unsigned short* dst = Wgu + (size_t)drow * 2048 + col;
      *(ushort4*)dst = pack4(a.x, a.y, a.z, a.w);
      *(ushort4*)(dst + 4) = pack4(b.x, b.y, b.z, b.w);
    } else if (xb < 13312) {
      const float* src; unsigned short* dst; size_t u;
      if (xb < 12288) { src = dw; dst = Wd; u = (size_t)(xb - 8192) * 512 + tid; }
      else            { src = ow; dst = Wo; u = (size_t)(xb - 12288) * 512 + tid; }
      const float4 a = ((const float4*)src)[2 * u];
      const float4 b = ((const float4*)src)[2 * u + 1];
      ((ushort4*)dst)[2 * u] = pack4(a.x, a.y, a.z, a.w);
      ((ushort4*)dst)[2 * u + 1] = pack4(b.x, b.y, b.z, b.w);
    } else {
      const size_t i = (size_t)(xb - 13312) * 512 + tid;
      ((float4*)outc)[2 * i] = ((const float4*)xin)[2 * i];
      ((float4*)outc)[2 * i + 1] = ((const float4*)xin)[2 * i + 1];
    }
    return;
  }
  const int h = blockIdx.x;
  const int tid = threadIdx.x;
  const int ln = tid & 63;
  const int wv = tid >> 6;        // 0..7
  const int fr = ln & 15;
  const int g  = ln >> 4;         // 0..3
  const int c0 = wv * 16;
  const int fsw = fr & 7;
  unsigned short* privA = &privAll[wv][0];     // [16 c][128 d], slot-swizzled
  unsigned short* privB = &privAll[wv][2048];  // [16 c][64 l], slot-swizzled
  const f32x4 zero = {0.f, 0.f, 0.f, 0.f};

  f32x4 acc2[8];                  // S^T state for this wave's 16 columns, d-tile dt
#pragma unroll
  for (int dt = 0; dt < 8; dt++) acc2[dt] = zero;

  auto stage_wk = [&](int buf, int n1) {
    const int t0n = n1 * 64;
    const size_t kbase = (size_t)(h * 64 + n1) * 8192;
#pragma unroll
    for (int q = 0; q < 2; q++) {
      const int m = wv * 2 + q;   // 0..15
      gl_lds16(wbf + (size_t)(t0n + m * 4 + (ln >> 4)) * 2048 + h * 128 + (ln & 15) * 8,
               &stage[buf][m * 512]);
      gl_lds16(kdT + kbase + (m * 8 + (ln >> 3)) * 64 + (ln & 7) * 8,
               &stage[buf][8192 + m * 512]);
    }
  };

  // prologue: u/adec for chunk 0 + stage chunk 0
  ushort4 ur4[4];
#pragma unroll
  for (int lt = 0; lt < 4; lt++)
    ur4[lt] = *(const ushort4*)(ubf + (size_t)(h * 64) * 8192 + (lt * 4 + g) * 512 + (c0 + fr) * 4);
  float ad = adecbuf[h * 64];
  stage_wk(0, 0);
  asm volatile("s_waitcnt vmcnt(0)" ::: "memory");
  __builtin_amdgcn_s_barrier();
  asm volatile("" ::: "memory");

  for (int n = 0; n < 64; n++) {
    const int blk = h * 64 + n;
    const unsigned short* wl = &stage[n & 1][0];
    const unsigned short* kl = &stage[n & 1][8192];
    // (1) issue staging for n+1 first (oldest VMEM ops of this chunk)
    if (n + 1 < 64) stage_wk((n + 1) & 1, n + 1);
    __builtin_amdgcn_sched_barrier(0);
    // (2) prefetch u/adec for n+1 (4 ushort4 + 1 scalar; younger than staging)
    ushort4 ur4n[4];
    float adn = 0.f;
    if (n + 1 < 64) {
      const size_t ub = (size_t)(blk + 1) * 8192;
#pragma unroll
      for (int lt = 0; lt < 4; lt++)
        ur4n[lt] = *(const ushort4*)(ubf + ub + (lt * 4 + g) * 512 + (c0 + fr) * 4);
      adn = adecbuf[blk + 1];
    } else {
#pragma unroll
      for (int lt = 0; lt < 4; lt++) { ur4n[lt].x = 0; ur4n[lt].y = 0; ur4n[lt].z = 0; ur4n[lt].w = 0; }
    }
    __builtin_amdgcn_sched_barrier(0);
    // (3) dump S_n^T -> privA (wave-private) ; export S_n coalesced (d4-packed)
#pragma unroll
    for (int dt = 0; dt < 8; dt++) {
      const int slot = dt * 2 + (g >> 1);
      const ushort4 pv = pack4(acc2[dt][0], acc2[dt][1], acc2[dt][2], acc2[dt][3]);
      *(ushort4*)&privA[fr * 128 + ((slot ^ fsw) << 3) + (g & 1) * 4] = pv;
      *(ushort4*)(STb + (size_t)blk * 16384 + (dt * 4 + g) * 512 + (c0 + fr) * 4) = pv;
    }
    // (4) MFMA1: v_new = u + (-w) @ S  (A from shared staged w, B from privA)
    f32x4 acc1[4];
#pragma unroll
    for (int lt = 0; lt < 4; lt++) {
      f32x4 t;
      t[0] = bf2f(ur4[lt].x); t[1] = bf2f(ur4[lt].y);
      t[2] = bf2f(ur4[lt].z); t[3] = bf2f(ur4[lt].w);
      acc1[lt] = t;
    }
#pragma unroll
    for (int ks = 0; ks < 4; ks++) {
      const int kb = ks * 4 + g;
      const bf16x8 b = *(const bf16x8*)&privA[fr * 128 + ((kb ^ fsw) << 3)];
#pragma unroll
      for (int lt = 0; lt < 4; lt++) {
        const bf16x8 a = *(const bf16x8*)&wl[(lt * 16 + fr) * 128 + ((kb ^ fsw) << 3)];
        acc1[lt] = __builtin_amdgcn_mfma_f32_16x16x32_bf16(a, b, acc1[lt], 0, 0, 0);
      }
    }
    // (5) v_new^T -> privB ; export v_new^T coalesced (l4-packed)
#pragma unroll
    for (int lt = 0; lt < 4; lt++) {
      const int slot = lt * 2 + (g >> 1);
      const ushort4 pv = pack4(acc1[lt][0], acc1[lt][1], acc1[lt][2], acc1[lt][3]);
      *(ushort4*)&privB[fr * 64 + ((slot ^ fsw) << 3) + (g & 1) * 4] = pv;
      *(ushort4*)(vtb + (size_t)blk * 8192 + (lt * 4 + g) * 512 + (c0 + fr) * 4) = pv;
    }
    // (6) MFMA2: S = adec*S + kdec^T @ v_new
#pragma unroll
    for (int dt = 0; dt < 8; dt++) {
      acc2[dt][0] *= ad; acc2[dt][1] *= ad; acc2[dt][2] *= ad; acc2[dt][3] *= ad;
    }
#pragma unroll
    for (int ks = 0; ks < 2; ks++) {
      const int kb = ks * 4 + g;
      const bf16x8 b = *(const bf16x8*)&privB[fr * 64 + ((kb ^ fsw) << 3)];
#pragma unroll
      for (int dt = 0; dt < 8; dt++) {
        const bf16x8 a = *(const bf16x8*)&kl[(dt * 16 + fr) * 64 + ((kb ^ fsw) << 3)];
        acc2[dt] = __builtin_amdgcn_mfma_f32_16x16x32_bf16(a, b, acc2[dt], 0, 0, 0);
      }
    }
    // (7) roll prefetched operands
#pragma unroll
    for (int lt = 0; lt < 4; lt++) ur4[lt] = ur4n[lt];
    ad = adn;
    // (8) publish staging: counted vmcnt (youngest 17 = 4 u + 1 adec + 12 export stores)
    if (n + 1 < 64) {
      asm volatile("s_waitcnt lgkmcnt(0)" ::: "memory");
      __builtin_amdgcn_sched_barrier(0);
      asm volatile("s_waitcnt vmcnt(17)" ::: "memory");
      __builtin_amdgcn_sched_barrier(0);
      __builtin_amdgcn_s_barrier();
      __builtin_amdgcn_sched_barrier(0);
    }
  }
}

// ---------------- MFMA o-compute + fused gated RMSNorm (reads d4/l4-packed ST/vt) ----------------
__global__ __launch_bounds__(256) void ocomp_kernel(const unsigned short* __restrict__ qe,
                                                    const unsigned short* __restrict__ STbuf,
                                                    const unsigned short* __restrict__ vtbuf,
                                                    const float* __restrict__ attnbuf,
                                                    const unsigned short* __restrict__ zb,
                                                    const float* __restrict__ onw,
                                                    unsigned short* __restrict__ ob) {
  __shared__ __align__(16) unsigned short STl[128 * 128];  // [c][d]
  __shared__ __align__(16) unsigned short vtl[128 * 64];   // [c][l]
  __shared__ __align__(16) unsigned short ql[64 * 128];    // [i][d]
  __shared__ __align__(16) unsigned short al[64 * 64];     // [i][l]
  const int blk = blockIdx.x;
  const int h = blk >> 6;
  const int n = blk & 63;
  const int t0 = n * 64;
  const int tid = threadIdx.x;
  // ST: d4-packed -> [c][d] swizzled LDS. uint4 o covers (dq = o>>6, cols 2w,2w+1, w = o&63)
#pragma unroll
  for (int q = 0; q < 8; q++) {
    const int o = tid + q * 256;
    const int dq = o >> 6, w = o & 63;
    const uint4 v = *(const uint4*)(STbuf + (size_t)blk * 16384 + (size_t)o * 8);
    const int cA = 2 * w, cB = 2 * w + 1;
    uint2 h0; h0.x = v.x; h0.y = v.y;
    uint2 h1; h1.x = v.z; h1.y = v.w;
    *(uint2*)&STl[cA * 128 + (((dq >> 1) ^ (cA & 7)) << 3) + (dq & 1) * 4] = h0;
    *(uint2*)&STl[cB * 128 + (((dq >> 1) ^ (cB & 7)) << 3) + (dq & 1) * 4] = h1;
  }
  // vt: l4-packed -> [c][l] swizzled LDS
#pragma unroll
  for (int q = 0; q < 4; q++) {
    const int o = tid + q * 256;
    const int lq = o >> 6, w = o & 63;
    const uint4 v = *(const uint4*)(vtbuf + (size_t)blk * 8192 + (size_t)o * 8);
    const int cA = 2 * w, cB = 2 * w + 1;
    uint2 h0; h0.x = v.x; h0.y = v.y;
    uint2 h1; h1.x = v.z; h1.y = v.w;
    *(uint2*)&vtl[cA * 64 + (((lq >> 1) ^ (cA & 7)) << 3) + (lq & 1) * 4] = h0;
    *(uint2*)&vtl[cB * 64 + (((lq >> 1) ^ (cB & 7)) << 3) + (lq & 1) * 4] = h1;
  }
#pragma unroll
  for (int q = 0; q < 4; q++) {
    const int idx = tid + q * 256;
    const int i = idx >> 4, dg = idx & 15;
    *(uint4*)&ql[i * 128 + ((dg ^ (i & 7)) << 3)] =
        *(const uint4*)(qe + (size_t)(t0 + i) * 2048 + h * 128 + dg * 8);
  }
#pragma unroll
  for (int q = 0; q < 4; q++) {
    const int idx = tid + q * 256;
    const int i = idx >> 4, l4 = (idx & 15) * 4;
    const float4 v = *(const float4*)(attnbuf + (size_t)blk * 4096 + i * 64 + l4);
    *(ushort4*)&al[i * 64 + (((l4 >> 3) ^ (i & 7)) << 3) + (l4 & 7)] =
        pack4(v.x, v.y, v.z, v.w);
  }
  __syncthreads();
  const int ln = tid & 63;
  const int wv = tid >> 6;
  const int fr = ln & 15;
  const int g = ln >> 4;
  const int i0 = wv * 16;
  f32x4 acc[8];
  const f32x4 zero = {0.f, 0.f, 0.f, 0.f};
#pragma unroll
  for (int nt = 0; nt < 8; nt++) acc[nt] = zero;
#pragma unroll
  for (int ks = 0; ks < 4; ks++) {
    const int kb = ks * 4 + g;
    const int ar = i0 + fr;
    const bf16x8 a = *(const bf16x8*)&ql[ar * 128 + ((kb ^ (ar & 7)) << 3)];
#pragma unroll
    for (int nt = 0; nt < 8; nt++) {
      const int c = nt * 16 + fr;
      const bf16x8 b = *(const bf16x8*)&STl[c * 128 + ((kb ^ (c & 7)) << 3)];
      acc[nt] = __builtin_amdgcn_mfma_f32_16x16x32_bf16(a, b, acc[nt], 0, 0, 0);
    }
  }
#pragma unroll
  for (int ks = 0; ks < 2; ks++) {
    const int kb = ks * 4 + g;
    const int ar = i0 + fr;
    const bf16x8 a = *(const bf16x8*)&al[ar * 64 + ((kb ^ (ar & 7)) << 3)];
#pragma unroll
    for (int nt = 0; nt < 8; nt++) {
      const int c = nt * 16 + fr;
      const bf16x8 b = *(const bf16x8*)&vtl[c * 64 + ((kb ^ (c & 7)) << 3)];
      acc[nt] = __builtin_amdgcn_mfma_f32_16x16x32_bf16(a, b, acc[nt], 0, 0, 0);
    }
  }
  float s0 = 0.f, s1 = 0.f, s2 = 0.f, s3 = 0.f;
#pragma unroll
  for (int nt = 0; nt < 8; nt++) {
    s0 += acc[nt][0] * acc[nt][0];
    s1 += acc[nt][1] * acc[nt][1];
    s2 += acc[nt][2] * acc[nt][2];
    s3 += acc[nt][3] * acc[nt][3];
  }
#pragma unroll
  for (int m = 1; m < 16; m <<= 1) {
    s0 += __shfl_xor(s0, m);
    s1 += __shfl_xor(s1, m);
    s2 += __shfl_xor(s2, m);
    s3 += __shfl_xor(s3, m);
  }
  float rn[4];
  rn[0] = rsqrtf(s0 * (1.0f / 128.0f) + 1e-5f);
  rn[1] = rsqrtf(s1 * (1.0f / 128.0f) + 1e-5f);
  rn[2] = rsqrtf(s2 * (1.0f / 128.0f) + 1e-5f);
  rn[3] = rsqrtf(s3 * (1.0f / 128.0f) + 1e-5f);
#pragma unroll
  for (int nt = 0; nt < 8; nt++) {
    const int c = nt * 16 + fr;
    const float wn = onw[c];
#pragma unroll
    for (int r = 0; r < 4; r++) {
      const size_t off = (size_t)(t0 + i0 + g * 4 + r) * 2048 + h * 128 + c;
      const float zz = siluf(bf2f(zb[off]));
      ob[off] = f2bf(acc[nt][r] * rn[r] * wn * zz);
    }
  }
}

extern "C" void kernel_launch(void* const* d_in, const int* in_sizes, int n_in,
                              void* d_out, int out_size, void* d_ws, size_t ws_size,
                              hipStream_t stream) {
  (void)in_sizes; (void)n_in; (void)out_size;
  const float* x        = (const float*)d_in[0];
  const float* mask     = (const float*)d_in[1];
  const float* ln1_w    = (const float*)d_in[2];
  const float* qkvz_w   = (const float*)d_in[3];
  const float* ba_w     = (const float*)d_in[4];
  const float* conv_w   = (const float*)d_in[5];
  const float* A_log    = (const float*)d_in[6];
  const float* dt_bias  = (const float*)d_in[7];
  const float* o_norm_w = (const float*)d_in[8];
  const float* out_w    = (const float*)d_in[9];
  const float* ln2_w    = (const float*)d_in[10];
  const float* gate_w   = (const float*)d_in[11];
  const float* up_w     = (const float*)d_in[12];
  const float* down_w   = (const float*)d_in[13];
  float* out = (float*)d_out;

  const size_t NEED_BYTES = (size_t)75825152 * 4;
  if (ws_size < NEED_BYTES) return;

  float* ws = (float*)d_ws;
  float* mixed_buf = ws;
  unsigned short* Wgu = (unsigned short*)ws;                 // [16384][2048] bf16, 16-col interleaved
  unsigned short* Wd = (unsigned short*)(ws + 16777216);
  unsigned short* qkvz_bf = (unsigned short*)(ws + 25165824);
  unsigned short* u_bf = (unsigned short*)(ws + 25165824);   // 1024 x 8192 bf16 (16 MB)
  unsigned short* wbf = (unsigned short*)(ws + 33554432);
  unsigned short* kdT = (unsigned short*)(ws + 37748736);
  unsigned short* comb_bf = (unsigned short*)(ws + 25165824);
  unsigned short* z_bf = (unsigned short*)(ws + 41943040);
  float* h_buf = ws + 46137344;
  float* a_buf = ws + 46137344;
  unsigned short* vt_buf = (unsigned short*)(ws + 46137344);
  float* t_buf = ws + 50331648;
  unsigned short* qe_bf = (unsigned short*)(ws + 50331648);  // after pre_uw, t_buf is dead
  unsigned short* h_bf  = (unsigned short*)(ws + 54525952);
  unsigned short* ob    = (unsigned short*)(ws + 54525952);
  unsigned short* h2_bf = (unsigned short*)(ws + 54525952);
  float* attn_buf = ws + 58720256;
  unsigned short* Wq = (unsigned short*)(ws + 62914560);
  unsigned short* ST_buf = (unsigned short*)(ws + 62914560);
  unsigned short* Wo = (unsigned short*)(ws + 71303168);
  float* ba_buf   = ws + 73400320;
  float* beta_buf = ws + 73531392;
  float* g_buf    = ws + 73596928;
  float* gcs_buf  = ws + 73662464;
  float* edk_buf  = ws + 73728000;
  float* egq_buf  = ws + 73793536;
  float* adec_buf = ws + 73859072;

  rmsnorm_kernel<1><<<4096, 256, 0, stream>>>(x, ln1_w, h_buf, h_bf);
  f2b_kernel<<<8192, 256, 0, stream>>>(qkvz_w, Wq);
  gemm8p_kernel<0><<<512, 512, 0, stream>>>(h_bf, Wq, nullptr, qkvz_bf, 4096, 8192, 2048);
  ba_gemm_kernel<<<4096, 256, 0, stream>>>(h_buf, ba_w, ba_buf);
  zcopy_kernel<<<4096, 256, 0, stream>>>(qkvz_bf, z_bf);
  conv_silu_kernel<<<24576, 256, 0, stream>>>(qkvz_bf, conv_w, mask, mixed_buf);
  l2norm_kernel<<<32768, 256, 0, stream>>>(mixed_buf);
  beta_g_kernel<<<256, 256, 0, stream>>>(ba_buf, A_log, dt_bias, mask, beta_buf, g_buf);
  gcs_kernel<<<4, 256, 0, stream>>>(g_buf, gcs_buf, edk_buf, egq_buf, adec_buf);
  pre_attn_kernel<<<1024, 256, 0, stream>>>(mixed_buf, gcs_buf, beta_buf, a_buf, attn_buf);
  pre_solve_kernel<<<1024, 256, 0, stream>>>(a_buf, beta_buf, t_buf);
  pre_uw_kernel<<<1024, 256, 0, stream>>>(mixed_buf, t_buf, gcs_buf, u_bf, wbf);
  ktrans_kernel<<<1024, 256, 0, stream>>>(mixed_buf, edk_buf, egq_buf, kdT, qe_bf);
  // column-decomposed MFMA scan (16 blocks, 8 waves) + fused f2b/copy (15360 blocks)
  scan_kernel<<<15376, 512, 0, stream>>>(wbf, kdT, u_bf, adec_buf, ST_buf, vt_buf,
                                         gate_w, up_w, down_w, out_w, x,
                                         Wgu, Wd, Wo, out);
  ocomp_kernel<<<1024, 256, 0, stream>>>(qe_bf, ST_buf, vt_buf, attn_buf,
                                         z_bf, o_norm_w, ob);
  gemm256_kernel<1, 128, 128><<<512, 512, 0, stream>>>(ob, Wo, out, nullptr, 4096, 2048, 2048);
  rmsnorm_kernel<2><<<4096, 256, 0, stream>>>(out, ln2_w, nullptr, h2_bf);
  // fused gate+up: N=16384 interleaved weights, epilogue writes silu(gate)*up (4096x8192 bf16)
  gemm8p_kernel<3><<<1024, 512, 0, stream>>>(h2_bf, Wgu, nullptr, comb_bf, 4096, 16384, 2048);
  gemm256_kernel<1, 128, 128><<<512, 512, 0, stream>>>(comb_bf, Wd, out, nullptr, 4096, 2048, 8192);
}

// Round 16
// 1276.789 us; speedup vs baseline: 1.3686x; 1.0157x over previous
//
#include <hip/hip_runtime.h>
#include <math.h>

#define T_LEN 4096
#define DMODEL 2048
#define NH 16
#define CQKV 6144
#define CQKVZ 8192
#define SCALE 0.08838834764831845f   // 128^-0.5

using bf16x8 = __attribute__((ext_vector_type(8))) short;
using f32x4  = __attribute__((ext_vector_type(4))) float;

__device__ __forceinline__ float siluf(float x) { return x / (1.0f + __expf(-x)); }

__device__ __forceinline__ unsigned short f2bf(float f) {  // RNE
  unsigned int u = __float_as_uint(f);
  u = (u + 0x7FFFu + ((u >> 16) & 1u)) >> 16;
  return (unsigned short)u;
}
__device__ __forceinline__ float bf2f(unsigned short u) {
  return __uint_as_float(((unsigned int)u) << 16);
}
__device__ __forceinline__ ushort4 pack4(float a, float b, float c, float d) {
  ushort4 r; r.x = f2bf(a); r.y = f2bf(b); r.z = f2bf(c); r.w = f2bf(d); return r;
}

// async global->LDS, 16 bytes per lane; LDS dest is wave-uniform base (+ lane*16 implicit)
__device__ __forceinline__ void gl_lds16(const unsigned short* g, unsigned short* l) {
  __builtin_amdgcn_global_load_lds(
      (const __attribute__((address_space(1))) void*)g,
      (__attribute__((address_space(3))) void*)l, 16, 0, 0);
}

// ---------------- RMSNorm over D=2048; MODE: 1 = f32+bf16, 2 = bf16 only ----------------
template<int MODE>
__global__ __launch_bounds__(256) void rmsnorm_kernel(const float* __restrict__ x,
                                                      const float* __restrict__ w,
                                                      float* __restrict__ outf,
                                                      unsigned short* __restrict__ outb) {
  const int t = blockIdx.x;
  const int tid = threadIdx.x;
  const float4* xr = (const float4*)(x + (size_t)t * DMODEL);
  float4 v0 = xr[tid];
  float4 v1 = xr[tid + 256];
  float s = v0.x*v0.x + v0.y*v0.y + v0.z*v0.z + v0.w*v0.w
          + v1.x*v1.x + v1.y*v1.y + v1.z*v1.z + v1.w*v1.w;
#pragma unroll
  for (int off = 32; off > 0; off >>= 1) s += __shfl_down(s, off);
  __shared__ float red[4];
  if ((tid & 63) == 0) red[tid >> 6] = s;
  __syncthreads();
  const float tot = red[0] + red[1] + red[2] + red[3];
  const float r = rsqrtf(tot * (1.0f / DMODEL) + 1e-5f);
  const float4* wr = (const float4*)w;
  const float4 w0 = wr[tid], w1 = wr[tid + 256];
  float4 o0, o1;
  o0.x = v0.x*r*w0.x; o0.y = v0.y*r*w0.y; o0.z = v0.z*r*w0.z; o0.w = v0.w*r*w0.w;
  o1.x = v1.x*r*w1.x; o1.y = v1.y*r*w1.y; o1.z = v1.z*r*w1.z; o1.w = v1.w*r*w1.w;
  if (MODE == 1) {
    float4* orow = (float4*)(outf + (size_t)t * DMODEL);
    orow[tid] = o0;
    orow[tid + 256] = o1;
  }
  ushort4* brow = (ushort4*)(outb + (size_t)t * DMODEL);
  brow[tid] = pack4(o0.x, o0.y, o0.z, o0.w);
  brow[tid + 256] = pack4(o1.x, o1.y, o1.z, o1.w);
}

// ---------------- fp32 -> bf16 bulk convert ----------------
__global__ __launch_bounds__(256) void f2b_kernel(const float* __restrict__ in,
                                                  unsigned short* __restrict__ out) {
  const size_t i = (size_t)blockIdx.x * 256 + threadIdx.x;
  const float4 a = ((const float4*)in)[2 * i];
  const float4 b = ((const float4*)in)[2 * i + 1];
  ((ushort4*)out)[2 * i] = pack4(a.x, a.y, a.z, a.w);
  ((ushort4*)out)[2 * i + 1] = pack4(b.x, b.y, b.z, b.w);
}

// ---------------- 4-phase slot-pipelined 256x256 bf16 MFMA GEMM (fat shapes): C = A @ B^T ---
// EPI: 0 = bf16 store; 3 = paired silu(gate)*up combine (B is 16-col-interleaved Wg/Wu,
// N=16384, output 4096x8192 bf16).
template<int EPI>
__global__ __launch_bounds__(512, 2) void gemm8p_kernel(const unsigned short* __restrict__ A,
                                                        const unsigned short* __restrict__ B,
                                                        float* __restrict__ Cf,
                                                        unsigned short* __restrict__ Cb,
                                                        int M, int N, int K) {
  __shared__ __align__(16) unsigned short lds[8][8192];   // 8 slots x 16 KB
  const int nbm = M >> 8, nbn = N >> 8, nwg = nbm * nbn;
  const int nt = K >> 6;   // K-tiles of 64
  int bmi, bni;
  {
    const int bid = blockIdx.x;
    const int cpx = nwg >> 3;
    int sc = 1;
    while (sc * sc < cpx) sc <<= 1;
    if (sc * sc > cpx) sc >>= 1;
    const int scn = (sc > 0) ? (cpx / sc) : 0;
    if ((nwg & 7) == 0 && sc > 0 && sc * scn == cpx && (nbm % sc) == 0 && (nbn % scn) == 0) {
      const int chunk = bid & 7, widx = bid >> 3;
      const int regc = nbn / scn;
      bmi = (chunk / regc) * sc + widx / scn;
      bni = (chunk % regc) * scn + widx % scn;
    } else {
      bmi = bid / nbn; bni = bid % nbn;
    }
  }
  const int bm = bmi << 8, bn = bni << 8;
  const int tid = threadIdx.x;
  const int wv = tid >> 6, ln = tid & 63;
  const int fr = ln & 15, qq = ln >> 4;
  const int wm = wv >> 2, wn = wv & 3;           // wave tile: rows wm*128, cols wn*64
  const int rsw = (fr >> 1) & 3;                 // read swizzle term
  const int s_sl = (ln & 3) ^ ((ln >> 3) & 3);   // staging source slot (inverse swizzle)

  f32x4 acc[8][4];
  const f32x4 zero = {0.f, 0.f, 0.f, 0.f};
#pragma unroll
  for (int mf = 0; mf < 8; mf++)
#pragma unroll
    for (int nf = 0; nf < 4; nf++) acc[mf][nf] = zero;

  bf16x8 afr[8], bfr[2];

  // stage one half: part 0=Ak0, 1=Ak1, 2=Bk0, 3=Bk1 of tile t2 -> slot ((t2&1)<<2)|part
  auto stage_half = [&](int t2, int part) {
    if (t2 >= nt) return;
    const unsigned short* Mat = (part >= 2) ? B : A;
    const int gb = (part >= 2) ? bn : bm;
    const int kk = part & 1;
    const int slot = ((t2 & 1) << 2) | part;
    const int k0 = t2 * 64 + kk * 32;
#pragma unroll
    for (int q = 0; q < 2; q++) {
      gl_lds16(Mat + (size_t)(gb + wv * 32 + q * 16 + (ln >> 2)) * K + k0 + s_sl * 8,
               &lds[slot][(wv * 32 + q * 16) * 32]);
    }
  };
  auto lda = [&](int tb, int kk) {
#pragma unroll
    for (int mf = 0; mf < 8; mf++) {
      const int ar = wm * 128 + mf * 16 + fr;
      afr[mf] = *(const bf16x8*)&lds[tb | kk][ar * 32 + ((qq ^ rsw) << 3)];
    }
  };
  auto ldb = [&](int tb, int kk, int nh) {
#pragma unroll
    for (int nj = 0; nj < 2; nj++) {
      const int br = wn * 64 + (nh * 2 + nj) * 16 + fr;
      bfr[nj] = *(const bf16x8*)&lds[tb | (2 + kk)][br * 32 + ((qq ^ rsw) << 3)];
    }
  };
  auto mm = [&](int nh) {
    __builtin_amdgcn_s_setprio(1);
#pragma unroll
    for (int mf = 0; mf < 8; mf++)
#pragma unroll
      for (int nj = 0; nj < 2; nj++)
        acc[mf][nh * 2 + nj] =
            __builtin_amdgcn_mfma_f32_16x16x32_bf16(afr[mf], bfr[nj], acc[mf][nh * 2 + nj], 0, 0, 0);
    __builtin_amdgcn_s_setprio(0);
  };

  // prologue: tile0 all 4 halves, tile1 k0 halves; wait tile0 (counted), publish
  stage_half(0, 0); stage_half(0, 2); stage_half(0, 1); stage_half(0, 3);
  stage_half(1, 0); stage_half(1, 2);
  asm volatile("s_waitcnt vmcnt(4)" ::: "memory");
  __builtin_amdgcn_s_barrier();
  asm volatile("" ::: "memory");

  for (int t = 0; t < nt; t++) {
    const int tb = (t & 1) << 2;
    // phase 0: (k0, N0); stage Ak1(t+1)
    lda(tb, 0); ldb(tb, 0, 0);
    stage_half(t + 1, 1);
    __builtin_amdgcn_s_barrier();
    mm(0);
    __builtin_amdgcn_s_barrier();
    // phase 1: (k0, N1); stage Bk1(t+1)
    ldb(tb, 0, 1);
    stage_half(t + 1, 3);
    __builtin_amdgcn_s_barrier();
    mm(1);
    __builtin_amdgcn_s_barrier();
    // phase 2: (k1, N1); stage Ak0(t+2)
    lda(tb, 1); ldb(tb, 1, 1);
    stage_half(t + 2, 0);
    __builtin_amdgcn_s_barrier();
    mm(1);
    __builtin_amdgcn_s_barrier();
    // phase 3: (k1, N0); stage Bk0(t+2)
    ldb(tb, 1, 0);
    stage_half(t + 2, 2);
    __builtin_amdgcn_s_barrier();
    mm(0);
    // tile boundary: counted vmcnt — next tile's 4 halves are older than newest in flight
    if (t + 1 < nt) {
      asm volatile("s_waitcnt lgkmcnt(0)" ::: "memory");
      __builtin_amdgcn_sched_barrier(0);
      if (t == nt - 2) {
        asm volatile("s_waitcnt vmcnt(0)" ::: "memory");
      } else {
        asm volatile("s_waitcnt vmcnt(4)" ::: "memory");
      }
      __builtin_amdgcn_sched_barrier(0);
      __builtin_amdgcn_s_barrier();
      __builtin_amdgcn_sched_barrier(0);
    }
  }

  const int cm4 = qq * 4;
  if (EPI == 3) {
    // paired combine: nf even = gate frag, nf odd = up frag at same output cols.
    const int bn2 = bn >> 1;
#pragma unroll
    for (int mf = 0; mf < 8; mf++) {
#pragma unroll
      for (int p = 0; p < 2; p++) {
#pragma unroll
        for (int r = 0; r < 4; r++) {
          const int grow = bm + wm * 128 + mf * 16 + cm4 + r;
          const int gcol = bn2 + wn * 32 + p * 16 + fr;
          Cb[(size_t)grow * 8192 + gcol] =
              f2bf(siluf(acc[mf][2 * p][r]) * acc[mf][2 * p + 1][r]);
        }
      }
    }
  } else {
#pragma unroll
    for (int mf = 0; mf < 8; mf++) {
#pragma unroll
      for (int nf = 0; nf < 4; nf++) {
#pragma unroll
        for (int r = 0; r < 4; r++) {
          const int grow = bm + wm * 128 + mf * 16 + cm4 + r;
          const int gcol = bn + wn * 64 + nf * 16 + fr;
          const size_t off = (size_t)grow * N + gcol;
          const float v = acc[mf][nf][r];
          if (EPI == 0) {
            Cb[off] = f2bf(v);
          } else {
            Cf[off] += v;
          }
        }
      }
    }
  }
}

// ---------------- pipelined bf16 MFMA GEMM (thin shapes): C[M][N] = A[M][K] * B[N][K]^T -----
// BM x BN block (8 waves, 64x64 per-wave tile), BK=32, 3 LDS buffers, counted vmcnt.
template<int EPI, int BM, int BN>
__global__ __launch_bounds__(512, 4) void gemm256_kernel(const unsigned short* __restrict__ A,
                                                         const unsigned short* __restrict__ B,
                                                         float* __restrict__ Cf,
                                                         unsigned short* __restrict__ Cb,
                                                         int M, int N, int K) {
  constexpr int MI = 4;
  constexpr int NI = BN / 64;
  constexpr int AW = BM / 128;
  constexpr int BW = BN / 128;
  __shared__ __align__(16) unsigned short lds[3][(BM + BN) * 32];
  const int nbm = M / BM, nbn = N / BN, nwg = nbm * nbn;
  const int nt = K >> 5;
  int bmi, bni;
  {
    const int bid = blockIdx.x;
    const int cpx = nwg >> 3;
    int sc = 1;
    while (sc * sc < cpx) sc <<= 1;
    if (sc * sc > cpx) sc >>= 1;
    const int scn = (sc > 0) ? (cpx / sc) : 0;
    if ((nwg & 7) == 0 && sc > 0 && sc * scn == cpx && (nbm % sc) == 0 && (nbn % scn) == 0) {
      const int chunk = bid & 7, widx = bid >> 3;
      const int regc = nbn / scn;
      bmi = (chunk / regc) * sc + widx / scn;
      bni = (chunk % regc) * scn + widx % scn;
    } else {
      bmi = bid / nbn; bni = bid % nbn;
    }
  }
  const int bm = bmi * BM, bn = bni * BN;
  const int tid = threadIdx.x;
  const int wv = tid >> 6, ln = tid & 63;
  const int fr = ln & 15, qq = ln >> 4;
  const int wm = wv >> 2, wn = wv & 3;
  const int ra0 = wm * 64, rb0 = wn * (BN / 4);
  const int lrow = ln >> 2;
  const int lslot = ln & 3;

  f32x4 acc[MI][NI];
  const f32x4 zero = {0.f, 0.f, 0.f, 0.f};
#pragma unroll
  for (int mi = 0; mi < MI; mi++)
#pragma unroll
    for (int ni = 0; ni < NI; ni++) acc[mi][ni] = zero;

  auto stage = [&](int buf, int t) {
    const int k0 = t << 5;
#pragma unroll
    for (int q = 0; q < AW; q++) {
      const int lr = q * 128 + wv * 16 + lrow;
      const int sl = lslot ^ ((lr >> 1) & 3);
      gl_lds16(A + (size_t)(bm + lr) * K + k0 + sl * 8,
               &lds[buf][(q * 128 + wv * 16) * 32]);
    }
#pragma unroll
    for (int q = 0; q < BW; q++) {
      const int lr = q * 128 + wv * 16 + lrow;
      const int sl = lslot ^ ((lr >> 1) & 3);
      gl_lds16(B + (size_t)(bn + lr) * K + k0 + sl * 8,
               &lds[buf][BM * 32 + (q * 128 + wv * 16) * 32]);
    }
  };

  stage(0, 0);
  stage(1, 1);
  asm volatile("s_waitcnt vmcnt(%0)" :: "i"(AW + BW) : "memory");
  __builtin_amdgcn_s_barrier();
  asm volatile("" ::: "memory");

  for (int t = 0; t < nt; t++) {
    const int cb = t % 3;
    const int b2 = (t + 2) % 3;
    const unsigned short* lA = &lds[cb][0];
    const unsigned short* lB = &lds[cb][BM * 32];
    bf16x8 bfr[NI];
#pragma unroll
    for (int ni = 0; ni < NI; ni++) {
      const int r = rb0 + ni * 16 + fr;
      bfr[ni] = *(const bf16x8*)&lB[r * 32 + ((qq ^ ((r >> 1) & 3)) << 3)];
    }
    bf16x8 afr[MI];
#pragma unroll
    for (int mi = 0; mi < MI; mi++) {
      const int r = ra0 + mi * 16 + fr;
      afr[mi] = *(const bf16x8*)&lA[r * 32 + ((qq ^ ((r >> 1) & 3)) << 3)];
    }
    if (t + 2 < nt) stage(b2, t + 2);
    __builtin_amdgcn_s_setprio(1);
#pragma unroll
    for (int mi = 0; mi < MI; mi++)
#pragma unroll
      for (int ni = 0; ni < NI; ni++)
        acc[mi][ni] = __builtin_amdgcn_mfma_f32_16x16x32_bf16(afr[mi], bfr[ni], acc[mi][ni], 0, 0, 0);
    __builtin_amdgcn_s_setprio(0);
    if (t + 1 < nt) {
      asm volatile("s_waitcnt lgkmcnt(0)" ::: "memory");
      if (t + 2 < nt) {
        asm volatile("s_waitcnt vmcnt(%0)" :: "i"(AW + BW) : "memory");
      } else {
        asm volatile("s_waitcnt vmcnt(0)" ::: "memory");
      }
      __builtin_amdgcn_s_barrier();
      asm volatile("" ::: "memory");
    }
  }

  const int cm4 = qq * 4;
#pragma unroll
  for (int mi = 0; mi < MI; mi++) {
#pragma unroll
    for (int ni = 0; ni < NI; ni++) {
#pragma unroll
      for (int r = 0; r < 4; r++) {
        const int grow = bm + ra0 + mi * 16 + cm4 + r;
        const int gcol = bn + rb0 + ni * 16 + fr;
        const size_t off = (size_t)grow * N + gcol;
        const float v = acc[mi][ni][r];
        if (EPI == 0) {
          Cb[off] = f2bf(v);
        } else if (EPI == 1) {
          Cf[off] += v;
        } else {
          Cb[off] = f2bf(siluf(bf2f(Cb[off])) * v);
        }
      }
    }
  }
}

// ---------------- ba = h @ ba_w^T ----------------
__global__ __launch_bounds__(256) void ba_gemm_kernel(const float* __restrict__ h_in,
                                                      const float* __restrict__ ba_w,
                                                      float* __restrict__ ba_out) {
  __shared__ __align__(16) float hl[2048];
  __shared__ float red[32][9];
  const int t = blockIdx.x;
  const int tid = threadIdx.x;
  const float4* hr = (const float4*)(h_in + (size_t)t * DMODEL);
  ((float4*)hl)[tid] = hr[tid];
  ((float4*)hl)[tid + 256] = hr[tid + 256];
  __syncthreads();
  const int c = tid & 31;
  const int p = tid >> 5;
  const float* wrow = ba_w + (size_t)c * DMODEL + p * 256;
  const float* hrow = hl + p * 256;
  float s = 0.f;
#pragma unroll 8
  for (int k = 0; k < 256; k++) s += hrow[k] * wrow[k];
  red[c][p] = s;
  __syncthreads();
  if (tid < 32) {
    float tot = 0.f;
#pragma unroll
    for (int q = 0; q < 8; q++) tot += red[tid][q];
    ba_out[(size_t)t * 32 + tid] = tot;
  }
}

// ---------------- extract z columns from bf16 qkvz ----------------
__global__ __launch_bounds__(256) void zcopy_kernel(const unsigned short* __restrict__ qkvz,
                                                    unsigned short* __restrict__ z) {
  const int idx = blockIdx.x * 256 + threadIdx.x;
  const int t = idx >> 8;
  const int c8 = (idx & 255) * 8;
  *(uint4*)(z + (size_t)t * 2048 + c8) =
      *(const uint4*)(qkvz + (size_t)t * CQKVZ + CQKV + c8);
}

// ---------------- causal depthwise conv (K=4) + SiLU; bf16 in, fp32 out ----------------
__global__ __launch_bounds__(256) void conv_silu_kernel(const unsigned short* __restrict__ qkvz,
                                                        const float* __restrict__ conv_w,
                                                        const float* __restrict__ mask,
                                                        float* __restrict__ mixed) {
  const int idx = blockIdx.x * 256 + threadIdx.x;
  const int c4 = (idx % 1536) * 4;
  const int t = idx / 1536;
  const float4 w0 = *(const float4*)(conv_w + (size_t)c4 * 4);
  const float4 w1 = *(const float4*)(conv_w + (size_t)c4 * 4 + 4);
  const float4 w2 = *(const float4*)(conv_w + (size_t)c4 * 4 + 8);
  const float4 w3 = *(const float4*)(conv_w + (size_t)c4 * 4 + 12);
  const float wj0[4] = {w0.x, w0.y, w0.z, w0.w};
  const float wj1[4] = {w1.x, w1.y, w1.z, w1.w};
  const float wj2[4] = {w2.x, w2.y, w2.z, w2.w};
  const float wj3[4] = {w3.x, w3.y, w3.z, w3.w};
  float4 acc = make_float4(0.f, 0.f, 0.f, 0.f);
#pragma unroll
  for (int j = 0; j < 4; j++) {
    const int tt = t - 3 + j;
    if (tt < 0) continue;
    const float m = mask[tt];
    const ushort4 xb = *(const ushort4*)(qkvz + (size_t)tt * CQKVZ + c4);
    acc.x += bf2f(xb.x) * m * wj0[j];
    acc.y += bf2f(xb.y) * m * wj1[j];
    acc.z += bf2f(xb.z) * m * wj2[j];
    acc.w += bf2f(xb.w) * m * wj3[j];
  }
  acc.x = siluf(acc.x); acc.y = siluf(acc.y); acc.z = siluf(acc.z); acc.w = siluf(acc.w);
  *(float4*)(mixed + (size_t)t * CQKV + c4) = acc;
}

// ---------------- l2norm over Dk=128 for q,k heads (in place, fp32) ----------------
__global__ __launch_bounds__(256) void l2norm_kernel(float* __restrict__ mixed) {
  const int r = blockIdx.x * 4 + (threadIdx.x >> 6);
  const int lane = threadIdx.x & 63;
  const int t = r >> 5;
  const int hh = r & 31;
  float* p = mixed + (size_t)t * CQKV + hh * 128 + lane * 2;
  float2 v = *(float2*)p;
  float s = v.x * v.x + v.y * v.y;
#pragma unroll
  for (int off = 32; off > 0; off >>= 1) s += __shfl_down(s, off);
  s = __shfl(s, 0);
  const float rn = rsqrtf(s + 1e-6f);
  v.x *= rn; v.y *= rn;
  *(float2*)p = v;
}

// ---------------- beta, g ----------------
__global__ __launch_bounds__(256) void beta_g_kernel(const float* __restrict__ ba,
                                                     const float* __restrict__ A_log,
                                                     const float* __restrict__ dt_bias,
                                                     const float* __restrict__ mask,
                                                     float* __restrict__ beta,
                                                     float* __restrict__ g) {
  const int idx = blockIdx.x * 256 + threadIdx.x;
  const int t = idx >> 4;
  const int h = idx & 15;
  const float b = ba[(size_t)t * 32 + h];
  const float a = ba[(size_t)t * 32 + 16 + h];
  const float m = mask[t];
  beta[idx] = m / (1.0f + expf(-b));
  const float xx = a + dt_bias[h];
  const float sp = (xx > 20.0f) ? xx : log1pf(expf(xx));
  g[idx] = -expf(A_log[h]) * sp * m;
}

// ---------------- per-chunk cumsum of g + decay factors ----------------
__global__ __launch_bounds__(256) void gcs_kernel(const float* __restrict__ g,
                                                  float* __restrict__ gcsbuf,
                                                  float* __restrict__ edkbuf,
                                                  float* __restrict__ egqbuf,
                                                  float* __restrict__ adecbuf) {
  const int idx = blockIdx.x * 256 + threadIdx.x;  // chunk id = h*64 + n
  if (idx >= 1024) return;
  const int h = idx >> 6;
  const int n = idx & 63;
  const int t0 = n * 64;
  float s = 0.f;
  for (int i = 0; i < 64; i++) {
    s += g[(size_t)(t0 + i) * NH + h];
    gcsbuf[(size_t)idx * 64 + i] = s;
  }
  const float glast = s;
  adecbuf[idx] = __expf(glast);
  for (int i = 0; i < 64; i++) {
    const float gi = gcsbuf[(size_t)idx * 64 + i];
    edkbuf[(size_t)idx * 64 + i] = __expf(glast - gi);
    egqbuf[(size_t)idx * 64 + i] = __expf(gi) * SCALE;
  }
}

// ---------------- per-chunk MFMA: A=(k_beta k^T)*decay (strict lower), attn=(q k^T)*decay*scale
// 4 waves; k,q staged bf16 into XOR-swizzled LDS; both products share k B-fragments.
__global__ __launch_bounds__(256) void pre_attn_kernel(const float* __restrict__ mixed,
                                                       const float* __restrict__ gcsbuf,
                                                       const float* __restrict__ betabuf,
                                                       float* __restrict__ abuf,
                                                       float* __restrict__ attnbuf) {
  __shared__ __align__(16) unsigned short kbl[64 * 128];
  __shared__ __align__(16) unsigned short qbl[64 * 128];
  __shared__ float gcs_s[64];
  __shared__ float betal[64];
  const int blk = blockIdx.x;
  const int h = blk >> 6;
  const int n = blk & 63;
  const int t0 = n * 64;
  const int tid = threadIdx.x;
  if (tid < 64) {
    gcs_s[tid] = gcsbuf[(size_t)blk * 64 + tid];
    betal[tid] = betabuf[(size_t)(t0 + tid) * NH + h];
  }
#pragma unroll
  for (int p = 0; p < 4; p++) {
    const int idx = tid + p * 256;          // 0..1023
    const int i = idx >> 4, dg = idx & 15;  // row, 16B granule
    const float* kb_ = mixed + (size_t)(t0 + i) * CQKV + 2048 + h * 128 + dg * 8;
    const float4 a = *(const float4*)kb_;
    const float4 b = *(const float4*)(kb_ + 4);
    unsigned short* dk = &kbl[i * 128 + ((dg ^ (i & 7)) << 3)];
    *(ushort4*)dk = pack4(a.x, a.y, a.z, a.w);
    *(ushort4*)(dk + 4) = pack4(b.x, b.y, b.z, b.w);
    const float* qb_ = mixed + (size_t)(t0 + i) * CQKV + h * 128 + dg * 8;
    const float4 c = *(const float4*)qb_;
    const float4 d = *(const float4*)(qb_ + 4);
    unsigned short* dq = &qbl[i * 128 + ((dg ^ (i & 7)) << 3)];
    *(ushort4*)dq = pack4(c.x, c.y, c.z, c.w);
    *(ushort4*)(dq + 4) = pack4(d.x, d.y, d.z, d.w);
  }
  __syncthreads();
  const int ln = tid & 63;
  const int wv = tid >> 6;      // 0..3
  const int fr = ln & 15;
  const int g = ln >> 4;        // 0..3
  const int i0 = wv * 16;
  f32x4 accA[4], accQ[4];
  const f32x4 zero = {0.f, 0.f, 0.f, 0.f};
#pragma unroll
  for (int jt = 0; jt < 4; jt++) { accA[jt] = zero; accQ[jt] = zero; }
#pragma unroll
  for (int ks = 0; ks < 4; ks++) {
    const int kb = ks * 4 + g;
    const int ar = i0 + fr;
    const bf16x8 aK = *(const bf16x8*)&kbl[ar * 128 + ((kb ^ (ar & 7)) << 3)];
    const bf16x8 aQ = *(const bf16x8*)&qbl[ar * 128 + ((kb ^ (ar & 7)) << 3)];
#pragma unroll
    for (int jt = 0; jt < 4; jt++) {
      const int br = jt * 16 + fr;
      const bf16x8 b = *(const bf16x8*)&kbl[br * 128 + ((kb ^ (br & 7)) << 3)];
      accA[jt] = __builtin_amdgcn_mfma_f32_16x16x32_bf16(aK, b, accA[jt], 0, 0, 0);
      accQ[jt] = __builtin_amdgcn_mfma_f32_16x16x32_bf16(aQ, b, accQ[jt], 0, 0, 0);
    }
  }
  // epilogue: i = i0 + g*4 + r ; j = jt*16 + fr
#pragma unroll
  for (int jt = 0; jt < 4; jt++) {
    const int j = jt * 16 + fr;
    const float gj = gcs_s[j];
#pragma unroll
    for (int r = 0; r < 4; r++) {
      const int i = i0 + g * 4 + r;
      const float gi = gcs_s[i];
      const float dec = __expf(fminf(gi - gj, 0.f));
      abuf[(size_t)blk * 4096 + i * 64 + j] = (i > j) ? accA[jt][r] * betal[i] * dec : 0.f;
      attnbuf[(size_t)blk * 4096 + i * 64 + j] = (i >= j) ? accQ[jt][r] * dec * SCALE : 0.f;
    }
  }
}

// ---------------- per-chunk: T = (I+A)^-1, then T *= beta[col] ----------------
__global__ __launch_bounds__(256) void pre_solve_kernel(const float* __restrict__ abuf,
                                                        const float* __restrict__ betabuf,
                                                        float* __restrict__ tbuf) {
  __shared__ float Al[64][65];
  __shared__ float Tl[64][65];
  const int blk = blockIdx.x;
  const int h = blk >> 6;
  const int n = blk & 63;
  const int t0 = n * 64;
  const int tid = threadIdx.x;
#pragma unroll
  for (int rep = 0; rep < 4; rep++) {
    const int lin = rep * 256 + tid;
    const int i = lin >> 4;
    const int j = (lin & 15) * 4;
    const float4 av = *(const float4*)(abuf + (size_t)blk * 4096 + i * 64 + j);
    Al[i][j] = av.x; Al[i][j + 1] = av.y; Al[i][j + 2] = av.z; Al[i][j + 3] = av.w;
  }
  __syncthreads();
  if (tid < 64) {
    const int j = tid;
    const float bj = betabuf[(size_t)(t0 + j) * NH + h];
    for (int i = 0; i < 64; i++) {
      float s = (i == j) ? 1.0f : 0.0f;
      for (int l = j; l < i; l++) s -= Al[i][l] * Tl[l][j];
      Tl[i][j] = s;
    }
    for (int i = j; i < 64; i++) Tl[i][j] *= bj;
  }
  __syncthreads();
#pragma unroll
  for (int rep = 0; rep < 4; rep++) {
    const int lin = rep * 256 + tid;
    const int i = lin >> 4;
    const int j = (lin & 15) * 4;
    float4 tv;
    tv.x = Tl[i][j]; tv.y = Tl[i][j + 1]; tv.z = Tl[i][j + 2]; tv.w = Tl[i][j + 3];
    *(float4*)(tbuf + (size_t)blk * 4096 + i * 64 + j) = tv;
  }
}

// ---------------- per-chunk: u = Tb @ v (bf16, l4-packed [blk][l>>2][c][l&3]) ;
//                  w = Tb @ (k * e^gcs), stored NEGATED + slot-swizzled ----
__global__ __launch_bounds__(256) void pre_uw_kernel(const float* __restrict__ mixed,
                                                     const float* __restrict__ tbuf,
                                                     const float* __restrict__ gcsbuf,
                                                     unsigned short* __restrict__ ubf,
                                                     unsigned short* __restrict__ wbf) {
  __shared__ __align__(16) float Tl[64][68];
  __shared__ __align__(16) float xl[64][132];
  __shared__ float egcs[64];
  const int blk = blockIdx.x;
  const int h = blk >> 6;
  const int n = blk & 63;
  const int t0 = n * 64;
  const int tid = threadIdx.x;
  if (tid < 64) egcs[tid] = __expf(gcsbuf[(size_t)blk * 64 + tid]);
#pragma unroll
  for (int rep = 0; rep < 4; rep++) {
    const int lin = rep * 256 + tid;
    const int i = lin >> 4;
    const int j = (lin & 15) * 4;
    const float4 tv = *(const float4*)(tbuf + (size_t)blk * 4096 + i * 64 + j);
    *(float4*)&Tl[i][j] = tv;
  }
#pragma unroll
  for (int rep = 0; rep < 8; rep++) {
    const int lin = rep * 256 + tid;
    const int i = lin >> 5;
    const int d = (lin & 31) * 4;
    const float4 vv = *(const float4*)(mixed + (size_t)(t0 + i) * CQKV + 4096 + h * 128 + d);
    *(float4*)&xl[i][d] = vv;
  }
  __syncthreads();
  const int cgu = tid & 15;
  const int riu = tid >> 4;
  const int i0 = riu * 4;
  const int d0 = cgu * 8;
  float acc[4][8];
#pragma unroll
  for (int a = 0; a < 4; a++)
#pragma unroll
    for (int b = 0; b < 8; b++) acc[a][b] = 0.f;
#pragma unroll 2
  for (int j = 0; j < 64; j++) {
    const float tv[4] = {Tl[i0][j], Tl[i0 + 1][j], Tl[i0 + 2][j], Tl[i0 + 3][j]};
    const float4 x0 = *(const float4*)&xl[j][d0];
    const float4 x1 = *(const float4*)&xl[j][d0 + 4];
    const float xv[8] = {x0.x, x0.y, x0.z, x0.w, x1.x, x1.y, x1.z, x1.w};
#pragma unroll
    for (int a = 0; a < 4; a++)
#pragma unroll
      for (int b = 0; b < 8; b++) acc[a][b] += tv[a] * xv[b];
  }
  // u store: bf16 l4-packed layout elem = blk*8192 + riu*512 + (d0+b)*4 + (l&3)
#pragma unroll
  for (int b = 0; b < 8; b++) {
    *(ushort4*)(ubf + (size_t)blk * 8192 + riu * 512 + (size_t)(d0 + b) * 4) =
        pack4(acc[0][b], acc[1][b], acc[2][b], acc[3][b]);
  }
  __syncthreads();
#pragma unroll
  for (int rep = 0; rep < 8; rep++) {
    const int lin = rep * 256 + tid;
    const int i = lin >> 5;
    const int d = (lin & 31) * 4;
    float4 kv = *(const float4*)(mixed + (size_t)(t0 + i) * CQKV + 2048 + h * 128 + d);
    const float e = egcs[i];
    kv.x *= e; kv.y *= e; kv.z *= e; kv.w *= e;
    *(float4*)&xl[i][d] = kv;
  }
  __syncthreads();
#pragma unroll
  for (int a = 0; a < 4; a++)
#pragma unroll
    for (int b = 0; b < 8; b++) acc[a][b] = 0.f;
#pragma unroll 2
  for (int j = 0; j < 64; j++) {
    const float tv[4] = {Tl[i0][j], Tl[i0 + 1][j], Tl[i0 + 2][j], Tl[i0 + 3][j]};
    const float4 x0 = *(const float4*)&xl[j][d0];
    const float4 x1 = *(const float4*)&xl[j][d0 + 4];
    const float xv[8] = {x0.x, x0.y, x0.z, x0.w, x1.x, x1.y, x1.z, x1.w};
#pragma unroll
    for (int a = 0; a < 4; a++)
#pragma unroll
      for (int b = 0; b < 8; b++) acc[a][b] += tv[a] * xv[b];
  }
  // store -w, column-slot swizzled by (row&7) so scan can global_load_lds linearly
#pragma unroll
  for (int a = 0; a < 4; a++) {
    const int l = i0 + a;
    unsigned short* wp = wbf + (size_t)(t0 + l) * 2048 + h * 128 + ((cgu ^ (l & 7)) << 3);
    *(ushort4*)wp = pack4(-acc[a][0], -acc[a][1], -acc[a][2], -acc[a][3]);
    *(ushort4*)(wp + 4) = pack4(-acc[a][4], -acc[a][5], -acc[a][6], -acc[a][7]);
  }
}

// ---------------- per-chunk: kdT[blk][d][l] = bf16(k*edk) slot-swizzled; qe = bf16(q*egq) ----------------
__global__ __launch_bounds__(256) void ktrans_kernel(const float* __restrict__ mixed,
                                                     const float* __restrict__ edkbuf,
                                                     const float* __restrict__ egqbuf,
                                                     unsigned short* __restrict__ kdT,
                                                     unsigned short* __restrict__ qe) {
  __shared__ __align__(16) float kl[64][132];
  __shared__ float edk_s[64];
  __shared__ float egq_s[64];
  const int blk = blockIdx.x;
  const int h = blk >> 6;
  const int n = blk & 63;
  const int t0 = n * 64;
  const int tid = threadIdx.x;
  if (tid < 64) {
    edk_s[tid] = edkbuf[(size_t)blk * 64 + tid];
    egq_s[tid] = egqbuf[(size_t)blk * 64 + tid];
  }
#pragma unroll
  for (int q = 0; q < 8; q++) {
    const int idx = tid + q * 256;
    const int l = idx >> 5, c4 = (idx & 31) * 4;
    *(float4*)&kl[l][c4] = *(const float4*)(mixed + (size_t)(t0 + l) * CQKV + 2048 + h * 128 + c4);
  }
  __syncthreads();
#pragma unroll
  for (int q = 0; q < 4; q++) {
    const int idx = tid + q * 256;
    const int d = idx >> 3, lsl = idx & 7;
    const int l8 = lsl * 8;
    float v[8];
#pragma unroll
    for (int j = 0; j < 8; j++) v[j] = kl[l8 + j][d] * edk_s[l8 + j];
    unsigned short* p = kdT + (size_t)blk * 8192 + d * 64 + ((lsl ^ (d & 7)) << 3);
    *(ushort4*)p = pack4(v[0], v[1], v[2], v[3]);
    *(ushort4*)(p + 4) = pack4(v[4], v[5], v[6], v[7]);
  }
#pragma unroll
  for (int q = 0; q < 8; q++) {
    const int idx = tid + q * 256;
    const int i = idx >> 5, c4 = (idx & 31) * 4;
    const float4 v = *(const float4*)(mixed + (size_t)(t0 + i) * CQKV + h * 128 + c4);
    const float e = egq_s[i];
    *(ushort4*)(qe + (size_t)(t0 + i) * 2048 + h * 128 + c4) =
        pack4(v.x * e, v.y * e, v.z * e, v.w * e);
  }
}

// ---------------- MFMA scan, column-decomposed: 8 waves x 16 c-columns, NO cross-wave data ---
// u read bf16 l4-packed (4x ushort4 per chunk). Exports d4/l4-packed (coalesced).
// blocks 0..15: per-head scan; ONE barrier/chunk (counted vmcnt(17)).
// blocks >=16: weight f2b (Wgu interleaved / Wd / Wo) + residual copy (512 threads).
__global__ __launch_bounds__(512, 1) void scan_kernel(const unsigned short* __restrict__ wbf,
                                                      const unsigned short* __restrict__ kdT,
                                                      const unsigned short* __restrict__ ubf,
                                                      const float* __restrict__ adecbuf,
                                                      unsigned short* __restrict__ STb,
                                                      unsigned short* __restrict__ vtb,
                                                      const float* __restrict__ gw,
                                                      const float* __restrict__ uw,
                                                      const float* __restrict__ dw,
                                                      const float* __restrict__ ow,
                                                      const float* __restrict__ xin,
                                                      unsigned short* __restrict__ Wgu,
                                                      unsigned short* __restrict__ Wd,
                                                      unsigned short* __restrict__ Wo,
                                                      float* __restrict__ outc) {
  __shared__ __align__(16) unsigned short stage[2][16384];  // [w 8192 | kT 8192] shorts each
  __shared__ __align__(16) unsigned short privAll[8][3072]; // per wave: A 16x128 | B 16x64
  if (blockIdx.x >= 16) {
    // side work (512 thr): Wg 4096 + Wu 4096 + Wd 4096 + Wo 1024 + copy 2048 = 15360 blocks
    const int xb = blockIdx.x - 16;
    const int tid = threadIdx.x;
    if (xb < 8192) {
      // gate/up f2b with 16-row interleave into Wgu:
      // src row r -> dst row (r>>4)*32 + (r&15) (+16 for up)
      const bool isUp = (xb >= 4096);
      const float* src = isUp ? uw : gw;
      const size_t e = ((size_t)(isUp ? xb - 4096 : xb) * 512 + tid) * 8;
      const int r = (int)(e >> 11);
      const int col = (int)(e & 2047);
      const int drow = (r >> 4) * 32 + (r & 15) + (isUp ? 16 : 0);
      const float4 a = *(const float4*)(src + e);
      const float4 b = *(const float4*)(src + e + 4);
      unsigned short* dst = Wgu + (size_t)drow * 2048 + col;
      *(ushort4*)dst = pack4(a.x, a.y, a.z, a.w);
      *(ushort4*)(dst + 4) = pack4(b.x, b.y, b.z, b.w);
    } else if (xb < 13312) {
      const float* src; unsigned short* dst; size_t u;
      if (xb < 12288) { src = dw; dst = Wd; u = (size_t)(xb - 8192) * 512 + tid; }
      else            { src = ow; dst = Wo; u = (size_t)(xb - 12288) * 512 + tid; }
      const float4 a = ((const float4*)src)[2 * u];
      const float4 b = ((const float4*)src)[2 * u + 1];
      ((ushort4*)dst)[2 * u] = pack4(a.x, a.y, a.z, a.w);
      ((ushort4*)dst)[2 * u + 1] = pack4(b.x, b.y, b.z, b.w);
    } else {
      const size_t i = (size_t)(xb - 13312) * 512 + tid;
      ((float4*)outc)[2 * i] = ((const float4*)xin)[2 * i];
      ((float4*)outc)[2 * i + 1] = ((const float4*)xin)[2 * i + 1];
    }
    return;
  }
  const int h = blockIdx.x;
  const int tid = threadIdx.x;
  const int ln = tid & 63;
  const int wv = tid >> 6;        // 0..7
  const int fr = ln & 15;
  const int g  = ln >> 4;         // 0..3
  const int c0 = wv * 16;
  const int fsw = fr & 7;
  unsigned short* privA = &privAll[wv][0];     // [16 c][128 d], slot-swizzled
  unsigned short* privB = &privAll[wv][2048];  // [16 c][64 l], slot-swizzled
  const f32x4 zero = {0.f, 0.f, 0.f, 0.f};

  f32x4 acc2[8];                  // S^T state for this wave's 16 columns, d-tile dt
#pragma unroll
  for (int dt = 0; dt < 8; dt++) acc2[dt] = zero;

  auto stage_wk = [&](int buf, int n1) {
    const int t0n = n1 * 64;
    const size_t kbase = (size_t)(h * 64 + n1) * 8192;
#pragma unroll
    for (int q = 0; q < 2; q++) {
      const int m = wv * 2 + q;   // 0..15
      gl_lds16(wbf + (size_t)(t0n + m * 4 + (ln >> 4)) * 2048 + h * 128 + (ln & 15) * 8,
               &stage[buf][m * 512]);
      gl_lds16(kdT + kbase + (m * 8 + (ln >> 3)) * 64 + (ln & 7) * 8,
               &stage[buf][8192 + m * 512]);
    }
  };

  // prologue: u/adec for chunk 0 + stage chunk 0
  ushort4 ur4[4];
#pragma unroll
  for (int lt = 0; lt < 4; lt++)
    ur4[lt] = *(const ushort4*)(ubf + (size_t)(h * 64) * 8192 + (lt * 4 + g) * 512 + (c0 + fr) * 4);
  float ad = adecbuf[h * 64];
  stage_wk(0, 0);
  asm volatile("s_waitcnt vmcnt(0)" ::: "memory");
  __builtin_amdgcn_s_barrier();
  asm volatile("" ::: "memory");

  for (int n = 0; n < 64; n++) {
    const int blk = h * 64 + n;
    const unsigned short* wl = &stage[n & 1][0];
    const unsigned short* kl = &stage[n & 1][8192];
    // (1) issue staging for n+1 first (oldest VMEM ops of this chunk)
    if (n + 1 < 64) stage_wk((n + 1) & 1, n + 1);
    __builtin_amdgcn_sched_barrier(0);
    // (2) prefetch u/adec for n+1 (4 ushort4 + 1 scalar; younger than staging)
    ushort4 ur4n[4];
    float adn = 0.f;
    if (n + 1 < 64) {
      const size_t ub = (size_t)(blk + 1) * 8192;
#pragma unroll
      for (int lt = 0; lt < 4; lt++)
        ur4n[lt] = *(const ushort4*)(ubf + ub + (lt * 4 + g) * 512 + (c0 + fr) * 4);
      adn = adecbuf[blk + 1];
    } else {
#pragma unroll
      for (int lt = 0; lt < 4; lt++) { ur4n[lt].x = 0; ur4n[lt].y = 0; ur4n[lt].z = 0; ur4n[lt].w = 0; }
    }
    __builtin_amdgcn_sched_barrier(0);
    // (3) dump S_n^T -> privA (wave-private) ; export S_n coalesced (d4-packed)
#pragma unroll
    for (int dt = 0; dt < 8; dt++) {
      const int slot = dt * 2 + (g >> 1);
      const ushort4 pv = pack4(acc2[dt][0], acc2[dt][1], acc2[dt][2], acc2[dt][3]);
      *(ushort4*)&privA[fr * 128 + ((slot ^ fsw) << 3) + (g & 1) * 4] = pv;
      *(ushort4*)(STb + (size_t)blk * 16384 + (dt * 4 + g) * 512 + (c0 + fr) * 4) = pv;
    }
    // (4) MFMA1: v_new = u + (-w) @ S  (A from shared staged w, B from privA)
    f32x4 acc1[4];
#pragma unroll
    for (int lt = 0; lt < 4; lt++) {
      f32x4 t;
      t[0] = bf2f(ur4[lt].x); t[1] = bf2f(ur4[lt].y);
      t[2] = bf2f(ur4[lt].z); t[3] = bf2f(ur4[lt].w);
      acc1[lt] = t;
    }
#pragma unroll
    for (int ks = 0; ks < 4; ks++) {
      const int kb = ks * 4 + g;
      const bf16x8 b = *(const bf16x8*)&privA[fr * 128 + ((kb ^ fsw) << 3)];
#pragma unroll
      for (int lt = 0; lt < 4; lt++) {
        const bf16x8 a = *(const bf16x8*)&wl[(lt * 16 + fr) * 128 + ((kb ^ fsw) << 3)];
        acc1[lt] = __builtin_amdgcn_mfma_f32_16x16x32_bf16(a, b, acc1[lt], 0, 0, 0);
      }
    }
    // (5) v_new^T -> privB ; export v_new^T coalesced (l4-packed)
#pragma unroll
    for (int lt = 0; lt < 4; lt++) {
      const int slot = lt * 2 + (g >> 1);
      const ushort4 pv = pack4(acc1[lt][0], acc1[lt][1], acc1[lt][2], acc1[lt][3]);
      *(ushort4*)&privB[fr * 64 + ((slot ^ fsw) << 3) + (g & 1) * 4] = pv;
      *(ushort4*)(vtb + (size_t)blk * 8192 + (lt * 4 + g) * 512 + (c0 + fr) * 4) = pv;
    }
    // (6) MFMA2: S = adec*S + kdec^T @ v_new
#pragma unroll
    for (int dt = 0; dt < 8; dt++) {
      acc2[dt][0] *= ad; acc2[dt][1] *= ad; acc2[dt][2] *= ad; acc2[dt][3] *= ad;
    }
#pragma unroll
    for (int ks = 0; ks < 2; ks++) {
      const int kb = ks * 4 + g;
      const bf16x8 b = *(const bf16x8*)&privB[fr * 64 + ((kb ^ fsw) << 3)];
#pragma unroll
      for (int dt = 0; dt < 8; dt++) {
        const bf16x8 a = *(const bf16x8*)&kl[(dt * 16 + fr) * 64 + ((kb ^ fsw) << 3)];
        acc2[dt] = __builtin_amdgcn_mfma_f32_16x16x32_bf16(a, b, acc2[dt], 0, 0, 0);
      }
    }
    // (7) roll prefetched operands
#pragma unroll
    for (int lt = 0; lt < 4; lt++) ur4[lt] = ur4n[lt];
    ad = adn;
    // (8) publish staging: counted vmcnt (youngest 17 = 4 u + 1 adec + 12 export stores)
    if (n + 1 < 64) {
      asm volatile("s_waitcnt lgkmcnt(0)" ::: "memory");
      __builtin_amdgcn_sched_barrier(0);
      asm volatile("s_waitcnt vmcnt(17)" ::: "memory");
      __builtin_amdgcn_sched_barrier(0);
      __builtin_amdgcn_s_barrier();
      __builtin_amdgcn_sched_barrier(0);
    }
  }
}

// ---------------- MFMA o-compute + fused gated RMSNorm (reads d4/l4-packed ST/vt) ----------------
__global__ __launch_bounds__(256) void ocomp_kernel(const unsigned short* __restrict__ qe,
                                                    const unsigned short* __restrict__ STbuf,
                                                    const unsigned short* __restrict__ vtbuf,
                                                    const float* __restrict__ attnbuf,
                                                    const unsigned short* __restrict__ zb,
                                                    const float* __restrict__ onw,
                                                    unsigned short* __restrict__ ob) {
  __shared__ __align__(16) unsigned short STl[128 * 128];  // [c][d]
  __shared__ __align__(16) unsigned short vtl[128 * 64];   // [c][l]
  __shared__ __align__(16) unsigned short ql[64 * 128];    // [i][d]
  __shared__ __align__(16) unsigned short al[64 * 64];     // [i][l]
  const int blk = blockIdx.x;
  const int h = blk >> 6;
  const int n = blk & 63;
  const int t0 = n * 64;
  const int tid = threadIdx.x;
  // ST: d4-packed -> [c][d] swizzled LDS. uint4 o covers (dq = o>>6, cols 2w,2w+1, w = o&63)
#pragma unroll
  for (int q = 0; q < 8; q++) {
    const int o = tid + q * 256;
    const int dq = o >> 6, w = o & 63;
    const uint4 v = *(const uint4*)(STbuf + (size_t)blk * 16384 + (size_t)o * 8);
    const int cA = 2 * w, cB = 2 * w + 1;
    uint2 h0; h0.x = v.x; h0.y = v.y;
    uint2 h1; h1.x = v.z; h1.y = v.w;
    *(uint2*)&STl[cA * 128 + (((dq >> 1) ^ (cA & 7)) << 3) + (dq & 1) * 4] = h0;
    *(uint2*)&STl[cB * 128 + (((dq >> 1) ^ (cB & 7)) << 3) + (dq & 1) * 4] = h1;
  }
  // vt: l4-packed -> [c][l] swizzled LDS
#pragma unroll
  for (int q = 0; q < 4; q++) {
    const int o = tid + q * 256;
    const int lq = o >> 6, w = o & 63;
    const uint4 v = *(const uint4*)(vtbuf + (size_t)blk * 8192 + (size_t)o * 8);
    const int cA = 2 * w, cB = 2 * w + 1;
    uint2 h0; h0.x = v.x; h0.y = v.y;
    uint2 h1; h1.x = v.z; h1.y = v.w;
    *(uint2*)&vtl[cA * 64 + (((lq >> 1) ^ (cA & 7)) << 3) + (lq & 1) * 4] = h0;
    *(uint2*)&vtl[cB * 64 + (((lq >> 1) ^ (cB & 7)) << 3) + (lq & 1) * 4] = h1;
  }
#pragma unroll
  for (int q = 0; q < 4; q++) {
    const int idx = tid + q * 256;
    const int i = idx >> 4, dg = idx & 15;
    *(uint4*)&ql[i * 128 + ((dg ^ (i & 7)) << 3)] =
        *(const uint4*)(qe + (size_t)(t0 + i) * 2048 + h * 128 + dg * 8);
  }
#pragma unroll
  for (int q = 0; q < 4; q++) {
    const int idx = tid + q * 256;
    const int i = idx >> 4, l4 = (idx & 15) * 4;
    const float4 v = *(const float4*)(attnbuf + (size_t)blk * 4096 + i * 64 + l4);
    *(ushort4*)&al[i * 64 + (((l4 >> 3) ^ (i & 7)) << 3) + (l4 & 7)] =
        pack4(v.x, v.y, v.z, v.w);
  }
  __syncthreads();
  const int ln = tid & 63;
  const int wv = tid >> 6;
  const int fr = ln & 15;
  const int g = ln >> 4;
  const int i0 = wv * 16;
  f32x4 acc[8];
  const f32x4 zero = {0.f, 0.f, 0.f, 0.f};
#pragma unroll
  for (int nt = 0; nt < 8; nt++) acc[nt] = zero;
#pragma unroll
  for (int ks = 0; ks < 4; ks++) {
    const int kb = ks * 4 + g;
    const int ar = i0 + fr;
    const bf16x8 a = *(const bf16x8*)&ql[ar * 128 + ((kb ^ (ar & 7)) << 3)];
#pragma unroll
    for (int nt = 0; nt < 8; nt++) {
      const int c = nt * 16 + fr;
      const bf16x8 b = *(const bf16x8*)&STl[c * 128 + ((kb ^ (c & 7)) << 3)];
      acc[nt] = __builtin_amdgcn_mfma_f32_16x16x32_bf16(a, b, acc[nt], 0, 0, 0);
    }
  }
#pragma unroll
  for (int ks = 0; ks < 2; ks++) {
    const int kb = ks * 4 + g;
    const int ar = i0 + fr;
    const bf16x8 a = *(const bf16x8*)&al[ar * 64 + ((kb ^ (ar & 7)) << 3)];
#pragma unroll
    for (int nt = 0; nt < 8; nt++) {
      const int c = nt * 16 + fr;
      const bf16x8 b = *(const bf16x8*)&vtl[c * 64 + ((kb ^ (c & 7)) << 3)];
      acc[nt] = __builtin_amdgcn_mfma_f32_16x16x32_bf16(a, b, acc[nt], 0, 0, 0);
    }
  }
  float s0 = 0.f, s1 = 0.f, s2 = 0.f, s3 = 0.f;
#pragma unroll
  for (int nt = 0; nt < 8; nt++) {
    s0 += acc[nt][0] * acc[nt][0];
    s1 += acc[nt][1] * acc[nt][1];
    s2 += acc[nt][2] * acc[nt][2];
    s3 += acc[nt][3] * acc[nt][3];
  }
#pragma unroll
  for (int m = 1; m < 16; m <<= 1) {
    s0 += __shfl_xor(s0, m);
    s1 += __shfl_xor(s1, m);
    s2 += __shfl_xor(s2, m);
    s3 += __shfl_xor(s3, m);
  }
  float rn[4];
  rn[0] = rsqrtf(s0 * (1.0f / 128.0f) + 1e-5f);
  rn[1] = rsqrtf(s1 * (1.0f / 128.0f) + 1e-5f);
  rn[2] = rsqrtf(s2 * (1.0f / 128.0f) + 1e-5f);
  rn[3] = rsqrtf(s3 * (1.0f / 128.0f) + 1e-5f);
#pragma unroll
  for (int nt = 0; nt < 8; nt++) {
    const int c = nt * 16 + fr;
    const float wn = onw[c];
#pragma unroll
    for (int r = 0; r < 4; r++) {
      const size_t off = (size_t)(t0 + i0 + g * 4 + r) * 2048 + h * 128 + c;
      const float zz = siluf(bf2f(zb[off]));
      ob[off] = f2bf(acc[nt][r] * rn[r] * wn * zz);
    }
  }
}

extern "C" void kernel_launch(void* const* d_in, const int* in_sizes, int n_in,
                              void* d_out, int out_size, void* d_ws, size_t ws_size,
                              hipStream_t stream) {
  (void)in_sizes; (void)n_in; (void)out_size;
  const float* x        = (const float*)d_in[0];
  const float* mask     = (const float*)d_in[1];
  const float* ln1_w    = (const float*)d_in[2];
  const float* qkvz_w   = (const float*)d_in[3];
  const float* ba_w     = (const float*)d_in[4];
  const float* conv_w   = (const float*)d_in[5];
  const float* A_log    = (const float*)d_in[6];
  const float* dt_bias  = (const float*)d_in[7];
  const float* o_norm_w = (const float*)d_in[8];
  const float* out_w    = (const float*)d_in[9];
  const float* ln2_w    = (const float*)d_in[10];
  const float* gate_w   = (const float*)d_in[11];
  const float* up_w     = (const float*)d_in[12];
  const float* down_w   = (const float*)d_in[13];
  float* out = (float*)d_out;

  const size_t NEED_BYTES = (size_t)75825152 * 4;
  if (ws_size < NEED_BYTES) return;

  float* ws = (float*)d_ws;
  float* mixed_buf = ws;
  unsigned short* Wgu = (unsigned short*)ws;                 // [16384][2048] bf16, 16-col interleaved
  unsigned short* Wd = (unsigned short*)(ws + 16777216);
  unsigned short* qkvz_bf = (unsigned short*)(ws + 25165824);
  unsigned short* u_bf = (unsigned short*)(ws + 25165824);   // 1024 x 8192 bf16 (16 MB)
  unsigned short* wbf = (unsigned short*)(ws + 33554432);
  unsigned short* kdT = (unsigned short*)(ws + 37748736);
  unsigned short* comb_bf = (unsigned short*)(ws + 25165824);
  unsigned short* z_bf = (unsigned short*)(ws + 41943040);
  float* h_buf = ws + 46137344;
  float* a_buf = ws + 46137344;
  unsigned short* vt_buf = (unsigned short*)(ws + 46137344);
  float* t_buf = ws + 50331648;
  unsigned short* qe_bf = (unsigned short*)(ws + 50331648);  // after pre_uw, t_buf is dead
  unsigned short* h_bf  = (unsigned short*)(ws + 54525952);
  unsigned short* ob    = (unsigned short*)(ws + 54525952);
  unsigned short* h2_bf = (unsigned short*)(ws + 54525952);
  float* attn_buf = ws + 58720256;
  unsigned short* Wq = (unsigned short*)(ws + 62914560);
  unsigned short* ST_buf = (unsigned short*)(ws + 62914560);
  unsigned short* Wo = (unsigned short*)(ws + 71303168);
  float* ba_buf   = ws + 73400320;
  float* beta_buf = ws + 73531392;
  float* g_buf    = ws + 73596928;
  float* gcs_buf  = ws + 73662464;
  float* edk_buf  = ws + 73728000;
  float* egq_buf  = ws + 73793536;
  float* adec_buf = ws + 73859072;

  rmsnorm_kernel<1><<<4096, 256, 0, stream>>>(x, ln1_w, h_buf, h_bf);
  f2b_kernel<<<8192, 256, 0, stream>>>(qkvz_w, Wq);
  gemm8p_kernel<0><<<512, 512, 0, stream>>>(h_bf, Wq, nullptr, qkvz_bf, 4096, 8192, 2048);
  ba_gemm_kernel<<<4096, 256, 0, stream>>>(h_buf, ba_w, ba_buf);
  zcopy_kernel<<<4096, 256, 0, stream>>>(qkvz_bf, z_bf);
  conv_silu_kernel<<<24576, 256, 0, stream>>>(qkvz_bf, conv_w, mask, mixed_buf);
  l2norm_kernel<<<32768, 256, 0, stream>>>(mixed_buf);
  beta_g_kernel<<<256, 256, 0, stream>>>(ba_buf, A_log, dt_bias, mask, beta_buf, g_buf);
  gcs_kernel<<<4, 256, 0, stream>>>(g_buf, gcs_buf, edk_buf, egq_buf, adec_buf);
  pre_attn_kernel<<<1024, 256, 0, stream>>>(mixed_buf, gcs_buf, beta_buf, a_buf, attn_buf);
  pre_solve_kernel<<<1024, 256, 0, stream>>>(a_buf, beta_buf, t_buf);
  pre_uw_kernel<<<1024, 256, 0, stream>>>(mixed_buf, t_buf, gcs_buf, u_bf, wbf);
  ktrans_kernel<<<1024, 256, 0, stream>>>(mixed_buf, edk_buf, egq_buf, kdT, qe_bf);
  // column-decomposed MFMA scan (16 blocks, 8 waves) + fused f2b/copy (15360 blocks)
  scan_kernel<<<15376, 512, 0, stream>>>(wbf, kdT, u_bf, adec_buf, ST_buf, vt_buf,
                                         gate_w, up_w, down_w, out_w, x,
                                         Wgu, Wd, Wo, out);
  ocomp_kernel<<<1024, 256, 0, stream>>>(qe_bf, ST_buf, vt_buf, attn_buf,
                                         z_bf, o_norm_w, ob);
  gemm256_kernel<1, 128, 128><<<512, 512, 0, stream>>>(ob, Wo, out, nullptr, 4096, 2048, 2048);
  rmsnorm_kernel<2><<<4096, 256, 0, stream>>>(out, ln2_w, nullptr, h2_bf);
  // fused gate+up: N=16384 interleaved weights, epilogue writes silu(gate)*up (4096x8192 bf16)
  gemm8p_kernel<3><<<1024, 512, 0, stream>>>(h2_bf, Wgu, nullptr, comb_bf, 4096, 16384, 2048);
  gemm256_kernel<1, 128, 128><<<512, 512, 0, stream>>>(comb_bf, Wd, out, nullptr, 4096, 2048, 8192);
}

// Round 17
// 1258.093 us; speedup vs baseline: 1.3889x; 1.0149x over previous
//
#include <hip/hip_runtime.h>
#include <math.h>

#define T_LEN 4096
#define DMODEL 2048
#define NH 16
#define CQKV 6144
#define CQKVZ 8192
#define SCALE 0.08838834764831845f   // 128^-0.5

using bf16x8 = __attribute__((ext_vector_type(8))) short;
using f32x4  = __attribute__((ext_vector_type(4))) float;

__device__ __forceinline__ float siluf(float x) { return x / (1.0f + __expf(-x)); }

__device__ __forceinline__ unsigned short f2bf(float f) {  // RNE
  unsigned int u = __float_as_uint(f);
  u = (u + 0x7FFFu + ((u >> 16) & 1u)) >> 16;
  return (unsigned short)u;
}
__device__ __forceinline__ float bf2f(unsigned short u) {
  return __uint_as_float(((unsigned int)u) << 16);
}
__device__ __forceinline__ ushort4 pack4(float a, float b, float c, float d) {
  ushort4 r; r.x = f2bf(a); r.y = f2bf(b); r.z = f2bf(c); r.w = f2bf(d); return r;
}

// async global->LDS, 16 bytes per lane; LDS dest is wave-uniform base (+ lane*16 implicit)
__device__ __forceinline__ void gl_lds16(const unsigned short* g, unsigned short* l) {
  __builtin_amdgcn_global_load_lds(
      (const __attribute__((address_space(1))) void*)g,
      (__attribute__((address_space(3))) void*)l, 16, 0, 0);
}

// ---------------- RMSNorm over D=2048; MODE: 1 = f32+bf16, 2 = bf16 only ----------------
template<int MODE>
__global__ __launch_bounds__(256) void rmsnorm_kernel(const float* __restrict__ x,
                                                      const float* __restrict__ w,
                                                      float* __restrict__ outf,
                                                      unsigned short* __restrict__ outb) {
  const int t = blockIdx.x;
  const int tid = threadIdx.x;
  const float4* xr = (const float4*)(x + (size_t)t * DMODEL);
  float4 v0 = xr[tid];
  float4 v1 = xr[tid + 256];
  float s = v0.x*v0.x + v0.y*v0.y + v0.z*v0.z + v0.w*v0.w
          + v1.x*v1.x + v1.y*v1.y + v1.z*v1.z + v1.w*v1.w;
#pragma unroll
  for (int off = 32; off > 0; off >>= 1) s += __shfl_down(s, off);
  __shared__ float red[4];
  if ((tid & 63) == 0) red[tid >> 6] = s;
  __syncthreads();
  const float tot = red[0] + red[1] + red[2] + red[3];
  const float r = rsqrtf(tot * (1.0f / DMODEL) + 1e-5f);
  const float4* wr = (const float4*)w;
  const float4 w0 = wr[tid], w1 = wr[tid + 256];
  float4 o0, o1;
  o0.x = v0.x*r*w0.x; o0.y = v0.y*r*w0.y; o0.z = v0.z*r*w0.z; o0.w = v0.w*r*w0.w;
  o1.x = v1.x*r*w1.x; o1.y = v1.y*r*w1.y; o1.z = v1.z*r*w1.z; o1.w = v1.w*r*w1.w;
  if (MODE == 1) {
    float4* orow = (float4*)(outf + (size_t)t * DMODEL);
    orow[tid] = o0;
    orow[tid + 256] = o1;
  }
  ushort4* brow = (ushort4*)(outb + (size_t)t * DMODEL);
  brow[tid] = pack4(o0.x, o0.y, o0.z, o0.w);
  brow[tid + 256] = pack4(o1.x, o1.y, o1.z, o1.w);
}

// ---------------- fp32 -> bf16 bulk convert ----------------
__global__ __launch_bounds__(256) void f2b_kernel(const float* __restrict__ in,
                                                  unsigned short* __restrict__ out) {
  const size_t i = (size_t)blockIdx.x * 256 + threadIdx.x;
  const float4 a = ((const float4*)in)[2 * i];
  const float4 b = ((const float4*)in)[2 * i + 1];
  ((ushort4*)out)[2 * i] = pack4(a.x, a.y, a.z, a.w);
  ((ushort4*)out)[2 * i + 1] = pack4(b.x, b.y, b.z, b.w);
}

// ---------------- 4-phase slot-pipelined 256x256 bf16 MFMA GEMM (fat shapes): C = A @ B^T ---
// EPI: 0 = bf16 store; 3 = paired silu(gate)*up combine (B is 16-col-interleaved Wg/Wu,
// N=16384, output 4096x8192 bf16).
template<int EPI>
__global__ __launch_bounds__(512, 2) void gemm8p_kernel(const unsigned short* __restrict__ A,
                                                        const unsigned short* __restrict__ B,
                                                        float* __restrict__ Cf,
                                                        unsigned short* __restrict__ Cb,
                                                        int M, int N, int K) {
  __shared__ __align__(16) unsigned short lds[8][8192];   // 8 slots x 16 KB
  const int nbm = M >> 8, nbn = N >> 8, nwg = nbm * nbn;
  const int nt = K >> 6;   // K-tiles of 64
  int bmi, bni;
  {
    const int bid = blockIdx.x;
    const int cpx = nwg >> 3;
    int sc = 1;
    while (sc * sc < cpx) sc <<= 1;
    if (sc * sc > cpx) sc >>= 1;
    const int scn = (sc > 0) ? (cpx / sc) : 0;
    if ((nwg & 7) == 0 && sc > 0 && sc * scn == cpx && (nbm % sc) == 0 && (nbn % scn) == 0) {
      const int chunk = bid & 7, widx = bid >> 3;
      const int regc = nbn / scn;
      bmi = (chunk / regc) * sc + widx / scn;
      bni = (chunk % regc) * scn + widx % scn;
    } else {
      bmi = bid / nbn; bni = bid % nbn;
    }
  }
  const int bm = bmi << 8, bn = bni << 8;
  const int tid = threadIdx.x;
  const int wv = tid >> 6, ln = tid & 63;
  const int fr = ln & 15, qq = ln >> 4;
  const int wm = wv >> 2, wn = wv & 3;           // wave tile: rows wm*128, cols wn*64
  const int rsw = (fr >> 1) & 3;                 // read swizzle term
  const int s_sl = (ln & 3) ^ ((ln >> 3) & 3);   // staging source slot (inverse swizzle)

  f32x4 acc[8][4];
  const f32x4 zero = {0.f, 0.f, 0.f, 0.f};
#pragma unroll
  for (int mf = 0; mf < 8; mf++)
#pragma unroll
    for (int nf = 0; nf < 4; nf++) acc[mf][nf] = zero;

  bf16x8 afr[8], bfr[2];

  // stage one half: part 0=Ak0, 1=Ak1, 2=Bk0, 3=Bk1 of tile t2 -> slot ((t2&1)<<2)|part
  auto stage_half = [&](int t2, int part) {
    if (t2 >= nt) return;
    const unsigned short* Mat = (part >= 2) ? B : A;
    const int gb = (part >= 2) ? bn : bm;
    const int kk = part & 1;
    const int slot = ((t2 & 1) << 2) | part;
    const int k0 = t2 * 64 + kk * 32;
#pragma unroll
    for (int q = 0; q < 2; q++) {
      gl_lds16(Mat + (size_t)(gb + wv * 32 + q * 16 + (ln >> 2)) * K + k0 + s_sl * 8,
               &lds[slot][(wv * 32 + q * 16) * 32]);
    }
  };
  auto lda = [&](int tb, int kk) {
#pragma unroll
    for (int mf = 0; mf < 8; mf++) {
      const int ar = wm * 128 + mf * 16 + fr;
      afr[mf] = *(const bf16x8*)&lds[tb | kk][ar * 32 + ((qq ^ rsw) << 3)];
    }
  };
  auto ldb = [&](int tb, int kk, int nh) {
#pragma unroll
    for (int nj = 0; nj < 2; nj++) {
      const int br = wn * 64 + (nh * 2 + nj) * 16 + fr;
      bfr[nj] = *(const bf16x8*)&lds[tb | (2 + kk)][br * 32 + ((qq ^ rsw) << 3)];
    }
  };
  auto mm = [&](int nh) {
    __builtin_amdgcn_s_setprio(1);
#pragma unroll
    for (int mf = 0; mf < 8; mf++)
#pragma unroll
      for (int nj = 0; nj < 2; nj++)
        acc[mf][nh * 2 + nj] =
            __builtin_amdgcn_mfma_f32_16x16x32_bf16(afr[mf], bfr[nj], acc[mf][nh * 2 + nj], 0, 0, 0);
    __builtin_amdgcn_s_setprio(0);
  };

  // prologue: tile0 all 4 halves, tile1 k0 halves; wait tile0 (counted), publish
  stage_half(0, 0); stage_half(0, 2); stage_half(0, 1); stage_half(0, 3);
  stage_half(1, 0); stage_half(1, 2);
  asm volatile("s_waitcnt vmcnt(4)" ::: "memory");
  __builtin_amdgcn_s_barrier();
  asm volatile("" ::: "memory");

  for (int t = 0; t < nt; t++) {
    const int tb = (t & 1) << 2;
    // phase 0: (k0, N0); stage Ak1(t+1)
    lda(tb, 0); ldb(tb, 0, 0);
    stage_half(t + 1, 1);
    __builtin_amdgcn_s_barrier();
    mm(0);
    __builtin_amdgcn_s_barrier();
    // phase 1: (k0, N1); stage Bk1(t+1)
    ldb(tb, 0, 1);
    stage_half(t + 1, 3);
    __builtin_amdgcn_s_barrier();
    mm(1);
    __builtin_amdgcn_s_barrier();
    // phase 2: (k1, N1); stage Ak0(t+2)
    lda(tb, 1); ldb(tb, 1, 1);
    stage_half(t + 2, 0);
    __builtin_amdgcn_s_barrier();
    mm(1);
    __builtin_amdgcn_s_barrier();
    // phase 3: (k1, N0); stage Bk0(t+2)
    ldb(tb, 1, 0);
    stage_half(t + 2, 2);
    __builtin_amdgcn_s_barrier();
    mm(0);
    // tile boundary: counted vmcnt — next tile's 4 halves are older than newest in flight
    if (t + 1 < nt) {
      asm volatile("s_waitcnt lgkmcnt(0)" ::: "memory");
      __builtin_amdgcn_sched_barrier(0);
      if (t == nt - 2) {
        asm volatile("s_waitcnt vmcnt(0)" ::: "memory");
      } else {
        asm volatile("s_waitcnt vmcnt(4)" ::: "memory");
      }
      __builtin_amdgcn_sched_barrier(0);
      __builtin_amdgcn_s_barrier();
      __builtin_amdgcn_sched_barrier(0);
    }
  }

  const int cm4 = qq * 4;
  if (EPI == 3) {
    // paired combine: nf even = gate frag, nf odd = up frag at same output cols.
    const int bn2 = bn >> 1;
#pragma unroll
    for (int mf = 0; mf < 8; mf++) {
#pragma unroll
      for (int p = 0; p < 2; p++) {
#pragma unroll
        for (int r = 0; r < 4; r++) {
          const int grow = bm + wm * 128 + mf * 16 + cm4 + r;
          const int gcol = bn2 + wn * 32 + p * 16 + fr;
          Cb[(size_t)grow * 8192 + gcol] =
              f2bf(siluf(acc[mf][2 * p][r]) * acc[mf][2 * p + 1][r]);
        }
      }
    }
  } else {
#pragma unroll
    for (int mf = 0; mf < 8; mf++) {
#pragma unroll
      for (int nf = 0; nf < 4; nf++) {
#pragma unroll
        for (int r = 0; r < 4; r++) {
          const int grow = bm + wm * 128 + mf * 16 + cm4 + r;
          const int gcol = bn + wn * 64 + nf * 16 + fr;
          const size_t off = (size_t)grow * N + gcol;
          const float v = acc[mf][nf][r];
          if (EPI == 0) {
            Cb[off] = f2bf(v);
          } else {
            Cf[off] += v;
          }
        }
      }
    }
  }
}

// ---------------- pipelined bf16 MFMA GEMM (thin shapes): C[M][N] = A[M][K] * B[N][K]^T -----
// BM x BN block (8 waves, 64x64 per-wave tile), BK=32, 3 LDS buffers, counted vmcnt.
template<int EPI, int BM, int BN>
__global__ __launch_bounds__(512, 4) void gemm256_kernel(const unsigned short* __restrict__ A,
                                                         const unsigned short* __restrict__ B,
                                                         float* __restrict__ Cf,
                                                         unsigned short* __restrict__ Cb,
                                                         int M, int N, int K) {
  constexpr int MI = 4;
  constexpr int NI = BN / 64;
  constexpr int AW = BM / 128;
  constexpr int BW = BN / 128;
  __shared__ __align__(16) unsigned short lds[3][(BM + BN) * 32];
  const int nbm = M / BM, nbn = N / BN, nwg = nbm * nbn;
  const int nt = K >> 5;
  int bmi, bni;
  {
    const int bid = blockIdx.x;
    const int cpx = nwg >> 3;
    int sc = 1;
    while (sc * sc < cpx) sc <<= 1;
    if (sc * sc > cpx) sc >>= 1;
    const int scn = (sc > 0) ? (cpx / sc) : 0;
    if ((nwg & 7) == 0 && sc > 0 && sc * scn == cpx && (nbm % sc) == 0 && (nbn % scn) == 0) {
      const int chunk = bid & 7, widx = bid >> 3;
      const int regc = nbn / scn;
      bmi = (chunk / regc) * sc + widx / scn;
      bni = (chunk % regc) * scn + widx % scn;
    } else {
      bmi = bid / nbn; bni = bid % nbn;
    }
  }
  const int bm = bmi * BM, bn = bni * BN;
  const int tid = threadIdx.x;
  const int wv = tid >> 6, ln = tid & 63;
  const int fr = ln & 15, qq = ln >> 4;
  const int wm = wv >> 2, wn = wv & 3;
  const int ra0 = wm * 64, rb0 = wn * (BN / 4);
  const int lrow = ln >> 2;
  const int lslot = ln & 3;

  f32x4 acc[MI][NI];
  const f32x4 zero = {0.f, 0.f, 0.f, 0.f};
#pragma unroll
  for (int mi = 0; mi < MI; mi++)
#pragma unroll
    for (int ni = 0; ni < NI; ni++) acc[mi][ni] = zero;

  auto stage = [&](int buf, int t) {
    const int k0 = t << 5;
#pragma unroll
    for (int q = 0; q < AW; q++) {
      const int lr = q * 128 + wv * 16 + lrow;
      const int sl = lslot ^ ((lr >> 1) & 3);
      gl_lds16(A + (size_t)(bm + lr) * K + k0 + sl * 8,
               &lds[buf][(q * 128 + wv * 16) * 32]);
    }
#pragma unroll
    for (int q = 0; q < BW; q++) {
      const int lr = q * 128 + wv * 16 + lrow;
      const int sl = lslot ^ ((lr >> 1) & 3);
      gl_lds16(B + (size_t)(bn + lr) * K + k0 + sl * 8,
               &lds[buf][BM * 32 + (q * 128 + wv * 16) * 32]);
    }
  };

  stage(0, 0);
  stage(1, 1);
  asm volatile("s_waitcnt vmcnt(%0)" :: "i"(AW + BW) : "memory");
  __builtin_amdgcn_s_barrier();
  asm volatile("" ::: "memory");

  for (int t = 0; t < nt; t++) {
    const int cb = t % 3;
    const int b2 = (t + 2) % 3;
    const unsigned short* lA = &lds[cb][0];
    const unsigned short* lB = &lds[cb][BM * 32];
    bf16x8 bfr[NI];
#pragma unroll
    for (int ni = 0; ni < NI; ni++) {
      const int r = rb0 + ni * 16 + fr;
      bfr[ni] = *(const bf16x8*)&lB[r * 32 + ((qq ^ ((r >> 1) & 3)) << 3)];
    }
    bf16x8 afr[MI];
#pragma unroll
    for (int mi = 0; mi < MI; mi++) {
      const int r = ra0 + mi * 16 + fr;
      afr[mi] = *(const bf16x8*)&lA[r * 32 + ((qq ^ ((r >> 1) & 3)) << 3)];
    }
    if (t + 2 < nt) stage(b2, t + 2);
    __builtin_amdgcn_s_setprio(1);
#pragma unroll
    for (int mi = 0; mi < MI; mi++)
#pragma unroll
      for (int ni = 0; ni < NI; ni++)
        acc[mi][ni] = __builtin_amdgcn_mfma_f32_16x16x32_bf16(afr[mi], bfr[ni], acc[mi][ni], 0, 0, 0);
    __builtin_amdgcn_s_setprio(0);
    if (t + 1 < nt) {
      asm volatile("s_waitcnt lgkmcnt(0)" ::: "memory");
      if (t + 2 < nt) {
        asm volatile("s_waitcnt vmcnt(%0)" :: "i"(AW + BW) : "memory");
      } else {
        asm volatile("s_waitcnt vmcnt(0)" ::: "memory");
      }
      __builtin_amdgcn_s_barrier();
      asm volatile("" ::: "memory");
    }
  }

  const int cm4 = qq * 4;
#pragma unroll
  for (int mi = 0; mi < MI; mi++) {
#pragma unroll
    for (int ni = 0; ni < NI; ni++) {
#pragma unroll
      for (int r = 0; r < 4; r++) {
        const int grow = bm + ra0 + mi * 16 + cm4 + r;
        const int gcol = bn + rb0 + ni * 16 + fr;
        const size_t off = (size_t)grow * N + gcol;
        const float v = acc[mi][ni][r];
        if (EPI == 0) {
          Cb[off] = f2bf(v);
        } else if (EPI == 1) {
          Cf[off] += v;
        } else {
          Cb[off] = f2bf(siluf(bf2f(Cb[off])) * v);
        }
      }
    }
  }
}

// ---------------- ba = h @ ba_w^T ----------------
__global__ __launch_bounds__(256) void ba_gemm_kernel(const float* __restrict__ h_in,
                                                      const float* __restrict__ ba_w,
                                                      float* __restrict__ ba_out) {
  __shared__ __align__(16) float hl[2048];
  __shared__ float red[32][9];
  const int t = blockIdx.x;
  const int tid = threadIdx.x;
  const float4* hr = (const float4*)(h_in + (size_t)t * DMODEL);
  ((float4*)hl)[tid] = hr[tid];
  ((float4*)hl)[tid + 256] = hr[tid + 256];
  __syncthreads();
  const int c = tid & 31;
  const int p = tid >> 5;
  const float* wrow = ba_w + (size_t)c * DMODEL + p * 256;
  const float* hrow = hl + p * 256;
  float s = 0.f;
#pragma unroll 8
  for (int k = 0; k < 256; k++) s += hrow[k] * wrow[k];
  red[c][p] = s;
  __syncthreads();
  if (tid < 32) {
    float tot = 0.f;
#pragma unroll
    for (int q = 0; q < 8; q++) tot += red[tid][q];
    ba_out[(size_t)t * 32 + tid] = tot;
  }
}

// ---------------- extract z columns from bf16 qkvz ----------------
__global__ __launch_bounds__(256) void zcopy_kernel(const unsigned short* __restrict__ qkvz,
                                                    unsigned short* __restrict__ z) {
  const int idx = blockIdx.x * 256 + threadIdx.x;
  const int t = idx >> 8;
  const int c8 = (idx & 255) * 8;
  *(uint4*)(z + (size_t)t * 2048 + c8) =
      *(const uint4*)(qkvz + (size_t)t * CQKVZ + CQKV + c8);
}

// ---------------- causal depthwise conv (K=4) + SiLU; bf16 in, bf16 out ----------------
__global__ __launch_bounds__(256) void conv_silu_kernel(const unsigned short* __restrict__ qkvz,
                                                        const float* __restrict__ conv_w,
                                                        const float* __restrict__ mask,
                                                        unsigned short* __restrict__ mixed) {
  const int idx = blockIdx.x * 256 + threadIdx.x;
  const int c4 = (idx % 1536) * 4;
  const int t = idx / 1536;
  const float4 w0 = *(const float4*)(conv_w + (size_t)c4 * 4);
  const float4 w1 = *(const float4*)(conv_w + (size_t)c4 * 4 + 4);
  const float4 w2 = *(const float4*)(conv_w + (size_t)c4 * 4 + 8);
  const float4 w3 = *(const float4*)(conv_w + (size_t)c4 * 4 + 12);
  const float wj0[4] = {w0.x, w0.y, w0.z, w0.w};
  const float wj1[4] = {w1.x, w1.y, w1.z, w1.w};
  const float wj2[4] = {w2.x, w2.y, w2.z, w2.w};
  const float wj3[4] = {w3.x, w3.y, w3.z, w3.w};
  float4 acc = make_float4(0.f, 0.f, 0.f, 0.f);
#pragma unroll
  for (int j = 0; j < 4; j++) {
    const int tt = t - 3 + j;
    if (tt < 0) continue;
    const float m = mask[tt];
    const ushort4 xb = *(const ushort4*)(qkvz + (size_t)tt * CQKVZ + c4);
    acc.x += bf2f(xb.x) * m * wj0[j];
    acc.y += bf2f(xb.y) * m * wj1[j];
    acc.z += bf2f(xb.z) * m * wj2[j];
    acc.w += bf2f(xb.w) * m * wj3[j];
  }
  *(ushort4*)(mixed + (size_t)t * CQKV + c4) =
      pack4(siluf(acc.x), siluf(acc.y), siluf(acc.z), siluf(acc.w));
}

// ---------------- l2norm over Dk=128 for q,k heads (in place, bf16) ----------------
__global__ __launch_bounds__(256) void l2norm_kernel(unsigned short* __restrict__ mixed) {
  const int r = blockIdx.x * 4 + (threadIdx.x >> 6);
  const int lane = threadIdx.x & 63;
  const int t = r >> 5;
  const int hh = r & 31;
  unsigned short* p = mixed + (size_t)t * CQKV + hh * 128 + lane * 2;
  const ushort2 v = *(ushort2*)p;
  const float vx = bf2f(v.x), vy = bf2f(v.y);
  float s = vx * vx + vy * vy;
#pragma unroll
  for (int off = 32; off > 0; off >>= 1) s += __shfl_down(s, off);
  s = __shfl(s, 0);
  const float rn = rsqrtf(s + 1e-6f);
  ushort2 o;
  o.x = f2bf(vx * rn);
  o.y = f2bf(vy * rn);
  *(ushort2*)p = o;
}

// ---------------- beta, g ----------------
__global__ __launch_bounds__(256) void beta_g_kernel(const float* __restrict__ ba,
                                                     const float* __restrict__ A_log,
                                                     const float* __restrict__ dt_bias,
                                                     const float* __restrict__ mask,
                                                     float* __restrict__ beta,
                                                     float* __restrict__ g) {
  const int idx = blockIdx.x * 256 + threadIdx.x;
  const int t = idx >> 4;
  const int h = idx & 15;
  const float b = ba[(size_t)t * 32 + h];
  const float a = ba[(size_t)t * 32 + 16 + h];
  const float m = mask[t];
  beta[idx] = m / (1.0f + expf(-b));
  const float xx = a + dt_bias[h];
  const float sp = (xx > 20.0f) ? xx : log1pf(expf(xx));
  g[idx] = -expf(A_log[h]) * sp * m;
}

// ---------------- per-chunk cumsum of g + decay factors ----------------
__global__ __launch_bounds__(256) void gcs_kernel(const float* __restrict__ g,
                                                  float* __restrict__ gcsbuf,
                                                  float* __restrict__ edkbuf,
                                                  float* __restrict__ egqbuf,
                                                  float* __restrict__ adecbuf) {
  const int idx = blockIdx.x * 256 + threadIdx.x;  // chunk id = h*64 + n
  if (idx >= 1024) return;
  const int h = idx >> 6;
  const int n = idx & 63;
  const int t0 = n * 64;
  float s = 0.f;
  for (int i = 0; i < 64; i++) {
    s += g[(size_t)(t0 + i) * NH + h];
    gcsbuf[(size_t)idx * 64 + i] = s;
  }
  const float glast = s;
  adecbuf[idx] = __expf(glast);
  for (int i = 0; i < 64; i++) {
    const float gi = gcsbuf[(size_t)idx * 64 + i];
    edkbuf[(size_t)idx * 64 + i] = __expf(glast - gi);
    egqbuf[(size_t)idx * 64 + i] = __expf(gi) * SCALE;
  }
}

// ---------------- per-chunk MFMA: A=(k_beta k^T)*decay (strict lower), attn=(q k^T)*decay*scale
// 4 waves; k,q copied (already bf16) into XOR-swizzled LDS; both products share k B-fragments.
__global__ __launch_bounds__(256) void pre_attn_kernel(const unsigned short* __restrict__ mixed,
                                                       const float* __restrict__ gcsbuf,
                                                       const float* __restrict__ betabuf,
                                                       float* __restrict__ abuf,
                                                       float* __restrict__ attnbuf) {
  __shared__ __align__(16) unsigned short kbl[64 * 128];
  __shared__ __align__(16) unsigned short qbl[64 * 128];
  __shared__ float gcs_s[64];
  __shared__ float betal[64];
  const int blk = blockIdx.x;
  const int h = blk >> 6;
  const int n = blk & 63;
  const int t0 = n * 64;
  const int tid = threadIdx.x;
  if (tid < 64) {
    gcs_s[tid] = gcsbuf[(size_t)blk * 64 + tid];
    betal[tid] = betabuf[(size_t)(t0 + tid) * NH + h];
  }
#pragma unroll
  for (int p = 0; p < 4; p++) {
    const int idx = tid + p * 256;          // 0..1023
    const int i = idx >> 4, dg = idx & 15;  // row, 16B granule
    *(uint4*)&kbl[i * 128 + ((dg ^ (i & 7)) << 3)] =
        *(const uint4*)(mixed + (size_t)(t0 + i) * CQKV + 2048 + h * 128 + dg * 8);
    *(uint4*)&qbl[i * 128 + ((dg ^ (i & 7)) << 3)] =
        *(const uint4*)(mixed + (size_t)(t0 + i) * CQKV + h * 128 + dg * 8);
  }
  __syncthreads();
  const int ln = tid & 63;
  const int wv = tid >> 6;      // 0..3
  const int fr = ln & 15;
  const int g = ln >> 4;        // 0..3
  const int i0 = wv * 16;
  f32x4 accA[4], accQ[4];
  const f32x4 zero = {0.f, 0.f, 0.f, 0.f};
#pragma unroll
  for (int jt = 0; jt < 4; jt++) { accA[jt] = zero; accQ[jt] = zero; }
#pragma unroll
  for (int ks = 0; ks < 4; ks++) {
    const int kb = ks * 4 + g;
    const int ar = i0 + fr;
    const bf16x8 aK = *(const bf16x8*)&kbl[ar * 128 + ((kb ^ (ar & 7)) << 3)];
    const bf16x8 aQ = *(const bf16x8*)&qbl[ar * 128 + ((kb ^ (ar & 7)) << 3)];
#pragma unroll
    for (int jt = 0; jt < 4; jt++) {
      const int br = jt * 16 + fr;
      const bf16x8 b = *(const bf16x8*)&kbl[br * 128 + ((kb ^ (br & 7)) << 3)];
      accA[jt] = __builtin_amdgcn_mfma_f32_16x16x32_bf16(aK, b, accA[jt], 0, 0, 0);
      accQ[jt] = __builtin_amdgcn_mfma_f32_16x16x32_bf16(aQ, b, accQ[jt], 0, 0, 0);
    }
  }
  // epilogue: i = i0 + g*4 + r ; j = jt*16 + fr
#pragma unroll
  for (int jt = 0; jt < 4; jt++) {
    const int j = jt * 16 + fr;
    const float gj = gcs_s[j];
#pragma unroll
    for (int r = 0; r < 4; r++) {
      const int i = i0 + g * 4 + r;
      const float gi = gcs_s[i];
      const float dec = __expf(fminf(gi - gj, 0.f));
      abuf[(size_t)blk * 4096 + i * 64 + j] = (i > j) ? accA[jt][r] * betal[i] * dec : 0.f;
      attnbuf[(size_t)blk * 4096 + i * 64 + j] = (i >= j) ? accQ[jt][r] * dec * SCALE : 0.f;
    }
  }
}

// ---------------- per-chunk: T = (I+A)^-1, then T *= beta[col] ----------------
__global__ __launch_bounds__(256) void pre_solve_kernel(const float* __restrict__ abuf,
                                                        const float* __restrict__ betabuf,
                                                        float* __restrict__ tbuf) {
  __shared__ float Al[64][65];
  __shared__ float Tl[64][65];
  const int blk = blockIdx.x;
  const int h = blk >> 6;
  const int n = blk & 63;
  const int t0 = n * 64;
  const int tid = threadIdx.x;
#pragma unroll
  for (int rep = 0; rep < 4; rep++) {
    const int lin = rep * 256 + tid;
    const int i = lin >> 4;
    const int j = (lin & 15) * 4;
    const float4 av = *(const float4*)(abuf + (size_t)blk * 4096 + i * 64 + j);
    Al[i][j] = av.x; Al[i][j + 1] = av.y; Al[i][j + 2] = av.z; Al[i][j + 3] = av.w;
  }
  __syncthreads();
  if (tid < 64) {
    const int j = tid;
    const float bj = betabuf[(size_t)(t0 + j) * NH + h];
    for (int i = 0; i < 64; i++) {
      float s = (i == j) ? 1.0f : 0.0f;
      for (int l = j; l < i; l++) s -= Al[i][l] * Tl[l][j];
      Tl[i][j] = s;
    }
    for (int i = j; i < 64; i++) Tl[i][j] *= bj;
  }
  __syncthreads();
#pragma unroll
  for (int rep = 0; rep < 4; rep++) {
    const int lin = rep * 256 + tid;
    const int i = lin >> 4;
    const int j = (lin & 15) * 4;
    float4 tv;
    tv.x = Tl[i][j]; tv.y = Tl[i][j + 1]; tv.z = Tl[i][j + 2]; tv.w = Tl[i][j + 3];
    *(float4*)(tbuf + (size_t)blk * 4096 + i * 64 + j) = tv;
  }
}

// ---------------- per-chunk: u = Tb @ v (bf16, l4-packed [blk][l>>2][c][l&3]) ;
//                  w = Tb @ (k * e^gcs), stored NEGATED + slot-swizzled ----
__global__ __launch_bounds__(256) void pre_uw_kernel(const unsigned short* __restrict__ mixed,
                                                     const float* __restrict__ tbuf,
                                                     const float* __restrict__ gcsbuf,
                                                     unsigned short* __restrict__ ubf,
                                                     unsigned short* __restrict__ wbf) {
  __shared__ __align__(16) float Tl[64][68];
  __shared__ __align__(16) float xl[64][132];
  __shared__ float egcs[64];
  const int blk = blockIdx.x;
  const int h = blk >> 6;
  const int n = blk & 63;
  const int t0 = n * 64;
  const int tid = threadIdx.x;
  if (tid < 64) egcs[tid] = __expf(gcsbuf[(size_t)blk * 64 + tid]);
#pragma unroll
  for (int rep = 0; rep < 4; rep++) {
    const int lin = rep * 256 + tid;
    const int i = lin >> 4;
    const int j = (lin & 15) * 4;
    const float4 tv = *(const float4*)(tbuf + (size_t)blk * 4096 + i * 64 + j);
    *(float4*)&Tl[i][j] = tv;
  }
#pragma unroll
  for (int rep = 0; rep < 4; rep++) {
    const int lin = rep * 256 + tid;
    const int i = lin >> 4;
    const int d8 = (lin & 15) * 8;
    union { uint4 u; unsigned short s[8]; } w;
    w.u = *(const uint4*)(mixed + (size_t)(t0 + i) * CQKV + 4096 + h * 128 + d8);
#pragma unroll
    for (int j = 0; j < 8; j++) xl[i][d8 + j] = bf2f(w.s[j]);
  }
  __syncthreads();
  const int cgu = tid & 15;
  const int riu = tid >> 4;
  const int i0 = riu * 4;
  const int d0 = cgu * 8;
  float acc[4][8];
#pragma unroll
  for (int a = 0; a < 4; a++)
#pragma unroll
    for (int b = 0; b < 8; b++) acc[a][b] = 0.f;
#pragma unroll 2
  for (int j = 0; j < 64; j++) {
    const float tv[4] = {Tl[i0][j], Tl[i0 + 1][j], Tl[i0 + 2][j], Tl[i0 + 3][j]};
    const float4 x0 = *(const float4*)&xl[j][d0];
    const float4 x1 = *(const float4*)&xl[j][d0 + 4];
    const float xv[8] = {x0.x, x0.y, x0.z, x0.w, x1.x, x1.y, x1.z, x1.w};
#pragma unroll
    for (int a = 0; a < 4; a++)
#pragma unroll
      for (int b = 0; b < 8; b++) acc[a][b] += tv[a] * xv[b];
  }
  // u store: bf16 l4-packed layout elem = blk*8192 + riu*512 + (d0+b)*4 + (l&3)
#pragma unroll
  for (int b = 0; b < 8; b++) {
    *(ushort4*)(ubf + (size_t)blk * 8192 + riu * 512 + (size_t)(d0 + b) * 4) =
        pack4(acc[0][b], acc[1][b], acc[2][b], acc[3][b]);
  }
  __syncthreads();
#pragma unroll
  for (int rep = 0; rep < 4; rep++) {
    const int lin = rep * 256 + tid;
    const int i = lin >> 4;
    const int d8 = (lin & 15) * 8;
    union { uint4 u; unsigned short s[8]; } w;
    w.u = *(const uint4*)(mixed + (size_t)(t0 + i) * CQKV + 2048 + h * 128 + d8);
    const float e = egcs[i];
#pragma unroll
    for (int j = 0; j < 8; j++) xl[i][d8 + j] = bf2f(w.s[j]) * e;
  }
  __syncthreads();
#pragma unroll
  for (int a = 0; a < 4; a++)
#pragma unroll
    for (int b = 0; b < 8; b++) acc[a][b] = 0.f;
#pragma unroll 2
  for (int j = 0; j < 64; j++) {
    const float tv[4] = {Tl[i0][j], Tl[i0 + 1][j], Tl[i0 + 2][j], Tl[i0 + 3][j]};
    const float4 x0 = *(const float4*)&xl[j][d0];
    const float4 x1 = *(const float4*)&xl[j][d0 + 4];
    const float xv[8] = {x0.x, x0.y, x0.z, x0.w, x1.x, x1.y, x1.z, x1.w};
#pragma unroll
    for (int a = 0; a < 4; a++)
#pragma unroll
      for (int b = 0; b < 8; b++) acc[a][b] += tv[a] * xv[b];
  }
  // store -w, column-slot swizzled by (row&7) so scan can global_load_lds linearly
#pragma unroll
  for (int a = 0; a < 4; a++) {
    const int l = i0 + a;
    unsigned short* wp = wbf + (size_t)(t0 + l) * 2048 + h * 128 + ((cgu ^ (l & 7)) << 3);
    *(ushort4*)wp = pack4(-acc[a][0], -acc[a][1], -acc[a][2], -acc[a][3]);
    *(ushort4*)(wp + 4) = pack4(-acc[a][4], -acc[a][5], -acc[a][6], -acc[a][7]);
  }
}

// ---------------- per-chunk: kdT[blk][d][l] = bf16(k*edk) slot-swizzled; qe = bf16(q*egq) ----------------
__global__ __launch_bounds__(256) void ktrans_kernel(const unsigned short* __restrict__ mixed,
                                                     const float* __restrict__ edkbuf,
                                                     const float* __restrict__ egqbuf,
                                                     unsigned short* __restrict__ kdT,
                                                     unsigned short* __restrict__ qe) {
  __shared__ __align__(16) float kl[64][132];
  __shared__ float edk_s[64];
  __shared__ float egq_s[64];
  const int blk = blockIdx.x;
  const int h = blk >> 6;
  const int n = blk & 63;
  const int t0 = n * 64;
  const int tid = threadIdx.x;
  if (tid < 64) {
    edk_s[tid] = edkbuf[(size_t)blk * 64 + tid];
    egq_s[tid] = egqbuf[(size_t)blk * 64 + tid];
  }
#pragma unroll
  for (int q = 0; q < 4; q++) {
    const int idx = tid + q * 256;
    const int l = idx >> 4, d8 = (idx & 15) * 8;
    union { uint4 u; unsigned short s[8]; } w;
    w.u = *(const uint4*)(mixed + (size_t)(t0 + l) * CQKV + 2048 + h * 128 + d8);
#pragma unroll
    for (int j = 0; j < 8; j++) kl[l][d8 + j] = bf2f(w.s[j]);
  }
  __syncthreads();
#pragma unroll
  for (int q = 0; q < 4; q++) {
    const int idx = tid + q * 256;
    const int d = idx >> 3, lsl = idx & 7;
    const int l8 = lsl * 8;
    float v[8];
#pragma unroll
    for (int j = 0; j < 8; j++) v[j] = kl[l8 + j][d] * edk_s[l8 + j];
    unsigned short* p = kdT + (size_t)blk * 8192 + d * 64 + ((lsl ^ (d & 7)) << 3);
    *(ushort4*)p = pack4(v[0], v[1], v[2], v[3]);
    *(ushort4*)(p + 4) = pack4(v[4], v[5], v[6], v[7]);
  }
#pragma unroll
  for (int q = 0; q < 4; q++) {
    const int idx = tid + q * 256;
    const int i = idx >> 4, c8 = (idx & 15) * 8;
    union { uint4 u; unsigned short s[8]; } w;
    w.u = *(const uint4*)(mixed + (size_t)(t0 + i) * CQKV + h * 128 + c8);
    const float e = egq_s[i];
    unsigned short* qp = qe + (size_t)(t0 + i) * 2048 + h * 128 + c8;
    *(ushort4*)qp = pack4(bf2f(w.s[0]) * e, bf2f(w.s[1]) * e, bf2f(w.s[2]) * e, bf2f(w.s[3]) * e);
    *(ushort4*)(qp + 4) = pack4(bf2f(w.s[4]) * e, bf2f(w.s[5]) * e, bf2f(w.s[6]) * e, bf2f(w.s[7]) * e);
  }
}

// ---------------- MFMA scan, column-decomposed: 8 waves x 16 c-columns, NO cross-wave data ---
// u read bf16 l4-packed (4x ushort4 per chunk). Exports d4/l4-packed (coalesced).
// blocks 0..15: per-head scan; ONE barrier/chunk (counted vmcnt(17)).
// blocks >=16: weight f2b (Wgu interleaved / Wd / Wo) + residual copy (512 threads).
__global__ __launch_bounds__(512, 1) void scan_kernel(const unsigned short* __restrict__ wbf,
                                                      const unsigned short* __restrict__ kdT,
                                                      const unsigned short* __restrict__ ubf,
                                                      const float* __restrict__ adecbuf,
                                                      unsigned short* __restrict__ STb,
                                                      unsigned short* __restrict__ vtb,
                                                      const float* __restrict__ gw,
                                                      const float* __restrict__ uw,
                                                      const float* __restrict__ dw,
                                                      const float* __restrict__ ow,
                                                      const float* __restrict__ xin,
                                                      unsigned short* __restrict__ Wgu,
                                                      unsigned short* __restrict__ Wd,
                                                      unsigned short* __restrict__ Wo,
                                                      float* __restrict__ outc) {
  __shared__ __align__(16) unsigned short stage[2][16384];  // [w 8192 | kT 8192] shorts each
  __shared__ __align__(16) unsigned short privAll[8][3072]; // per wave: A 16x128 | B 16x64
  if (blockIdx.x >= 16) {
    // side work (512 thr): Wg 4096 + Wu 4096 + Wd 4096 + Wo 1024 + copy 2048 = 15360 blocks
    const int xb = blockIdx.x - 16;
    const int tid = threadIdx.x;
    if (xb < 8192) {
      // gate/up f2b with 16-row interleave into Wgu:
      // src row r -> dst row (r>>4)*32 + (r&15) (+16 for up)
      const bool isUp = (xb >= 4096);
      const float* src = isUp ? uw : gw;
      const size_t e = ((size_t)(isUp ? xb - 4096 : xb) * 512 + tid) * 8;
      const int r = (int)(e >> 11);
      const int col = (int)(e & 2047);
      const int drow = (r >> 4) * 32 + (r & 15) + (isUp ? 16 : 0);
      const float4 a = *(const float4*)(src + e);
      const float4 b = *(const float4*)(src + e + 4);
      unsigned short* dst = Wgu + (size_t)drow * 2048 + col;
      *(ushort4*)dst = pack4(a.x, a.y, a.z, a.w);
      *(ushort4*)(dst + 4) = pack4(b.x, b.y, b.z, b.w);
    } else if (xb < 13312) {
      const float* src; unsigned short* dst; size_t u;
      if (xb < 12288) { src = dw; dst = Wd; u = (size_t)(xb - 8192) * 512 + tid; }
      else            { src = ow; dst = Wo; u = (size_t)(xb - 12288) * 512 + tid; }
      const float4 a = ((const float4*)src)[2 * u];
      const float4 b = ((const float4*)src)[2 * u + 1];
      ((ushort4*)dst)[2 * u] = pack4(a.x, a.y, a.z, a.w);
      ((ushort4*)dst)[2 * u + 1] = pack4(b.x, b.y, b.z, b.w);
    } else {
      const size_t i = (size_t)(xb - 13312) * 512 + tid;
      ((float4*)outc)[2 * i] = ((const float4*)xin)[2 * i];
      ((float4*)outc)[2 * i + 1] = ((const float4*)xin)[2 * i + 1];
    }
    return;
  }
  const int h = blockIdx.x;
  const int tid = threadIdx.x;
  const int ln = tid & 63;
  const int wv = tid >> 6;        // 0..7
  const int fr = ln & 15;
  const int g  = ln >> 4;         // 0..3
  const int c0 = wv * 16;
  const int fsw = fr & 7;
  unsigned short* privA = &privAll[wv][0];     // [16 c][128 d], slot-swizzled
  unsigned short* privB = &privAll[wv][2048];  // [16 c][64 l], slot-swizzled
  const f32x4 zero = {0.f, 0.f, 0.f, 0.f};

  f32x4 acc2[8];                  // S^T state for this wave's 16 columns, d-tile dt
#pragma unroll
  for (int dt = 0; dt < 8; dt++) acc2[dt] = zero;

  auto stage_wk = [&](int buf, int n1) {
    const int t0n = n1 * 64;
    const size_t kbase = (size_t)(h * 64 + n1) * 8192;
#pragma unroll
    for (int q = 0; q < 2; q++) {
      const int m = wv * 2 + q;   // 0..15
      gl_lds16(wbf + (size_t)(t0n + m * 4 + (ln >> 4)) * 2048 + h * 128 + (ln & 15) * 8,
               &stage[buf][m * 512]);
      gl_lds16(kdT + kbase + (m * 8 + (ln >> 3)) * 64 + (ln & 7) * 8,
               &stage[buf][8192 + m * 512]);
    }
  };

  // prologue: u/adec for chunk 0 + stage chunk 0
  ushort4 ur4[4];
#pragma unroll
  for (int lt = 0; lt < 4; lt++)
    ur4[lt] = *(const ushort4*)(ubf + (size_t)(h * 64) * 8192 + (lt * 4 + g) * 512 + (c0 + fr) * 4);
  float ad = adecbuf[h * 64];
  stage_wk(0, 0);
  asm volatile("s_waitcnt vmcnt(0)" ::: "memory");
  __builtin_amdgcn_s_barrier();
  asm volatile("" ::: "memory");

  for (int n = 0; n < 64; n++) {
    const int blk = h * 64 + n;
    const unsigned short* wl = &stage[n & 1][0];
    const unsigned short* kl = &stage[n & 1][8192];
    // (1) issue staging for n+1 first (oldest VMEM ops of this chunk)
    if (n + 1 < 64) stage_wk((n + 1) & 1, n + 1);
    __builtin_amdgcn_sched_barrier(0);
    // (2) prefetch u/adec for n+1 (4 ushort4 + 1 scalar; younger than staging)
    ushort4 ur4n[4];
    float adn = 0.f;
    if (n + 1 < 64) {
      const size_t ub = (size_t)(blk + 1) * 8192;
#pragma unroll
      for (int lt = 0; lt < 4; lt++)
        ur4n[lt] = *(const ushort4*)(ubf + ub + (lt * 4 + g) * 512 + (c0 + fr) * 4);
      adn = adecbuf[blk + 1];
    } else {
#pragma unroll
      for (int lt = 0; lt < 4; lt++) { ur4n[lt].x = 0; ur4n[lt].y = 0; ur4n[lt].z = 0; ur4n[lt].w = 0; }
    }
    __builtin_amdgcn_sched_barrier(0);
    // (3) dump S_n^T -> privA (wave-private) ; export S_n coalesced (d4-packed)
#pragma unroll
    for (int dt = 0; dt < 8; dt++) {
      const int slot = dt * 2 + (g >> 1);
      const ushort4 pv = pack4(acc2[dt][0], acc2[dt][1], acc2[dt][2], acc2[dt][3]);
      *(ushort4*)&privA[fr * 128 + ((slot ^ fsw) << 3) + (g & 1) * 4] = pv;
      *(ushort4*)(STb + (size_t)blk * 16384 + (dt * 4 + g) * 512 + (c0 + fr) * 4) = pv;
    }
    // (4) MFMA1: v_new = u + (-w) @ S  (A from shared staged w, B from privA)
    f32x4 acc1[4];
#pragma unroll
    for (int lt = 0; lt < 4; lt++) {
      f32x4 t;
      t[0] = bf2f(ur4[lt].x); t[1] = bf2f(ur4[lt].y);
      t[2] = bf2f(ur4[lt].z); t[3] = bf2f(ur4[lt].w);
      acc1[lt] = t;
    }
#pragma unroll
    for (int ks = 0; ks < 4; ks++) {
      const int kb = ks * 4 + g;
      const bf16x8 b = *(const bf16x8*)&privA[fr * 128 + ((kb ^ fsw) << 3)];
#pragma unroll
      for (int lt = 0; lt < 4; lt++) {
        const bf16x8 a = *(const bf16x8*)&wl[(lt * 16 + fr) * 128 + ((kb ^ fsw) << 3)];
        acc1[lt] = __builtin_amdgcn_mfma_f32_16x16x32_bf16(a, b, acc1[lt], 0, 0, 0);
      }
    }
    // (5) v_new^T -> privB ; export v_new^T coalesced (l4-packed)
#pragma unroll
    for (int lt = 0; lt < 4; lt++) {
      const int slot = lt * 2 + (g >> 1);
      const ushort4 pv = pack4(acc1[lt][0], acc1[lt][1], acc1[lt][2], acc1[lt][3]);
      *(ushort4*)&privB[fr * 64 + ((slot ^ fsw) << 3) + (g & 1) * 4] = pv;
      *(ushort4*)(vtb + (size_t)blk * 8192 + (lt * 4 + g) * 512 + (c0 + fr) * 4) = pv;
    }
    // (6) MFMA2: S = adec*S + kdec^T @ v_new
#pragma unroll
    for (int dt = 0; dt < 8; dt++) {
      acc2[dt][0] *= ad; acc2[dt][1] *= ad; acc2[dt][2] *= ad; acc2[dt][3] *= ad;
    }
#pragma unroll
    for (int ks = 0; ks < 2; ks++) {
      const int kb = ks * 4 + g;
      const bf16x8 b = *(const bf16x8*)&privB[fr * 64 + ((kb ^ fsw) << 3)];
#pragma unroll
      for (int dt = 0; dt < 8; dt++) {
        const bf16x8 a = *(const bf16x8*)&kl[(dt * 16 + fr) * 64 + ((kb ^ fsw) << 3)];
        acc2[dt] = __builtin_amdgcn_mfma_f32_16x16x32_bf16(a, b, acc2[dt], 0, 0, 0);
      }
    }
    // (7) roll prefetched operands
#pragma unroll
    for (int lt = 0; lt < 4; lt++) ur4[lt] = ur4n[lt];
    ad = adn;
    // (8) publish staging: counted vmcnt (youngest 17 = 4 u + 1 adec + 12 export stores)
    if (n + 1 < 64) {
      asm volatile("s_waitcnt lgkmcnt(0)" ::: "memory");
      __builtin_amdgcn_sched_barrier(0);
      asm volatile("s_waitcnt vmcnt(17)" ::: "memory");
      __builtin_amdgcn_sched_barrier(0);
      __builtin_amdgcn_s_barrier();
      __builtin_amdgcn_sched_barrier(0);
    }
  }
}

// ---------------- MFMA o-compute + fused gated RMSNorm (reads d4/l4-packed ST/vt) ----------------
__global__ __launch_bounds__(256) void ocomp_kernel(const unsigned short* __restrict__ qe,
                                                    const unsigned short* __restrict__ STbuf,
                                                    const unsigned short* __restrict__ vtbuf,
                                                    const float* __restrict__ attnbuf,
                                                    const unsigned short* __restrict__ zb,
                                                    const float* __restrict__ onw,
                                                    unsigned short* __restrict__ ob) {
  __shared__ __align__(16) unsigned short STl[128 * 128];  // [c][d]
  __shared__ __align__(16) unsigned short vtl[128 * 64];   // [c][l]
  __shared__ __align__(16) unsigned short ql[64 * 128];    // [i][d]
  __shared__ __align__(16) unsigned short al[64 * 64];     // [i][l]
  const int blk = blockIdx.x;
  const int h = blk >> 6;
  const int n = blk & 63;
  const int t0 = n * 64;
  const int tid = threadIdx.x;
  // ST: d4-packed -> [c][d] swizzled LDS. uint4 o covers (dq = o>>6, cols 2w,2w+1, w = o&63)
#pragma unroll
  for (int q = 0; q < 8; q++) {
    const int o = tid + q * 256;
    const int dq = o >> 6, w = o & 63;
    const uint4 v = *(const uint4*)(STbuf + (size_t)blk * 16384 + (size_t)o * 8);
    const int cA = 2 * w, cB = 2 * w + 1;
    uint2 h0; h0.x = v.x; h0.y = v.y;
    uint2 h1; h1.x = v.z; h1.y = v.w;
    *(uint2*)&STl[cA * 128 + (((dq >> 1) ^ (cA & 7)) << 3) + (dq & 1) * 4] = h0;
    *(uint2*)&STl[cB * 128 + (((dq >> 1) ^ (cB & 7)) << 3) + (dq & 1) * 4] = h1;
  }
  // vt: l4-packed -> [c][l] swizzled LDS
#pragma unroll
  for (int q = 0; q < 4; q++) {
    const int o = tid + q * 256;
    const int lq = o >> 6, w = o & 63;
    const uint4 v = *(const uint4*)(vtbuf + (size_t)blk * 8192 + (size_t)o * 8);
    const int cA = 2 * w, cB = 2 * w + 1;
    uint2 h0; h0.x = v.x; h0.y = v.y;
    uint2 h1; h1.x = v.z; h1.y = v.w;
    *(uint2*)&vtl[cA * 64 + (((lq >> 1) ^ (cA & 7)) << 3) + (lq & 1) * 4] = h0;
    *(uint2*)&vtl[cB * 64 + (((lq >> 1) ^ (cB & 7)) << 3) + (lq & 1) * 4] = h1;
  }
#pragma unroll
  for (int q = 0; q < 4; q++) {
    const int idx = tid + q * 256;
    const int i = idx >> 4, dg = idx & 15;
    *(uint4*)&ql[i * 128 + ((dg ^ (i & 7)) << 3)] =
        *(const uint4*)(qe + (size_t)(t0 + i) * 2048 + h * 128 + dg * 8);
  }
#pragma unroll
  for (int q = 0; q < 4; q++) {
    const int idx = tid + q * 256;
    const int i = idx >> 4, l4 = (idx & 15) * 4;
    const float4 v = *(const float4*)(attnbuf + (size_t)blk * 4096 + i * 64 + l4);
    *(ushort4*)&al[i * 64 + (((l4 >> 3) ^ (i & 7)) << 3) + (l4 & 7)] =
        pack4(v.x, v.y, v.z, v.w);
  }
  __syncthreads();
  const int ln = tid & 63;
  const int wv = tid >> 6;
  const int fr = ln & 15;
  const int g = ln >> 4;
  const int i0 = wv * 16;
  f32x4 acc[8];
  const f32x4 zero = {0.f, 0.f, 0.f, 0.f};
#pragma unroll
  for (int nt = 0; nt < 8; nt++) acc[nt] = zero;
#pragma unroll
  for (int ks = 0; ks < 4; ks++) {
    const int kb = ks * 4 + g;
    const int ar = i0 + fr;
    const bf16x8 a = *(const bf16x8*)&ql[ar * 128 + ((kb ^ (ar & 7)) << 3)];
#pragma unroll
    for (int nt = 0; nt < 8; nt++) {
      const int c = nt * 16 + fr;
      const bf16x8 b = *(const bf16x8*)&STl[c * 128 + ((kb ^ (c & 7)) << 3)];
      acc[nt] = __builtin_amdgcn_mfma_f32_16x16x32_bf16(a, b, acc[nt], 0, 0, 0);
    }
  }
#pragma unroll
  for (int ks = 0; ks < 2; ks++) {
    const int kb = ks * 4 + g;
    const int ar = i0 + fr;
    const bf16x8 a = *(const bf16x8*)&al[ar * 64 + ((kb ^ (ar & 7)) << 3)];
#pragma unroll
    for (int nt = 0; nt < 8; nt++) {
      const int c = nt * 16 + fr;
      const bf16x8 b = *(const bf16x8*)&vtl[c * 64 + ((kb ^ (c & 7)) << 3)];
      acc[nt] = __builtin_amdgcn_mfma_f32_16x16x32_bf16(a, b, acc[nt], 0, 0, 0);
    }
  }
  float s0 = 0.f, s1 = 0.f, s2 = 0.f, s3 = 0.f;
#pragma unroll
  for (int nt = 0; nt < 8; nt++) {
    s0 += acc[nt][0] * acc[nt][0];
    s1 += acc[nt][1] * acc[nt][1];
    s2 += acc[nt][2] * acc[nt][2];
    s3 += acc[nt][3] * acc[nt][3];
  }
#pragma unroll
  for (int m = 1; m < 16; m <<= 1) {
    s0 += __shfl_xor(s0, m);
    s1 += __shfl_xor(s1, m);
    s2 += __shfl_xor(s2, m);
    s3 += __shfl_xor(s3, m);
  }
  float rn[4];
  rn[0] = rsqrtf(s0 * (1.0f / 128.0f) + 1e-5f);
  rn[1] = rsqrtf(s1 * (1.0f / 128.0f) + 1e-5f);
  rn[2] = rsqrtf(s2 * (1.0f / 128.0f) + 1e-5f);
  rn[3] = rsqrtf(s3 * (1.0f / 128.0f) + 1e-5f);
#pragma unroll
  for (int nt = 0; nt < 8; nt++) {
    const int c = nt * 16 + fr;
    const float wn = onw[c];
#pragma unroll
    for (int r = 0; r < 4; r++) {
      const size_t off = (size_t)(t0 + i0 + g * 4 + r) * 2048 + h * 128 + c;
      const float zz = siluf(bf2f(zb[off]));
      ob[off] = f2bf(acc[nt][r] * rn[r] * wn * zz);
    }
  }
}

extern "C" void kernel_launch(void* const* d_in, const int* in_sizes, int n_in,
                              void* d_out, int out_size, void* d_ws, size_t ws_size,
                              hipStream_t stream) {
  (void)in_sizes; (void)n_in; (void)out_size;
  const float* x        = (const float*)d_in[0];
  const float* mask     = (const float*)d_in[1];
  const float* ln1_w    = (const float*)d_in[2];
  const float* qkvz_w   = (const float*)d_in[3];
  const float* ba_w     = (const float*)d_in[4];
  const float* conv_w   = (const float*)d_in[5];
  const float* A_log    = (const float*)d_in[6];
  const float* dt_bias  = (const float*)d_in[7];
  const float* o_norm_w = (const float*)d_in[8];
  const float* out_w    = (const float*)d_in[9];
  const float* ln2_w    = (const float*)d_in[10];
  const float* gate_w   = (const float*)d_in[11];
  const float* up_w     = (const float*)d_in[12];
  const float* down_w   = (const float*)d_in[13];
  float* out = (float*)d_out;

  const size_t NEED_BYTES = (size_t)75825152 * 4;
  if (ws_size < NEED_BYTES) return;

  float* ws = (float*)d_ws;
  unsigned short* mixed_bf = (unsigned short*)ws;            // 4096 x 6144 bf16 (50 MB)
  unsigned short* Wgu = (unsigned short*)ws;                 // [16384][2048] bf16, 16-col interleaved
  unsigned short* Wd = (unsigned short*)(ws + 16777216);
  unsigned short* qkvz_bf = (unsigned short*)(ws + 25165824);
  unsigned short* u_bf = (unsigned short*)(ws + 25165824);   // 1024 x 8192 bf16 (16 MB)
  unsigned short* wbf = (unsigned short*)(ws + 33554432);
  unsigned short* kdT = (unsigned short*)(ws + 37748736);
  unsigned short* comb_bf = (unsigned short*)(ws + 25165824);
  unsigned short* z_bf = (unsigned short*)(ws + 41943040);
  float* h_buf = ws + 46137344;
  float* a_buf = ws + 46137344;
  unsigned short* vt_buf = (unsigned short*)(ws + 46137344);
  float* t_buf = ws + 50331648;
  unsigned short* qe_bf = (unsigned short*)(ws + 50331648);  // after pre_uw, t_buf is dead
  unsigned short* h_bf  = (unsigned short*)(ws + 54525952);
  unsigned short* ob    = (unsigned short*)(ws + 54525952);
  unsigned short* h2_bf = (unsigned short*)(ws + 54525952);
  float* attn_buf = ws + 58720256;
  unsigned short* Wq = (unsigned short*)(ws + 62914560);
  unsigned short* ST_buf = (unsigned short*)(ws + 62914560);
  unsigned short* Wo = (unsigned short*)(ws + 71303168);
  float* ba_buf   = ws + 73400320;
  float* beta_buf = ws + 73531392;
  float* g_buf    = ws + 73596928;
  float* gcs_buf  = ws + 73662464;
  float* edk_buf  = ws + 73728000;
  float* egq_buf  = ws + 73793536;
  float* adec_buf = ws + 73859072;

  rmsnorm_kernel<1><<<4096, 256, 0, stream>>>(x, ln1_w, h_buf, h_bf);
  f2b_kernel<<<8192, 256, 0, stream>>>(qkvz_w, Wq);
  gemm8p_kernel<0><<<512, 512, 0, stream>>>(h_bf, Wq, nullptr, qkvz_bf, 4096, 8192, 2048);
  ba_gemm_kernel<<<4096, 256, 0, stream>>>(h_buf, ba_w, ba_buf);
  zcopy_kernel<<<4096, 256, 0, stream>>>(qkvz_bf, z_bf);
  conv_silu_kernel<<<24576, 256, 0, stream>>>(qkvz_bf, conv_w, mask, mixed_bf);
  l2norm_kernel<<<32768, 256, 0, stream>>>(mixed_bf);
  beta_g_kernel<<<256, 256, 0, stream>>>(ba_buf, A_log, dt_bias, mask, beta_buf, g_buf);
  gcs_kernel<<<4, 256, 0, stream>>>(g_buf, gcs_buf, edk_buf, egq_buf, adec_buf);
  pre_attn_kernel<<<1024, 256, 0, stream>>>(mixed_bf, gcs_buf, beta_buf, a_buf, attn_buf);
  pre_solve_kernel<<<1024, 256, 0, stream>>>(a_buf, beta_buf, t_buf);
  pre_uw_kernel<<<1024, 256, 0, stream>>>(mixed_bf, t_buf, gcs_buf, u_bf, wbf);
  ktrans_kernel<<<1024, 256, 0, stream>>>(mixed_bf, edk_buf, egq_buf, kdT, qe_bf);
  // column-decomposed MFMA scan (16 blocks, 8 waves) + fused f2b/copy (15360 blocks)
  scan_kernel<<<15376, 512, 0, stream>>>(wbf, kdT, u_bf, adec_buf, ST_buf, vt_buf,
                                         gate_w, up_w, down_w, out_w, x,
                                         Wgu, Wd, Wo, out);
  ocomp_kernel<<<1024, 256, 0, stream>>>(qe_bf, ST_buf, vt_buf, attn_buf,
                                         z_bf, o_norm_w, ob);
  gemm256_kernel<1, 128, 128><<<512, 512, 0, stream>>>(ob, Wo, out, nullptr, 4096, 2048, 2048);
  rmsnorm_kernel<2><<<4096, 256, 0, stream>>>(out, ln2_w, nullptr, h2_bf);
  // fused gate+up: N=16384 interleaved weights, epilogue writes silu(gate)*up (4096x8192 bf16)
  gemm8p_kernel<3><<<1024, 512, 0, stream>>>(h2_bf, Wgu, nullptr, comb_bf, 4096, 16384, 2048);
  gemm256_kernel<1, 128, 128><<<512, 512, 0, stream>>>(comb_bf, Wd, out, nullptr, 4096, 2048, 8192);
}

// Round 19
// 1245.704 us; speedup vs baseline: 1.4027x; 1.0099x over previous
//
#include <hip/hip_runtime.h>
#include <math.h>

#define T_LEN 4096
#define DMODEL 2048
#define NH 16
#define CQKV 6144
#define CQKVZ 8192
#define SCALE 0.08838834764831845f   // 128^-0.5

using bf16x8 = __attribute__((ext_vector_type(8))) short;
using f32x4  = __attribute__((ext_vector_type(4))) float;

__device__ __forceinline__ float siluf(float x) { return x / (1.0f + __expf(-x)); }

__device__ __forceinline__ unsigned short f2bf(float f) {  // RNE
  unsigned int u = __float_as_uint(f);
  u = (u + 0x7FFFu + ((u >> 16) & 1u)) >> 16;
  return (unsigned short)u;
}
__device__ __forceinline__ float bf2f(unsigned short u) {
  return __uint_as_float(((unsigned int)u) << 16);
}
__device__ __forceinline__ ushort4 pack4(float a, float b, float c, float d) {
  ushort4 r; r.x = f2bf(a); r.y = f2bf(b); r.z = f2bf(c); r.w = f2bf(d); return r;
}

// async global->LDS, 16 bytes per lane; LDS dest is wave-uniform base (+ lane*16 implicit)
__device__ __forceinline__ void gl_lds16(const unsigned short* g, unsigned short* l) {
  __builtin_amdgcn_global_load_lds(
      (const __attribute__((address_space(1))) void*)g,
      (__attribute__((address_space(3))) void*)l, 16, 0, 0);
}

// ---------------- RMSNorm over D=2048; MODE: 1 = f32+bf16, 2 = bf16 only ----------------
template<int MODE>
__global__ __launch_bounds__(256) void rmsnorm_kernel(const float* __restrict__ x,
                                                      const float* __restrict__ w,
                                                      float* __restrict__ outf,
                                                      unsigned short* __restrict__ outb) {
  const int t = blockIdx.x;
  const int tid = threadIdx.x;
  const float4* xr = (const float4*)(x + (size_t)t * DMODEL);
  float4 v0 = xr[tid];
  float4 v1 = xr[tid + 256];
  float s = v0.x*v0.x + v0.y*v0.y + v0.z*v0.z + v0.w*v0.w
          + v1.x*v1.x + v1.y*v1.y + v1.z*v1.z + v1.w*v1.w;
#pragma unroll
  for (int off = 32; off > 0; off >>= 1) s += __shfl_down(s, off);
  __shared__ float red[4];
  if ((tid & 63) == 0) red[tid >> 6] = s;
  __syncthreads();
  const float tot = red[0] + red[1] + red[2] + red[3];
  const float r = rsqrtf(tot * (1.0f / DMODEL) + 1e-5f);
  const float4* wr = (const float4*)w;
  const float4 w0 = wr[tid], w1 = wr[tid + 256];
  float4 o0, o1;
  o0.x = v0.x*r*w0.x; o0.y = v0.y*r*w0.y; o0.z = v0.z*r*w0.z; o0.w = v0.w*r*w0.w;
  o1.x = v1.x*r*w1.x; o1.y = v1.y*r*w1.y; o1.z = v1.z*r*w1.z; o1.w = v1.w*r*w1.w;
  if (MODE == 1) {
    float4* orow = (float4*)(outf + (size_t)t * DMODEL);
    orow[tid] = o0;
    orow[tid + 256] = o1;
  }
  ushort4* brow = (ushort4*)(outb + (size_t)t * DMODEL);
  brow[tid] = pack4(o0.x, o0.y, o0.z, o0.w);
  brow[tid + 256] = pack4(o1.x, o1.y, o1.z, o1.w);
}

// ---------------- fp32 -> bf16 bulk convert ----------------
__global__ __launch_bounds__(256) void f2b_kernel(const float* __restrict__ in,
                                                  unsigned short* __restrict__ out) {
  const size_t i = (size_t)blockIdx.x * 256 + threadIdx.x;
  const float4 a = ((const float4*)in)[2 * i];
  const float4 b = ((const float4*)in)[2 * i + 1];
  ((ushort4*)out)[2 * i] = pack4(a.x, a.y, a.z, a.w);
  ((ushort4*)out)[2 * i + 1] = pack4(b.x, b.y, b.z, b.w);
}

// ---------------- 4-phase slot-pipelined 256x256 bf16 MFMA GEMM (fat shapes): C = A @ B^T ---
// EPI: 0 = bf16 store (optional dual-write of z columns >= CQKV into Zb);
//      3 = paired silu(gate)*up combine (B is 16-col-interleaved Wg/Wu, N=16384).
template<int EPI>
__global__ __launch_bounds__(512, 2) void gemm8p_kernel(const unsigned short* __restrict__ A,
                                                        const unsigned short* __restrict__ B,
                                                        float* __restrict__ Cf,
                                                        unsigned short* __restrict__ Cb,
                                                        unsigned short* __restrict__ Zb,
                                                        int M, int N, int K) {
  __shared__ __align__(16) unsigned short lds[8][8192];   // 8 slots x 16 KB
  const int nbm = M >> 8, nbn = N >> 8, nwg = nbm * nbn;
  const int nt = K >> 6;   // K-tiles of 64
  int bmi, bni;
  {
    const int bid = blockIdx.x;
    const int cpx = nwg >> 3;
    int sc = 1;
    while (sc * sc < cpx) sc <<= 1;
    if (sc * sc > cpx) sc >>= 1;
    const int scn = (sc > 0) ? (cpx / sc) : 0;
    if ((nwg & 7) == 0 && sc > 0 && sc * scn == cpx && (nbm % sc) == 0 && (nbn % scn) == 0) {
      const int chunk = bid & 7, widx = bid >> 3;
      const int regc = nbn / scn;
      bmi = (chunk / regc) * sc + widx / scn;
      bni = (chunk % regc) * scn + widx % scn;
    } else {
      bmi = bid / nbn; bni = bid % nbn;
    }
  }
  const int bm = bmi << 8, bn = bni << 8;
  const int tid = threadIdx.x;
  const int wv = tid >> 6, ln = tid & 63;
  const int fr = ln & 15, qq = ln >> 4;
  const int wm = wv >> 2, wn = wv & 3;           // wave tile: rows wm*128, cols wn*64
  const int rsw = (fr >> 1) & 3;                 // read swizzle term
  const int s_sl = (ln & 3) ^ ((ln >> 3) & 3);   // staging source slot (inverse swizzle)

  f32x4 acc[8][4];
  const f32x4 zero = {0.f, 0.f, 0.f, 0.f};
#pragma unroll
  for (int mf = 0; mf < 8; mf++)
#pragma unroll
    for (int nf = 0; nf < 4; nf++) acc[mf][nf] = zero;

  bf16x8 afr[8], bfr[2];

  // stage one half: part 0=Ak0, 1=Ak1, 2=Bk0, 3=Bk1 of tile t2 -> slot ((t2&1)<<2)|part
  auto stage_half = [&](int t2, int part) {
    if (t2 >= nt) return;
    const unsigned short* Mat = (part >= 2) ? B : A;
    const int gb = (part >= 2) ? bn : bm;
    const int kk = part & 1;
    const int slot = ((t2 & 1) << 2) | part;
    const int k0 = t2 * 64 + kk * 32;
#pragma unroll
    for (int q = 0; q < 2; q++) {
      gl_lds16(Mat + (size_t)(gb + wv * 32 + q * 16 + (ln >> 2)) * K + k0 + s_sl * 8,
               &lds[slot][(wv * 32 + q * 16) * 32]);
    }
  };
  auto lda = [&](int tb, int kk) {
#pragma unroll
    for (int mf = 0; mf < 8; mf++) {
      const int ar = wm * 128 + mf * 16 + fr;
      afr[mf] = *(const bf16x8*)&lds[tb | kk][ar * 32 + ((qq ^ rsw) << 3)];
    }
  };
  auto ldb = [&](int tb, int kk, int nh) {
#pragma unroll
    for (int nj = 0; nj < 2; nj++) {
      const int br = wn * 64 + (nh * 2 + nj) * 16 + fr;
      bfr[nj] = *(const bf16x8*)&lds[tb | (2 + kk)][br * 32 + ((qq ^ rsw) << 3)];
    }
  };
  auto mm = [&](int nh) {
    __builtin_amdgcn_s_setprio(1);
#pragma unroll
    for (int mf = 0; mf < 8; mf++)
#pragma unroll
      for (int nj = 0; nj < 2; nj++)
        acc[mf][nh * 2 + nj] =
            __builtin_amdgcn_mfma_f32_16x16x32_bf16(afr[mf], bfr[nj], acc[mf][nh * 2 + nj], 0, 0, 0);
    __builtin_amdgcn_s_setprio(0);
  };

  // prologue: tile0 all 4 halves, tile1 k0 halves; wait tile0 (counted), publish
  stage_half(0, 0); stage_half(0, 2); stage_half(0, 1); stage_half(0, 3);
  stage_half(1, 0); stage_half(1, 2);
  asm volatile("s_waitcnt vmcnt(4)" ::: "memory");
  __builtin_amdgcn_s_barrier();
  asm volatile("" ::: "memory");

  for (int t = 0; t < nt; t++) {
    const int tb = (t & 1) << 2;
    // phase 0: (k0, N0); stage Ak1(t+1)
    lda(tb, 0); ldb(tb, 0, 0);
    stage_half(t + 1, 1);
    __builtin_amdgcn_s_barrier();
    mm(0);
    __builtin_amdgcn_s_barrier();
    // phase 1: (k0, N1); stage Bk1(t+1)
    ldb(tb, 0, 1);
    stage_half(t + 1, 3);
    __builtin_amdgcn_s_barrier();
    mm(1);
    __builtin_amdgcn_s_barrier();
    // phase 2: (k1, N1); stage Ak0(t+2)
    lda(tb, 1); ldb(tb, 1, 1);
    stage_half(t + 2, 0);
    __builtin_amdgcn_s_barrier();
    mm(1);
    __builtin_amdgcn_s_barrier();
    // phase 3: (k1, N0); stage Bk0(t+2)
    ldb(tb, 1, 0);
    stage_half(t + 2, 2);
    __builtin_amdgcn_s_barrier();
    mm(0);
    // tile boundary: counted vmcnt — next tile's 4 halves are older than newest in flight
    if (t + 1 < nt) {
      asm volatile("s_waitcnt lgkmcnt(0)" ::: "memory");
      __builtin_amdgcn_sched_barrier(0);
      if (t == nt - 2) {
        asm volatile("s_waitcnt vmcnt(0)" ::: "memory");
      } else {
        asm volatile("s_waitcnt vmcnt(4)" ::: "memory");
      }
      __builtin_amdgcn_sched_barrier(0);
      __builtin_amdgcn_s_barrier();
      __builtin_amdgcn_sched_barrier(0);
    }
  }

  const int cm4 = qq * 4;
  if (EPI == 3) {
    // paired combine: nf even = gate frag, nf odd = up frag at same output cols.
    const int bn2 = bn >> 1;
#pragma unroll
    for (int mf = 0; mf < 8; mf++) {
#pragma unroll
      for (int p = 0; p < 2; p++) {
#pragma unroll
        for (int r = 0; r < 4; r++) {
          const int grow = bm + wm * 128 + mf * 16 + cm4 + r;
          const int gcol = bn2 + wn * 32 + p * 16 + fr;
          Cb[(size_t)grow * 8192 + gcol] =
              f2bf(siluf(acc[mf][2 * p][r]) * acc[mf][2 * p + 1][r]);
        }
      }
    }
  } else {
    const bool isZ = (Zb != nullptr) && (bn >= CQKV);   // block-uniform
#pragma unroll
    for (int mf = 0; mf < 8; mf++) {
#pragma unroll
      for (int nf = 0; nf < 4; nf++) {
#pragma unroll
        for (int r = 0; r < 4; r++) {
          const int grow = bm + wm * 128 + mf * 16 + cm4 + r;
          const int gcol = bn + wn * 64 + nf * 16 + fr;
          const size_t off = (size_t)grow * N + gcol;
          const float v = acc[mf][nf][r];
          if (EPI == 0) {
            const unsigned short bv = f2bf(v);
            Cb[off] = bv;
            if (isZ) Zb[(size_t)grow * 2048 + (gcol - CQKV)] = bv;
          } else {
            Cf[off] += v;
          }
        }
      }
    }
  }
}

// ---------------- pipelined bf16 MFMA GEMM (thin shapes): C[M][N] = A[M][K] * B[N][K]^T -----
// BM x BN block (8 waves, 64x64 per-wave tile), BK=32, 3 LDS buffers, counted vmcnt.
template<int EPI, int BM, int BN>
__global__ __launch_bounds__(512, 4) void gemm256_kernel(const unsigned short* __restrict__ A,
                                                         const unsigned short* __restrict__ B,
                                                         float* __restrict__ Cf,
                                                         unsigned short* __restrict__ Cb,
                                                         int M, int N, int K) {
  constexpr int MI = 4;
  constexpr int NI = BN / 64;
  constexpr int AW = BM / 128;
  constexpr int BW = BN / 128;
  __shared__ __align__(16) unsigned short lds[3][(BM + BN) * 32];
  const int nbm = M / BM, nbn = N / BN, nwg = nbm * nbn;
  const int nt = K >> 5;
  int bmi, bni;
  {
    const int bid = blockIdx.x;
    const int cpx = nwg >> 3;
    int sc = 1;
    while (sc * sc < cpx) sc <<= 1;
    if (sc * sc > cpx) sc >>= 1;
    const int scn = (sc > 0) ? (cpx / sc) : 0;
    if ((nwg & 7) == 0 && sc > 0 && sc * scn == cpx && (nbm % sc) == 0 && (nbn % scn) == 0) {
      const int chunk = bid & 7, widx = bid >> 3;
      const int regc = nbn / scn;
      bmi = (chunk / regc) * sc + widx / scn;
      bni = (chunk % regc) * scn + widx % scn;
    } else {
      bmi = bid / nbn; bni = bid % nbn;
    }
  }
  const int bm = bmi * BM, bn = bni * BN;
  const int tid = threadIdx.x;
  const int wv = tid >> 6, ln = tid & 63;
  const int fr = ln & 15, qq = ln >> 4;
  const int wm = wv >> 2, wn = wv & 3;
  const int ra0 = wm * 64, rb0 = wn * (BN / 4);
  const int lrow = ln >> 2;
  const int lslot = ln & 3;

  f32x4 acc[MI][NI];
  const f32x4 zero = {0.f, 0.f, 0.f, 0.f};
#pragma unroll
  for (int mi = 0; mi < MI; mi++)
#pragma unroll
    for (int ni = 0; ni < NI; ni++) acc[mi][ni] = zero;

  auto stage = [&](int buf, int t) {
    const int k0 = t << 5;
#pragma unroll
    for (int q = 0; q < AW; q++) {
      const int lr = q * 128 + wv * 16 + lrow;
      const int sl = lslot ^ ((lr >> 1) & 3);
      gl_lds16(A + (size_t)(bm + lr) * K + k0 + sl * 8,
               &lds[buf][(q * 128 + wv * 16) * 32]);
    }
#pragma unroll
    for (int q = 0; q < BW; q++) {
      const int lr = q * 128 + wv * 16 + lrow;
      const int sl = lslot ^ ((lr >> 1) & 3);
      gl_lds16(B + (size_t)(bn + lr) * K + k0 + sl * 8,
               &lds[buf][BM * 32 + (q * 128 + wv * 16) * 32]);
    }
  };

  stage(0, 0);
  stage(1, 1);
  asm volatile("s_waitcnt vmcnt(%0)" :: "i"(AW + BW) : "memory");
  __builtin_amdgcn_s_barrier();
  asm volatile("" ::: "memory");

  for (int t = 0; t < nt; t++) {
    const int cb = t % 3;
    const int b2 = (t + 2) % 3;
    const unsigned short* lA = &lds[cb][0];
    const unsigned short* lB = &lds[cb][BM * 32];
    bf16x8 bfr[NI];
#pragma unroll
    for (int ni = 0; ni < NI; ni++) {
      const int r = rb0 + ni * 16 + fr;
      bfr[ni] = *(const bf16x8*)&lB[r * 32 + ((qq ^ ((r >> 1) & 3)) << 3)];
    }
    bf16x8 afr[MI];
#pragma unroll
    for (int mi = 0; mi < MI; mi++) {
      const int r = ra0 + mi * 16 + fr;
      afr[mi] = *(const bf16x8*)&lA[r * 32 + ((qq ^ ((r >> 1) & 3)) << 3)];
    }
    if (t + 2 < nt) stage(b2, t + 2);
    __builtin_amdgcn_s_setprio(1);
#pragma unroll
    for (int mi = 0; mi < MI; mi++)
#pragma unroll
      for (int ni = 0; ni < NI; ni++)
        acc[mi][ni] = __builtin_amdgcn_mfma_f32_16x16x32_bf16(afr[mi], bfr[ni], acc[mi][ni], 0, 0, 0);
    __builtin_amdgcn_s_setprio(0);
    if (t + 1 < nt) {
      asm volatile("s_waitcnt lgkmcnt(0)" ::: "memory");
      if (t + 2 < nt) {
        asm volatile("s_waitcnt vmcnt(%0)" :: "i"(AW + BW) : "memory");
      } else {
        asm volatile("s_waitcnt vmcnt(0)" ::: "memory");
      }
      __builtin_amdgcn_s_barrier();
      asm volatile("" ::: "memory");
    }
  }

  const int cm4 = qq * 4;
#pragma unroll
  for (int mi = 0; mi < MI; mi++) {
#pragma unroll
    for (int ni = 0; ni < NI; ni++) {
#pragma unroll
      for (int r = 0; r < 4; r++) {
        const int grow = bm + ra0 + mi * 16 + cm4 + r;
        const int gcol = bn + rb0 + ni * 16 + fr;
        const size_t off = (size_t)grow * N + gcol;
        const float v = acc[mi][ni][r];
        if (EPI == 0) {
          Cb[off] = f2bf(v);
        } else if (EPI == 1) {
          Cf[off] += v;
        } else {
          Cb[off] = f2bf(siluf(bf2f(Cb[off])) * v);
        }
      }
    }
  }
}

// ---------------- ba = h @ ba_w^T (h read as bf16) ----------------
__global__ __launch_bounds__(256) void ba_gemm_kernel(const unsigned short* __restrict__ h_in,
                                                      const float* __restrict__ ba_w,
                                                      float* __restrict__ ba_out) {
  __shared__ __align__(16) float hl[2048];
  __shared__ float red[32][9];
  const int t = blockIdx.x;
  const int tid = threadIdx.x;
  union { uint4 u; unsigned short s[8]; } wv_;
  wv_.u = *(const uint4*)(h_in + (size_t)t * DMODEL + tid * 8);
#pragma unroll
  for (int j = 0; j < 8; j++) hl[tid * 8 + j] = bf2f(wv_.s[j]);
  __syncthreads();
  const int c = tid & 31;
  const int p = tid >> 5;
  const float* wrow = ba_w + (size_t)c * DMODEL + p * 256;
  const float* hrow = hl + p * 256;
  float s = 0.f;
#pragma unroll 8
  for (int k = 0; k < 256; k++) s += hrow[k] * wrow[k];
  red[c][p] = s;
  __syncthreads();
  if (tid < 32) {
    float tot = 0.f;
#pragma unroll
    for (int q = 0; q < 8; q++) tot += red[tid][q];
    ba_out[(size_t)t * 32 + tid] = tot;
  }
}

// ---------------- fused causal depthwise conv (K=4) + SiLU + per-head l2norm; bf16 out ------
// one block per t-row; conv into LDS, then q/k heads l2norm (8 lanes/head) + v pack.
__global__ __launch_bounds__(256) void conv_norm_kernel(const unsigned short* __restrict__ qkvz,
                                                        const float* __restrict__ conv_w,
                                                        const float* __restrict__ mask,
                                                        unsigned short* __restrict__ mixed) {
  __shared__ float vals[6144];
  const int t = blockIdx.x;
  const int tid = threadIdx.x;
  float mj[4];
#pragma unroll
  for (int j = 0; j < 4; j++) {
    const int tt = t - 3 + j;
    mj[j] = (tt >= 0) ? mask[tt] : 0.f;
  }
#pragma unroll
  for (int p = 0; p < 6; p++) {
    const int c4 = (p * 256 + tid) * 4;
    const float4 w0 = *(const float4*)(conv_w + (size_t)c4 * 4);
    const float4 w1 = *(const float4*)(conv_w + (size_t)c4 * 4 + 4);
    const float4 w2 = *(const float4*)(conv_w + (size_t)c4 * 4 + 8);
    const float4 w3 = *(const float4*)(conv_w + (size_t)c4 * 4 + 12);
    const float wj0[4] = {w0.x, w0.y, w0.z, w0.w};
    const float wj1[4] = {w1.x, w1.y, w1.z, w1.w};
    const float wj2[4] = {w2.x, w2.y, w2.z, w2.w};
    const float wj3[4] = {w3.x, w3.y, w3.z, w3.w};
    float4 acc = make_float4(0.f, 0.f, 0.f, 0.f);
#pragma unroll
    for (int j = 0; j < 4; j++) {
      const int tt = t - 3 + j;
      if (tt < 0) continue;
      const ushort4 xb = *(const ushort4*)(qkvz + (size_t)tt * CQKVZ + c4);
      acc.x += bf2f(xb.x) * mj[j] * wj0[j];
      acc.y += bf2f(xb.y) * mj[j] * wj1[j];
      acc.z += bf2f(xb.z) * mj[j] * wj2[j];
      acc.w += bf2f(xb.w) * mj[j] * wj3[j];
    }
    vals[c4]     = siluf(acc.x);
    vals[c4 + 1] = siluf(acc.y);
    vals[c4 + 2] = siluf(acc.z);
    vals[c4 + 3] = siluf(acc.w);
  }
  __syncthreads();
  unsigned short* orow = mixed + (size_t)t * CQKV;
  // l2norm q/k: 32 heads x 128; 8 lanes per head, 16 elems per lane
  const int hh = tid >> 3;
  const int li = tid & 7;
  const int base = hh * 128 + li * 16;
  float loc[16];
  float s = 0.f;
#pragma unroll
  for (int j = 0; j < 16; j++) { loc[j] = vals[base + j]; s += loc[j] * loc[j]; }
#pragma unroll
  for (int msk = 1; msk < 8; msk <<= 1) s += __shfl_xor(s, msk);
  const float rn = rsqrtf(s + 1e-6f);
#pragma unroll
  for (int j8 = 0; j8 < 2; j8++) {
    *(ushort4*)(orow + base + j8 * 8) =
        pack4(loc[j8*8+0]*rn, loc[j8*8+1]*rn, loc[j8*8+2]*rn, loc[j8*8+3]*rn);
    *(ushort4*)(orow + base + j8 * 8 + 4) =
        pack4(loc[j8*8+4]*rn, loc[j8*8+5]*rn, loc[j8*8+6]*rn, loc[j8*8+7]*rn);
  }
  // v part: channels 4096..6143 pack straight out
  const int vc = 4096 + tid * 8;
  *(ushort4*)(orow + vc) = pack4(vals[vc], vals[vc+1], vals[vc+2], vals[vc+3]);
  *(ushort4*)(orow + vc + 4) = pack4(vals[vc+4], vals[vc+5], vals[vc+6], vals[vc+7]);
}

// ---------------- beta, g ----------------
__global__ __launch_bounds__(256) void beta_g_kernel(const float* __restrict__ ba,
                                                     const float* __restrict__ A_log,
                                                     const float* __restrict__ dt_bias,
                                                     const float* __restrict__ mask,
                                                     float* __restrict__ beta,
                                                     float* __restrict__ g) {
  const int idx = blockIdx.x * 256 + threadIdx.x;
  const int t = idx >> 4;
  const int h = idx & 15;
  const float b = ba[(size_t)t * 32 + h];
  const float a = ba[(size_t)t * 32 + 16 + h];
  const float m = mask[t];
  beta[idx] = m / (1.0f + expf(-b));
  const float xx = a + dt_bias[h];
  const float sp = (xx > 20.0f) ? xx : log1pf(expf(xx));
  g[idx] = -expf(A_log[h]) * sp * m;
}

// ---------------- per-chunk cumsum of g + decay factors ----------------
__global__ __launch_bounds__(256) void gcs_kernel(const float* __restrict__ g,
                                                  float* __restrict__ gcsbuf,
                                                  float* __restrict__ edkbuf,
                                                  float* __restrict__ egqbuf,
                                                  float* __restrict__ adecbuf) {
  const int idx = blockIdx.x * 256 + threadIdx.x;  // chunk id = h*64 + n
  if (idx >= 1024) return;
  const int h = idx >> 6;
  const int n = idx & 63;
  const int t0 = n * 64;
  float s = 0.f;
  for (int i = 0; i < 64; i++) {
    s += g[(size_t)(t0 + i) * NH + h];
    gcsbuf[(size_t)idx * 64 + i] = s;
  }
  const float glast = s;
  adecbuf[idx] = __expf(glast);
  for (int i = 0; i < 64; i++) {
    const float gi = gcsbuf[(size_t)idx * 64 + i];
    edkbuf[(size_t)idx * 64 + i] = __expf(glast - gi);
    egqbuf[(size_t)idx * 64 + i] = __expf(gi) * SCALE;
  }
}

// ---------------- per-chunk MFMA: A=(k_beta k^T)*decay (strict lower), attn=(q k^T)*decay*scale
// 4 waves; k,q copied (already bf16) into XOR-swizzled LDS; both products share k B-fragments.
__global__ __launch_bounds__(256) void pre_attn_kernel(const unsigned short* __restrict__ mixed,
                                                       const float* __restrict__ gcsbuf,
                                                       const float* __restrict__ betabuf,
                                                       float* __restrict__ abuf,
                                                       float* __restrict__ attnbuf) {
  __shared__ __align__(16) unsigned short kbl[64 * 128];
  __shared__ __align__(16) unsigned short qbl[64 * 128];
  __shared__ float gcs_s[64];
  __shared__ float betal[64];
  const int blk = blockIdx.x;
  const int h = blk >> 6;
  const int n = blk & 63;
  const int t0 = n * 64;
  const int tid = threadIdx.x;
  if (tid < 64) {
    gcs_s[tid] = gcsbuf[(size_t)blk * 64 + tid];
    betal[tid] = betabuf[(size_t)(t0 + tid) * NH + h];
  }
#pragma unroll
  for (int p = 0; p < 4; p++) {
    const int idx = tid + p * 256;          // 0..1023
    const int i = idx >> 4, dg = idx & 15;  // row, 16B granule
    *(uint4*)&kbl[i * 128 + ((dg ^ (i & 7)) << 3)] =
        *(const uint4*)(mixed + (size_t)(t0 + i) * CQKV + 2048 + h * 128 + dg * 8);
    *(uint4*)&qbl[i * 128 + ((dg ^ (i & 7)) << 3)] =
        *(const uint4*)(mixed + (size_t)(t0 + i) * CQKV + h * 128 + dg * 8);
  }
  __syncthreads();
  const int ln = tid & 63;
  const int wv = tid >> 6;      // 0..3
  const int fr = ln & 15;
  const int g = ln >> 4;        // 0..3
  const int i0 = wv * 16;
  f32x4 accA[4], accQ[4];
  const f32x4 zero = {0.f, 0.f, 0.f, 0.f};
#pragma unroll
  for (int jt = 0; jt < 4; jt++) { accA[jt] = zero; accQ[jt] = zero; }
#pragma unroll
  for (int ks = 0; ks < 4; ks++) {
    const int kb = ks * 4 + g;
    const int ar = i0 + fr;
    const bf16x8 aK = *(const bf16x8*)&kbl[ar * 128 + ((kb ^ (ar & 7)) << 3)];
    const bf16x8 aQ = *(const bf16x8*)&qbl[ar * 128 + ((kb ^ (ar & 7)) << 3)];
#pragma unroll
    for (int jt = 0; jt < 4; jt++) {
      const int br = jt * 16 + fr;
      const bf16x8 b = *(const bf16x8*)&kbl[br * 128 + ((kb ^ (br & 7)) << 3)];
      accA[jt] = __builtin_amdgcn_mfma_f32_16x16x32_bf16(aK, b, accA[jt], 0, 0, 0);
      accQ[jt] = __builtin_amdgcn_mfma_f32_16x16x32_bf16(aQ, b, accQ[jt], 0, 0, 0);
    }
  }
  // epilogue: i = i0 + g*4 + r ; j = jt*16 + fr
#pragma unroll
  for (int jt = 0; jt < 4; jt++) {
    const int j = jt * 16 + fr;
    const float gj = gcs_s[j];
#pragma unroll
    for (int r = 0; r < 4; r++) {
      const int i = i0 + g * 4 + r;
      const float gi = gcs_s[i];
      const float dec = __expf(fminf(gi - gj, 0.f));
      abuf[(size_t)blk * 4096 + i * 64 + j] = (i > j) ? accA[jt][r] * betal[i] * dec : 0.f;
      attnbuf[(size_t)blk * 4096 + i * 64 + j] = (i >= j) ? accQ[jt][r] * dec * SCALE : 0.f;
    }
  }
}

// ---------------- per-chunk: T = (I+A)^-1, then T *= beta[col] ----------------
__global__ __launch_bounds__(256) void pre_solve_kernel(const float* __restrict__ abuf,
                                                        const float* __restrict__ betabuf,
                                                        float* __restrict__ tbuf) {
  __shared__ float Al[64][65];
  __shared__ float Tl[64][65];
  const int blk = blockIdx.x;
  const int h = blk >> 6;
  const int n = blk & 63;
  const int t0 = n * 64;
  const int tid = threadIdx.x;
#pragma unroll
  for (int rep = 0; rep < 4; rep++) {
    const int lin = rep * 256 + tid;
    const int i = lin >> 4;
    const int j = (lin & 15) * 4;
    const float4 av = *(const float4*)(abuf + (size_t)blk * 4096 + i * 64 + j);
    Al[i][j] = av.x; Al[i][j + 1] = av.y; Al[i][j + 2] = av.z; Al[i][j + 3] = av.w;
  }
  __syncthreads();
  if (tid < 64) {
    const int j = tid;
    const float bj = betabuf[(size_t)(t0 + j) * NH + h];
    for (int i = 0; i < 64; i++) {
      float s = (i == j) ? 1.0f : 0.0f;
      for (int l = j; l < i; l++) s -= Al[i][l] * Tl[l][j];
      Tl[i][j] = s;
    }
    for (int i = j; i < 64; i++) Tl[i][j] *= bj;
  }
  __syncthreads();
#pragma unroll
  for (int rep = 0; rep < 4; rep++) {
    const int lin = rep * 256 + tid;
    const int i = lin >> 4;
    const int j = (lin & 15) * 4;
    float4 tv;
    tv.x = Tl[i][j]; tv.y = Tl[i][j + 1]; tv.z = Tl[i][j + 2]; tv.w = Tl[i][j + 3];
    *(float4*)(tbuf + (size_t)blk * 4096 + i * 64 + j) = tv;
  }
}

// ---------------- per-chunk: u = Tb @ v (bf16, l4-packed [blk][l>>2][c][l&3]) ;
//                  w = Tb @ (k * e^gcs), stored NEGATED + slot-swizzled ----
__global__ __launch_bounds__(256) void pre_uw_kernel(const unsigned short* __restrict__ mixed,
                                                     const float* __restrict__ tbuf,
                                                     const float* __restrict__ gcsbuf,
                                                     unsigned short* __restrict__ ubf,
                                                     unsigned short* __restrict__ wbf) {
  __shared__ __align__(16) float Tl[64][68];
  __shared__ __align__(16) float xl[64][132];
  __shared__ float egcs[64];
  const int blk = blockIdx.x;
  const int h = blk >> 6;
  const int n = blk & 63;
  const int t0 = n * 64;
  const int tid = threadIdx.x;
  if (tid < 64) egcs[tid] = __expf(gcsbuf[(size_t)blk * 64 + tid]);
#pragma unroll
  for (int rep = 0; rep < 4; rep++) {
    const int lin = rep * 256 + tid;
    const int i = lin >> 4;
    const int j = (lin & 15) * 4;
    const float4 tv = *(const float4*)(tbuf + (size_t)blk * 4096 + i * 64 + j);
    *(float4*)&Tl[i][j] = tv;
  }
#pragma unroll
  for (int rep = 0; rep < 4; rep++) {
    const int lin = rep * 256 + tid;
    const int i = lin >> 4;
    const int d8 = (lin & 15) * 8;
    union { uint4 u; unsigned short s[8]; } w;
    w.u = *(const uint4*)(mixed + (size_t)(t0 + i) * CQKV + 4096 + h * 128 + d8);
#pragma unroll
    for (int j = 0; j < 8; j++) xl[i][d8 + j] = bf2f(w.s[j]);
  }
  __syncthreads();
  const int cgu = tid & 15;
  const int riu = tid >> 4;
  const int i0 = riu * 4;
  const int d0 = cgu * 8;
  float acc[4][8];
#pragma unroll
  for (int a = 0; a < 4; a++)
#pragma unroll
    for (int b = 0; b < 8; b++) acc[a][b] = 0.f;
#pragma unroll 2
  for (int j = 0; j < 64; j++) {
    const float tv[4] = {Tl[i0][j], Tl[i0 + 1][j], Tl[i0 + 2][j], Tl[i0 + 3][j]};
    const float4 x0 = *(const float4*)&xl[j][d0];
    const float4 x1 = *(const float4*)&xl[j][d0 + 4];
    const float xv[8] = {x0.x, x0.y, x0.z, x0.w, x1.x, x1.y, x1.z, x1.w};
#pragma unroll
    for (int a = 0; a < 4; a++)
#pragma unroll
      for (int b = 0; b < 8; b++) acc[a][b] += tv[a] * xv[b];
  }
  // u store: bf16 l4-packed layout elem = blk*8192 + riu*512 + (d0+b)*4 + (l&3)
#pragma unroll
  for (int b = 0; b < 8; b++) {
    *(ushort4*)(ubf + (size_t)blk * 8192 + riu * 512 + (size_t)(d0 + b) * 4) =
        pack4(acc[0][b], acc[1][b], acc[2][b], acc[3][b]);
  }
  __syncthreads();
#pragma unroll
  for (int rep = 0; rep < 4; rep++) {
    const int lin = rep * 256 + tid;
    const int i = lin >> 4;
    const int d8 = (lin & 15) * 8;
    union { uint4 u; unsigned short s[8]; } w;
    w.u = *(const uint4*)(mixed + (size_t)(t0 + i) * CQKV + 2048 + h * 128 + d8);
    const float e = egcs[i];
#pragma unroll
    for (int j = 0; j < 8; j++) xl[i][d8 + j] = bf2f(w.s[j]) * e;
  }
  __syncthreads();
#pragma unroll
  for (int a = 0; a < 4; a++)
#pragma unroll
    for (int b = 0; b < 8; b++) acc[a][b] = 0.f;
#pragma unroll 2
  for (int j = 0; j < 64; j++) {
    const float tv[4] = {Tl[i0][j], Tl[i0 + 1][j], Tl[i0 + 2][j], Tl[i0 + 3][j]};
    const float4 x0 = *(const float4*)&xl[j][d0];
    const float4 x1 = *(const float4*)&xl[j][d0 + 4];
    const float xv[8] = {x0.x, x0.y, x0.z, x0.w, x1.x, x1.y, x1.z, x1.w};
#pragma unroll
    for (int a = 0; a < 4; a++)
#pragma unroll
      for (int b = 0; b < 8; b++) acc[a][b] += tv[a] * xv[b];
  }
  // store -w, column-slot swizzled by (row&7) so scan can global_load_lds linearly
#pragma unroll
  for (int a = 0; a < 4; a++) {
    const int l = i0 + a;
    unsigned short* wp = wbf + (size_t)(t0 + l) * 2048 + h * 128 + ((cgu ^ (l & 7)) << 3);
    *(ushort4*)wp = pack4(-acc[a][0], -acc[a][1], -acc[a][2], -acc[a][3]);
    *(ushort4*)(wp + 4) = pack4(-acc[a][4], -acc[a][5], -acc[a][6], -acc[a][7]);
  }
}

// ---------------- per-chunk: kdT[blk][d][l] = bf16(k*edk) slot-swizzled; qe = bf16(q*egq) ----------------
__global__ __launch_bounds__(256) void ktrans_kernel(const unsigned short* __restrict__ mixed,
                                                     const float* __restrict__ edkbuf,
                                                     const float* __restrict__ egqbuf,
                                                     unsigned short* __restrict__ kdT,
                                                     unsigned short* __restrict__ qe) {
  __shared__ __align__(16) float kl[64][132];
  __shared__ float edk_s[64];
  __shared__ float egq_s[64];
  const int blk = blockIdx.x;
  const int h = blk >> 6;
  const int n = blk & 63;
  const int t0 = n * 64;
  const int tid = threadIdx.x;
  if (tid < 64) {
    edk_s[tid] = edkbuf[(size_t)blk * 64 + tid];
    egq_s[tid] = egqbuf[(size_t)blk * 64 + tid];
  }
#pragma unroll
  for (int q = 0; q < 4; q++) {
    const int idx = tid + q * 256;
    const int l = idx >> 4, d8 = (idx & 15) * 8;
    union { uint4 u; unsigned short s[8]; } w;
    w.u = *(const uint4*)(mixed + (size_t)(t0 + l) * CQKV + 2048 + h * 128 + d8);
#pragma unroll
    for (int j = 0; j < 8; j++) kl[l][d8 + j] = bf2f(w.s[j]);
  }
  __syncthreads();
#pragma unroll
  for (int q = 0; q < 4; q++) {
    const int idx = tid + q * 256;
    const int d = idx >> 3, lsl = idx & 7;
    const int l8 = lsl * 8;
    float v[8];
#pragma unroll
    for (int j = 0; j < 8; j++) v[j] = kl[l8 + j][d] * edk_s[l8 + j];
    unsigned short* p = kdT + (size_t)blk * 8192 + d * 64 + ((lsl ^ (d & 7)) << 3);
    *(ushort4*)p = pack4(v[0], v[1], v[2], v[3]);
    *(ushort4*)(p + 4) = pack4(v[4], v[5], v[6], v[7]);
  }
#pragma unroll
  for (int q = 0; q < 4; q++) {
    const int idx = tid + q * 256;
    const int i = idx >> 4, c8 = (idx & 15) * 8;
    union { uint4 u; unsigned short s[8]; } w;
    w.u = *(const uint4*)(mixed + (size_t)(t0 + i) * CQKV + h * 128 + c8);
    const float e = egq_s[i];
    unsigned short* qp = qe + (size_t)(t0 + i) * 2048 + h * 128 + c8;
    *(ushort4*)qp = pack4(bf2f(w.s[0]) * e, bf2f(w.s[1]) * e, bf2f(w.s[2]) * e, bf2f(w.s[3]) * e);
    *(ushort4*)(qp + 4) = pack4(bf2f(w.s[4]) * e, bf2f(w.s[5]) * e, bf2f(w.s[6]) * e, bf2f(w.s[7]) * e);
  }
}

// ---------------- MFMA scan, column-decomposed: 8 waves x 16 c-columns, NO cross-wave data ---
// u read bf16 l4-packed (4x ushort4 per chunk). Exports d4/l4-packed (coalesced).
// blocks 0..15: per-head scan; ONE barrier/chunk (counted vmcnt(17)).
// blocks >=16: weight f2b (Wgu interleaved / Wd / Wo) + residual copy (512 threads).
__global__ __launch_bounds__(512, 1) void scan_kernel(const unsigned short* __restrict__ wbf,
                                                      const unsigned short* __restrict__ kdT,
                                                      const unsigned short* __restrict__ ubf,
                                                      const float* __restrict__ adecbuf,
                                                      unsigned short* __restrict__ STb,
                                                      unsigned short* __restrict__ vtb,
                                                      const float* __restrict__ gw,
                                                      const float* __restrict__ uw,
                                                      const float* __restrict__ dw,
                                                      const float* __restrict__ ow,
                                                      const float* __restrict__ xin,
                                                      unsigned short* __restrict__ Wgu,
                                                      unsigned short* __restrict__ Wd,
                                                      unsigned short* __restrict__ Wo,
                                                      float* __restrict__ outc) {
  __shared__ __align__(16) unsigned short stage[2][16384];  // [w 8192 | kT 8192] shorts each
  __shared__ __align__(16) unsigned short privAll[8][3072]; // per wave: A 16x128 | B 16x64
  if (blockIdx.x >= 16) {
    // side work (512 thr): Wg 4096 + Wu 4096 + Wd 4096 + Wo 1024 + copy 2048 = 15360 blocks
    const int xb = blockIdx.x - 16;
    const int tid = threadIdx.x;
    if (xb < 8192) {
      // gate/up f2b with 16-row interleave into Wgu:
      // src row r -> dst row (r>>4)*32 + (r&15) (+16 for up)
      const bool isUp = (xb >= 4096);
      const float* src = isUp ? uw : gw;
      const size_t e = ((size_t)(isUp ? xb - 4096 : xb) * 512 + tid) * 8;
      const int r = (int)(e >> 11);
      const int col = (int)(e & 2047);
      const int drow = (r >> 4) * 32 + (r & 15) + (isUp ? 16 : 0);
      const float4 a = *(const float4*)(src + e);
      const float4 b = *(const float4*)(src + e + 4);
      unsigned short* dst = Wgu + (size_t)drow * 2048 + col;
      *(ushort4*)dst = pack4(a.x, a.y, a.z, a.w);
      *(ushort4*)(dst + 4) = pack4(b.x, b.y, b.z, b.w);
    } else if (xb < 13312) {
      const float* src; unsigned short* dst; size_t u;
      if (xb < 12288) { src = dw; dst = Wd; u = (size_t)(xb - 8192) * 512 + tid; }
      else            { src = ow; dst = Wo; u = (size_t)(xb - 12288) * 512 + tid; }
      const float4 a = ((const float4*)src)[2 * u];
      const float4 b = ((const float4*)src)[2 * u + 1];
      ((ushort4*)dst)[2 * u] = pack4(a.x, a.y, a.z, a.w);
      ((ushort4*)dst)[2 * u + 1] = pack4(b.x, b.y, b.z, b.w);
    } else {
      const size_t i = (size_t)(xb - 13312) * 512 + tid;
      ((float4*)outc)[2 * i] = ((const float4*)xin)[2 * i];
      ((float4*)outc)[2 * i + 1] = ((const float4*)xin)[2 * i + 1];
    }
    return;
  }
  const int h = blockIdx.x;
  const int tid = threadIdx.x;
  const int ln = tid & 63;
  const int wv = tid >> 6;        // 0..7
  const int fr = ln & 15;
  const int g  = ln >> 4;         // 0..3
  const int c0 = wv * 16;
  const int fsw = fr & 7;
  unsigned short* privA = &privAll[wv][0];     // [16 c][128 d], slot-swizzled
  unsigned short* privB = &privAll[wv][2048];  // [16 c][64 l], slot-swizzled
  const f32x4 zero = {0.f, 0.f, 0.f, 0.f};

  f32x4 acc2[8];                  // S^T state for this wave's 16 columns, d-tile dt
#pragma unroll
  for (int dt = 0; dt < 8; dt++) acc2[dt] = zero;

  auto stage_wk = [&](int buf, int n1) {
    const int t0n = n1 * 64;
    const size_t kbase = (size_t)(h * 64 + n1) * 8192;
#pragma unroll
    for (int q = 0; q < 2; q++) {
      const int m = wv * 2 + q;   // 0..15
      gl_lds16(wbf + (size_t)(t0n + m * 4 + (ln >> 4)) * 2048 + h * 128 + (ln & 15) * 8,
               &stage[buf][m * 512]);
      gl_lds16(kdT + kbase + (m * 8 + (ln >> 3)) * 64 + (ln & 7) * 8,
               &stage[buf][8192 + m * 512]);
    }
  };

  // prologue: u/adec for chunk 0 + stage chunk 0
  ushort4 ur4[4];
#pragma unroll
  for (int lt = 0; lt < 4; lt++)
    ur4[lt] = *(const ushort4*)(ubf + (size_t)(h * 64) * 8192 + (lt * 4 + g) * 512 + (c0 + fr) * 4);
  float ad = adecbuf[h * 64];
  stage_wk(0, 0);
  asm volatile("s_waitcnt vmcnt(0)" ::: "memory");
  __builtin_amdgcn_s_barrier();
  asm volatile("" ::: "memory");

  for (int n = 0; n < 64; n++) {
    const int blk = h * 64 + n;
    const unsigned short* wl = &stage[n & 1][0];
    const unsigned short* kl = &stage[n & 1][8192];
    // (1) issue staging for n+1 first (oldest VMEM ops of this chunk)
    if (n + 1 < 64) stage_wk((n + 1) & 1, n + 1);
    __builtin_amdgcn_sched_barrier(0);
    // (2) prefetch u/adec for n+1 (4 ushort4 + 1 scalar; younger than staging)
    ushort4 ur4n[4];
    float adn = 0.f;
    if (n + 1 < 64) {
      const size_t ub = (size_t)(blk + 1) * 8192;
#pragma unroll
      for (int lt = 0; lt < 4; lt++)
        ur4n[lt] = *(const ushort4*)(ubf + ub + (lt * 4 + g) * 512 + (c0 + fr) * 4);
      adn = adecbuf[blk + 1];
    } else {
#pragma unroll
      for (int lt = 0; lt < 4; lt++) { ur4n[lt].x = 0; ur4n[lt].y = 0; ur4n[lt].z = 0; ur4n[lt].w = 0; }
    }
    __builtin_amdgcn_sched_barrier(0);
    // (3) dump S_n^T -> privA (wave-private) ; export S_n coalesced (d4-packed)
#pragma unroll
    for (int dt = 0; dt < 8; dt++) {
      const int slot = dt * 2 + (g >> 1);
      const ushort4 pv = pack4(acc2[dt][0], acc2[dt][1], acc2[dt][2], acc2[dt][3]);
      *(ushort4*)&privA[fr * 128 + ((slot ^ fsw) << 3) + (g & 1) * 4] = pv;
      *(ushort4*)(STb + (size_t)blk * 16384 + (dt * 4 + g) * 512 + (c0 + fr) * 4) = pv;
    }
    // (4) MFMA1: v_new = u + (-w) @ S  (A from shared staged w, B from privA)
    f32x4 acc1[4];
#pragma unroll
    for (int lt = 0; lt < 4; lt++) {
      f32x4 t;
      t[0] = bf2f(ur4[lt].x); t[1] = bf2f(ur4[lt].y);
      t[2] = bf2f(ur4[lt].z); t[3] = bf2f(ur4[lt].w);
      acc1[lt] = t;
    }
#pragma unroll
    for (int ks = 0; ks < 4; ks++) {
      const int kb = ks * 4 + g;
      const bf16x8 b = *(const bf16x8*)&privA[fr * 128 + ((kb ^ fsw) << 3)];
#pragma unroll
      for (int lt = 0; lt < 4; lt++) {
        const bf16x8 a = *(const bf16x8*)&wl[(lt * 16 + fr) * 128 + ((kb ^ fsw) << 3)];
        acc1[lt] = __builtin_amdgcn_mfma_f32_16x16x32_bf16(a, b, acc1[lt], 0, 0, 0);
      }
    }
    // (5) v_new^T -> privB ; export v_new^T coalesced (l4-packed)
#pragma unroll
    for (int lt = 0; lt < 4; lt++) {
      const int slot = lt * 2 + (g >> 1);
      const ushort4 pv = pack4(acc1[lt][0], acc1[lt][1], acc1[lt][2], acc1[lt][3]);
      *(ushort4*)&privB[fr * 64 + ((slot ^ fsw) << 3) + (g & 1) * 4] = pv;
      *(ushort4*)(vtb + (size_t)blk * 8192 + (lt * 4 + g) * 512 + (c0 + fr) * 4) = pv;
    }
    // (6) MFMA2: S = adec*S + kdec^T @ v_new
#pragma unroll
    for (int dt = 0; dt < 8; dt++) {
      acc2[dt][0] *= ad; acc2[dt][1] *= ad; acc2[dt][2] *= ad; acc2[dt][3] *= ad;
    }
#pragma unroll
    for (int ks = 0; ks < 2; ks++) {
      const int kb = ks * 4 + g;
      const bf16x8 b = *(const bf16x8*)&privB[fr * 64 + ((kb ^ fsw) << 3)];
#pragma unroll
      for (int dt = 0; dt < 8; dt++) {
        const bf16x8 a = *(const bf16x8*)&kl[(dt * 16 + fr) * 64 + ((kb ^ fsw) << 3)];
        acc2[dt] = __builtin_amdgcn_mfma_f32_16x16x32_bf16(a, b, acc2[dt], 0, 0, 0);
      }
    }
    // (7) roll prefetched operands
#pragma unroll
    for (int lt = 0; lt < 4; lt++) ur4[lt] = ur4n[lt];
    ad = adn;
    // (8) publish staging: counted vmcnt (youngest 17 = 4 u + 1 adec + 12 export stores)
    if (n + 1 < 64) {
      asm volatile("s_waitcnt lgkmcnt(0)" ::: "memory");
      __builtin_amdgcn_sched_barrier(0);
      asm volatile("s_waitcnt vmcnt(17)" ::: "memory");
      __builtin_amdgcn_sched_barrier(0);
      __builtin_amdgcn_s_barrier();
      __builtin_amdgcn_sched_barrier(0);
    }
  }
}

// ---------------- MFMA o-compute + fused gated RMSNorm (reads d4/l4-packed ST/vt) ----------------
__global__ __launch_bounds__(256) void ocomp_kernel(const unsigned short* __restrict__ qe,
                                                    const unsigned short* __restrict__ STbuf,
                                                    const unsigned short* __restrict__ vtbuf,
                                                    const float* __restrict__ attnbuf,
                                                    const unsigned short* __restrict__ zb,
                                                    const float* __restrict__ onw,
                                                    unsigned short* __restrict__ ob) {
  __shared__ __align__(16) unsigned short STl[128 * 128];  // [c][d]
  __shared__ __align__(16) unsigned short vtl[128 * 64];   // [c][l]
  __shared__ __align__(16) unsigned short ql[64 * 128];    // [i][d]
  __shared__ __align__(16) unsigned short al[64 * 64];     // [i][l]
  const int blk = blockIdx.x;
  const int h = blk >> 6;
  const int n = blk & 63;
  const int t0 = n * 64;
  const int tid = threadIdx.x;
  // ST: d4-packed -> [c][d] swizzled LDS. uint4 o covers (dq = o>>6, cols 2w,2w+1, w = o&63)
#pragma unroll
  for (int q = 0; q < 8; q++) {
    const int o = tid + q * 256;
    const int dq = o >> 6, w = o & 63;
    const uint4 v = *(const uint4*)(STbuf + (size_t)blk * 16384 + (size_t)o * 8);
    const int cA = 2 * w, cB = 2 * w + 1;
    uint2 h0; h0.x = v.x; h0.y = v.y;
    uint2 h1; h1.x = v.z; h1.y = v.w;
    *(uint2*)&STl[cA * 128 + (((dq >> 1) ^ (cA & 7)) << 3) + (dq & 1) * 4] = h0;
    *(uint2*)&STl[cB * 128 + (((dq >> 1) ^ (cB & 7)) << 3) + (dq & 1) * 4] = h1;
  }
  // vt: l4-packed -> [c][l] swizzled LDS
#pragma unroll
  for (int q = 0; q < 4; q++) {
    const int o = tid + q * 256;
    const int lq = o >> 6, w = o & 63;
    const uint4 v = *(const uint4*)(vtbuf + (size_t)blk * 8192 + (size_t)o * 8);
    const int cA = 2 * w, cB = 2 * w + 1;
    uint2 h0; h0.x = v.x; h0.y = v.y;
    uint2 h1; h1.x = v.z; h1.y = v.w;
    *(uint2*)&vtl[cA * 64 + (((lq >> 1) ^ (cA & 7)) << 3) + (lq & 1) * 4] = h0;
    *(uint2*)&vtl[cB * 64 + (((lq >> 1) ^ (cB & 7)) << 3) + (lq & 1) * 4] = h1;
  }
#pragma unroll
  for (int q = 0; q < 4; q++) {
    const int idx = tid + q * 256;
    const int i = idx >> 4, dg = idx & 15;
    *(uint4*)&ql[i * 128 + ((dg ^ (i & 7)) << 3)] =
        *(const uint4*)(qe + (size_t)(t0 + i) * 2048 + h * 128 + dg * 8);
  }
#pragma unroll
  for (int q = 0; q < 4; q++) {
    const int idx = tid + q * 256;
    const int i = idx >> 4, l4 = (idx & 15) * 4;
    const float4 v = *(const float4*)(attnbuf + (size_t)blk * 4096 + i * 64 + l4);
    *(ushort4*)&al[i * 64 + (((l4 >> 3) ^ (i & 7)) << 3) + (l4 & 7)] =
        pack4(v.x, v.y, v.z, v.w);
  }
  __syncthreads();
  const int ln = tid & 63;
  const int wv = tid >> 6;
  const int fr = ln & 15;
  const int g = ln >> 4;
  const int i0 = wv * 16;
  f32x4 acc[8];
  const f32x4 zero = {0.f, 0.f, 0.f, 0.f};
#pragma unroll
  for (int nt = 0; nt < 8; nt++) acc[nt] = zero;
#pragma unroll
  for (int ks = 0; ks < 4; ks++) {
    const int kb = ks * 4 + g;
    const int ar = i0 + fr;
    const bf16x8 a = *(const bf16x8*)&ql[ar * 128 + ((kb ^ (ar & 7)) << 3)];
#pragma unroll
    for (int nt = 0; nt < 8; nt++) {
      const int c = nt * 16 + fr;
      const bf16x8 b = *(const bf16x8*)&STl[c * 128 + ((kb ^ (c & 7)) << 3)];
      acc[nt] = __builtin_amdgcn_mfma_f32_16x16x32_bf16(a, b, acc[nt], 0, 0, 0);
    }
  }
#pragma unroll
  for (int ks = 0; ks < 2; ks++) {
    const int kb = ks * 4 + g;
    const int ar = i0 + fr;
    const bf16x8 a = *(const bf16x8*)&al[ar * 64 + ((kb ^ (ar & 7)) << 3)];
#pragma unroll
    for (int nt = 0; nt < 8; nt++) {
      const int c = nt * 16 + fr;
      const bf16x8 b = *(const bf16x8*)&vtl[c * 64 + ((kb ^ (c & 7)) << 3)];
      acc[nt] = __builtin_amdgcn_mfma_f32_16x16x32_bf16(a, b, acc[nt], 0, 0, 0);
    }
  }
  float s0 = 0.f, s1 = 0.f, s2 = 0.f, s3 = 0.f;
#pragma unroll
  for (int nt = 0; nt < 8; nt++) {
    s0 += acc[nt][0] * acc[nt][0];
    s1 += acc[nt][1] * acc[nt][1];
    s2 += acc[nt][2] * acc[nt][2];
    s3 += acc[nt][3] * acc[nt][3];
  }
#pragma unroll
  for (int m = 1; m < 16; m <<= 1) {
    s0 += __shfl_xor(s0, m);
    s1 += __shfl_xor(s1, m);
    s2 += __shfl_xor(s2, m);
    s3 += __shfl_xor(s3, m);
  }
  float rn[4];
  rn[0] = rsqrtf(s0 * (1.0f / 128.0f) + 1e-5f);
  rn[1] = rsqrtf(s1 * (1.0f / 128.0f) + 1e-5f);
  rn[2] = rsqrtf(s2 * (1.0f / 128.0f) + 1e-5f);
  rn[3] = rsqrtf(s3 * (1.0f / 128.0f) + 1e-5f);
#pragma unroll
  for (int nt = 0; nt < 8; nt++) {
    const int c = nt * 16 + fr;
    const float wn = onw[c];
#pragma unroll
    for (int r = 0; r < 4; r++) {
      const size_t off = (size_t)(t0 + i0 + g * 4 + r) * 2048 + h * 128 + c;
      const float zz = siluf(bf2f(zb[off]));
      ob[off] = f2bf(acc[nt][r] * rn[r] * wn * zz);
    }
  }
}

extern "C" void kernel_launch(void* const* d_in, const int* in_sizes, int n_in,
                              void* d_out, int out_size, void* d_ws, size_t ws_size,
                              hipStream_t stream) {
  (void)in_sizes; (void)n_in; (void)out_size;
  const float* x        = (const float*)d_in[0];
  const float* mask     = (const float*)d_in[1];
  const float* ln1_w    = (const float*)d_in[2];
  const float* qkvz_w   = (const float*)d_in[3];
  const float* ba_w     = (const float*)d_in[4];
  const float* conv_w   = (const float*)d_in[5];
  const float* A_log    = (const float*)d_in[6];
  const float* dt_bias  = (const float*)d_in[7];
  const float* o_norm_w = (const float*)d_in[8];
  const float* out_w    = (const float*)d_in[9];
  const float* ln2_w    = (const float*)d_in[10];
  const float* gate_w   = (const float*)d_in[11];
  const float* up_w     = (const float*)d_in[12];
  const float* down_w   = (const float*)d_in[13];
  float* out = (float*)d_out;

  const size_t NEED_BYTES = (size_t)75825152 * 4;
  if (ws_size < NEED_BYTES) return;

  float* ws = (float*)d_ws;
  unsigned short* mixed_bf = (unsigned short*)ws;            // 4096 x 6144 bf16 (50 MB)
  unsigned short* Wgu = (unsigned short*)ws;                 // [16384][2048] bf16, 16-col interleaved
  unsigned short* Wd = (unsigned short*)(ws + 16777216);
  unsigned short* qkvz_bf = (unsigned short*)(ws + 25165824);
  unsigned short* u_bf = (unsigned short*)(ws + 25165824);   // 1024 x 8192 bf16 (16 MB)
  unsigned short* wbf = (unsigned short*)(ws + 33554432);
  unsigned short* kdT = (unsigned short*)(ws + 37748736);
  unsigned short* comb_bf = (unsigned short*)(ws + 25165824);
  unsigned short* z_bf = (unsigned short*)(ws + 41943040);
  float* a_buf = ws + 46137344;
  unsigned short* vt_buf = (unsigned short*)(ws + 46137344);
  float* t_buf = ws + 50331648;
  unsigned short* qe_bf = (unsigned short*)(ws + 50331648);  // after pre_uw, t_buf is dead
  unsigned short* h_bf  = (unsigned short*)(ws + 54525952);
  unsigned short* ob    = (unsigned short*)(ws + 54525952);
  unsigned short* h2_bf = (unsigned short*)(ws + 54525952);
  float* attn_buf = ws + 58720256;
  unsigned short* Wq = (unsigned short*)(ws + 62914560);
  unsigned short* ST_buf = (unsigned short*)(ws + 62914560);
  unsigned short* Wo = (unsigned short*)(ws + 71303168);
  float* ba_buf   = ws + 73400320;
  float* beta_buf = ws + 73531392;
  float* g_buf    = ws + 73596928;
  float* gcs_buf  = ws + 73662464;
  float* edk_buf  = ws + 73728000;
  float* egq_buf  = ws + 73793536;
  float* adec_buf = ws + 73859072;

  rmsnorm_kernel<2><<<4096, 256, 0, stream>>>(x, ln1_w, nullptr, h_bf);
  f2b_kernel<<<8192, 256, 0, stream>>>(qkvz_w, Wq);
  // qkvz GEMM; z columns (>= 6144) dual-written straight into z_bf
  gemm8p_kernel<0><<<512, 512, 0, stream>>>(h_bf, Wq, nullptr, qkvz_bf, z_bf, 4096, 8192, 2048);
  ba_gemm_kernel<<<4096, 256, 0, stream>>>(h_bf, ba_w, ba_buf);
  conv_norm_kernel<<<4096, 256, 0, stream>>>(qkvz_bf, conv_w, mask, mixed_bf);
  beta_g_kernel<<<256, 256, 0, stream>>>(ba_buf, A_log, dt_bias, mask, beta_buf, g_buf);
  gcs_kernel<<<4, 256, 0, stream>>>(g_buf, gcs_buf, edk_buf, egq_buf, adec_buf);
  pre_attn_kernel<<<1024, 256, 0, stream>>>(mixed_bf, gcs_buf, beta_buf, a_buf, attn_buf);
  pre_solve_kernel<<<1024, 256, 0, stream>>>(a_buf, beta_buf, t_buf);
  pre_uw_kernel<<<1024, 256, 0, stream>>>(mixed_bf, t_buf, gcs_buf, u_bf, wbf);
  ktrans_kernel<<<1024, 256, 0, stream>>>(mixed_bf, edk_buf, egq_buf, kdT, qe_bf);
  // column-decomposed MFMA scan (16 blocks, 8 waves) + fused f2b/copy (15360 blocks)
  scan_kernel<<<15376, 512, 0, stream>>>(wbf, kdT, u_bf, adec_buf, ST_buf, vt_buf,
                                         gate_w, up_w, down_w, out_w, x,
                                         Wgu, Wd, Wo, out);
  ocomp_kernel<<<1024, 256, 0, stream>>>(qe_bf, ST_buf, vt_buf, attn_buf,
                                         z_bf, o_norm_w, ob);
  gemm256_kernel<1, 128, 128><<<512, 512, 0, stream>>>(ob, Wo, out, nullptr, 4096, 2048, 2048);
  rmsnorm_kernel<2><<<4096, 256, 0, stream>>>(out, ln2_w, nullptr, h2_bf);
  // fused gate+up: N=16384 interleaved weights, epilogue writes silu(gate)*up (4096x8192 bf16)
  gemm8p_kernel<3><<<1024, 512, 0, stream>>>(h2_bf, Wgu, nullptr, comb_bf, nullptr, 4096, 16384, 2048);
  gemm256_kernel<1, 128, 128><<<512, 512, 0, stream>>>(comb_bf, Wd, out, nullptr, 4096, 2048, 8192);
}

// Round 20
// 1233.075 us; speedup vs baseline: 1.4171x; 1.0102x over previous
//
#include <hip/hip_runtime.h>
#include <math.h>

#define T_LEN 4096
#define DMODEL 2048
#define NH 16
#define CQKV 6144
#define CQKVZ 8192
#define SCALE 0.08838834764831845f   // 128^-0.5

using bf16x8 = __attribute__((ext_vector_type(8))) short;
using f32x4  = __attribute__((ext_vector_type(4))) float;

__device__ __forceinline__ float siluf(float x) { return x / (1.0f + __expf(-x)); }

__device__ __forceinline__ unsigned short f2bf(float f) {  // RNE
  unsigned int u = __float_as_uint(f);
  u = (u + 0x7FFFu + ((u >> 16) & 1u)) >> 16;
  return (unsigned short)u;
}
__device__ __forceinline__ float bf2f(unsigned short u) {
  return __uint_as_float(((unsigned int)u) << 16);
}
__device__ __forceinline__ ushort4 pack4(float a, float b, float c, float d) {
  ushort4 r; r.x = f2bf(a); r.y = f2bf(b); r.z = f2bf(c); r.w = f2bf(d); return r;
}

// async global->LDS, 16 bytes per lane; LDS dest is wave-uniform base (+ lane*16 implicit)
__device__ __forceinline__ void gl_lds16(const unsigned short* g, unsigned short* l) {
  __builtin_amdgcn_global_load_lds(
      (const __attribute__((address_space(1))) void*)g,
      (__attribute__((address_space(3))) void*)l, 16, 0, 0);
}

// ---------------- RMSNorm over D=2048; MODE: 1 = f32+bf16, 2 = bf16 only ----------------
template<int MODE>
__global__ __launch_bounds__(256) void rmsnorm_kernel(const float* __restrict__ x,
                                                      const float* __restrict__ w,
                                                      float* __restrict__ outf,
                                                      unsigned short* __restrict__ outb) {
  const int t = blockIdx.x;
  const int tid = threadIdx.x;
  const float4* xr = (const float4*)(x + (size_t)t * DMODEL);
  float4 v0 = xr[tid];
  float4 v1 = xr[tid + 256];
  float s = v0.x*v0.x + v0.y*v0.y + v0.z*v0.z + v0.w*v0.w
          + v1.x*v1.x + v1.y*v1.y + v1.z*v1.z + v1.w*v1.w;
#pragma unroll
  for (int off = 32; off > 0; off >>= 1) s += __shfl_down(s, off);
  __shared__ float red[4];
  if ((tid & 63) == 0) red[tid >> 6] = s;
  __syncthreads();
  const float tot = red[0] + red[1] + red[2] + red[3];
  const float r = rsqrtf(tot * (1.0f / DMODEL) + 1e-5f);
  const float4* wr = (const float4*)w;
  const float4 w0 = wr[tid], w1 = wr[tid + 256];
  float4 o0, o1;
  o0.x = v0.x*r*w0.x; o0.y = v0.y*r*w0.y; o0.z = v0.z*r*w0.z; o0.w = v0.w*r*w0.w;
  o1.x = v1.x*r*w1.x; o1.y = v1.y*r*w1.y; o1.z = v1.z*r*w1.z; o1.w = v1.w*r*w1.w;
  if (MODE == 1) {
    float4* orow = (float4*)(outf + (size_t)t * DMODEL);
    orow[tid] = o0;
    orow[tid + 256] = o1;
  }
  ushort4* brow = (ushort4*)(outb + (size_t)t * DMODEL);
  brow[tid] = pack4(o0.x, o0.y, o0.z, o0.w);
  brow[tid + 256] = pack4(o1.x, o1.y, o1.z, o1.w);
}

// ---------------- fp32 -> bf16 bulk convert ----------------
__global__ __launch_bounds__(256) void f2b_kernel(const float* __restrict__ in,
                                                  unsigned short* __restrict__ out) {
  const size_t i = (size_t)blockIdx.x * 256 + threadIdx.x;
  const float4 a = ((const float4*)in)[2 * i];
  const float4 b = ((const float4*)in)[2 * i + 1];
  ((ushort4*)out)[2 * i] = pack4(a.x, a.y, a.z, a.w);
  ((ushort4*)out)[2 * i + 1] = pack4(b.x, b.y, b.z, b.w);
}

// ---------------- 4-phase slot-pipelined 256x256 bf16 MFMA GEMM (fat shapes): C = A @ B^T ---
// EPI: 0 = bf16 store (blocks with bn >= CQKV write ONLY into Zb when Zb != null);
//      3 = paired silu(gate)*up combine (B is 16-col-interleaved Wg/Wu, N=16384).
template<int EPI>
__global__ __launch_bounds__(512, 2) void gemm8p_kernel(const unsigned short* __restrict__ A,
                                                        const unsigned short* __restrict__ B,
                                                        float* __restrict__ Cf,
                                                        unsigned short* __restrict__ Cb,
                                                        unsigned short* __restrict__ Zb,
                                                        int M, int N, int K) {
  __shared__ __align__(16) unsigned short lds[8][8192];   // 8 slots x 16 KB
  const int nbm = M >> 8, nbn = N >> 8, nwg = nbm * nbn;
  const int nt = K >> 6;   // K-tiles of 64
  int bmi, bni;
  {
    const int bid = blockIdx.x;
    const int cpx = nwg >> 3;
    int sc = 1;
    while (sc * sc < cpx) sc <<= 1;
    if (sc * sc > cpx) sc >>= 1;
    const int scn = (sc > 0) ? (cpx / sc) : 0;
    if ((nwg & 7) == 0 && sc > 0 && sc * scn == cpx && (nbm % sc) == 0 && (nbn % scn) == 0) {
      const int chunk = bid & 7, widx = bid >> 3;
      const int regc = nbn / scn;
      bmi = (chunk / regc) * sc + widx / scn;
      bni = (chunk % regc) * scn + widx % scn;
    } else {
      bmi = bid / nbn; bni = bid % nbn;
    }
  }
  const int bm = bmi << 8, bn = bni << 8;
  const int tid = threadIdx.x;
  const int wv = tid >> 6, ln = tid & 63;
  const int fr = ln & 15, qq = ln >> 4;
  const int wm = wv >> 2, wn = wv & 3;           // wave tile: rows wm*128, cols wn*64
  const int rsw = (fr >> 1) & 3;                 // read swizzle term
  const int s_sl = (ln & 3) ^ ((ln >> 3) & 3);   // staging source slot (inverse swizzle)

  f32x4 acc[8][4];
  const f32x4 zero = {0.f, 0.f, 0.f, 0.f};
#pragma unroll
  for (int mf = 0; mf < 8; mf++)
#pragma unroll
    for (int nf = 0; nf < 4; nf++) acc[mf][nf] = zero;

  bf16x8 afr[8], bfr[2];

  // stage one half: part 0=Ak0, 1=Ak1, 2=Bk0, 3=Bk1 of tile t2 -> slot ((t2&1)<<2)|part
  auto stage_half = [&](int t2, int part) {
    if (t2 >= nt) return;
    const unsigned short* Mat = (part >= 2) ? B : A;
    const int gb = (part >= 2) ? bn : bm;
    const int kk = part & 1;
    const int slot = ((t2 & 1) << 2) | part;
    const int k0 = t2 * 64 + kk * 32;
#pragma unroll
    for (int q = 0; q < 2; q++) {
      gl_lds16(Mat + (size_t)(gb + wv * 32 + q * 16 + (ln >> 2)) * K + k0 + s_sl * 8,
               &lds[slot][(wv * 32 + q * 16) * 32]);
    }
  };
  auto lda = [&](int tb, int kk) {
#pragma unroll
    for (int mf = 0; mf < 8; mf++) {
      const int ar = wm * 128 + mf * 16 + fr;
      afr[mf] = *(const bf16x8*)&lds[tb | kk][ar * 32 + ((qq ^ rsw) << 3)];
    }
  };
  auto ldb = [&](int tb, int kk, int nh) {
#pragma unroll
    for (int nj = 0; nj < 2; nj++) {
      const int br = wn * 64 + (nh * 2 + nj) * 16 + fr;
      bfr[nj] = *(const bf16x8*)&lds[tb | (2 + kk)][br * 32 + ((qq ^ rsw) << 3)];
    }
  };
  auto mm = [&](int nh) {
    __builtin_amdgcn_s_setprio(1);
#pragma unroll
    for (int mf = 0; mf < 8; mf++)
#pragma unroll
      for (int nj = 0; nj < 2; nj++)
        acc[mf][nh * 2 + nj] =
            __builtin_amdgcn_mfma_f32_16x16x32_bf16(afr[mf], bfr[nj], acc[mf][nh * 2 + nj], 0, 0, 0);
    __builtin_amdgcn_s_setprio(0);
  };

  // prologue: tile0 all 4 halves, tile1 k0 halves; wait tile0 (counted), publish
  stage_half(0, 0); stage_half(0, 2); stage_half(0, 1); stage_half(0, 3);
  stage_half(1, 0); stage_half(1, 2);
  asm volatile("s_waitcnt vmcnt(4)" ::: "memory");
  __builtin_amdgcn_s_barrier();
  asm volatile("" ::: "memory");

  for (int t = 0; t < nt; t++) {
    const int tb = (t & 1) << 2;
    // phase 0: (k0, N0); stage Ak1(t+1)
    lda(tb, 0); ldb(tb, 0, 0);
    stage_half(t + 1, 1);
    __builtin_amdgcn_s_barrier();
    mm(0);
    __builtin_amdgcn_s_barrier();
    // phase 1: (k0, N1); stage Bk1(t+1)
    ldb(tb, 0, 1);
    stage_half(t + 1, 3);
    __builtin_amdgcn_s_barrier();
    mm(1);
    __builtin_amdgcn_s_barrier();
    // phase 2: (k1, N1); stage Ak0(t+2)
    lda(tb, 1); ldb(tb, 1, 1);
    stage_half(t + 2, 0);
    __builtin_amdgcn_s_barrier();
    mm(1);
    __builtin_amdgcn_s_barrier();
    // phase 3: (k1, N0); stage Bk0(t+2)
    ldb(tb, 1, 0);
    stage_half(t + 2, 2);
    __builtin_amdgcn_s_barrier();
    mm(0);
    // tile boundary: counted vmcnt — next tile's 4 halves are older than newest in flight
    if (t + 1 < nt) {
      asm volatile("s_waitcnt lgkmcnt(0)" ::: "memory");
      __builtin_amdgcn_sched_barrier(0);
      if (t == nt - 2) {
        asm volatile("s_waitcnt vmcnt(0)" ::: "memory");
      } else {
        asm volatile("s_waitcnt vmcnt(4)" ::: "memory");
      }
      __builtin_amdgcn_sched_barrier(0);
      __builtin_amdgcn_s_barrier();
      __builtin_amdgcn_sched_barrier(0);
    }
  }

  const int cm4 = qq * 4;
  if (EPI == 3) {
    // paired combine: nf even = gate frag, nf odd = up frag at same output cols.
    const int bn2 = bn >> 1;
#pragma unroll
    for (int mf = 0; mf < 8; mf++) {
#pragma unroll
      for (int p = 0; p < 2; p++) {
#pragma unroll
        for (int r = 0; r < 4; r++) {
          const int grow = bm + wm * 128 + mf * 16 + cm4 + r;
          const int gcol = bn2 + wn * 32 + p * 16 + fr;
          Cb[(size_t)grow * 8192 + gcol] =
              f2bf(siluf(acc[mf][2 * p][r]) * acc[mf][2 * p + 1][r]);
        }
      }
    }
  } else {
    const bool isZ = (Zb != nullptr) && (bn >= CQKV);   // block-uniform
#pragma unroll
    for (int mf = 0; mf < 8; mf++) {
#pragma unroll
      for (int nf = 0; nf < 4; nf++) {
#pragma unroll
        for (int r = 0; r < 4; r++) {
          const int grow = bm + wm * 128 + mf * 16 + cm4 + r;
          const int gcol = bn + wn * 64 + nf * 16 + fr;
          const float v = acc[mf][nf][r];
          if (EPI == 0) {
            const unsigned short bv = f2bf(v);
            if (isZ) Zb[(size_t)grow * 2048 + (gcol - CQKV)] = bv;
            else     Cb[(size_t)grow * N + gcol] = bv;
          } else {
            Cf[(size_t)grow * N + gcol] += v;
          }
        }
      }
    }
  }
}

// ---------------- pipelined bf16 MFMA GEMM (thin shapes): C[M][N] = A[M][K] * B[N][K]^T -----
// BM x BN block (8 waves, 64x64 per-wave tile), BK=32, 3 LDS buffers, counted vmcnt.
// EPI: 1 = fp32 accumulate into Cf; 4 = Cf = Xres + acc (fused residual).
template<int EPI, int BM, int BN>
__global__ __launch_bounds__(512, 4) void gemm256_kernel(const unsigned short* __restrict__ A,
                                                         const unsigned short* __restrict__ B,
                                                         float* __restrict__ Cf,
                                                         const float* __restrict__ Xres,
                                                         int M, int N, int K) {
  constexpr int MI = 4;
  constexpr int NI = BN / 64;
  constexpr int AW = BM / 128;
  constexpr int BW = BN / 128;
  __shared__ __align__(16) unsigned short lds[3][(BM + BN) * 32];
  const int nbm = M / BM, nbn = N / BN, nwg = nbm * nbn;
  const int nt = K >> 5;
  int bmi, bni;
  {
    const int bid = blockIdx.x;
    const int cpx = nwg >> 3;
    int sc = 1;
    while (sc * sc < cpx) sc <<= 1;
    if (sc * sc > cpx) sc >>= 1;
    const int scn = (sc > 0) ? (cpx / sc) : 0;
    if ((nwg & 7) == 0 && sc > 0 && sc * scn == cpx && (nbm % sc) == 0 && (nbn % scn) == 0) {
      const int chunk = bid & 7, widx = bid >> 3;
      const int regc = nbn / scn;
      bmi = (chunk / regc) * sc + widx / scn;
      bni = (chunk % regc) * scn + widx % scn;
    } else {
      bmi = bid / nbn; bni = bid % nbn;
    }
  }
  const int bm = bmi * BM, bn = bni * BN;
  const int tid = threadIdx.x;
  const int wv = tid >> 6, ln = tid & 63;
  const int fr = ln & 15, qq = ln >> 4;
  const int wm = wv >> 2, wn = wv & 3;
  const int ra0 = wm * 64, rb0 = wn * (BN / 4);
  const int lrow = ln >> 2;
  const int lslot = ln & 3;

  f32x4 acc[MI][NI];
  const f32x4 zero = {0.f, 0.f, 0.f, 0.f};
#pragma unroll
  for (int mi = 0; mi < MI; mi++)
#pragma unroll
    for (int ni = 0; ni < NI; ni++) acc[mi][ni] = zero;

  auto stage = [&](int buf, int t) {
    const int k0 = t << 5;
#pragma unroll
    for (int q = 0; q < AW; q++) {
      const int lr = q * 128 + wv * 16 + lrow;
      const int sl = lslot ^ ((lr >> 1) & 3);
      gl_lds16(A + (size_t)(bm + lr) * K + k0 + sl * 8,
               &lds[buf][(q * 128 + wv * 16) * 32]);
    }
#pragma unroll
    for (int q = 0; q < BW; q++) {
      const int lr = q * 128 + wv * 16 + lrow;
      const int sl = lslot ^ ((lr >> 1) & 3);
      gl_lds16(B + (size_t)(bn + lr) * K + k0 + sl * 8,
               &lds[buf][BM * 32 + (q * 128 + wv * 16) * 32]);
    }
  };

  stage(0, 0);
  stage(1, 1);
  asm volatile("s_waitcnt vmcnt(%0)" :: "i"(AW + BW) : "memory");
  __builtin_amdgcn_s_barrier();
  asm volatile("" ::: "memory");

  for (int t = 0; t < nt; t++) {
    const int cb = t % 3;
    const int b2 = (t + 2) % 3;
    const unsigned short* lA = &lds[cb][0];
    const unsigned short* lB = &lds[cb][BM * 32];
    bf16x8 bfr[NI];
#pragma unroll
    for (int ni = 0; ni < NI; ni++) {
      const int r = rb0 + ni * 16 + fr;
      bfr[ni] = *(const bf16x8*)&lB[r * 32 + ((qq ^ ((r >> 1) & 3)) << 3)];
    }
    bf16x8 afr[MI];
#pragma unroll
    for (int mi = 0; mi < MI; mi++) {
      const int r = ra0 + mi * 16 + fr;
      afr[mi] = *(const bf16x8*)&lA[r * 32 + ((qq ^ ((r >> 1) & 3)) << 3)];
    }
    if (t + 2 < nt) stage(b2, t + 2);
    __builtin_amdgcn_s_setprio(1);
#pragma unroll
    for (int mi = 0; mi < MI; mi++)
#pragma unroll
      for (int ni = 0; ni < NI; ni++)
        acc[mi][ni] = __builtin_amdgcn_mfma_f32_16x16x32_bf16(afr[mi], bfr[ni], acc[mi][ni], 0, 0, 0);
    __builtin_amdgcn_s_setprio(0);
    if (t + 1 < nt) {
      asm volatile("s_waitcnt lgkmcnt(0)" ::: "memory");
      if (t + 2 < nt) {
        asm volatile("s_waitcnt vmcnt(%0)" :: "i"(AW + BW) : "memory");
      } else {
        asm volatile("s_waitcnt vmcnt(0)" ::: "memory");
      }
      __builtin_amdgcn_s_barrier();
      asm volatile("" ::: "memory");
    }
  }

  const int cm4 = qq * 4;
#pragma unroll
  for (int mi = 0; mi < MI; mi++) {
#pragma unroll
    for (int ni = 0; ni < NI; ni++) {
#pragma unroll
      for (int r = 0; r < 4; r++) {
        const int grow = bm + ra0 + mi * 16 + cm4 + r;
        const int gcol = bn + rb0 + ni * 16 + fr;
        const size_t off = (size_t)grow * N + gcol;
        const float v = acc[mi][ni][r];
        if (EPI == 1) {
          Cf[off] += v;
        } else {
          Cf[off] = Xres[off] + v;
        }
      }
    }
  }
}

// ---------------- ba = h @ ba_w^T (h read as bf16) ----------------
__global__ __launch_bounds__(256) void ba_gemm_kernel(const unsigned short* __restrict__ h_in,
                                                      const float* __restrict__ ba_w,
                                                      float* __restrict__ ba_out) {
  __shared__ __align__(16) float hl[2048];
  __shared__ float red[32][9];
  const int t = blockIdx.x;
  const int tid = threadIdx.x;
  union { uint4 u; unsigned short s[8]; } wv_;
  wv_.u = *(const uint4*)(h_in + (size_t)t * DMODEL + tid * 8);
#pragma unroll
  for (int j = 0; j < 8; j++) hl[tid * 8 + j] = bf2f(wv_.s[j]);
  __syncthreads();
  const int c = tid & 31;
  const int p = tid >> 5;
  const float* wrow = ba_w + (size_t)c * DMODEL + p * 256;
  const float* hrow = hl + p * 256;
  float s = 0.f;
#pragma unroll 8
  for (int k = 0; k < 256; k++) s += hrow[k] * wrow[k];
  red[c][p] = s;
  __syncthreads();
  if (tid < 32) {
    float tot = 0.f;
#pragma unroll
    for (int q = 0; q < 8; q++) tot += red[tid][q];
    ba_out[(size_t)t * 32 + tid] = tot;
  }
}

// ---------------- fused causal depthwise conv (K=4) + SiLU + per-head l2norm; bf16 out ------
__global__ __launch_bounds__(256) void conv_norm_kernel(const unsigned short* __restrict__ qkvz,
                                                        const float* __restrict__ conv_w,
                                                        const float* __restrict__ mask,
                                                        unsigned short* __restrict__ mixed) {
  __shared__ float vals[6144];
  const int t = blockIdx.x;
  const int tid = threadIdx.x;
  float mj[4];
#pragma unroll
  for (int j = 0; j < 4; j++) {
    const int tt = t - 3 + j;
    mj[j] = (tt >= 0) ? mask[tt] : 0.f;
  }
#pragma unroll
  for (int p = 0; p < 6; p++) {
    const int c4 = (p * 256 + tid) * 4;
    const float4 w0 = *(const float4*)(conv_w + (size_t)c4 * 4);
    const float4 w1 = *(const float4*)(conv_w + (size_t)c4 * 4 + 4);
    const float4 w2 = *(const float4*)(conv_w + (size_t)c4 * 4 + 8);
    const float4 w3 = *(const float4*)(conv_w + (size_t)c4 * 4 + 12);
    const float wj0[4] = {w0.x, w0.y, w0.z, w0.w};
    const float wj1[4] = {w1.x, w1.y, w1.z, w1.w};
    const float wj2[4] = {w2.x, w2.y, w2.z, w2.w};
    const float wj3[4] = {w3.x, w3.y, w3.z, w3.w};
    float4 acc = make_float4(0.f, 0.f, 0.f, 0.f);
#pragma unroll
    for (int j = 0; j < 4; j++) {
      const int tt = t - 3 + j;
      if (tt < 0) continue;
      const ushort4 xb = *(const ushort4*)(qkvz + (size_t)tt * CQKVZ + c4);
      acc.x += bf2f(xb.x) * mj[j] * wj0[j];
      acc.y += bf2f(xb.y) * mj[j] * wj1[j];
      acc.z += bf2f(xb.z) * mj[j] * wj2[j];
      acc.w += bf2f(xb.w) * mj[j] * wj3[j];
    }
    vals[c4]     = siluf(acc.x);
    vals[c4 + 1] = siluf(acc.y);
    vals[c4 + 2] = siluf(acc.z);
    vals[c4 + 3] = siluf(acc.w);
  }
  __syncthreads();
  unsigned short* orow = mixed + (size_t)t * CQKV;
  // l2norm q/k: 32 heads x 128; 8 lanes per head, 16 elems per lane
  const int hh = tid >> 3;
  const int li = tid & 7;
  const int base = hh * 128 + li * 16;
  float loc[16];
  float s = 0.f;
#pragma unroll
  for (int j = 0; j < 16; j++) { loc[j] = vals[base + j]; s += loc[j] * loc[j]; }
#pragma unroll
  for (int msk = 1; msk < 8; msk <<= 1) s += __shfl_xor(s, msk);
  const float rn = rsqrtf(s + 1e-6f);
#pragma unroll
  for (int j8 = 0; j8 < 2; j8++) {
    *(ushort4*)(orow + base + j8 * 8) =
        pack4(loc[j8*8+0]*rn, loc[j8*8+1]*rn, loc[j8*8+2]*rn, loc[j8*8+3]*rn);
    *(ushort4*)(orow + base + j8 * 8 + 4) =
        pack4(loc[j8*8+4]*rn, loc[j8*8+5]*rn, loc[j8*8+6]*rn, loc[j8*8+7]*rn);
  }
  // v part: channels 4096..6143 pack straight out
  const int vc = 4096 + tid * 8;
  *(ushort4*)(orow + vc) = pack4(vals[vc], vals[vc+1], vals[vc+2], vals[vc+3]);
  *(ushort4*)(orow + vc + 4) = pack4(vals[vc+4], vals[vc+5], vals[vc+6], vals[vc+7]);
}

// ---------------- beta, g ----------------
__global__ __launch_bounds__(256) void beta_g_kernel(const float* __restrict__ ba,
                                                     const float* __restrict__ A_log,
                                                     const float* __restrict__ dt_bias,
                                                     const float* __restrict__ mask,
                                                     float* __restrict__ beta,
                                                     float* __restrict__ g) {
  const int idx = blockIdx.x * 256 + threadIdx.x;
  const int t = idx >> 4;
  const int h = idx & 15;
  const float b = ba[(size_t)t * 32 + h];
  const float a = ba[(size_t)t * 32 + 16 + h];
  const float m = mask[t];
  beta[idx] = m / (1.0f + expf(-b));
  const float xx = a + dt_bias[h];
  const float sp = (xx > 20.0f) ? xx : log1pf(expf(xx));
  g[idx] = -expf(A_log[h]) * sp * m;
}

// ---------------- per-chunk cumsum of g + decay factors ----------------
__global__ __launch_bounds__(256) void gcs_kernel(const float* __restrict__ g,
                                                  float* __restrict__ gcsbuf,
                                                  float* __restrict__ edkbuf,
                                                  float* __restrict__ egqbuf,
                                                  float* __restrict__ adecbuf) {
  const int idx = blockIdx.x * 256 + threadIdx.x;  // chunk id = h*64 + n
  if (idx >= 1024) return;
  const int h = idx >> 6;
  const int n = idx & 63;
  const int t0 = n * 64;
  float s = 0.f;
  for (int i = 0; i < 64; i++) {
    s += g[(size_t)(t0 + i) * NH + h];
    gcsbuf[(size_t)idx * 64 + i] = s;
  }
  const float glast = s;
  adecbuf[idx] = __expf(glast);
  for (int i = 0; i < 64; i++) {
    const float gi = gcsbuf[(size_t)idx * 64 + i];
    edkbuf[(size_t)idx * 64 + i] = __expf(glast - gi);
    egqbuf[(size_t)idx * 64 + i] = __expf(gi) * SCALE;
  }
}

// ---------------- per-chunk MFMA: A=(k_beta k^T)*decay (strict lower, f32) ;
//                  attn=(q k^T)*decay*scale stored bf16 ----
__global__ __launch_bounds__(256) void pre_attn_kernel(const unsigned short* __restrict__ mixed,
                                                       const float* __restrict__ gcsbuf,
                                                       const float* __restrict__ betabuf,
                                                       float* __restrict__ abuf,
                                                       unsigned short* __restrict__ attnb) {
  __shared__ __align__(16) unsigned short kbl[64 * 128];
  __shared__ __align__(16) unsigned short qbl[64 * 128];
  __shared__ float gcs_s[64];
  __shared__ float betal[64];
  const int blk = blockIdx.x;
  const int h = blk >> 6;
  const int n = blk & 63;
  const int t0 = n * 64;
  const int tid = threadIdx.x;
  if (tid < 64) {
    gcs_s[tid] = gcsbuf[(size_t)blk * 64 + tid];
    betal[tid] = betabuf[(size_t)(t0 + tid) * NH + h];
  }
#pragma unroll
  for (int p = 0; p < 4; p++) {
    const int idx = tid + p * 256;          // 0..1023
    const int i = idx >> 4, dg = idx & 15;  // row, 16B granule
    *(uint4*)&kbl[i * 128 + ((dg ^ (i & 7)) << 3)] =
        *(const uint4*)(mixed + (size_t)(t0 + i) * CQKV + 2048 + h * 128 + dg * 8);
    *(uint4*)&qbl[i * 128 + ((dg ^ (i & 7)) << 3)] =
        *(const uint4*)(mixed + (size_t)(t0 + i) * CQKV + h * 128 + dg * 8);
  }
  __syncthreads();
  const int ln = tid & 63;
  const int wv = tid >> 6;      // 0..3
  const int fr = ln & 15;
  const int g = ln >> 4;        // 0..3
  const int i0 = wv * 16;
  f32x4 accA[4], accQ[4];
  const f32x4 zero = {0.f, 0.f, 0.f, 0.f};
#pragma unroll
  for (int jt = 0; jt < 4; jt++) { accA[jt] = zero; accQ[jt] = zero; }
#pragma unroll
  for (int ks = 0; ks < 4; ks++) {
    const int kb = ks * 4 + g;
    const int ar = i0 + fr;
    const bf16x8 aK = *(const bf16x8*)&kbl[ar * 128 + ((kb ^ (ar & 7)) << 3)];
    const bf16x8 aQ = *(const bf16x8*)&qbl[ar * 128 + ((kb ^ (ar & 7)) << 3)];
#pragma unroll
    for (int jt = 0; jt < 4; jt++) {
      const int br = jt * 16 + fr;
      const bf16x8 b = *(const bf16x8*)&kbl[br * 128 + ((kb ^ (br & 7)) << 3)];
      accA[jt] = __builtin_amdgcn_mfma_f32_16x16x32_bf16(aK, b, accA[jt], 0, 0, 0);
      accQ[jt] = __builtin_amdgcn_mfma_f32_16x16x32_bf16(aQ, b, accQ[jt], 0, 0, 0);
    }
  }
  // epilogue: i = i0 + g*4 + r ; j = jt*16 + fr
#pragma unroll
  for (int jt = 0; jt < 4; jt++) {
    const int j = jt * 16 + fr;
    const float gj = gcs_s[j];
#pragma unroll
    for (int r = 0; r < 4; r++) {
      const int i = i0 + g * 4 + r;
      const float gi = gcs_s[i];
      const float dec = __expf(fminf(gi - gj, 0.f));
      abuf[(size_t)blk * 4096 + i * 64 + j] = (i > j) ? accA[jt][r] * betal[i] * dec : 0.f;
      attnb[(size_t)blk * 4096 + i * 64 + j] =
          f2bf((i >= j) ? accQ[jt][r] * dec * SCALE : 0.f);
    }
  }
}

// ---------------- per-chunk: T = (I+A)^-1, then T *= beta[col] ----------------
__global__ __launch_bounds__(256) void pre_solve_kernel(const float* __restrict__ abuf,
                                                        const float* __restrict__ betabuf,
                                                        float* __restrict__ tbuf) {
  __shared__ float Al[64][65];
  __shared__ float Tl[64][65];
  const int blk = blockIdx.x;
  const int h = blk >> 6;
  const int n = blk & 63;
  const int t0 = n * 64;
  const int tid = threadIdx.x;
#pragma unroll
  for (int rep = 0; rep < 4; rep++) {
    const int lin = rep * 256 + tid;
    const int i = lin >> 4;
    const int j = (lin & 15) * 4;
    const float4 av = *(const float4*)(abuf + (size_t)blk * 4096 + i * 64 + j);
    Al[i][j] = av.x; Al[i][j + 1] = av.y; Al[i][j + 2] = av.z; Al[i][j + 3] = av.w;
  }
  __syncthreads();
  if (tid < 64) {
    const int j = tid;
    const float bj = betabuf[(size_t)(t0 + j) * NH + h];
    for (int i = 0; i < 64; i++) {
      float s = (i == j) ? 1.0f : 0.0f;
      for (int l = j; l < i; l++) s -= Al[i][l] * Tl[l][j];
      Tl[i][j] = s;
    }
    for (int i = j; i < 64; i++) Tl[i][j] *= bj;
  }
  __syncthreads();
#pragma unroll
  for (int rep = 0; rep < 4; rep++) {
    const int lin = rep * 256 + tid;
    const int i = lin >> 4;
    const int j = (lin & 15) * 4;
    float4 tv;
    tv.x = Tl[i][j]; tv.y = Tl[i][j + 1]; tv.z = Tl[i][j + 2]; tv.w = Tl[i][j + 3];
    *(float4*)(tbuf + (size_t)blk * 4096 + i * 64 + j) = tv;
  }
}

// ---------------- per-chunk: u = Tb @ v (bf16, l4-packed [blk][l>>2][c][l&3]) ;
//                  w = Tb @ (k * e^gcs), stored NEGATED + slot-swizzled ----
__global__ __launch_bounds__(256) void pre_uw_kernel(const unsigned short* __restrict__ mixed,
                                                     const float* __restrict__ tbuf,
                                                     const float* __restrict__ gcsbuf,
                                                     unsigned short* __restrict__ ubf,
                                                     unsigned short* __restrict__ wbf) {
  __shared__ __align__(16) float Tl[64][68];
  __shared__ __align__(16) float xl[64][132];
  __shared__ float egcs[64];
  const int blk = blockIdx.x;
  const int h = blk >> 6;
  const int n = blk & 63;
  const int t0 = n * 64;
  const int tid = threadIdx.x;
  if (tid < 64) egcs[tid] = __expf(gcsbuf[(size_t)blk * 64 + tid]);
#pragma unroll
  for (int rep = 0; rep < 4; rep++) {
    const int lin = rep * 256 + tid;
    const int i = lin >> 4;
    const int j = (lin & 15) * 4;
    const float4 tv = *(const float4*)(tbuf + (size_t)blk * 4096 + i * 64 + j);
    *(float4*)&Tl[i][j] = tv;
  }
#pragma unroll
  for (int rep = 0; rep < 4; rep++) {
    const int lin = rep * 256 + tid;
    const int i = lin >> 4;
    const int d8 = (lin & 15) * 8;
    union { uint4 u; unsigned short s[8]; } w;
    w.u = *(const uint4*)(mixed + (size_t)(t0 + i) * CQKV + 4096 + h * 128 + d8);
#pragma unroll
    for (int j = 0; j < 8; j++) xl[i][d8 + j] = bf2f(w.s[j]);
  }
  __syncthreads();
  const int cgu = tid & 15;
  const int riu = tid >> 4;
  const int i0 = riu * 4;
  const int d0 = cgu * 8;
  float acc[4][8];
#pragma unroll
  for (int a = 0; a < 4; a++)
#pragma unroll
    for (int b = 0; b < 8; b++) acc[a][b] = 0.f;
#pragma unroll 2
  for (int j = 0; j < 64; j++) {
    const float tv[4] = {Tl[i0][j], Tl[i0 + 1][j], Tl[i0 + 2][j], Tl[i0 + 3][j]};
    const float4 x0 = *(const float4*)&xl[j][d0];
    const float4 x1 = *(const float4*)&xl[j][d0 + 4];
    const float xv[8] = {x0.x, x0.y, x0.z, x0.w, x1.x, x1.y, x1.z, x1.w};
#pragma unroll
    for (int a = 0; a < 4; a++)
#pragma unroll
      for (int b = 0; b < 8; b++) acc[a][b] += tv[a] * xv[b];
  }
  // u store: bf16 l4-packed layout elem = blk*8192 + riu*512 + (d0+b)*4 + (l&3)
#pragma unroll
  for (int b = 0; b < 8; b++) {
    *(ushort4*)(ubf + (size_t)blk * 8192 + riu * 512 + (size_t)(d0 + b) * 4) =
        pack4(acc[0][b], acc[1][b], acc[2][b], acc[3][b]);
  }
  __syncthreads();
#pragma unroll
  for (int rep = 0; rep < 4; rep++) {
    const int lin = rep * 256 + tid;
    const int i = lin >> 4;
    const int d8 = (lin & 15) * 8;
    union { uint4 u; unsigned short s[8]; } w;
    w.u = *(const uint4*)(mixed + (size_t)(t0 + i) * CQKV + 2048 + h * 128 + d8);
    const float e = egcs[i];
#pragma unroll
    for (int j = 0; j < 8; j++) xl[i][d8 + j] = bf2f(w.s[j]) * e;
  }
  __syncthreads();
#pragma unroll
  for (int a = 0; a < 4; a++)
#pragma unroll
    for (int b = 0; b < 8; b++) acc[a][b] = 0.f;
#pragma unroll 2
  for (int j = 0; j < 64; j++) {
    const float tv[4] = {Tl[i0][j], Tl[i0 + 1][j], Tl[i0 + 2][j], Tl[i0 + 3][j]};
    const float4 x0 = *(const float4*)&xl[j][d0];
    const float4 x1 = *(const float4*)&xl[j][d0 + 4];
    const float xv[8] = {x0.x, x0.y, x0.z, x0.w, x1.x, x1.y, x1.z, x1.w};
#pragma unroll
    for (int a = 0; a < 4; a++)
#pragma unroll
      for (int b = 0; b < 8; b++) acc[a][b] += tv[a] * xv[b];
  }
  // store -w, column-slot swizzled by (row&7) so scan can global_load_lds linearly
#pragma unroll
  for (int a = 0; a < 4; a++) {
    const int l = i0 + a;
    unsigned short* wp = wbf + (size_t)(t0 + l) * 2048 + h * 128 + ((cgu ^ (l & 7)) << 3);
    *(ushort4*)wp = pack4(-acc[a][0], -acc[a][1], -acc[a][2], -acc[a][3]);
    *(ushort4*)(wp + 4) = pack4(-acc[a][4], -acc[a][5], -acc[a][6], -acc[a][7]);
  }
}

// ---------------- per-chunk: kdT[blk][d][l] = bf16(k*edk) slot-swizzled; qe = bf16(q*egq) ----------------
__global__ __launch_bounds__(256) void ktrans_kernel(const unsigned short* __restrict__ mixed,
                                                     const float* __restrict__ edkbuf,
                                                     const float* __restrict__ egqbuf,
                                                     unsigned short* __restrict__ kdT,
                                                     unsigned short* __restrict__ qe) {
  __shared__ __align__(16) float kl[64][132];
  __shared__ float edk_s[64];
  __shared__ float egq_s[64];
  const int blk = blockIdx.x;
  const int h = blk >> 6;
  const int n = blk & 63;
  const int t0 = n * 64;
  const int tid = threadIdx.x;
  if (tid < 64) {
    edk_s[tid] = edkbuf[(size_t)blk * 64 + tid];
    egq_s[tid] = egqbuf[(size_t)blk * 64 + tid];
  }
#pragma unroll
  for (int q = 0; q < 4; q++) {
    const int idx = tid + q * 256;
    const int l = idx >> 4, d8 = (idx & 15) * 8;
    union { uint4 u; unsigned short s[8]; } w;
    w.u = *(const uint4*)(mixed + (size_t)(t0 + l) * CQKV + 2048 + h * 128 + d8);
#pragma unroll
    for (int j = 0; j < 8; j++) kl[l][d8 + j] = bf2f(w.s[j]);
  }
  __syncthreads();
#pragma unroll
  for (int q = 0; q < 4; q++) {
    const int idx = tid + q * 256;
    const int d = idx >> 3, lsl = idx & 7;
    const int l8 = lsl * 8;
    float v[8];
#pragma unroll
    for (int j = 0; j < 8; j++) v[j] = kl[l8 + j][d] * edk_s[l8 + j];
    unsigned short* p = kdT + (size_t)blk * 8192 + d * 64 + ((lsl ^ (d & 7)) << 3);
    *(ushort4*)p = pack4(v[0], v[1], v[2], v[3]);
    *(ushort4*)(p + 4) = pack4(v[4], v[5], v[6], v[7]);
  }
#pragma unroll
  for (int q = 0; q < 4; q++) {
    const int idx = tid + q * 256;
    const int i = idx >> 4, c8 = (idx & 15) * 8;
    union { uint4 u; unsigned short s[8]; } w;
    w.u = *(const uint4*)(mixed + (size_t)(t0 + i) * CQKV + h * 128 + c8);
    const float e = egq_s[i];
    unsigned short* qp = qe + (size_t)(t0 + i) * 2048 + h * 128 + c8;
    *(ushort4*)qp = pack4(bf2f(w.s[0]) * e, bf2f(w.s[1]) * e, bf2f(w.s[2]) * e, bf2f(w.s[3]) * e);
    *(ushort4*)(qp + 4) = pack4(bf2f(w.s[4]) * e, bf2f(w.s[5]) * e, bf2f(w.s[6]) * e, bf2f(w.s[7]) * e);
  }
}

// ---------------- MFMA scan, column-decomposed: 8 waves x 16 c-columns, NO cross-wave data ---
// u read bf16 l4-packed (4x ushort4 per chunk). Exports d4/l4-packed (coalesced).
// blocks 0..15: per-head scan; ONE barrier/chunk (counted vmcnt(17)).
// blocks >=16: weight f2b (Wgu interleaved / Wd / Wo) (512 threads).
__global__ __launch_bounds__(512, 1) void scan_kernel(const unsigned short* __restrict__ wbf,
                                                      const unsigned short* __restrict__ kdT,
                                                      const unsigned short* __restrict__ ubf,
                                                      const float* __restrict__ adecbuf,
                                                      unsigned short* __restrict__ STb,
                                                      unsigned short* __restrict__ vtb,
                                                      const float* __restrict__ gw,
                                                      const float* __restrict__ uw,
                                                      const float* __restrict__ dw,
                                                      const float* __restrict__ ow,
                                                      unsigned short* __restrict__ Wgu,
                                                      unsigned short* __restrict__ Wd,
                                                      unsigned short* __restrict__ Wo) {
  __shared__ __align__(16) unsigned short stage[2][16384];  // [w 8192 | kT 8192] shorts each
  __shared__ __align__(16) unsigned short privAll[8][3072]; // per wave: A 16x128 | B 16x64
  if (blockIdx.x >= 16) {
    // side work (512 thr): Wg 4096 + Wu 4096 + Wd 4096 + Wo 1024 = 13312 blocks
    const int xb = blockIdx.x - 16;
    const int tid = threadIdx.x;
    if (xb < 8192) {
      // gate/up f2b with 16-row interleave into Wgu:
      // src row r -> dst row (r>>4)*32 + (r&15) (+16 for up)
      const bool isUp = (xb >= 4096);
      const float* src = isUp ? uw : gw;
      const size_t e = ((size_t)(isUp ? xb - 4096 : xb) * 512 + tid) * 8;
      const int r = (int)(e >> 11);
      const int col = (int)(e & 2047);
      const int drow = (r >> 4) * 32 + (r & 15) + (isUp ? 16 : 0);
      const float4 a = *(const float4*)(src + e);
      const float4 b = *(const float4*)(src + e + 4);
      unsigned short* dst = Wgu + (size_t)drow * 2048 + col;
      *(ushort4*)dst = pack4(a.x, a.y, a.z, a.w);
      *(ushort4*)(dst + 4) = pack4(b.x, b.y, b.z, b.w);
    } else {
      const float* src; unsigned short* dst; size_t u;
      if (xb < 12288) { src = dw; dst = Wd; u = (size_t)(xb - 8192) * 512 + tid; }
      else            { src = ow; dst = Wo; u = (size_t)(xb - 12288) * 512 + tid; }
      const float4 a = ((const float4*)src)[2 * u];
      const float4 b = ((const float4*)src)[2 * u + 1];
      ((ushort4*)dst)[2 * u] = pack4(a.x, a.y, a.z, a.w);
      ((ushort4*)dst)[2 * u + 1] = pack4(b.x, b.y, b.z, b.w);
    }
    return;
  }
  const int h = blockIdx.x;
  const int tid = threadIdx.x;
  const int ln = tid & 63;
  const int wv = tid >> 6;        // 0..7
  const int fr = ln & 15;
  const int g  = ln >> 4;         // 0..3
  const int c0 = wv * 16;
  const int fsw = fr & 7;
  unsigned short* privA = &privAll[wv][0];     // [16 c][128 d], slot-swizzled
  unsigned short* privB = &privAll[wv][2048];  // [16 c][64 l], slot-swizzled
  const f32x4 zero = {0.f, 0.f, 0.f, 0.f};

  f32x4 acc2[8];                  // S^T state for this wave's 16 columns, d-tile dt
#pragma unroll
  for (int dt = 0; dt < 8; dt++) acc2[dt] = zero;

  auto stage_wk = [&](int buf, int n1) {
    const int t0n = n1 * 64;
    const size_t kbase = (size_t)(h * 64 + n1) * 8192;
#pragma unroll
    for (int q = 0; q < 2; q++) {
      const int m = wv * 2 + q;   // 0..15
      gl_lds16(wbf + (size_t)(t0n + m * 4 + (ln >> 4)) * 2048 + h * 128 + (ln & 15) * 8,
               &stage[buf][m * 512]);
      gl_lds16(kdT + kbase + (m * 8 + (ln >> 3)) * 64 + (ln & 7) * 8,
               &stage[buf][8192 + m * 512]);
    }
  };

  // prologue: u/adec for chunk 0 + stage chunk 0
  ushort4 ur4[4];
#pragma unroll
  for (int lt = 0; lt < 4; lt++)
    ur4[lt] = *(const ushort4*)(ubf + (size_t)(h * 64) * 8192 + (lt * 4 + g) * 512 + (c0 + fr) * 4);
  float ad = adecbuf[h * 64];
  stage_wk(0, 0);
  asm volatile("s_waitcnt vmcnt(0)" ::: "memory");
  __builtin_amdgcn_s_barrier();
  asm volatile("" ::: "memory");

  for (int n = 0; n < 64; n++) {
    const int blk = h * 64 + n;
    const unsigned short* wl = &stage[n & 1][0];
    const unsigned short* kl = &stage[n & 1][8192];
    // (1) issue staging for n+1 first (oldest VMEM ops of this chunk)
    if (n + 1 < 64) stage_wk((n + 1) & 1, n + 1);
    __builtin_amdgcn_sched_barrier(0);
    // (2) prefetch u/adec for n+1 (4 ushort4 + 1 scalar; younger than staging)
    ushort4 ur4n[4];
    float adn = 0.f;
    if (n + 1 < 64) {
      const size_t ub = (size_t)(blk + 1) * 8192;
#pragma unroll
      for (int lt = 0; lt < 4; lt++)
        ur4n[lt] = *(const ushort4*)(ubf + ub + (lt * 4 + g) * 512 + (c0 + fr) * 4);
      adn = adecbuf[blk + 1];
    } else {
#pragma unroll
      for (int lt = 0; lt < 4; lt++) { ur4n[lt].x = 0; ur4n[lt].y = 0; ur4n[lt].z = 0; ur4n[lt].w = 0; }
    }
    __builtin_amdgcn_sched_barrier(0);
    // (3) dump S_n^T -> privA (wave-private) ; export S_n coalesced (d4-packed)
#pragma unroll
    for (int dt = 0; dt < 8; dt++) {
      const int slot = dt * 2 + (g >> 1);
      const ushort4 pv = pack4(acc2[dt][0], acc2[dt][1], acc2[dt][2], acc2[dt][3]);
      *(ushort4*)&privA[fr * 128 + ((slot ^ fsw) << 3) + (g & 1) * 4] = pv;
      *(ushort4*)(STb + (size_t)blk * 16384 + (dt * 4 + g) * 512 + (c0 + fr) * 4) = pv;
    }
    // (4) MFMA1: v_new = u + (-w) @ S  (A from shared staged w, B from privA)
    f32x4 acc1[4];
#pragma unroll
    for (int lt = 0; lt < 4; lt++) {
      f32x4 t;
      t[0] = bf2f(ur4[lt].x); t[1] = bf2f(ur4[lt].y);
      t[2] = bf2f(ur4[lt].z); t[3] = bf2f(ur4[lt].w);
      acc1[lt] = t;
    }
#pragma unroll
    for (int ks = 0; ks < 4; ks++) {
      const int kb = ks * 4 + g;
      const bf16x8 b = *(const bf16x8*)&privA[fr * 128 + ((kb ^ fsw) << 3)];
#pragma unroll
      for (int lt = 0; lt < 4; lt++) {
        const bf16x8 a = *(const bf16x8*)&wl[(lt * 16 + fr) * 128 + ((kb ^ fsw) << 3)];
        acc1[lt] = __builtin_amdgcn_mfma_f32_16x16x32_bf16(a, b, acc1[lt], 0, 0, 0);
      }
    }
    // (5) v_new^T -> privB ; export v_new^T coalesced (l4-packed)
#pragma unroll
    for (int lt = 0; lt < 4; lt++) {
      const int slot = lt * 2 + (g >> 1);
      const ushort4 pv = pack4(acc1[lt][0], acc1[lt][1], acc1[lt][2], acc1[lt][3]);
      *(ushort4*)&privB[fr * 64 + ((slot ^ fsw) << 3) + (g & 1) * 4] = pv;
      *(ushort4*)(vtb + (size_t)blk * 8192 + (lt * 4 + g) * 512 + (c0 + fr) * 4) = pv;
    }
    // (6) MFMA2: S = adec*S + kdec^T @ v_new
#pragma unroll
    for (int dt = 0; dt < 8; dt++) {
      acc2[dt][0] *= ad; acc2[dt][1] *= ad; acc2[dt][2] *= ad; acc2[dt][3] *= ad;
    }
#pragma unroll
    for (int ks = 0; ks < 2; ks++) {
      const int kb = ks * 4 + g;
      const bf16x8 b = *(const bf16x8*)&privB[fr * 64 + ((kb ^ fsw) << 3)];
#pragma unroll
      for (int dt = 0; dt < 8; dt++) {
        const bf16x8 a = *(const bf16x8*)&kl[(dt * 16 + fr) * 64 + ((kb ^ fsw) << 3)];
        acc2[dt] = __builtin_amdgcn_mfma_f32_16x16x32_bf16(a, b, acc2[dt], 0, 0, 0);
      }
    }
    // (7) roll prefetched operands
#pragma unroll
    for (int lt = 0; lt < 4; lt++) ur4[lt] = ur4n[lt];
    ad = adn;
    // (8) publish staging: counted vmcnt (youngest 17 = 4 u + 1 adec + 12 export stores)
    if (n + 1 < 64) {
      asm volatile("s_waitcnt lgkmcnt(0)" ::: "memory");
      __builtin_amdgcn_sched_barrier(0);
      asm volatile("s_waitcnt vmcnt(17)" ::: "memory");
      __builtin_amdgcn_sched_barrier(0);
      __builtin_amdgcn_s_barrier();
      __builtin_amdgcn_sched_barrier(0);
    }
  }
}

// ---------------- MFMA o-compute + fused gated RMSNorm (reads d4/l4-packed ST/vt, bf16 attn) --
__global__ __launch_bounds__(256) void ocomp_kernel(const unsigned short* __restrict__ qe,
                                                    const unsigned short* __restrict__ STbuf,
                                                    const unsigned short* __restrict__ vtbuf,
                                                    const unsigned short* __restrict__ attnb,
                                                    const unsigned short* __restrict__ zb,
                                                    const float* __restrict__ onw,
                                                    unsigned short* __restrict__ ob) {
  __shared__ __align__(16) unsigned short STl[128 * 128];  // [c][d]
  __shared__ __align__(16) unsigned short vtl[128 * 64];   // [c][l]
  __shared__ __align__(16) unsigned short ql[64 * 128];    // [i][d]
  __shared__ __align__(16) unsigned short al[64 * 64];     // [i][l]
  const int blk = blockIdx.x;
  const int h = blk >> 6;
  const int n = blk & 63;
  const int t0 = n * 64;
  const int tid = threadIdx.x;
  // ST: d4-packed -> [c][d] swizzled LDS. uint4 o covers (dq = o>>6, cols 2w,2w+1, w = o&63)
#pragma unroll
  for (int q = 0; q < 8; q++) {
    const int o = tid + q * 256;
    const int dq = o >> 6, w = o & 63;
    const uint4 v = *(const uint4*)(STbuf + (size_t)blk * 16384 + (size_t)o * 8);
    const int cA = 2 * w, cB = 2 * w + 1;
    uint2 h0; h0.x = v.x; h0.y = v.y;
    uint2 h1; h1.x = v.z; h1.y = v.w;
    *(uint2*)&STl[cA * 128 + (((dq >> 1) ^ (cA & 7)) << 3) + (dq & 1) * 4] = h0;
    *(uint2*)&STl[cB * 128 + (((dq >> 1) ^ (cB & 7)) << 3) + (dq & 1) * 4] = h1;
  }
  // vt: l4-packed -> [c][l] swizzled LDS
#pragma unroll
  for (int q = 0; q < 4; q++) {
    const int o = tid + q * 256;
    const int lq = o >> 6, w = o & 63;
    const uint4 v = *(const uint4*)(vtbuf + (size_t)blk * 8192 + (size_t)o * 8);
    const int cA = 2 * w, cB = 2 * w + 1;
    uint2 h0; h0.x = v.x; h0.y = v.y;
    uint2 h1; h1.x = v.z; h1.y = v.w;
    *(uint2*)&vtl[cA * 64 + (((lq >> 1) ^ (cA & 7)) << 3) + (lq & 1) * 4] = h0;
    *(uint2*)&vtl[cB * 64 + (((lq >> 1) ^ (cB & 7)) << 3) + (lq & 1) * 4] = h1;
  }
#pragma unroll
  for (int q = 0; q < 4; q++) {
    const int idx = tid + q * 256;
    const int i = idx >> 4, dg = idx & 15;
    *(uint4*)&ql[i * 128 + ((dg ^ (i & 7)) << 3)] =
        *(const uint4*)(qe + (size_t)(t0 + i) * 2048 + h * 128 + dg * 8);
  }
  // attn: bf16 [i][l] -> swizzled LDS (8-elem slots)
#pragma unroll
  for (int q = 0; q < 2; q++) {
    const int idx = tid + q * 256;
    const int i = idx >> 3, lsl = idx & 7;
    *(uint4*)&al[i * 64 + ((lsl ^ (i & 7)) << 3)] =
        *(const uint4*)(attnb + (size_t)blk * 4096 + i * 64 + lsl * 8);
  }
  __syncthreads();
  const int ln = tid & 63;
  const int wv = tid >> 6;
  const int fr = ln & 15;
  const int g = ln >> 4;
  const int i0 = wv * 16;
  f32x4 acc[8];
  const f32x4 zero = {0.f, 0.f, 0.f, 0.f};
#pragma unroll
  for (int nt = 0; nt < 8; nt++) acc[nt] = zero;
#pragma unroll
  for (int ks = 0; ks < 4; ks++) {
    const int kb = ks * 4 + g;
    const int ar = i0 + fr;
    const bf16x8 a = *(const bf16x8*)&ql[ar * 128 + ((kb ^ (ar & 7)) << 3)];
#pragma unroll
    for (int nt = 0; nt < 8; nt++) {
      const int c = nt * 16 + fr;
      const bf16x8 b = *(const bf16x8*)&STl[c * 128 + ((kb ^ (c & 7)) << 3)];
      acc[nt] = __builtin_amdgcn_mfma_f32_16x16x32_bf16(a, b, acc[nt], 0, 0, 0);
    }
  }
#pragma unroll
  for (int ks = 0; ks < 2; ks++) {
    const int kb = ks * 4 + g;
    const int ar = i0 + fr;
    const bf16x8 a = *(const bf16x8*)&al[ar * 64 + ((kb ^ (ar & 7)) << 3)];
#pragma unroll
    for (int nt = 0; nt < 8; nt++) {
      const int c = nt * 16 + fr;
      const bf16x8 b = *(const bf16x8*)&vtl[c * 64 + ((kb ^ (c & 7)) << 3)];
      acc[nt] = __builtin_amdgcn_mfma_f32_16x16x32_bf16(a, b, acc[nt], 0, 0, 0);
    }
  }
  float s0 = 0.f, s1 = 0.f, s2 = 0.f, s3 = 0.f;
#pragma unroll
  for (int nt = 0; nt < 8; nt++) {
    s0 += acc[nt][0] * acc[nt][0];
    s1 += acc[nt][1] * acc[nt][1];
    s2 += acc[nt][2] * acc[nt][2];
    s3 += acc[nt][3] * acc[nt][3];
  }
#pragma unroll
  for (int m = 1; m < 16; m <<= 1) {
    s0 += __shfl_xor(s0, m);
    s1 += __shfl_xor(s1, m);
    s2 += __shfl_xor(s2, m);
    s3 += __shfl_xor(s3, m);
  }
  float rn[4];
  rn[0] = rsqrtf(s0 * (1.0f / 128.0f) + 1e-5f);
  rn[1] = rsqrtf(s1 * (1.0f / 128.0f) + 1e-5f);
  rn[2] = rsqrtf(s2 * (1.0f / 128.0f) + 1e-5f);
  rn[3] = rsqrtf(s3 * (1.0f / 128.0f) + 1e-5f);
#pragma unroll
  for (int nt = 0; nt < 8; nt++) {
    const int c = nt * 16 + fr;
    const float wn = onw[c];
#pragma unroll
    for (int r = 0; r < 4; r++) {
      const size_t off = (size_t)(t0 + i0 + g * 4 + r) * 2048 + h * 128 + c;
      const float zz = siluf(bf2f(zb[off]));
      ob[off] = f2bf(acc[nt][r] * rn[r] * wn * zz);
    }
  }
}

extern "C" void kernel_launch(void* const* d_in, const int* in_sizes, int n_in,
                              void* d_out, int out_size, void* d_ws, size_t ws_size,
                              hipStream_t stream) {
  (void)in_sizes; (void)n_in; (void)out_size;
  const float* x        = (const float*)d_in[0];
  const float* mask     = (const float*)d_in[1];
  const float* ln1_w    = (const float*)d_in[2];
  const float* qkvz_w   = (const float*)d_in[3];
  const float* ba_w     = (const float*)d_in[4];
  const float* conv_w   = (const float*)d_in[5];
  const float* A_log    = (const float*)d_in[6];
  const float* dt_bias  = (const float*)d_in[7];
  const float* o_norm_w = (const float*)d_in[8];
  const float* out_w    = (const float*)d_in[9];
  const float* ln2_w    = (const float*)d_in[10];
  const float* gate_w   = (const float*)d_in[11];
  const float* up_w     = (const float*)d_in[12];
  const float* down_w   = (const float*)d_in[13];
  float* out = (float*)d_out;

  const size_t NEED_BYTES = (size_t)75825152 * 4;
  if (ws_size < NEED_BYTES) return;

  float* ws = (float*)d_ws;
  unsigned short* mixed_bf = (unsigned short*)ws;            // 4096 x 6144 bf16 (50 MB)
  unsigned short* Wgu = (unsigned short*)ws;                 // [16384][2048] bf16, 16-col interleaved
  unsigned short* Wd = (unsigned short*)(ws + 16777216);
  unsigned short* qkvz_bf = (unsigned short*)(ws + 25165824);
  unsigned short* u_bf = (unsigned short*)(ws + 25165824);   // 1024 x 8192 bf16 (16 MB)
  unsigned short* wbf = (unsigned short*)(ws + 33554432);
  unsigned short* kdT = (unsigned short*)(ws + 37748736);
  unsigned short* comb_bf = (unsigned short*)(ws + 25165824);
  unsigned short* z_bf = (unsigned short*)(ws + 41943040);
  float* a_buf = ws + 46137344;
  unsigned short* vt_buf = (unsigned short*)(ws + 46137344);
  float* t_buf = ws + 50331648;
  unsigned short* qe_bf = (unsigned short*)(ws + 50331648);  // after pre_uw, t_buf is dead
  unsigned short* h_bf  = (unsigned short*)(ws + 54525952);
  unsigned short* ob    = (unsigned short*)(ws + 54525952);
  unsigned short* h2_bf = (unsigned short*)(ws + 54525952);
  unsigned short* attn_bf = (unsigned short*)(ws + 58720256); // 1024 x 4096 bf16 (8 MB)
  unsigned short* Wq = (unsigned short*)(ws + 62914560);
  unsigned short* ST_buf = (unsigned short*)(ws + 62914560);
  unsigned short* Wo = (unsigned short*)(ws + 71303168);
  float* ba_buf   = ws + 73400320;
  float* beta_buf = ws + 73531392;
  float* g_buf    = ws + 73596928;
  float* gcs_buf  = ws + 73662464;
  float* edk_buf  = ws + 73728000;
  float* egq_buf  = ws + 73793536;
  float* adec_buf = ws + 73859072;

  rmsnorm_kernel<2><<<4096, 256, 0, stream>>>(x, ln1_w, nullptr, h_bf);
  f2b_kernel<<<8192, 256, 0, stream>>>(qkvz_w, Wq);
  // qkvz GEMM; z columns (>= 6144) written ONLY into z_bf
  gemm8p_kernel<0><<<512, 512, 0, stream>>>(h_bf, Wq, nullptr, qkvz_bf, z_bf, 4096, 8192, 2048);
  ba_gemm_kernel<<<4096, 256, 0, stream>>>(h_bf, ba_w, ba_buf);
  conv_norm_kernel<<<4096, 256, 0, stream>>>(qkvz_bf, conv_w, mask, mixed_bf);
  beta_g_kernel<<<256, 256, 0, stream>>>(ba_buf, A_log, dt_bias, mask, beta_buf, g_buf);
  gcs_kernel<<<4, 256, 0, stream>>>(g_buf, gcs_buf, edk_buf, egq_buf, adec_buf);
  pre_attn_kernel<<<1024, 256, 0, stream>>>(mixed_bf, gcs_buf, beta_buf, a_buf, attn_bf);
  pre_solve_kernel<<<1024, 256, 0, stream>>>(a_buf, beta_buf, t_buf);
  pre_uw_kernel<<<1024, 256, 0, stream>>>(mixed_bf, t_buf, gcs_buf, u_bf, wbf);
  ktrans_kernel<<<1024, 256, 0, stream>>>(mixed_bf, edk_buf, egq_buf, kdT, qe_bf);
  // column-decomposed MFMA scan (16 blocks, 8 waves) + fused weight f2b (13312 blocks)
  scan_kernel<<<13328, 512, 0, stream>>>(wbf, kdT, u_bf, adec_buf, ST_buf, vt_buf,
                                         gate_w, up_w, down_w, out_w,
                                         Wgu, Wd, Wo);
  ocomp_kernel<<<1024, 256, 0, stream>>>(qe_bf, ST_buf, vt_buf, attn_bf,
                                         z_bf, o_norm_w, ob);
  // Wo projection with fused residual: out = x + ob @ Wo^T
  gemm256_kernel<4, 128, 128><<<512, 512, 0, stream>>>(ob, Wo, out, x, 4096, 2048, 2048);
  rmsnorm_kernel<2><<<4096, 256, 0, stream>>>(out, ln2_w, nullptr, h2_bf);
  // fused gate+up: N=16384 interleaved weights, epilogue writes silu(gate)*up (4096x8192 bf16)
  gemm8p_kernel<3><<<1024, 512, 0, stream>>>(h2_bf, Wgu, nullptr, comb_bf, nullptr, 4096, 16384, 2048);
  gemm256_kernel<1, 128, 128><<<512, 512, 0, stream>>>(comb_bf, Wd, out, nullptr, 4096, 2048, 8192);
}